// Round 6
// baseline (8010.104 us; speedup 1.0000x reference)
//
#include <hip/hip_runtime.h>
#include <hip/hip_bf16.h>
#include <math.h>

#define D_DIM 1024
#define B_ROWS 4096
#define M_ROWS 32768
#define TOPK 8
#define TOPC 16
#define QROWS 1024                       // q-rows per sims quarter

#define BM 128
#define BN 64
#define BK 32

typedef __attribute__((ext_vector_type(8))) short bf16x8;
typedef __attribute__((ext_vector_type(4))) float f32x4;

__device__ __forceinline__ unsigned short f32_to_bf16(float f) {
  unsigned int u = __float_as_uint(f);
  unsigned int r = (u + 0x7FFFu + ((u >> 16) & 1u)) >> 16;
  return (unsigned short)r;
}
__device__ __forceinline__ float bf16_to_f32(unsigned short h) {
  return __uint_as_float(((unsigned int)h) << 16);
}
__device__ __forceinline__ void async_copy16(void* lds, const void* g) {
  __builtin_amdgcn_global_load_lds(
      (const __attribute__((address_space(1))) unsigned int*)g,
      (__attribute__((address_space(3))) unsigned int*)lds, 16, 0, 0);
}

// ---------------------------------------------------------------------------
// out[r][n] = sum_d X[r][d]*W[n][d] + bias[n], fp64 accumulation over fp32
// inputs, rounded once to fp32 on store (selection chain — do not touch).
// Also emits bf16 copy for the MFMA candidate pass.
// ---------------------------------------------------------------------------
__global__ __launch_bounds__(256) void gemm_nt_bias_f64(
    const float* __restrict__ X, const float* __restrict__ W,
    const float* __restrict__ bias, float* __restrict__ out,
    unsigned short* __restrict__ outbf)
{
  __shared__ float sA[BK][BM + 4];
  __shared__ float sB[BK][BN + 4];
  const int tid = threadIdx.x;
  const int tx = tid & 15, ty = tid >> 4;
  const int row0 = blockIdx.x * BM;
  const int col0 = blockIdx.y * BN;
  const int lr = tid >> 3;         // 0..31
  const int lc = (tid & 7) << 2;   // 0,4,...,28

  double acc[2][4][4];
#pragma unroll
  for (int g = 0; g < 2; ++g)
#pragma unroll
    for (int i = 0; i < 4; ++i)
#pragma unroll
      for (int j = 0; j < 4; ++j) acc[g][i][j] = 0.0;

  for (int k0 = 0; k0 < D_DIM; k0 += BK) {
#pragma unroll
    for (int rr = 0; rr < 4; ++rr) {
      const float4 v = *(const float4*)(X + (size_t)(row0 + lr + 32 * rr) * D_DIM + k0 + lc);
      sA[lc + 0][lr + 32 * rr] = v.x;
      sA[lc + 1][lr + 32 * rr] = v.y;
      sA[lc + 2][lr + 32 * rr] = v.z;
      sA[lc + 3][lr + 32 * rr] = v.w;
    }
#pragma unroll
    for (int rr = 0; rr < 2; ++rr) {
      const float4 v = *(const float4*)(W + (size_t)(col0 + lr + 32 * rr) * D_DIM + k0 + lc);
      sB[lc + 0][lr + 32 * rr] = v.x;
      sB[lc + 1][lr + 32 * rr] = v.y;
      sB[lc + 2][lr + 32 * rr] = v.z;
      sB[lc + 3][lr + 32 * rr] = v.w;
    }
    __syncthreads();
#pragma unroll
    for (int kk = 0; kk < BK; ++kk) {
      const float4 A0 = *(const float4*)&sA[kk][ty * 4];
      const float4 A1 = *(const float4*)&sA[kk][64 + ty * 4];
      const float4 Bv = *(const float4*)&sB[kk][tx * 4];
      const double a0[4] = {A0.x, A0.y, A0.z, A0.w};
      const double a1[4] = {A1.x, A1.y, A1.z, A1.w};
      const double bb[4] = {Bv.x, Bv.y, Bv.z, Bv.w};
#pragma unroll
      for (int i = 0; i < 4; ++i)
#pragma unroll
        for (int j = 0; j < 4; ++j) {
          acc[0][i][j] = fma(a0[i], bb[j], acc[0][i][j]);
          acc[1][i][j] = fma(a1[i], bb[j], acc[1][i][j]);
        }
    }
    __syncthreads();
  }
  const float4 bv4 = *(const float4*)(bias + col0 + tx * 4);
  const double bb[4] = {bv4.x, bv4.y, bv4.z, bv4.w};
#pragma unroll
  for (int g = 0; g < 2; ++g)
#pragma unroll
    for (int i = 0; i < 4; ++i) {
      float4 o;
      o.x = (float)(acc[g][i][0] + bb[0]);
      o.y = (float)(acc[g][i][1] + bb[1]);
      o.z = (float)(acc[g][i][2] + bb[2]);
      o.w = (float)(acc[g][i][3] + bb[3]);
      const size_t base = (size_t)(row0 + g * 64 + ty * 4 + i) * D_DIM + col0 + tx * 4;
      *(float4*)(out + base) = o;
      ushort4 ob;
      ob.x = f32_to_bf16(o.x);
      ob.y = f32_to_bf16(o.y);
      ob.z = f32_to_bf16(o.z);
      ob.w = f32_to_bf16(o.w);
      *(ushort4*)(outbf + base) = ob;
    }
}

// ---------------------------------------------------------------------------
// fp32 version for V (values only; 2% output threshold).
// ---------------------------------------------------------------------------
__global__ __launch_bounds__(256) void gemm_nt_bias_f32(
    const float* __restrict__ X, const float* __restrict__ W,
    const float* __restrict__ bias, float* __restrict__ out)
{
  __shared__ float sA[BK][BM + 4];
  __shared__ float sB[BK][BN + 4];
  const int tid = threadIdx.x;
  const int tx = tid & 15, ty = tid >> 4;
  const int row0 = blockIdx.x * BM;
  const int col0 = blockIdx.y * BN;
  const int lr = tid >> 3;
  const int lc = (tid & 7) << 2;

  float acc[2][4][4];
#pragma unroll
  for (int g = 0; g < 2; ++g)
#pragma unroll
    for (int i = 0; i < 4; ++i)
#pragma unroll
      for (int j = 0; j < 4; ++j) acc[g][i][j] = 0.f;

  for (int k0 = 0; k0 < D_DIM; k0 += BK) {
#pragma unroll
    for (int rr = 0; rr < 4; ++rr) {
      const float4 v = *(const float4*)(X + (size_t)(row0 + lr + 32 * rr) * D_DIM + k0 + lc);
      sA[lc + 0][lr + 32 * rr] = v.x;
      sA[lc + 1][lr + 32 * rr] = v.y;
      sA[lc + 2][lr + 32 * rr] = v.z;
      sA[lc + 3][lr + 32 * rr] = v.w;
    }
#pragma unroll
    for (int rr = 0; rr < 2; ++rr) {
      const float4 v = *(const float4*)(W + (size_t)(col0 + lr + 32 * rr) * D_DIM + k0 + lc);
      sB[lc + 0][lr + 32 * rr] = v.x;
      sB[lc + 1][lr + 32 * rr] = v.y;
      sB[lc + 2][lr + 32 * rr] = v.z;
      sB[lc + 3][lr + 32 * rr] = v.w;
    }
    __syncthreads();
#pragma unroll
    for (int kk = 0; kk < BK; ++kk) {
      const float4 A0 = *(const float4*)&sA[kk][ty * 4];
      const float4 A1 = *(const float4*)&sA[kk][64 + ty * 4];
      const float4 Bv = *(const float4*)&sB[kk][tx * 4];
      const float a0[4] = {A0.x, A0.y, A0.z, A0.w};
      const float a1[4] = {A1.x, A1.y, A1.z, A1.w};
      const float bb[4] = {Bv.x, Bv.y, Bv.z, Bv.w};
#pragma unroll
      for (int i = 0; i < 4; ++i)
#pragma unroll
        for (int j = 0; j < 4; ++j) {
          acc[0][i][j] = fmaf(a0[i], bb[j], acc[0][i][j]);
          acc[1][i][j] = fmaf(a1[i], bb[j], acc[1][i][j]);
        }
    }
    __syncthreads();
  }
  const float4 bv4 = *(const float4*)(bias + col0 + tx * 4);
  const float bb[4] = {bv4.x, bv4.y, bv4.z, bv4.w};
#pragma unroll
  for (int g = 0; g < 2; ++g)
#pragma unroll
    for (int i = 0; i < 4; ++i) {
      float4 o;
      o.x = acc[g][i][0] + bb[0];
      o.y = acc[g][i][1] + bb[1];
      o.z = acc[g][i][2] + bb[2];
      o.w = acc[g][i][3] + bb[3];
      *(float4*)(out + (size_t)(row0 + g * 64 + ty * 4 + i) * D_DIM + col0 + tx * 4) = o;
    }
}

// ---------------------------------------------------------------------------
// Pure m97-shape bf16 GEMM (NT), bf16 C store — UNCHANGED from round 5
// (textually the round-4-proven GEMM core; under test by elimination).
// ---------------------------------------------------------------------------
__global__ __launch_bounds__(256) void sims_gemm_bf16(
    const unsigned short* __restrict__ A, const unsigned short* __restrict__ B,
    unsigned short* __restrict__ C)
{
  __shared__ unsigned short sA[128 * 32];   // 8 KB
  __shared__ unsigned short sB[128 * 32];   // 8 KB

  const int tid = threadIdx.x;
  const int lane = tid & 63;
  const int wave = tid >> 6;
  const int wr = wave >> 1, wc = wave & 1;
  const int row0 = blockIdx.x * 128;
  const int col0 = blockIdx.y * 128;

  const int st_r = lane >> 2;          // row within 16-row segment
  const int st_cb = (lane & 3) * 16;   // byte offset within 64B row

  f32x4 acc[4][4];
#pragma unroll
  for (int m = 0; m < 4; ++m)
#pragma unroll
    for (int n = 0; n < 4; ++n) acc[m][n] = (f32x4){0.f, 0.f, 0.f, 0.f};

  for (int k0 = 0; k0 < D_DIM; k0 += 32) {
#pragma unroll
    for (int i = 0; i < 2; ++i) {
      const int seg = wave * 2 + i;
      const int rr = seg * 16 + st_r;
      async_copy16((char*)sA + seg * 1024,
                   (const char*)(A + (size_t)(row0 + rr) * D_DIM + k0) + st_cb);
      async_copy16((char*)sB + seg * 1024,
                   (const char*)(B + (size_t)(col0 + rr) * D_DIM + k0) + st_cb);
    }
    __syncthreads();
    bf16x8 af[4], bfr[4];
#pragma unroll
    for (int m = 0; m < 4; ++m)
      af[m] = *(const bf16x8*)(sA + (wr * 64 + m * 16 + (lane & 15)) * 32 + (lane >> 4) * 8);
#pragma unroll
    for (int n = 0; n < 4; ++n)
      bfr[n] = *(const bf16x8*)(sB + (wc * 64 + n * 16 + (lane & 15)) * 32 + (lane >> 4) * 8);
#pragma unroll
    for (int m = 0; m < 4; ++m)
#pragma unroll
      for (int n = 0; n < 4; ++n)
        acc[m][n] = __builtin_amdgcn_mfma_f32_16x16x32_bf16(af[m], bfr[n], acc[m][n], 0, 0, 0);
    __syncthreads();
  }

  // C/D layout (m89): col = lane&15, row = (lane>>4)*4 + reg.
#pragma unroll
  for (int m = 0; m < 4; ++m)
#pragma unroll
    for (int n = 0; n < 4; ++n)
#pragma unroll
      for (int r = 0; r < 4; ++r) {
        const int row = row0 + wr * 64 + m * 16 + (lane >> 4) * 4 + r;
        const int col = col0 + wc * 64 + n * 16 + (lane & 15);
        C[(size_t)row * M_ROWS + col] = f32_to_bf16(acc[m][n][r]);
      }
}

// ---------------------------------------------------------------------------
// REPLACEMENT scan (isolation round): 1 wave per row. Thread t scans its
// contiguous 512-col segment (scalar uint loads, ascending, strict > insert
// => lower index wins ties — the round-2/3/4-proven pattern). Thread 0 then
// sequentially re-inserts all 64x16 LDS entries in thread-ascending order —
// textually the proven merge_cand idiom => global (v desc, idx asc) top-16.
// ---------------------------------------------------------------------------
__global__ __launch_bounds__(64) void row_topc_wave(
    const unsigned short* __restrict__ simsbf, int row_base,
    int* __restrict__ cand)
{
  const int r = blockIdx.x;
  const int t = threadIdx.x;            // 0..63
  const unsigned short* rowp = simsbf + (size_t)r * M_ROWS;

  float tv[TOPC];
  int ti_[TOPC];
#pragma unroll
  for (int p = 0; p < TOPC; ++p) { tv[p] = -INFINITY; ti_[p] = 0; }

  const int base = t * 512;
  for (int c = 0; c < 256; ++c) {
    const unsigned int u = *(const unsigned int*)(rowp + base + c * 2);
    const float v0 = bf16_to_f32((unsigned short)(u & 0xFFFFu));
    const float v1 = bf16_to_f32((unsigned short)(u >> 16));
    if (v0 > tv[TOPC - 1]) {
      float cv = v0; int ci = base + c * 2;
#pragma unroll
      for (int p = 0; p < TOPC; ++p) {
        if (cv > tv[p]) {
          const float t0 = tv[p]; tv[p] = cv; cv = t0;
          const int t1 = ti_[p]; ti_[p] = ci; ci = t1;
        }
      }
    }
    if (v1 > tv[TOPC - 1]) {
      float cv = v1; int ci = base + c * 2 + 1;
#pragma unroll
      for (int p = 0; p < TOPC; ++p) {
        if (cv > tv[p]) {
          const float t0 = tv[p]; tv[p] = cv; cv = t0;
          const int t1 = ti_[p]; ti_[p] = ci; ci = t1;
        }
      }
    }
  }

  __shared__ float lv[64][TOPC];
  __shared__ int li[64][TOPC];
#pragma unroll
  for (int p = 0; p < TOPC; ++p) { lv[t][p] = tv[p]; li[t][p] = ti_[p]; }
  __syncthreads();

  if (t == 0) {
    float mv[TOPC];
    int mi[TOPC];
#pragma unroll
    for (int p = 0; p < TOPC; ++p) { mv[p] = -INFINITY; mi[p] = 0; }
    for (int s = 0; s < 64; ++s) {
      for (int p0 = 0; p0 < TOPC; ++p0) {
        const float v = lv[s][p0];
        if (v > mv[TOPC - 1]) {
          float cv = v; int ci = li[s][p0];
#pragma unroll
          for (int p = 0; p < TOPC; ++p) {
            if (cv > mv[p]) {
              const float t0 = mv[p]; mv[p] = cv; cv = t0;
              const int t1 = mi[p]; mi[p] = ci; ci = t1;
            }
          }
        }
      }
    }
#pragma unroll
    for (int p = 0; p < TOPC; ++p)
      cand[(size_t)(row_base + r) * TOPC + p] = mi[p];
  }
}

// ---------------------------------------------------------------------------
// fp64 rescore of the 16 candidates per row + stable top-8 selection
// (value desc, index asc on exact ties == np/lax top_k semantics).
// UNCHANGED from passing rounds.
// ---------------------------------------------------------------------------
__global__ __launch_bounds__(256) void rescore_topk(
    const float* __restrict__ Q, const float* __restrict__ Km,
    const int* __restrict__ cand, int* __restrict__ topi)
{
  const int b = blockIdx.x;
  const int tid = threadIdx.x;
  const int wave = tid >> 6;
  const int lane = tid & 63;

  __shared__ double sval[TOPC];
  __shared__ int sidx[TOPC];

  const float* qrow = Q + (size_t)b * D_DIM + lane * 16;
  float4 qv[4];
#pragma unroll
  for (int i = 0; i < 4; ++i) qv[i] = *(const float4*)(qrow + i * 4);

  for (int c = wave; c < TOPC; c += 4) {
    const int ci = cand[(size_t)b * TOPC + c];
    const float* krow = Km + (size_t)ci * D_DIM + lane * 16;
    double acc = 0.0;
#pragma unroll
    for (int i = 0; i < 4; ++i) {
      const float4 kv = *(const float4*)(krow + i * 4);
      acc = fma((double)qv[i].x, (double)kv.x, acc);
      acc = fma((double)qv[i].y, (double)kv.y, acc);
      acc = fma((double)qv[i].z, (double)kv.z, acc);
      acc = fma((double)qv[i].w, (double)kv.w, acc);
    }
#pragma unroll
    for (int off = 32; off > 0; off >>= 1) acc += __shfl_down(acc, off);
    if (lane == 0) { sval[c] = acc; sidx[c] = ci; }
  }
  __syncthreads();

  if (tid == 0) {
    bool used[TOPC];
#pragma unroll
    for (int p = 0; p < TOPC; ++p) used[p] = false;
#pragma unroll
    for (int p = 0; p < TOPK; ++p) {
      int best = -1;
      double bv = 0.0;
      int bi = 0;
      for (int c = 0; c < TOPC; ++c) {
        if (used[c]) continue;
        const double v = sval[c];
        const int ix = sidx[c];
        if (best < 0 || v > bv || (v == bv && ix < bi)) { best = c; bv = v; bi = ix; }
      }
      used[best] = true;
      topi[(size_t)b * TOPK + p] = bi;
    }
  }
}

// ---------------------------------------------------------------------------
// Gather selected V rows + LayerNorm (biased var, eps=1e-5, affine).
// ---------------------------------------------------------------------------
__global__ __launch_bounds__(256) void gather_ln(
    const float* __restrict__ V, const int* __restrict__ topi,
    const float* __restrict__ gamma, const float* __restrict__ beta,
    float* __restrict__ out)
{
  const int row = blockIdx.x;  // b*8 + rank
  const int tid = threadIdx.x;
  const int idx = topi[row];
  const float* src = V + (size_t)idx * D_DIM;
  const float4 v = *(const float4*)(src + tid * 4);
  float s = v.x + v.y + v.z + v.w;
  float s2 = v.x * v.x + v.y * v.y + v.z * v.z + v.w * v.w;
#pragma unroll
  for (int off = 32; off > 0; off >>= 1) {
    s += __shfl_down(s, off);
    s2 += __shfl_down(s2, off);
  }
  __shared__ float red[8];
  __shared__ float stats[2];
  const int wid = tid >> 6;
  if ((tid & 63) == 0) { red[wid] = s; red[4 + wid] = s2; }
  __syncthreads();
  if (tid == 0) {
    const float S = red[0] + red[1] + red[2] + red[3];
    const float S2 = red[4] + red[5] + red[6] + red[7];
    const float mu = S * (1.0f / D_DIM);
    const float var = S2 * (1.0f / D_DIM) - mu * mu;
    stats[0] = mu;
    stats[1] = rsqrtf(var + 1e-5f);
  }
  __syncthreads();
  const float mu = stats[0], rstd = stats[1];
  const float4 g4 = *(const float4*)(gamma + tid * 4);
  const float4 b4 = *(const float4*)(beta + tid * 4);
  float4 o;
  o.x = (v.x - mu) * rstd * g4.x + b4.x;
  o.y = (v.y - mu) * rstd * g4.y + b4.y;
  o.z = (v.z - mu) * rstd * g4.z + b4.z;
  o.w = (v.w - mu) * rstd * g4.w + b4.w;
  *(float4*)(out + (size_t)row * D_DIM + tid * 4) = o;
}

extern "C" void kernel_launch(void* const* d_in, const int* in_sizes, int n_in,
                              void* d_out, int out_size, void* d_ws, size_t ws_size,
                              hipStream_t stream)
{
  const float* query = (const float*)d_in[0];
  const float* mem   = (const float*)d_in[1];
  const float* Wq    = (const float*)d_in[2];
  const float* bq    = (const float*)d_in[3];
  const float* Wk    = (const float*)d_in[4];
  const float* bk    = (const float*)d_in[5];
  const float* Wv    = (const float*)d_in[6];
  const float* bv    = (const float*)d_in[7];
  const float* gamma = (const float*)d_in[8];
  const float* beta  = (const float*)d_in[9];
  float* out = (float*)d_out;

  char* ws = (char*)d_ws;
  float* q = (float*)ws;       ws += (size_t)B_ROWS * D_DIM * sizeof(float);
  float* K = (float*)ws;       ws += (size_t)M_ROWS * D_DIM * sizeof(float);
  float* V = (float*)ws;       ws += (size_t)M_ROWS * D_DIM * sizeof(float);
  unsigned short* qbf = (unsigned short*)ws;
  ws += (size_t)B_ROWS * D_DIM * sizeof(unsigned short);
  int* cand = (int*)ws;        ws += (size_t)B_ROWS * TOPC * sizeof(int);
  int* topi = (int*)ws;

  // Parked in the not-yet-written V region (exact fit: 67.1 MB + 67.1 MB):
  unsigned short* simsbf = (unsigned short*)V;                       // [QROWS][M_ROWS]
  unsigned short* Kbf = (unsigned short*)((char*)V + (size_t)QROWS * M_ROWS * sizeof(unsigned short));

  gemm_nt_bias_f64<<<dim3(B_ROWS / BM, D_DIM / BN), 256, 0, stream>>>(query, Wq, bq, q, qbf);
  gemm_nt_bias_f64<<<dim3(M_ROWS / BM, D_DIM / BN), 256, 0, stream>>>(mem, Wk, bk, K, Kbf);

  for (int qt = 0; qt < B_ROWS / QROWS; ++qt) {
    sims_gemm_bf16<<<dim3(QROWS / 128, M_ROWS / 128), 256, 0, stream>>>(
        qbf + (size_t)qt * QROWS * D_DIM, Kbf, simsbf);
    row_topc_wave<<<dim3(QROWS), 64, 0, stream>>>(simsbf, qt * QROWS, cand);
  }

  rescore_topk<<<dim3(B_ROWS), 256, 0, stream>>>(q, K, cand, topi);
  // V-proj AFTER sims/scan: it overwrites simsbf/Kbf parked in V's region.
  gemm_nt_bias_f32<<<dim3(M_ROWS / BM, D_DIM / BN), 256, 0, stream>>>(mem, Wv, bv, V);
  gather_ln<<<dim3(B_ROWS * TOPK), 256, 0, stream>>>(V, topi, gamma, beta, out);
}

// Round 7
// 5215.153 us; speedup vs baseline: 1.5359x; 1.5359x over previous
//
#include <hip/hip_runtime.h>
#include <hip/hip_bf16.h>
#include <math.h>

#define D_DIM 1024
#define B_ROWS 4096
#define M_ROWS 32768
#define TOPK 8
#define TOPC 16
#define QROWS 1024                       // q-rows per sims quarter

#define BM 128
#define BN 64
#define BK 32

typedef __attribute__((ext_vector_type(8))) short bf16x8;
typedef __attribute__((ext_vector_type(4))) float f32x4;

__device__ __forceinline__ unsigned short f32_to_bf16(float f) {
  unsigned int u = __float_as_uint(f);
  unsigned int r = (u + 0x7FFFu + ((u >> 16) & 1u)) >> 16;
  return (unsigned short)r;
}
__device__ __forceinline__ float bf16_to_f32(unsigned short h) {
  return __uint_as_float(((unsigned int)h) << 16);
}
__device__ __forceinline__ void async_copy16(void* lds, const void* g) {
  __builtin_amdgcn_global_load_lds(
      (const __attribute__((address_space(1))) unsigned int*)g,
      (__attribute__((address_space(3))) unsigned int*)lds, 16, 0, 0);
}

// Ordered insert into a register top-16 list sorted by (value desc, index asc).
// Comparator-based => result independent of visitation order; exactly equals
// the sequential ascending-index scan's list (lax.top_k tie semantics).
__device__ __forceinline__ void ins16(float v, int idx,
                                      float* __restrict__ tv,
                                      int* __restrict__ ti) {
  if (v < tv[TOPC - 1]) return;
  if (v == tv[TOPC - 1] && idx > ti[TOPC - 1]) return;
  float cv = v;
  int ci = idx;
#pragma unroll
  for (int p = 0; p < TOPC; ++p) {
    if (cv > tv[p] || (cv == tv[p] && ci < ti[p])) {
      const float t0 = tv[p]; tv[p] = cv; cv = t0;
      const int t1 = ti[p]; ti[p] = ci; ci = t1;
    }
  }
}

// ---------------------------------------------------------------------------
// out[r][n] = sum_d X[r][d]*W[n][d] + bias[n], fp64 accumulation over fp32
// inputs, rounded once to fp32 on store (selection chain — do not touch).
// Also emits bf16 copy for the MFMA candidate pass.
// ---------------------------------------------------------------------------
__global__ __launch_bounds__(256) void gemm_nt_bias_f64(
    const float* __restrict__ X, const float* __restrict__ W,
    const float* __restrict__ bias, float* __restrict__ out,
    unsigned short* __restrict__ outbf)
{
  __shared__ float sA[BK][BM + 4];
  __shared__ float sB[BK][BN + 4];
  const int tid = threadIdx.x;
  const int tx = tid & 15, ty = tid >> 4;
  const int row0 = blockIdx.x * BM;
  const int col0 = blockIdx.y * BN;
  const int lr = tid >> 3;         // 0..31
  const int lc = (tid & 7) << 2;   // 0,4,...,28

  double acc[2][4][4];
#pragma unroll
  for (int g = 0; g < 2; ++g)
#pragma unroll
    for (int i = 0; i < 4; ++i)
#pragma unroll
      for (int j = 0; j < 4; ++j) acc[g][i][j] = 0.0;

  for (int k0 = 0; k0 < D_DIM; k0 += BK) {
#pragma unroll
    for (int rr = 0; rr < 4; ++rr) {
      const float4 v = *(const float4*)(X + (size_t)(row0 + lr + 32 * rr) * D_DIM + k0 + lc);
      sA[lc + 0][lr + 32 * rr] = v.x;
      sA[lc + 1][lr + 32 * rr] = v.y;
      sA[lc + 2][lr + 32 * rr] = v.z;
      sA[lc + 3][lr + 32 * rr] = v.w;
    }
#pragma unroll
    for (int rr = 0; rr < 2; ++rr) {
      const float4 v = *(const float4*)(W + (size_t)(col0 + lr + 32 * rr) * D_DIM + k0 + lc);
      sB[lc + 0][lr + 32 * rr] = v.x;
      sB[lc + 1][lr + 32 * rr] = v.y;
      sB[lc + 2][lr + 32 * rr] = v.z;
      sB[lc + 3][lr + 32 * rr] = v.w;
    }
    __syncthreads();
#pragma unroll
    for (int kk = 0; kk < BK; ++kk) {
      const float4 A0 = *(const float4*)&sA[kk][ty * 4];
      const float4 A1 = *(const float4*)&sA[kk][64 + ty * 4];
      const float4 Bv = *(const float4*)&sB[kk][tx * 4];
      const double a0[4] = {A0.x, A0.y, A0.z, A0.w};
      const double a1[4] = {A1.x, A1.y, A1.z, A1.w};
      const double bb[4] = {Bv.x, Bv.y, Bv.z, Bv.w};
#pragma unroll
      for (int i = 0; i < 4; ++i)
#pragma unroll
        for (int j = 0; j < 4; ++j) {
          acc[0][i][j] = fma(a0[i], bb[j], acc[0][i][j]);
          acc[1][i][j] = fma(a1[i], bb[j], acc[1][i][j]);
        }
    }
    __syncthreads();
  }
  const float4 bv4 = *(const float4*)(bias + col0 + tx * 4);
  const double bb[4] = {bv4.x, bv4.y, bv4.z, bv4.w};
#pragma unroll
  for (int g = 0; g < 2; ++g)
#pragma unroll
    for (int i = 0; i < 4; ++i) {
      float4 o;
      o.x = (float)(acc[g][i][0] + bb[0]);
      o.y = (float)(acc[g][i][1] + bb[1]);
      o.z = (float)(acc[g][i][2] + bb[2]);
      o.w = (float)(acc[g][i][3] + bb[3]);
      const size_t base = (size_t)(row0 + g * 64 + ty * 4 + i) * D_DIM + col0 + tx * 4;
      *(float4*)(out + base) = o;
      ushort4 ob;
      ob.x = f32_to_bf16(o.x);
      ob.y = f32_to_bf16(o.y);
      ob.z = f32_to_bf16(o.z);
      ob.w = f32_to_bf16(o.w);
      *(ushort4*)(outbf + base) = ob;
    }
}

// ---------------------------------------------------------------------------
// Pure m97-shape bf16 GEMM (NT), bf16 C store — proven in rounds 5/6.
// ---------------------------------------------------------------------------
__global__ __launch_bounds__(256) void sims_gemm_bf16(
    const unsigned short* __restrict__ A, const unsigned short* __restrict__ B,
    unsigned short* __restrict__ C)
{
  __shared__ unsigned short sA[128 * 32];   // 8 KB
  __shared__ unsigned short sB[128 * 32];   // 8 KB

  const int tid = threadIdx.x;
  const int lane = tid & 63;
  const int wave = tid >> 6;
  const int wr = wave >> 1, wc = wave & 1;
  const int row0 = blockIdx.x * 128;
  const int col0 = blockIdx.y * 128;

  const int st_r = lane >> 2;          // row within 16-row segment
  const int st_cb = (lane & 3) * 16;   // byte offset within 64B row

  f32x4 acc[4][4];
#pragma unroll
  for (int m = 0; m < 4; ++m)
#pragma unroll
    for (int n = 0; n < 4; ++n) acc[m][n] = (f32x4){0.f, 0.f, 0.f, 0.f};

  for (int k0 = 0; k0 < D_DIM; k0 += 32) {
#pragma unroll
    for (int i = 0; i < 2; ++i) {
      const int seg = wave * 2 + i;
      const int rr = seg * 16 + st_r;
      async_copy16((char*)sA + seg * 1024,
                   (const char*)(A + (size_t)(row0 + rr) * D_DIM + k0) + st_cb);
      async_copy16((char*)sB + seg * 1024,
                   (const char*)(B + (size_t)(col0 + rr) * D_DIM + k0) + st_cb);
    }
    __syncthreads();
    bf16x8 af[4], bfr[4];
#pragma unroll
    for (int m = 0; m < 4; ++m)
      af[m] = *(const bf16x8*)(sA + (wr * 64 + m * 16 + (lane & 15)) * 32 + (lane >> 4) * 8);
#pragma unroll
    for (int n = 0; n < 4; ++n)
      bfr[n] = *(const bf16x8*)(sB + (wc * 64 + n * 16 + (lane & 15)) * 32 + (lane >> 4) * 8);
#pragma unroll
    for (int m = 0; m < 4; ++m)
#pragma unroll
      for (int n = 0; n < 4; ++n)
        acc[m][n] = __builtin_amdgcn_mfma_f32_16x16x32_bf16(af[m], bfr[n], acc[m][n], 0, 0, 0);
    __syncthreads();
  }

  // C/D layout (m89): col = lane&15, row = (lane>>4)*4 + reg.
#pragma unroll
  for (int m = 0; m < 4; ++m)
#pragma unroll
    for (int n = 0; n < 4; ++n)
#pragma unroll
      for (int r = 0; r < 4; ++r) {
        const int row = row0 + wr * 64 + m * 16 + (lane >> 4) * 4 + r;
        const int col = col0 + wc * 64 + n * 16 + (lane & 15);
        C[(size_t)row * M_ROWS + col] = f32_to_bf16(acc[m][n][r]);
      }
}

// ---------------------------------------------------------------------------
// Coalesced per-row top-16: 256 threads/row; thread t reads cols g*1024+4t..+3
// via uint2 (8B/lane, coalesced). Comparator-based insert makes the candidate
// list independent of scan order. Hierarchical merge: 256 lists -> 16 (16
// threads in parallel) -> 1 (thread 0), all via the same ins16 idiom.
// ---------------------------------------------------------------------------
__global__ __launch_bounds__(256) void row_topc_coal(
    const unsigned short* __restrict__ simsbf, int row_base,
    int* __restrict__ cand)
{
  const int r = blockIdx.x;
  const int tid = threadIdx.x;
  const unsigned short* rowp = simsbf + (size_t)r * M_ROWS;

  float tv[TOPC];
  int ti_[TOPC];
#pragma unroll
  for (int p = 0; p < TOPC; ++p) { tv[p] = -INFINITY; ti_[p] = 0; }

  for (int g = 0; g < 32; ++g) {
    const int c0 = g * 1024 + tid * 4;
    const uint2 u = *(const uint2*)(rowp + c0);
    ins16(bf16_to_f32((unsigned short)(u.x & 0xFFFFu)), c0 + 0, tv, ti_);
    ins16(bf16_to_f32((unsigned short)(u.x >> 16)),     c0 + 1, tv, ti_);
    ins16(bf16_to_f32((unsigned short)(u.y & 0xFFFFu)), c0 + 2, tv, ti_);
    ins16(bf16_to_f32((unsigned short)(u.y >> 16)),     c0 + 3, tv, ti_);
  }

  __shared__ float lv[256][TOPC];   // 16 KB
  __shared__ int li[256][TOPC];     // 16 KB
#pragma unroll
  for (int p = 0; p < TOPC; ++p) { lv[tid][p] = tv[p]; li[tid][p] = ti_[p]; }
  __syncthreads();

  if (tid < 16) {
    float mv[TOPC];
    int mi[TOPC];
#pragma unroll
    for (int p = 0; p < TOPC; ++p) { mv[p] = -INFINITY; mi[p] = 0; }
    for (int s = tid * 16; s < tid * 16 + 16; ++s)
      for (int p0 = 0; p0 < TOPC; ++p0) ins16(lv[s][p0], li[s][p0], mv, mi);
#pragma unroll
    for (int p = 0; p < TOPC; ++p) { lv[tid][p] = mv[p]; li[tid][p] = mi[p]; }
  }
  __syncthreads();

  if (tid == 0) {
    float mv[TOPC];
    int mi[TOPC];
#pragma unroll
    for (int p = 0; p < TOPC; ++p) { mv[p] = -INFINITY; mi[p] = 0; }
    for (int s = 0; s < 16; ++s)
      for (int p0 = 0; p0 < TOPC; ++p0) ins16(lv[s][p0], li[s][p0], mv, mi);
#pragma unroll
    for (int p = 0; p < TOPC; ++p)
      cand[(size_t)(row_base + r) * TOPC + p] = mi[p];
  }
}

// ---------------------------------------------------------------------------
// fp64 rescore of the 16 candidates per row + stable top-8 selection
// (value desc, index asc on exact ties == np/lax top_k semantics).
// UNCHANGED from passing rounds.
// ---------------------------------------------------------------------------
__global__ __launch_bounds__(256) void rescore_topk(
    const float* __restrict__ Q, const float* __restrict__ Km,
    const int* __restrict__ cand, int* __restrict__ topi)
{
  const int b = blockIdx.x;
  const int tid = threadIdx.x;
  const int wave = tid >> 6;
  const int lane = tid & 63;

  __shared__ double sval[TOPC];
  __shared__ int sidx[TOPC];

  const float* qrow = Q + (size_t)b * D_DIM + lane * 16;
  float4 qv[4];
#pragma unroll
  for (int i = 0; i < 4; ++i) qv[i] = *(const float4*)(qrow + i * 4);

  for (int c = wave; c < TOPC; c += 4) {
    const int ci = cand[(size_t)b * TOPC + c];
    const float* krow = Km + (size_t)ci * D_DIM + lane * 16;
    double acc = 0.0;
#pragma unroll
    for (int i = 0; i < 4; ++i) {
      const float4 kv = *(const float4*)(krow + i * 4);
      acc = fma((double)qv[i].x, (double)kv.x, acc);
      acc = fma((double)qv[i].y, (double)kv.y, acc);
      acc = fma((double)qv[i].z, (double)kv.z, acc);
      acc = fma((double)qv[i].w, (double)kv.w, acc);
    }
#pragma unroll
    for (int off = 32; off > 0; off >>= 1) acc += __shfl_down(acc, off);
    if (lane == 0) { sval[c] = acc; sidx[c] = ci; }
  }
  __syncthreads();

  if (tid == 0) {
    bool used[TOPC];
#pragma unroll
    for (int p = 0; p < TOPC; ++p) used[p] = false;
#pragma unroll
    for (int p = 0; p < TOPK; ++p) {
      int best = -1;
      double bv = 0.0;
      int bi = 0;
      for (int c = 0; c < TOPC; ++c) {
        if (used[c]) continue;
        const double v = sval[c];
        const int ix = sidx[c];
        if (best < 0 || v > bv || (v == bv && ix < bi)) { best = c; bv = v; bi = ix; }
      }
      used[best] = true;
      topi[(size_t)b * TOPK + p] = bi;
    }
  }
}

// ---------------------------------------------------------------------------
// f32 -> bf16 cast (vectorized, for mem and Wv feeding the V MFMA GEMM).
// ---------------------------------------------------------------------------
__global__ __launch_bounds__(256) void cast_f32_bf16(
    const float* __restrict__ src, unsigned short* __restrict__ dst, int n4)
{
  const int i = blockIdx.x * 256 + threadIdx.x;
  if (i >= n4) return;
  const float4 v = *(const float4*)(src + (size_t)i * 4);
  ushort4 o;
  o.x = f32_to_bf16(v.x);
  o.y = f32_to_bf16(v.y);
  o.z = f32_to_bf16(v.z);
  o.w = f32_to_bf16(v.w);
  *(ushort4*)(dst + (size_t)i * 4) = o;
}

// ---------------------------------------------------------------------------
// V projection via bf16 MFMA (values only; bf16 error ~0.008 << 0.105 abs
// threshold). Same m97 structure as sims_gemm; fp32 C + bias.
// ---------------------------------------------------------------------------
__global__ __launch_bounds__(256) void vproj_bf16(
    const unsigned short* __restrict__ A,   // mem_bf [M_ROWS][D_DIM]
    const unsigned short* __restrict__ B,   // Wv_bf  [D_DIM][D_DIM]
    const float* __restrict__ bias,
    float* __restrict__ C)                  // [M_ROWS][D_DIM] fp32
{
  __shared__ unsigned short sA[128 * 32];
  __shared__ unsigned short sB[128 * 32];

  const int tid = threadIdx.x;
  const int lane = tid & 63;
  const int wave = tid >> 6;
  const int wr = wave >> 1, wc = wave & 1;
  const int row0 = blockIdx.x * 128;
  const int col0 = blockIdx.y * 128;

  const int st_r = lane >> 2;
  const int st_cb = (lane & 3) * 16;

  f32x4 acc[4][4];
#pragma unroll
  for (int m = 0; m < 4; ++m)
#pragma unroll
    for (int n = 0; n < 4; ++n) acc[m][n] = (f32x4){0.f, 0.f, 0.f, 0.f};

  for (int k0 = 0; k0 < D_DIM; k0 += 32) {
#pragma unroll
    for (int i = 0; i < 2; ++i) {
      const int seg = wave * 2 + i;
      const int rr = seg * 16 + st_r;
      async_copy16((char*)sA + seg * 1024,
                   (const char*)(A + (size_t)(row0 + rr) * D_DIM + k0) + st_cb);
      async_copy16((char*)sB + seg * 1024,
                   (const char*)(B + (size_t)(col0 + rr) * D_DIM + k0) + st_cb);
    }
    __syncthreads();
    bf16x8 af[4], bfr[4];
#pragma unroll
    for (int m = 0; m < 4; ++m)
      af[m] = *(const bf16x8*)(sA + (wr * 64 + m * 16 + (lane & 15)) * 32 + (lane >> 4) * 8);
#pragma unroll
    for (int n = 0; n < 4; ++n)
      bfr[n] = *(const bf16x8*)(sB + (wc * 64 + n * 16 + (lane & 15)) * 32 + (lane >> 4) * 8);
#pragma unroll
    for (int m = 0; m < 4; ++m)
#pragma unroll
      for (int n = 0; n < 4; ++n)
        acc[m][n] = __builtin_amdgcn_mfma_f32_16x16x32_bf16(af[m], bfr[n], acc[m][n], 0, 0, 0);
    __syncthreads();
  }

#pragma unroll
  for (int n = 0; n < 4; ++n) {
    const int col = col0 + wc * 64 + n * 16 + (lane & 15);
    const float bcol = bias[col];
#pragma unroll
    for (int m = 0; m < 4; ++m)
#pragma unroll
      for (int r = 0; r < 4; ++r) {
        const int row = row0 + wr * 64 + m * 16 + (lane >> 4) * 4 + r;
        C[(size_t)row * D_DIM + col] = acc[m][n][r] + bcol;
      }
  }
}

// ---------------------------------------------------------------------------
// Gather selected V rows + LayerNorm (biased var, eps=1e-5, affine).
// ---------------------------------------------------------------------------
__global__ __launch_bounds__(256) void gather_ln(
    const float* __restrict__ V, const int* __restrict__ topi,
    const float* __restrict__ gamma, const float* __restrict__ beta,
    float* __restrict__ out)
{
  const int row = blockIdx.x;  // b*8 + rank
  const int tid = threadIdx.x;
  const int idx = topi[row];
  const float* src = V + (size_t)idx * D_DIM;
  const float4 v = *(const float4*)(src + tid * 4);
  float s = v.x + v.y + v.z + v.w;
  float s2 = v.x * v.x + v.y * v.y + v.z * v.z + v.w * v.w;
#pragma unroll
  for (int off = 32; off > 0; off >>= 1) {
    s += __shfl_down(s, off);
    s2 += __shfl_down(s2, off);
  }
  __shared__ float red[8];
  __shared__ float stats[2];
  const int wid = tid >> 6;
  if ((tid & 63) == 0) { red[wid] = s; red[4 + wid] = s2; }
  __syncthreads();
  if (tid == 0) {
    const float S = red[0] + red[1] + red[2] + red[3];
    const float S2 = red[4] + red[5] + red[6] + red[7];
    const float mu = S * (1.0f / D_DIM);
    const float var = S2 * (1.0f / D_DIM) - mu * mu;
    stats[0] = mu;
    stats[1] = rsqrtf(var + 1e-5f);
  }
  __syncthreads();
  const float mu = stats[0], rstd = stats[1];
  const float4 g4 = *(const float4*)(gamma + tid * 4);
  const float4 b4 = *(const float4*)(beta + tid * 4);
  float4 o;
  o.x = (v.x - mu) * rstd * g4.x + b4.x;
  o.y = (v.y - mu) * rstd * g4.y + b4.y;
  o.z = (v.z - mu) * rstd * g4.z + b4.z;
  o.w = (v.w - mu) * rstd * g4.w + b4.w;
  *(float4*)(out + (size_t)row * D_DIM + tid * 4) = o;
}

extern "C" void kernel_launch(void* const* d_in, const int* in_sizes, int n_in,
                              void* d_out, int out_size, void* d_ws, size_t ws_size,
                              hipStream_t stream)
{
  const float* query = (const float*)d_in[0];
  const float* mem   = (const float*)d_in[1];
  const float* Wq    = (const float*)d_in[2];
  const float* bq    = (const float*)d_in[3];
  const float* Wk    = (const float*)d_in[4];
  const float* bk    = (const float*)d_in[5];
  const float* Wv    = (const float*)d_in[6];
  const float* bv    = (const float*)d_in[7];
  const float* gamma = (const float*)d_in[8];
  const float* beta  = (const float*)d_in[9];
  float* out = (float*)d_out;

  char* ws = (char*)d_ws;
  float* q = (float*)ws;       ws += (size_t)B_ROWS * D_DIM * sizeof(float);
  float* K = (float*)ws;       ws += (size_t)M_ROWS * D_DIM * sizeof(float);
  char* Vregion = ws;          ws += (size_t)M_ROWS * D_DIM * sizeof(float);
  unsigned short* qbf = (unsigned short*)ws;
  ws += (size_t)B_ROWS * D_DIM * sizeof(unsigned short);
  int* cand = (int*)ws;        ws += (size_t)B_ROWS * TOPC * sizeof(int);
  int* topi = (int*)ws;

  // Region lifetime map (all in-stream, in-order):
  //  phase A (sims):   Vregion = simsbf[QROWS][M_ROWS] (67MB) + Kbf (67MB)
  //  phase B (V-proj): simsbf slot -> mem_bf; qbf slot -> Wv_bf;
  //                    K region (dead after rescore) -> V output.
  unsigned short* simsbf = (unsigned short*)Vregion;
  unsigned short* Kbf = (unsigned short*)(Vregion + (size_t)QROWS * M_ROWS * sizeof(unsigned short));
  unsigned short* membf = simsbf;
  unsigned short* wvbf = qbf;
  float* Vout = K;

  gemm_nt_bias_f64<<<dim3(B_ROWS / BM, D_DIM / BN), 256, 0, stream>>>(query, Wq, bq, q, qbf);
  gemm_nt_bias_f64<<<dim3(M_ROWS / BM, D_DIM / BN), 256, 0, stream>>>(mem, Wk, bk, K, Kbf);

  for (int qt = 0; qt < B_ROWS / QROWS; ++qt) {
    sims_gemm_bf16<<<dim3(QROWS / 128, M_ROWS / 128), 256, 0, stream>>>(
        qbf + (size_t)qt * QROWS * D_DIM, Kbf, simsbf);
    row_topc_coal<<<dim3(QROWS), 256, 0, stream>>>(simsbf, qt * QROWS, cand);
  }

  rescore_topk<<<dim3(B_ROWS), 256, 0, stream>>>(q, K, cand, topi);

  // V path (bf16 MFMA): casts overwrite dead simsbf/qbf; output overwrites K.
  cast_f32_bf16<<<dim3((M_ROWS * D_DIM / 4 + 255) / 256), 256, 0, stream>>>(mem, membf, M_ROWS * D_DIM / 4);
  cast_f32_bf16<<<dim3((D_DIM * D_DIM / 4 + 255) / 256), 256, 0, stream>>>(Wv, wvbf, D_DIM * D_DIM / 4);
  vproj_bf16<<<dim3(M_ROWS / 128, D_DIM / 128), 256, 0, stream>>>(membf, wvbf, bv, Vout);
  gather_ln<<<dim3(B_ROWS * TOPK), 256, 0, stream>>>(Vout, topi, gamma, beta, out);
}

// Round 8
// 3844.884 us; speedup vs baseline: 2.0833x; 1.3564x over previous
//
#include <hip/hip_runtime.h>
#include <hip/hip_bf16.h>
#include <math.h>

#define D_DIM 1024
#define B_ROWS 4096
#define M_ROWS 32768
#define TOPK 8
#define TOPC 16                // candidates per row after merge
#define TOPB 8                 // candidates kept per 128-col block
#define NCB (M_ROWS / 128)     // 256 col-blocks

#define BM 128
#define BN 64
#define BK 32

typedef __attribute__((ext_vector_type(8))) short bf16x8;
typedef __attribute__((ext_vector_type(4))) float f32x4;

__device__ __forceinline__ unsigned short f32_to_bf16(float f) {
  unsigned int u = __float_as_uint(f);
  unsigned int r = (u + 0x7FFFu + ((u >> 16) & 1u)) >> 16;
  return (unsigned short)r;
}
__device__ __forceinline__ float bf16_to_f32(unsigned short h) {
  return __uint_as_float(((unsigned int)h) << 16);
}
__device__ __forceinline__ void async_copy16(void* lds, const void* g) {
  __builtin_amdgcn_global_load_lds(
      (const __attribute__((address_space(1))) unsigned int*)g,
      (__attribute__((address_space(3))) unsigned int*)lds, 16, 0, 0);
}

// Ordered insert into a register top-N list sorted by (value desc, index asc).
// Comparator-based => result independent of visitation order (round-7-proven).
template <int N>
__device__ __forceinline__ void insN(float v, int idx,
                                     float* __restrict__ tv,
                                     int* __restrict__ ti) {
  if (v < tv[N - 1]) return;
  if (v == tv[N - 1] && idx > ti[N - 1]) return;
  float cv = v;
  int ci = idx;
#pragma unroll
  for (int p = 0; p < N; ++p) {
    if (cv > tv[p] || (cv == tv[p] && ci < ti[p])) {
      const float t0 = tv[p]; tv[p] = cv; cv = t0;
      const int t1 = ti[p]; ti[p] = ci; ci = t1;
    }
  }
}

// ---------------------------------------------------------------------------
// out[r][n] = sum_d X[r][d]*W[n][d] + bias[n], fp64 accumulation over fp32
// inputs, rounded once to fp32 on store (selection chain — do not touch).
// Also emits bf16 copy for the MFMA candidate pass.
// ---------------------------------------------------------------------------
__global__ __launch_bounds__(256) void gemm_nt_bias_f64(
    const float* __restrict__ X, const float* __restrict__ W,
    const float* __restrict__ bias, float* __restrict__ out,
    unsigned short* __restrict__ outbf)
{
  __shared__ float sA[BK][BM + 4];
  __shared__ float sB[BK][BN + 4];
  const int tid = threadIdx.x;
  const int tx = tid & 15, ty = tid >> 4;
  const int row0 = blockIdx.x * BM;
  const int col0 = blockIdx.y * BN;
  const int lr = tid >> 3;         // 0..31
  const int lc = (tid & 7) << 2;   // 0,4,...,28

  double acc[2][4][4];
#pragma unroll
  for (int g = 0; g < 2; ++g)
#pragma unroll
    for (int i = 0; i < 4; ++i)
#pragma unroll
      for (int j = 0; j < 4; ++j) acc[g][i][j] = 0.0;

  for (int k0 = 0; k0 < D_DIM; k0 += BK) {
#pragma unroll
    for (int rr = 0; rr < 4; ++rr) {
      const float4 v = *(const float4*)(X + (size_t)(row0 + lr + 32 * rr) * D_DIM + k0 + lc);
      sA[lc + 0][lr + 32 * rr] = v.x;
      sA[lc + 1][lr + 32 * rr] = v.y;
      sA[lc + 2][lr + 32 * rr] = v.z;
      sA[lc + 3][lr + 32 * rr] = v.w;
    }
#pragma unroll
    for (int rr = 0; rr < 2; ++rr) {
      const float4 v = *(const float4*)(W + (size_t)(col0 + lr + 32 * rr) * D_DIM + k0 + lc);
      sB[lc + 0][lr + 32 * rr] = v.x;
      sB[lc + 1][lr + 32 * rr] = v.y;
      sB[lc + 2][lr + 32 * rr] = v.z;
      sB[lc + 3][lr + 32 * rr] = v.w;
    }
    __syncthreads();
#pragma unroll
    for (int kk = 0; kk < BK; ++kk) {
      const float4 A0 = *(const float4*)&sA[kk][ty * 4];
      const float4 A1 = *(const float4*)&sA[kk][64 + ty * 4];
      const float4 Bv = *(const float4*)&sB[kk][tx * 4];
      const double a0[4] = {A0.x, A0.y, A0.z, A0.w};
      const double a1[4] = {A1.x, A1.y, A1.z, A1.w};
      const double bb[4] = {Bv.x, Bv.y, Bv.z, Bv.w};
#pragma unroll
      for (int i = 0; i < 4; ++i)
#pragma unroll
        for (int j = 0; j < 4; ++j) {
          acc[0][i][j] = fma(a0[i], bb[j], acc[0][i][j]);
          acc[1][i][j] = fma(a1[i], bb[j], acc[1][i][j]);
        }
    }
    __syncthreads();
  }
  const float4 bv4 = *(const float4*)(bias + col0 + tx * 4);
  const double bb[4] = {bv4.x, bv4.y, bv4.z, bv4.w};
#pragma unroll
  for (int g = 0; g < 2; ++g)
#pragma unroll
    for (int i = 0; i < 4; ++i) {
      float4 o;
      o.x = (float)(acc[g][i][0] + bb[0]);
      o.y = (float)(acc[g][i][1] + bb[1]);
      o.z = (float)(acc[g][i][2] + bb[2]);
      o.w = (float)(acc[g][i][3] + bb[3]);
      const size_t base = (size_t)(row0 + g * 64 + ty * 4 + i) * D_DIM + col0 + tx * 4;
      *(float4*)(out + base) = o;
      ushort4 ob;
      ob.x = f32_to_bf16(o.x);
      ob.y = f32_to_bf16(o.y);
      ob.z = f32_to_bf16(o.z);
      ob.w = f32_to_bf16(o.w);
      *(ushort4*)(outbf + base) = ob;
    }
}

// ---------------------------------------------------------------------------
// Fused sims + per-block top-8: full 4096x32768 in one launch. K-loop is
// byte-identical to the rounds-5/6/7-proven sims_gemm_bf16; epilogue is
// round-4's proven acc->bf16-LDS-tile + 128-thread row scan, emitting
// [row][colblock][8] candidate lists instead of the sims matrix.
// ---------------------------------------------------------------------------
#define CSTR 132
__global__ __launch_bounds__(256) void sims_topc_gemm(
    const unsigned short* __restrict__ A, const unsigned short* __restrict__ B,
    float* __restrict__ part_v, int* __restrict__ part_i)
{
  __shared__ unsigned short sA[128 * 32];   // 8 KB
  __shared__ unsigned short sB[128 * 32];   // 8 KB
  __shared__ unsigned short sC[128 * CSTR]; // 33.8 KB

  const int tid = threadIdx.x;
  const int lane = tid & 63;
  const int wave = tid >> 6;
  const int wr = wave >> 1, wc = wave & 1;
  const int row0 = blockIdx.x * 128;
  const int cb = blockIdx.y;           // col-block 0..255
  const int col0 = cb * 128;

  const int st_r = lane >> 2;          // row within 16-row segment
  const int st_cb = (lane & 3) * 16;   // byte offset within 64B row

  f32x4 acc[4][4];
#pragma unroll
  for (int m = 0; m < 4; ++m)
#pragma unroll
    for (int n = 0; n < 4; ++n) acc[m][n] = (f32x4){0.f, 0.f, 0.f, 0.f};

  for (int k0 = 0; k0 < D_DIM; k0 += 32) {
#pragma unroll
    for (int i = 0; i < 2; ++i) {
      const int seg = wave * 2 + i;
      const int rr = seg * 16 + st_r;
      async_copy16((char*)sA + seg * 1024,
                   (const char*)(A + (size_t)(row0 + rr) * D_DIM + k0) + st_cb);
      async_copy16((char*)sB + seg * 1024,
                   (const char*)(B + (size_t)(col0 + rr) * D_DIM + k0) + st_cb);
    }
    __syncthreads();
    bf16x8 af[4], bfr[4];
#pragma unroll
    for (int m = 0; m < 4; ++m)
      af[m] = *(const bf16x8*)(sA + (wr * 64 + m * 16 + (lane & 15)) * 32 + (lane >> 4) * 8);
#pragma unroll
    for (int n = 0; n < 4; ++n)
      bfr[n] = *(const bf16x8*)(sB + (wc * 64 + n * 16 + (lane & 15)) * 32 + (lane >> 4) * 8);
#pragma unroll
    for (int m = 0; m < 4; ++m)
#pragma unroll
      for (int n = 0; n < 4; ++n)
        acc[m][n] = __builtin_amdgcn_mfma_f32_16x16x32_bf16(af[m], bfr[n], acc[m][n], 0, 0, 0);
    __syncthreads();
  }

  // acc -> bf16 LDS tile. C/D layout (m89): col=lane&15, row=(lane>>4)*4+reg.
#pragma unroll
  for (int m = 0; m < 4; ++m)
#pragma unroll
    for (int n = 0; n < 4; ++n)
#pragma unroll
      for (int r = 0; r < 4; ++r) {
        const int row = wr * 64 + m * 16 + (lane >> 4) * 4 + r;
        const int col = wc * 64 + n * 16 + (lane & 15);
        sC[row * CSTR + col] = f32_to_bf16(acc[m][n][r]);
      }
  __syncthreads();

  if (tid < 128) {
    float tv[TOPB];
    int ti_[TOPB];
#pragma unroll
    for (int p = 0; p < TOPB; ++p) { tv[p] = -INFINITY; ti_[p] = 0; }
    const unsigned short* crow = sC + tid * CSTR;
    for (int j = 0; j < 128; j += 4) {
      const ushort4 c4 = *(const ushort4*)(crow + j);
      insN<TOPB>(bf16_to_f32(c4.x), col0 + j + 0, tv, ti_);
      insN<TOPB>(bf16_to_f32(c4.y), col0 + j + 1, tv, ti_);
      insN<TOPB>(bf16_to_f32(c4.z), col0 + j + 2, tv, ti_);
      insN<TOPB>(bf16_to_f32(c4.w), col0 + j + 3, tv, ti_);
    }
    const size_t base = ((size_t)(row0 + tid) * NCB + cb) * TOPB;
    *(float4*)(part_v + base)     = (float4){tv[0], tv[1], tv[2], tv[3]};
    *(float4*)(part_v + base + 4) = (float4){tv[4], tv[5], tv[6], tv[7]};
    *(int4*)(part_i + base)       = (int4){ti_[0], ti_[1], ti_[2], ti_[3]};
    *(int4*)(part_i + base + 4)   = (int4){ti_[4], ti_[5], ti_[6], ti_[7]};
  }
}

// ---------------------------------------------------------------------------
// Merge 256 per-block top-8 lists per row -> 16 candidates. Hierarchy is the
// round-7-proven pattern: 256 threads stage to LDS, 16 threads merge 16
// lists each, thread 0 merges 16 -> cand. All via the same insN comparator.
// ---------------------------------------------------------------------------
__global__ __launch_bounds__(256) void merge_cand256(
    const float* __restrict__ part_v, const int* __restrict__ part_i,
    int* __restrict__ cand)
{
  const int r = blockIdx.x;
  const int tid = threadIdx.x;

  __shared__ float lv[256][TOPB];   // 8 KB
  __shared__ int li[256][TOPB];     // 8 KB

  {
    const size_t base = ((size_t)r * NCB + tid) * TOPB;
    const float4 a0 = *(const float4*)(part_v + base);
    const float4 a1 = *(const float4*)(part_v + base + 4);
    const int4 b0 = *(const int4*)(part_i + base);
    const int4 b1 = *(const int4*)(part_i + base + 4);
    lv[tid][0] = a0.x; lv[tid][1] = a0.y; lv[tid][2] = a0.z; lv[tid][3] = a0.w;
    lv[tid][4] = a1.x; lv[tid][5] = a1.y; lv[tid][6] = a1.z; lv[tid][7] = a1.w;
    li[tid][0] = b0.x; li[tid][1] = b0.y; li[tid][2] = b0.z; li[tid][3] = b0.w;
    li[tid][4] = b1.x; li[tid][5] = b1.y; li[tid][6] = b1.z; li[tid][7] = b1.w;
  }
  __syncthreads();

  __shared__ float mv16[16][TOPC];
  __shared__ int mi16[16][TOPC];
  if (tid < 16) {
    float mv[TOPC];
    int mi[TOPC];
#pragma unroll
    for (int p = 0; p < TOPC; ++p) { mv[p] = -INFINITY; mi[p] = 0; }
    for (int s = tid * 16; s < tid * 16 + 16; ++s)
      for (int p0 = 0; p0 < TOPB; ++p0) insN<TOPC>(lv[s][p0], li[s][p0], mv, mi);
#pragma unroll
    for (int p = 0; p < TOPC; ++p) { mv16[tid][p] = mv[p]; mi16[tid][p] = mi[p]; }
  }
  __syncthreads();

  if (tid == 0) {
    float mv[TOPC];
    int mi[TOPC];
#pragma unroll
    for (int p = 0; p < TOPC; ++p) { mv[p] = -INFINITY; mi[p] = 0; }
    for (int s = 0; s < 16; ++s)
      for (int p0 = 0; p0 < TOPC; ++p0) insN<TOPC>(mv16[s][p0], mi16[s][p0], mv, mi);
#pragma unroll
    for (int p = 0; p < TOPC; ++p)
      cand[(size_t)r * TOPC + p] = mi[p];
  }
}

// ---------------------------------------------------------------------------
// fp64 rescore of the 16 candidates per row + stable top-8 selection
// (value desc, index asc on exact ties == np/lax top_k semantics).
// UNCHANGED from passing rounds.
// ---------------------------------------------------------------------------
__global__ __launch_bounds__(256) void rescore_topk(
    const float* __restrict__ Q, const float* __restrict__ Km,
    const int* __restrict__ cand, int* __restrict__ topi)
{
  const int b = blockIdx.x;
  const int tid = threadIdx.x;
  const int wave = tid >> 6;
  const int lane = tid & 63;

  __shared__ double sval[TOPC];
  __shared__ int sidx[TOPC];

  const float* qrow = Q + (size_t)b * D_DIM + lane * 16;
  float4 qv[4];
#pragma unroll
  for (int i = 0; i < 4; ++i) qv[i] = *(const float4*)(qrow + i * 4);

  for (int c = wave; c < TOPC; c += 4) {
    const int ci = cand[(size_t)b * TOPC + c];
    const float* krow = Km + (size_t)ci * D_DIM + lane * 16;
    double acc = 0.0;
#pragma unroll
    for (int i = 0; i < 4; ++i) {
      const float4 kv = *(const float4*)(krow + i * 4);
      acc = fma((double)qv[i].x, (double)kv.x, acc);
      acc = fma((double)qv[i].y, (double)kv.y, acc);
      acc = fma((double)qv[i].z, (double)kv.z, acc);
      acc = fma((double)qv[i].w, (double)kv.w, acc);
    }
#pragma unroll
    for (int off = 32; off > 0; off >>= 1) acc += __shfl_down(acc, off);
    if (lane == 0) { sval[c] = acc; sidx[c] = ci; }
  }
  __syncthreads();

  if (tid == 0) {
    bool used[TOPC];
#pragma unroll
    for (int p = 0; p < TOPC; ++p) used[p] = false;
#pragma unroll
    for (int p = 0; p < TOPK; ++p) {
      int best = -1;
      double bv = 0.0;
      int bi = 0;
      for (int c = 0; c < TOPC; ++c) {
        if (used[c]) continue;
        const double v = sval[c];
        const int ix = sidx[c];
        if (best < 0 || v > bv || (v == bv && ix < bi)) { best = c; bv = v; bi = ix; }
      }
      used[best] = true;
      topi[(size_t)b * TOPK + p] = bi;
    }
  }
}

// ---------------------------------------------------------------------------
// f32 -> bf16 cast (vectorized, for mem and Wv feeding the V MFMA GEMM).
// ---------------------------------------------------------------------------
__global__ __launch_bounds__(256) void cast_f32_bf16(
    const float* __restrict__ src, unsigned short* __restrict__ dst, int n4)
{
  const int i = blockIdx.x * 256 + threadIdx.x;
  if (i >= n4) return;
  const float4 v = *(const float4*)(src + (size_t)i * 4);
  ushort4 o;
  o.x = f32_to_bf16(v.x);
  o.y = f32_to_bf16(v.y);
  o.z = f32_to_bf16(v.z);
  o.w = f32_to_bf16(v.w);
  *(ushort4*)(dst + (size_t)i * 4) = o;
}

// ---------------------------------------------------------------------------
// V projection via bf16 MFMA (values only; error << 0.105 abs threshold).
// ---------------------------------------------------------------------------
__global__ __launch_bounds__(256) void vproj_bf16(
    const unsigned short* __restrict__ A,   // mem_bf [M_ROWS][D_DIM]
    const unsigned short* __restrict__ B,   // Wv_bf  [D_DIM][D_DIM]
    const float* __restrict__ bias,
    float* __restrict__ C)                  // [M_ROWS][D_DIM] fp32
{
  __shared__ unsigned short sA[128 * 32];
  __shared__ unsigned short sB[128 * 32];

  const int tid = threadIdx.x;
  const int lane = tid & 63;
  const int wave = tid >> 6;
  const int wr = wave >> 1, wc = wave & 1;
  const int row0 = blockIdx.x * 128;
  const int col0 = blockIdx.y * 128;

  const int st_r = lane >> 2;
  const int st_cb = (lane & 3) * 16;

  f32x4 acc[4][4];
#pragma unroll
  for (int m = 0; m < 4; ++m)
#pragma unroll
    for (int n = 0; n < 4; ++n) acc[m][n] = (f32x4){0.f, 0.f, 0.f, 0.f};

  for (int k0 = 0; k0 < D_DIM; k0 += 32) {
#pragma unroll
    for (int i = 0; i < 2; ++i) {
      const int seg = wave * 2 + i;
      const int rr = seg * 16 + st_r;
      async_copy16((char*)sA + seg * 1024,
                   (const char*)(A + (size_t)(row0 + rr) * D_DIM + k0) + st_cb);
      async_copy16((char*)sB + seg * 1024,
                   (const char*)(B + (size_t)(col0 + rr) * D_DIM + k0) + st_cb);
    }
    __syncthreads();
    bf16x8 af[4], bfr[4];
#pragma unroll
    for (int m = 0; m < 4; ++m)
      af[m] = *(const bf16x8*)(sA + (wr * 64 + m * 16 + (lane & 15)) * 32 + (lane >> 4) * 8);
#pragma unroll
    for (int n = 0; n < 4; ++n)
      bfr[n] = *(const bf16x8*)(sB + (wc * 64 + n * 16 + (lane & 15)) * 32 + (lane >> 4) * 8);
#pragma unroll
    for (int m = 0; m < 4; ++m)
#pragma unroll
      for (int n = 0; n < 4; ++n)
        acc[m][n] = __builtin_amdgcn_mfma_f32_16x16x32_bf16(af[m], bfr[n], acc[m][n], 0, 0, 0);
    __syncthreads();
  }

#pragma unroll
  for (int n = 0; n < 4; ++n) {
    const int col = col0 + wc * 64 + n * 16 + (lane & 15);
    const float bcol = bias[col];
#pragma unroll
    for (int m = 0; m < 4; ++m)
#pragma unroll
      for (int r = 0; r < 4; ++r) {
        const int row = row0 + wr * 64 + m * 16 + (lane >> 4) * 4 + r;
        C[(size_t)row * D_DIM + col] = acc[m][n][r] + bcol;
      }
  }
}

// ---------------------------------------------------------------------------
// Gather selected V rows + LayerNorm (biased var, eps=1e-5, affine).
// ---------------------------------------------------------------------------
__global__ __launch_bounds__(256) void gather_ln(
    const float* __restrict__ V, const int* __restrict__ topi,
    const float* __restrict__ gamma, const float* __restrict__ beta,
    float* __restrict__ out)
{
  const int row = blockIdx.x;  // b*8 + rank
  const int tid = threadIdx.x;
  const int idx = topi[row];
  const float* src = V + (size_t)idx * D_DIM;
  const float4 v = *(const float4*)(src + tid * 4);
  float s = v.x + v.y + v.z + v.w;
  float s2 = v.x * v.x + v.y * v.y + v.z * v.z + v.w * v.w;
#pragma unroll
  for (int off = 32; off > 0; off >>= 1) {
    s += __shfl_down(s, off);
    s2 += __shfl_down(s2, off);
  }
  __shared__ float red[8];
  __shared__ float stats[2];
  const int wid = tid >> 6;
  if ((tid & 63) == 0) { red[wid] = s; red[4 + wid] = s2; }
  __syncthreads();
  if (tid == 0) {
    const float S = red[0] + red[1] + red[2] + red[3];
    const float S2 = red[4] + red[5] + red[6] + red[7];
    const float mu = S * (1.0f / D_DIM);
    const float var = S2 * (1.0f / D_DIM) - mu * mu;
    stats[0] = mu;
    stats[1] = rsqrtf(var + 1e-5f);
  }
  __syncthreads();
  const float mu = stats[0], rstd = stats[1];
  const float4 g4 = *(const float4*)(gamma + tid * 4);
  const float4 b4 = *(const float4*)(beta + tid * 4);
  float4 o;
  o.x = (v.x - mu) * rstd * g4.x + b4.x;
  o.y = (v.y - mu) * rstd * g4.y + b4.y;
  o.z = (v.z - mu) * rstd * g4.z + b4.z;
  o.w = (v.w - mu) * rstd * g4.w + b4.w;
  *(float4*)(out + (size_t)row * D_DIM + tid * 4) = o;
}

extern "C" void kernel_launch(void* const* d_in, const int* in_sizes, int n_in,
                              void* d_out, int out_size, void* d_ws, size_t ws_size,
                              hipStream_t stream)
{
  const float* query = (const float*)d_in[0];
  const float* mem   = (const float*)d_in[1];
  const float* Wq    = (const float*)d_in[2];
  const float* bq    = (const float*)d_in[3];
  const float* Wk    = (const float*)d_in[4];
  const float* bk    = (const float*)d_in[5];
  const float* Wv    = (const float*)d_in[6];
  const float* bv    = (const float*)d_in[7];
  const float* gamma = (const float*)d_in[8];
  const float* beta  = (const float*)d_in[9];
  float* out = (float*)d_out;

  char* ws = (char*)d_ws;
  float* q = (float*)ws;       ws += (size_t)B_ROWS * D_DIM * sizeof(float);
  float* K = (float*)ws;       ws += (size_t)M_ROWS * D_DIM * sizeof(float);
  char* Vregion = ws;          ws += (size_t)M_ROWS * D_DIM * sizeof(float);
  unsigned short* qbf = (unsigned short*)ws;
  ws += (size_t)B_ROWS * D_DIM * sizeof(unsigned short);
  int* cand = (int*)ws;        ws += (size_t)B_ROWS * TOPC * sizeof(int);
  int* topi = (int*)ws;

  // Region lifetime map (in-stream, in-order):
  //  phase A (sims):   Vregion = Kbf (67.1MB) + part_v (33.5MB) + part_i (33.5MB)
  //  phase B (V-proj): Kbf slot -> mem_bf (67.1MB); qbf slot -> Wv_bf (2.1MB);
  //                    K region (dead after rescore) -> V output.
  unsigned short* Kbf = (unsigned short*)Vregion;
  float* part_v = (float*)(Vregion + (size_t)M_ROWS * D_DIM * sizeof(unsigned short));
  int* part_i = (int*)((char*)part_v + (size_t)B_ROWS * NCB * TOPB * sizeof(float));
  unsigned short* membf = Kbf;
  unsigned short* wvbf = qbf;
  float* Vout = K;

  gemm_nt_bias_f64<<<dim3(B_ROWS / BM, D_DIM / BN), 256, 0, stream>>>(query, Wq, bq, q, qbf);
  gemm_nt_bias_f64<<<dim3(M_ROWS / BM, D_DIM / BN), 256, 0, stream>>>(mem, Wk, bk, K, Kbf);

  sims_topc_gemm<<<dim3(B_ROWS / 128, NCB), 256, 0, stream>>>(qbf, Kbf, part_v, part_i);
  merge_cand256<<<dim3(B_ROWS), 256, 0, stream>>>(part_v, part_i, cand);

  rescore_topk<<<dim3(B_ROWS), 256, 0, stream>>>(q, K, cand, topi);

  // V path (bf16 MFMA): casts overwrite dead Kbf/qbf; output overwrites K.
  cast_f32_bf16<<<dim3((M_ROWS * D_DIM / 4 + 255) / 256), 256, 0, stream>>>(mem, membf, M_ROWS * D_DIM / 4);
  cast_f32_bf16<<<dim3((D_DIM * D_DIM / 4 + 255) / 256), 256, 0, stream>>>(Wv, wvbf, D_DIM * D_DIM / 4);
  vproj_bf16<<<dim3(M_ROWS / 128, D_DIM / 128), 256, 0, stream>>>(membf, wvbf, bv, Vout);
  gather_ln<<<dim3(B_ROWS * TOPK), 256, 0, stream>>>(Vout, topi, gamma, beta, out);
}

// Round 10
// 2498.080 us; speedup vs baseline: 3.2065x; 1.5391x over previous
//
#include <hip/hip_runtime.h>
#include <hip/hip_bf16.h>
#include <math.h>

#define D_DIM 1024
#define B_ROWS 4096
#define M_ROWS 32768
#define TOPK 8
#define TOPC 16                // candidates per row after merge
#define TOPB 8                 // candidates kept per 128-col block
#define NCB (M_ROWS / 128)     // 256 col-blocks

#define BM 128
#define BN 64
#define BK 32

typedef __attribute__((ext_vector_type(8))) short bf16x8;
typedef __attribute__((ext_vector_type(4))) float f32x4;

__device__ __forceinline__ unsigned short f32_to_bf16(float f) {
  unsigned int u = __float_as_uint(f);
  unsigned int r = (u + 0x7FFFu + ((u >> 16) & 1u)) >> 16;
  return (unsigned short)r;
}
__device__ __forceinline__ float bf16_to_f32(unsigned short h) {
  return __uint_as_float(((unsigned int)h) << 16);
}
__device__ __forceinline__ void async_copy16(void* lds, const void* g) {
  __builtin_amdgcn_global_load_lds(
      (const __attribute__((address_space(1))) unsigned int*)g,
      (__attribute__((address_space(3))) unsigned int*)lds, 16, 0, 0);
}

// Ordered insert into a register top-N list sorted by (value desc, index asc).
template <int N>
__device__ __forceinline__ void insN(float v, int idx,
                                     float* __restrict__ tv,
                                     int* __restrict__ ti) {
  if (v < tv[N - 1]) return;
  if (v == tv[N - 1] && idx > ti[N - 1]) return;
  float cv = v;
  int ci = idx;
#pragma unroll
  for (int p = 0; p < N; ++p) {
    if (cv > tv[p] || (cv == tv[p] && ci < ti[p])) {
      const float t0 = tv[p]; tv[p] = cv; cv = t0;
      const int t1 = ti[p]; ti[p] = ci; ci = t1;
    }
  }
}

// ---------------------------------------------------------------------------
// q projection: q64[b,n] = sum_e query[b,e]*Wq[n,e] + bq[n], f64 accumulation
// (selection chain). Emits f64 q (for uproj/qbk) + bf16 q (candidate GEMM).
// Same proven NT structure as the previous gemm_nt_bias_f64.
// ---------------------------------------------------------------------------
__global__ __launch_bounds__(256) void qproj_f64(
    const float* __restrict__ X, const float* __restrict__ W,
    const float* __restrict__ bias, double* __restrict__ out64,
    unsigned short* __restrict__ outbf)
{
  __shared__ float sA[BK][BM + 4];
  __shared__ float sB[BK][BN + 4];
  const int tid = threadIdx.x;
  const int tx = tid & 15, ty = tid >> 4;
  const int row0 = blockIdx.x * BM;
  const int col0 = blockIdx.y * BN;
  const int lr = tid >> 3;         // 0..31
  const int lc = (tid & 7) << 2;   // 0,4,...,28

  double acc[2][4][4];
#pragma unroll
  for (int g = 0; g < 2; ++g)
#pragma unroll
    for (int i = 0; i < 4; ++i)
#pragma unroll
      for (int j = 0; j < 4; ++j) acc[g][i][j] = 0.0;

  for (int k0 = 0; k0 < D_DIM; k0 += BK) {
#pragma unroll
    for (int rr = 0; rr < 4; ++rr) {
      const float4 v = *(const float4*)(X + (size_t)(row0 + lr + 32 * rr) * D_DIM + k0 + lc);
      sA[lc + 0][lr + 32 * rr] = v.x;
      sA[lc + 1][lr + 32 * rr] = v.y;
      sA[lc + 2][lr + 32 * rr] = v.z;
      sA[lc + 3][lr + 32 * rr] = v.w;
    }
#pragma unroll
    for (int rr = 0; rr < 2; ++rr) {
      const float4 v = *(const float4*)(W + (size_t)(col0 + lr + 32 * rr) * D_DIM + k0 + lc);
      sB[lc + 0][lr + 32 * rr] = v.x;
      sB[lc + 1][lr + 32 * rr] = v.y;
      sB[lc + 2][lr + 32 * rr] = v.z;
      sB[lc + 3][lr + 32 * rr] = v.w;
    }
    __syncthreads();
#pragma unroll
    for (int kk = 0; kk < BK; ++kk) {
      const float4 A0 = *(const float4*)&sA[kk][ty * 4];
      const float4 A1 = *(const float4*)&sA[kk][64 + ty * 4];
      const float4 Bv = *(const float4*)&sB[kk][tx * 4];
      const double a0[4] = {A0.x, A0.y, A0.z, A0.w};
      const double a1[4] = {A1.x, A1.y, A1.z, A1.w};
      const double bb[4] = {Bv.x, Bv.y, Bv.z, Bv.w};
#pragma unroll
      for (int i = 0; i < 4; ++i)
#pragma unroll
        for (int j = 0; j < 4; ++j) {
          acc[0][i][j] = fma(a0[i], bb[j], acc[0][i][j]);
          acc[1][i][j] = fma(a1[i], bb[j], acc[1][i][j]);
        }
    }
    __syncthreads();
  }
  const float4 bv4 = *(const float4*)(bias + col0 + tx * 4);
  const double bb[4] = {bv4.x, bv4.y, bv4.z, bv4.w};
#pragma unroll
  for (int g = 0; g < 2; ++g)
#pragma unroll
    for (int i = 0; i < 4; ++i) {
      double o[4];
#pragma unroll
      for (int j = 0; j < 4; ++j) o[j] = acc[g][i][j] + bb[j];
      const size_t base = (size_t)(row0 + g * 64 + ty * 4 + i) * D_DIM + col0 + tx * 4;
      *(double2*)(out64 + base)     = (double2){o[0], o[1]};
      *(double2*)(out64 + base + 2) = (double2){o[2], o[3]};
      ushort4 ob;
      ob.x = f32_to_bf16((float)o[0]);
      ob.y = f32_to_bf16((float)o[1]);
      ob.z = f32_to_bf16((float)o[2]);
      ob.w = f32_to_bf16((float)o[3]);
      *(ushort4*)(outbf + base) = ob;
    }
}

// ---------------------------------------------------------------------------
// qbk[b] = dot_f64(q64[b,:], bk). One wave per row.
// ---------------------------------------------------------------------------
__global__ __launch_bounds__(256) void qbk_dot(
    const double* __restrict__ Q64, const float* __restrict__ bk_,
    double* __restrict__ qbk)
{
  const int b = blockIdx.x * 4 + (threadIdx.x >> 6);
  const int lane = threadIdx.x & 63;
  const double* qrow = Q64 + (size_t)b * D_DIM + lane * 16;
  const float* bkrow = bk_ + lane * 16;
  double acc = 0.0;
#pragma unroll
  for (int i = 0; i < 4; ++i) {
    const float4 bv = *(const float4*)(bkrow + i * 4);
    const double2 qa = *(const double2*)(qrow + i * 4);
    const double2 qb2 = *(const double2*)(qrow + i * 4 + 2);
    acc = fma(qa.x, (double)bv.x, acc);
    acc = fma(qa.y, (double)bv.y, acc);
    acc = fma(qb2.x, (double)bv.z, acc);
    acc = fma(qb2.y, (double)bv.w, acc);
  }
#pragma unroll
  for (int off = 32; off > 0; off >>= 1) acc += __shfl_down(acc, off);
  if (lane == 0) qbk[b] = acc;
}

// ---------------------------------------------------------------------------
// u = q64 @ Wk (NN, f64): u[b,d] = sum_n q64[b,n]*Wk[n,d]. Replaces the f64
// K-projection (8x less f64 work). A staged linear [BM][BK+1] (2-way store
// banks, broadcast reads); B staged [BK][BN+4] from row-major Wk (coalesced).
// Inner loop body identical to the proven f64 kernel.
// ---------------------------------------------------------------------------
__global__ __launch_bounds__(256) void uproj_f64(
    const double* __restrict__ A, const float* __restrict__ Bw,
    double* __restrict__ U)
{
  __shared__ double sAd[BM][BK + 1];   // 33.0 KB
  __shared__ float sBf[BK][BN + 4];    // 8.7 KB
  const int tid = threadIdx.x;
  const int tx = tid & 15, ty = tid >> 4;
  const int row0 = blockIdx.x * BM;
  const int col0 = blockIdx.y * BN;

  double acc[2][4][4];
#pragma unroll
  for (int g = 0; g < 2; ++g)
#pragma unroll
    for (int i = 0; i < 4; ++i)
#pragma unroll
      for (int j = 0; j < 4; ++j) acc[g][i][j] = 0.0;

  for (int k0 = 0; k0 < D_DIM; k0 += BK) {
#pragma unroll
    for (int it = 0; it < 8; ++it) {
      const int L = it * 256 + tid;
      const int row = L >> 4, kp = (L & 15) * 2;
      const double2 d2 = *(const double2*)(A + (size_t)(row0 + row) * D_DIM + k0 + kp);
      sAd[row][kp] = d2.x;
      sAd[row][kp + 1] = d2.y;
    }
#pragma unroll
    for (int it = 0; it < 2; ++it) {
      const int L = it * 256 + tid;
      const int kk = L >> 4, j4 = (L & 15) * 4;
      const float4 v = *(const float4*)(Bw + (size_t)(k0 + kk) * D_DIM + col0 + j4);
      sBf[kk][j4 + 0] = v.x;
      sBf[kk][j4 + 1] = v.y;
      sBf[kk][j4 + 2] = v.z;
      sBf[kk][j4 + 3] = v.w;
    }
    __syncthreads();
#pragma unroll
    for (int kk = 0; kk < BK; ++kk) {
      const double a0[4] = {sAd[ty * 4 + 0][kk], sAd[ty * 4 + 1][kk],
                            sAd[ty * 4 + 2][kk], sAd[ty * 4 + 3][kk]};
      const double a1[4] = {sAd[64 + ty * 4 + 0][kk], sAd[64 + ty * 4 + 1][kk],
                            sAd[64 + ty * 4 + 2][kk], sAd[64 + ty * 4 + 3][kk]};
      const float4 Bv = *(const float4*)&sBf[kk][tx * 4];
      const double bb[4] = {Bv.x, Bv.y, Bv.z, Bv.w};
#pragma unroll
      for (int i = 0; i < 4; ++i)
#pragma unroll
        for (int j = 0; j < 4; ++j) {
          acc[0][i][j] = fma(a0[i], bb[j], acc[0][i][j]);
          acc[1][i][j] = fma(a1[i], bb[j], acc[1][i][j]);
        }
    }
    __syncthreads();
  }
#pragma unroll
  for (int g = 0; g < 2; ++g)
#pragma unroll
    for (int i = 0; i < 4; ++i) {
      const size_t base = (size_t)(row0 + g * 64 + ty * 4 + i) * D_DIM + col0 + tx * 4;
      *(double2*)(U + base)     = (double2){acc[g][i][0], acc[g][i][1]};
      *(double2*)(U + base + 2) = (double2){acc[g][i][2], acc[g][i][3]};
    }
}

// ---------------------------------------------------------------------------
// Fused sims + per-block top-8 (round-8-proven, unchanged).
// ---------------------------------------------------------------------------
#define CSTR 132
__global__ __launch_bounds__(256) void sims_topc_gemm(
    const unsigned short* __restrict__ A, const unsigned short* __restrict__ B,
    float* __restrict__ part_v, int* __restrict__ part_i)
{
  __shared__ unsigned short sA[128 * 32];   // 8 KB
  __shared__ unsigned short sB[128 * 32];   // 8 KB
  __shared__ unsigned short sC[128 * CSTR]; // 33.8 KB

  const int tid = threadIdx.x;
  const int lane = tid & 63;
  const int wave = tid >> 6;
  const int wr = wave >> 1, wc = wave & 1;
  const int row0 = blockIdx.x * 128;
  const int cb = blockIdx.y;
  const int col0 = cb * 128;

  const int st_r = lane >> 2;
  const int st_cb = (lane & 3) * 16;

  f32x4 acc[4][4];
#pragma unroll
  for (int m = 0; m < 4; ++m)
#pragma unroll
    for (int n = 0; n < 4; ++n) acc[m][n] = (f32x4){0.f, 0.f, 0.f, 0.f};

  for (int k0 = 0; k0 < D_DIM; k0 += 32) {
#pragma unroll
    for (int i = 0; i < 2; ++i) {
      const int seg = wave * 2 + i;
      const int rr = seg * 16 + st_r;
      async_copy16((char*)sA + seg * 1024,
                   (const char*)(A + (size_t)(row0 + rr) * D_DIM + k0) + st_cb);
      async_copy16((char*)sB + seg * 1024,
                   (const char*)(B + (size_t)(col0 + rr) * D_DIM + k0) + st_cb);
    }
    __syncthreads();
    bf16x8 af[4], bfr[4];
#pragma unroll
    for (int m = 0; m < 4; ++m)
      af[m] = *(const bf16x8*)(sA + (wr * 64 + m * 16 + (lane & 15)) * 32 + (lane >> 4) * 8);
#pragma unroll
    for (int n = 0; n < 4; ++n)
      bfr[n] = *(const bf16x8*)(sB + (wc * 64 + n * 16 + (lane & 15)) * 32 + (lane >> 4) * 8);
#pragma unroll
    for (int m = 0; m < 4; ++m)
#pragma unroll
      for (int n = 0; n < 4; ++n)
        acc[m][n] = __builtin_amdgcn_mfma_f32_16x16x32_bf16(af[m], bfr[n], acc[m][n], 0, 0, 0);
    __syncthreads();
  }

#pragma unroll
  for (int m = 0; m < 4; ++m)
#pragma unroll
    for (int n = 0; n < 4; ++n)
#pragma unroll
      for (int r = 0; r < 4; ++r) {
        const int row = wr * 64 + m * 16 + (lane >> 4) * 4 + r;
        const int col = wc * 64 + n * 16 + (lane & 15);
        sC[row * CSTR + col] = f32_to_bf16(acc[m][n][r]);
      }
  __syncthreads();

  if (tid < 128) {
    float tv[TOPB];
    int ti_[TOPB];
#pragma unroll
    for (int p = 0; p < TOPB; ++p) { tv[p] = -INFINITY; ti_[p] = 0; }
    const unsigned short* crow = sC + tid * CSTR;
    for (int j = 0; j < 128; j += 4) {
      const ushort4 c4 = *(const ushort4*)(crow + j);
      insN<TOPB>(bf16_to_f32(c4.x), col0 + j + 0, tv, ti_);
      insN<TOPB>(bf16_to_f32(c4.y), col0 + j + 1, tv, ti_);
      insN<TOPB>(bf16_to_f32(c4.z), col0 + j + 2, tv, ti_);
      insN<TOPB>(bf16_to_f32(c4.w), col0 + j + 3, tv, ti_);
    }
    const size_t base = ((size_t)(row0 + tid) * NCB + cb) * TOPB;
    *(float4*)(part_v + base)     = (float4){tv[0], tv[1], tv[2], tv[3]};
    *(float4*)(part_v + base + 4) = (float4){tv[4], tv[5], tv[6], tv[7]};
    *(int4*)(part_i + base)       = (int4){ti_[0], ti_[1], ti_[2], ti_[3]};
    *(int4*)(part_i + base + 4)   = (int4){ti_[4], ti_[5], ti_[6], ti_[7]};
  }
}

// ---------------------------------------------------------------------------
// Merge 256 per-block top-8 lists per row -> 16 candidates (round-8-proven).
// ---------------------------------------------------------------------------
__global__ __launch_bounds__(256) void merge_cand256(
    const float* __restrict__ part_v, const int* __restrict__ part_i,
    int* __restrict__ cand)
{
  const int r = blockIdx.x;
  const int tid = threadIdx.x;

  __shared__ float lv[256][TOPB];
  __shared__ int li[256][TOPB];

  {
    const size_t base = ((size_t)r * NCB + tid) * TOPB;
    const float4 a0 = *(const float4*)(part_v + base);
    const float4 a1 = *(const float4*)(part_v + base + 4);
    const int4 b0 = *(const int4*)(part_i + base);
    const int4 b1 = *(const int4*)(part_i + base + 4);
    lv[tid][0] = a0.x; lv[tid][1] = a0.y; lv[tid][2] = a0.z; lv[tid][3] = a0.w;
    lv[tid][4] = a1.x; lv[tid][5] = a1.y; lv[tid][6] = a1.z; lv[tid][7] = a1.w;
    li[tid][0] = b0.x; li[tid][1] = b0.y; li[tid][2] = b0.z; li[tid][3] = b0.w;
    li[tid][4] = b1.x; li[tid][5] = b1.y; li[tid][6] = b1.z; li[tid][7] = b1.w;
  }
  __syncthreads();

  __shared__ float mv16[16][TOPC];
  __shared__ int mi16[16][TOPC];
  if (tid < 16) {
    float mv[TOPC];
    int mi[TOPC];
#pragma unroll
    for (int p = 0; p < TOPC; ++p) { mv[p] = -INFINITY; mi[p] = 0; }
    for (int s = tid * 16; s < tid * 16 + 16; ++s)
      for (int p0 = 0; p0 < TOPB; ++p0) insN<TOPC>(lv[s][p0], li[s][p0], mv, mi);
#pragma unroll
    for (int p = 0; p < TOPC; ++p) { mv16[tid][p] = mv[p]; mi16[tid][p] = mi[p]; }
  }
  __syncthreads();

  if (tid == 0) {
    float mv[TOPC];
    int mi[TOPC];
#pragma unroll
    for (int p = 0; p < TOPC; ++p) { mv[p] = -INFINITY; mi[p] = 0; }
    for (int s = 0; s < 16; ++s)
      for (int p0 = 0; p0 < TOPC; ++p0) insN<TOPC>(mv16[s][p0], mi16[s][p0], mv, mi);
#pragma unroll
    for (int p = 0; p < TOPC; ++p)
      cand[(size_t)r * TOPC + p] = mi[p];
  }
}

// ---------------------------------------------------------------------------
// fp64 rescore via u: sims_ci = dot_f64(u_b, mem_ci) + qbk_b. Stable top-8
// selection (value desc, index asc) — thread-0 logic identical to proven.
// ---------------------------------------------------------------------------
__global__ __launch_bounds__(256) void rescore_topk_u(
    const double* __restrict__ U, const double* __restrict__ qbk,
    const float* __restrict__ mem, const int* __restrict__ cand,
    int* __restrict__ topi)
{
  const int b = blockIdx.x;
  const int tid = threadIdx.x;
  const int wave = tid >> 6;
  const int lane = tid & 63;

  __shared__ double sval[TOPC];
  __shared__ int sidx[TOPC];

  const double* urow = U + (size_t)b * D_DIM + lane * 16;
  double uv[16];
#pragma unroll
  for (int i = 0; i < 8; ++i) {
    const double2 d2 = *(const double2*)(urow + i * 2);
    uv[i * 2] = d2.x;
    uv[i * 2 + 1] = d2.y;
  }
  const double qb = qbk[b];

  for (int c = wave; c < TOPC; c += 4) {
    const int ci = cand[(size_t)b * TOPC + c];
    const float* mrow = mem + (size_t)ci * D_DIM + lane * 16;
    double acc = 0.0;
#pragma unroll
    for (int i = 0; i < 4; ++i) {
      const float4 mv = *(const float4*)(mrow + i * 4);
      acc = fma(uv[i * 4 + 0], (double)mv.x, acc);
      acc = fma(uv[i * 4 + 1], (double)mv.y, acc);
      acc = fma(uv[i * 4 + 2], (double)mv.z, acc);
      acc = fma(uv[i * 4 + 3], (double)mv.w, acc);
    }
#pragma unroll
    for (int off = 32; off > 0; off >>= 1) acc += __shfl_down(acc, off);
    if (lane == 0) { sval[c] = acc + qb; sidx[c] = ci; }
  }
  __syncthreads();

  if (tid == 0) {
    bool used[TOPC];
#pragma unroll
    for (int p = 0; p < TOPC; ++p) used[p] = false;
#pragma unroll
    for (int p = 0; p < TOPK; ++p) {
      int best = -1;
      double bv = 0.0;
      int bi = 0;
      for (int c = 0; c < TOPC; ++c) {
        if (used[c]) continue;
        const double v = sval[c];
        const int ix = sidx[c];
        if (best < 0 || v > bv || (v == bv && ix < bi)) { best = c; bv = v; bi = ix; }
      }
      used[best] = true;
      topi[(size_t)b * TOPK + p] = bi;
    }
  }
}

// ---------------------------------------------------------------------------
// f32 -> bf16 cast (vectorized).
// ---------------------------------------------------------------------------
__global__ __launch_bounds__(256) void cast_f32_bf16(
    const float* __restrict__ src, unsigned short* __restrict__ dst, int n4)
{
  const int i = blockIdx.x * 256 + threadIdx.x;
  if (i >= n4) return;
  const float4 v = *(const float4*)(src + (size_t)i * 4);
  ushort4 o;
  o.x = f32_to_bf16(v.x);
  o.y = f32_to_bf16(v.y);
  o.z = f32_to_bf16(v.z);
  o.w = f32_to_bf16(v.w);
  *(ushort4*)(dst + (size_t)i * 4) = o;
}

// ---------------------------------------------------------------------------
// K projection via bf16 MFMA, bf16 output (candidate path only; margin 50x).
// Structure = proven vproj with bf16 store.
// ---------------------------------------------------------------------------
__global__ __launch_bounds__(256) void kproj_bf16(
    const unsigned short* __restrict__ A,   // mem_bf [M_ROWS][D_DIM]
    const unsigned short* __restrict__ B,   // Wk_bf  [D_DIM][D_DIM]
    const float* __restrict__ bias,
    unsigned short* __restrict__ C)         // [M_ROWS][D_DIM] bf16
{
  __shared__ unsigned short sA[128 * 32];
  __shared__ unsigned short sB[128 * 32];

  const int tid = threadIdx.x;
  const int lane = tid & 63;
  const int wave = tid >> 6;
  const int wr = wave >> 1, wc = wave & 1;
  const int row0 = blockIdx.x * 128;
  const int col0 = blockIdx.y * 128;

  const int st_r = lane >> 2;
  const int st_cb = (lane & 3) * 16;

  f32x4 acc[4][4];
#pragma unroll
  for (int m = 0; m < 4; ++m)
#pragma unroll
    for (int n = 0; n < 4; ++n) acc[m][n] = (f32x4){0.f, 0.f, 0.f, 0.f};

  for (int k0 = 0; k0 < D_DIM; k0 += 32) {
#pragma unroll
    for (int i = 0; i < 2; ++i) {
      const int seg = wave * 2 + i;
      const int rr = seg * 16 + st_r;
      async_copy16((char*)sA + seg * 1024,
                   (const char*)(A + (size_t)(row0 + rr) * D_DIM + k0) + st_cb);
      async_copy16((char*)sB + seg * 1024,
                   (const char*)(B + (size_t)(col0 + rr) * D_DIM + k0) + st_cb);
    }
    __syncthreads();
    bf16x8 af[4], bfr[4];
#pragma unroll
    for (int m = 0; m < 4; ++m)
      af[m] = *(const bf16x8*)(sA + (wr * 64 + m * 16 + (lane & 15)) * 32 + (lane >> 4) * 8);
#pragma unroll
    for (int n = 0; n < 4; ++n)
      bfr[n] = *(const bf16x8*)(sB + (wc * 64 + n * 16 + (lane & 15)) * 32 + (lane >> 4) * 8);
#pragma unroll
    for (int m = 0; m < 4; ++m)
#pragma unroll
      for (int n = 0; n < 4; ++n)
        acc[m][n] = __builtin_amdgcn_mfma_f32_16x16x32_bf16(af[m], bfr[n], acc[m][n], 0, 0, 0);
    __syncthreads();
  }

#pragma unroll
  for (int n = 0; n < 4; ++n) {
    const int col = col0 + wc * 64 + n * 16 + (lane & 15);
    const float bcol = bias[col];
#pragma unroll
    for (int m = 0; m < 4; ++m)
#pragma unroll
      for (int r = 0; r < 4; ++r) {
        const int row = row0 + wr * 64 + m * 16 + (lane >> 4) * 4 + r;
        C[(size_t)row * D_DIM + col] = f32_to_bf16(acc[m][n][r] + bcol);
      }
  }
}

// ---------------------------------------------------------------------------
// V projection via bf16 MFMA (round-7/8-proven, unchanged).
// ---------------------------------------------------------------------------
__global__ __launch_bounds__(256) void vproj_bf16(
    const unsigned short* __restrict__ A,
    const unsigned short* __restrict__ B,
    const float* __restrict__ bias,
    float* __restrict__ C)
{
  __shared__ unsigned short sA[128 * 32];
  __shared__ unsigned short sB[128 * 32];

  const int tid = threadIdx.x;
  const int lane = tid & 63;
  const int wave = tid >> 6;
  const int wr = wave >> 1, wc = wave & 1;
  const int row0 = blockIdx.x * 128;
  const int col0 = blockIdx.y * 128;

  const int st_r = lane >> 2;
  const int st_cb = (lane & 3) * 16;

  f32x4 acc[4][4];
#pragma unroll
  for (int m = 0; m < 4; ++m)
#pragma unroll
    for (int n = 0; n < 4; ++n) acc[m][n] = (f32x4){0.f, 0.f, 0.f, 0.f};

  for (int k0 = 0; k0 < D_DIM; k0 += 32) {
#pragma unroll
    for (int i = 0; i < 2; ++i) {
      const int seg = wave * 2 + i;
      const int rr = seg * 16 + st_r;
      async_copy16((char*)sA + seg * 1024,
                   (const char*)(A + (size_t)(row0 + rr) * D_DIM + k0) + st_cb);
      async_copy16((char*)sB + seg * 1024,
                   (const char*)(B + (size_t)(col0 + rr) * D_DIM + k0) + st_cb);
    }
    __syncthreads();
    bf16x8 af[4], bfr[4];
#pragma unroll
    for (int m = 0; m < 4; ++m)
      af[m] = *(const bf16x8*)(sA + (wr * 64 + m * 16 + (lane & 15)) * 32 + (lane >> 4) * 8);
#pragma unroll
    for (int n = 0; n < 4; ++n)
      bfr[n] = *(const bf16x8*)(sB + (wc * 64 + n * 16 + (lane & 15)) * 32 + (lane >> 4) * 8);
#pragma unroll
    for (int m = 0; m < 4; ++m)
#pragma unroll
      for (int n = 0; n < 4; ++n)
        acc[m][n] = __builtin_amdgcn_mfma_f32_16x16x32_bf16(af[m], bfr[n], acc[m][n], 0, 0, 0);
    __syncthreads();
  }

#pragma unroll
  for (int n = 0; n < 4; ++n) {
    const int col = col0 + wc * 64 + n * 16 + (lane & 15);
    const float bcol = bias[col];
#pragma unroll
    for (int m = 0; m < 4; ++m)
#pragma unroll
      for (int r = 0; r < 4; ++r) {
        const int row = row0 + wr * 64 + m * 16 + (lane >> 4) * 4 + r;
        C[(size_t)row * D_DIM + col] = acc[m][n][r] + bcol;
      }
  }
}

// ---------------------------------------------------------------------------
// Gather selected V rows + LayerNorm (unchanged).
// ---------------------------------------------------------------------------
__global__ __launch_bounds__(256) void gather_ln(
    const float* __restrict__ V, const int* __restrict__ topi,
    const float* __restrict__ gamma, const float* __restrict__ beta,
    float* __restrict__ out)
{
  const int row = blockIdx.x;
  const int tid = threadIdx.x;
  const int idx = topi[row];
  const float* src = V + (size_t)idx * D_DIM;
  const float4 v = *(const float4*)(src + tid * 4);
  float s = v.x + v.y + v.z + v.w;
  float s2 = v.x * v.x + v.y * v.y + v.z * v.z + v.w * v.w;
#pragma unroll
  for (int off = 32; off > 0; off >>= 1) {
    s += __shfl_down(s, off);
    s2 += __shfl_down(s2, off);
  }
  __shared__ float red[8];
  __shared__ float stats[2];
  const int wid = tid >> 6;
  if ((tid & 63) == 0) { red[wid] = s; red[4 + wid] = s2; }
  __syncthreads();
  if (tid == 0) {
    const float S = red[0] + red[1] + red[2] + red[3];
    const float S2 = red[4] + red[5] + red[6] + red[7];
    const float mu = S * (1.0f / D_DIM);
    const float var = S2 * (1.0f / D_DIM) - mu * mu;
    stats[0] = mu;
    stats[1] = rsqrtf(var + 1e-5f);
  }
  __syncthreads();
  const float mu = stats[0], rstd = stats[1];
  const float4 g4 = *(const float4*)(gamma + tid * 4);
  const float4 b4 = *(const float4*)(beta + tid * 4);
  float4 o;
  o.x = (v.x - mu) * rstd * g4.x + b4.x;
  o.y = (v.y - mu) * rstd * g4.y + b4.y;
  o.z = (v.z - mu) * rstd * g4.z + b4.z;
  o.w = (v.w - mu) * rstd * g4.w + b4.w;
  *(float4*)(out + (size_t)row * D_DIM + tid * 4) = o;
}

extern "C" void kernel_launch(void* const* d_in, const int* in_sizes, int n_in,
                              void* d_out, int out_size, void* d_ws, size_t ws_size,
                              hipStream_t stream)
{
  const float* query = (const float*)d_in[0];
  const float* mem   = (const float*)d_in[1];
  const float* Wq    = (const float*)d_in[2];
  const float* bq    = (const float*)d_in[3];
  const float* Wk    = (const float*)d_in[4];
  const float* bk    = (const float*)d_in[5];
  const float* Wv    = (const float*)d_in[6];
  const float* bv    = (const float*)d_in[7];
  const float* gamma = (const float*)d_in[8];
  const float* beta  = (const float*)d_in[9];
  float* out = (float*)d_out;

  char* ws = (char*)d_ws;
  double* q64 = (double*)ws;   ws += (size_t)B_ROWS * D_DIM * sizeof(double);   // 33.6 MB
  double* u64 = (double*)ws;   ws += (size_t)B_ROWS * D_DIM * sizeof(double);   // 33.6 MB
  unsigned short* qbf = (unsigned short*)ws;
  ws += (size_t)B_ROWS * D_DIM * sizeof(unsigned short);                        // 8.4 MB
  unsigned short* membf = (unsigned short*)ws;
  ws += (size_t)M_ROWS * D_DIM * sizeof(unsigned short);                        // 67.1 MB
  char* Aregion = ws;
  ws += (size_t)M_ROWS * D_DIM * sizeof(unsigned short)                         // Kbf 67.1
      + 2 * (size_t)B_ROWS * NCB * TOPB * sizeof(float);                        // parts 67.1
  double* qbk = (double*)ws;   ws += (size_t)B_ROWS * sizeof(double);
  int* cand = (int*)ws;        ws += (size_t)B_ROWS * TOPC * sizeof(int);
  int* topi = (int*)ws;

  // Lifetimes (in-order stream):
  //  q64: dead after qbk+uproj -> hosts wkbf/wvbf casts.
  //  Aregion: Kbf+parts until merge; then Vout (exactly 134.2 MB) overlays.
  unsigned short* Kbf = (unsigned short*)Aregion;
  float* part_v = (float*)(Aregion + (size_t)M_ROWS * D_DIM * sizeof(unsigned short));
  int* part_i = (int*)((char*)part_v + (size_t)B_ROWS * NCB * TOPB * sizeof(float));
  unsigned short* wkbf = (unsigned short*)q64;
  unsigned short* wvbf = wkbf + (size_t)D_DIM * D_DIM;
  float* Vout = (float*)Aregion;

  qproj_f64<<<dim3(B_ROWS / BM, D_DIM / BN), 256, 0, stream>>>(query, Wq, bq, q64, qbf);
  qbk_dot<<<dim3(B_ROWS / 4), 256, 0, stream>>>(q64, bk, qbk);
  uproj_f64<<<dim3(B_ROWS / BM, D_DIM / BN), 256, 0, stream>>>(q64, Wk, u64);

  // q64 now dead -> casts may overwrite it.
  cast_f32_bf16<<<dim3((M_ROWS * D_DIM / 4 + 255) / 256), 256, 0, stream>>>(mem, membf, M_ROWS * D_DIM / 4);
  cast_f32_bf16<<<dim3((D_DIM * D_DIM / 4 + 255) / 256), 256, 0, stream>>>(Wk, wkbf, D_DIM * D_DIM / 4);
  cast_f32_bf16<<<dim3((D_DIM * D_DIM / 4 + 255) / 256), 256, 0, stream>>>(Wv, wvbf, D_DIM * D_DIM / 4);

  kproj_bf16<<<dim3(M_ROWS / 128, D_DIM / 128), 256, 0, stream>>>(membf, wkbf, bk, Kbf);
  sims_topc_gemm<<<dim3(B_ROWS / 128, NCB), 256, 0, stream>>>(qbf, Kbf, part_v, part_i);
  merge_cand256<<<dim3(B_ROWS), 256, 0, stream>>>(part_v, part_i, cand);
  rescore_topk_u<<<dim3(B_ROWS), 256, 0, stream>>>(u64, qbk, mem, cand, topi);

  vproj_bf16<<<dim3(M_ROWS / 128, D_DIM / 128), 256, 0, stream>>>(membf, wvbf, bv, Vout);
  gather_ln<<<dim3(B_ROWS * TOPK), 256, 0, stream>>>(Vout, topi, gamma, beta, out);
}

// Round 11
// 2456.063 us; speedup vs baseline: 3.2614x; 1.0171x over previous
//
#include <hip/hip_runtime.h>
#include <hip/hip_bf16.h>
#include <math.h>

#define D_DIM 1024
#define B_ROWS 4096
#define M_ROWS 32768
#define TOPK 8
#define TOPC 16                // candidates per row after merge
#define TOPB 8                 // entries stored per (row, col-block): 2 halves x top-4
#define NCB (M_ROWS / 128)     // 256 col-blocks

#define BM 128
#define BN 64
#define BK 32

typedef __attribute__((ext_vector_type(8))) short bf16x8;
typedef __attribute__((ext_vector_type(4))) float f32x4;

__device__ __forceinline__ unsigned short f32_to_bf16(float f) {
  unsigned int u = __float_as_uint(f);
  unsigned int r = (u + 0x7FFFu + ((u >> 16) & 1u)) >> 16;
  return (unsigned short)r;
}
__device__ __forceinline__ float bf16_to_f32(unsigned short h) {
  return __uint_as_float(((unsigned int)h) << 16);
}
__device__ __forceinline__ void async_copy16(void* lds, const void* g) {
  __builtin_amdgcn_global_load_lds(
      (const __attribute__((address_space(1))) unsigned int*)g,
      (__attribute__((address_space(3))) unsigned int*)lds, 16, 0, 0);
}

// Ordered insert into a register top-N list sorted by (value desc, index asc).
template <int N>
__device__ __forceinline__ void insN(float v, int idx,
                                     float* __restrict__ tv,
                                     int* __restrict__ ti) {
  if (v < tv[N - 1]) return;
  if (v == tv[N - 1] && idx > ti[N - 1]) return;
  float cv = v;
  int ci = idx;
#pragma unroll
  for (int p = 0; p < N; ++p) {
    if (cv > tv[p] || (cv == tv[p] && ci < ti[p])) {
      const float t0 = tv[p]; tv[p] = cv; cv = t0;
      const int t1 = ti[p]; ti[p] = ci; ci = t1;
    }
  }
}

// ---------------------------------------------------------------------------
// q projection: q64[b,n] = sum_e query[b,e]*Wq[n,e] + bq[n], f64 accumulation
// (selection chain). Emits f64 q (for uproj/qbk) + bf16 q (candidate GEMM).
// ---------------------------------------------------------------------------
__global__ __launch_bounds__(256) void qproj_f64(
    const float* __restrict__ X, const float* __restrict__ W,
    const float* __restrict__ bias, double* __restrict__ out64,
    unsigned short* __restrict__ outbf)
{
  __shared__ float sA[BK][BM + 4];
  __shared__ float sB[BK][BN + 4];
  const int tid = threadIdx.x;
  const int tx = tid & 15, ty = tid >> 4;
  const int row0 = blockIdx.x * BM;
  const int col0 = blockIdx.y * BN;
  const int lr = tid >> 3;         // 0..31
  const int lc = (tid & 7) << 2;   // 0,4,...,28

  double acc[2][4][4];
#pragma unroll
  for (int g = 0; g < 2; ++g)
#pragma unroll
    for (int i = 0; i < 4; ++i)
#pragma unroll
      for (int j = 0; j < 4; ++j) acc[g][i][j] = 0.0;

  for (int k0 = 0; k0 < D_DIM; k0 += BK) {
#pragma unroll
    for (int rr = 0; rr < 4; ++rr) {
      const float4 v = *(const float4*)(X + (size_t)(row0 + lr + 32 * rr) * D_DIM + k0 + lc);
      sA[lc + 0][lr + 32 * rr] = v.x;
      sA[lc + 1][lr + 32 * rr] = v.y;
      sA[lc + 2][lr + 32 * rr] = v.z;
      sA[lc + 3][lr + 32 * rr] = v.w;
    }
#pragma unroll
    for (int rr = 0; rr < 2; ++rr) {
      const float4 v = *(const float4*)(W + (size_t)(col0 + lr + 32 * rr) * D_DIM + k0 + lc);
      sB[lc + 0][lr + 32 * rr] = v.x;
      sB[lc + 1][lr + 32 * rr] = v.y;
      sB[lc + 2][lr + 32 * rr] = v.z;
      sB[lc + 3][lr + 32 * rr] = v.w;
    }
    __syncthreads();
#pragma unroll
    for (int kk = 0; kk < BK; ++kk) {
      const float4 A0 = *(const float4*)&sA[kk][ty * 4];
      const float4 A1 = *(const float4*)&sA[kk][64 + ty * 4];
      const float4 Bv = *(const float4*)&sB[kk][tx * 4];
      const double a0[4] = {A0.x, A0.y, A0.z, A0.w};
      const double a1[4] = {A1.x, A1.y, A1.z, A1.w};
      const double bb[4] = {Bv.x, Bv.y, Bv.z, Bv.w};
#pragma unroll
      for (int i = 0; i < 4; ++i)
#pragma unroll
        for (int j = 0; j < 4; ++j) {
          acc[0][i][j] = fma(a0[i], bb[j], acc[0][i][j]);
          acc[1][i][j] = fma(a1[i], bb[j], acc[1][i][j]);
        }
    }
    __syncthreads();
  }
  const float4 bv4 = *(const float4*)(bias + col0 + tx * 4);
  const double bb[4] = {bv4.x, bv4.y, bv4.z, bv4.w};
#pragma unroll
  for (int g = 0; g < 2; ++g)
#pragma unroll
    for (int i = 0; i < 4; ++i) {
      double o[4];
#pragma unroll
      for (int j = 0; j < 4; ++j) o[j] = acc[g][i][j] + bb[j];
      const size_t base = (size_t)(row0 + g * 64 + ty * 4 + i) * D_DIM + col0 + tx * 4;
      *(double2*)(out64 + base)     = (double2){o[0], o[1]};
      *(double2*)(out64 + base + 2) = (double2){o[2], o[3]};
      ushort4 ob;
      ob.x = f32_to_bf16((float)o[0]);
      ob.y = f32_to_bf16((float)o[1]);
      ob.z = f32_to_bf16((float)o[2]);
      ob.w = f32_to_bf16((float)o[3]);
      *(ushort4*)(outbf + base) = ob;
    }
}

// ---------------------------------------------------------------------------
// qbk[b] = dot_f64(q64[b,:], bk). One wave per row.
// ---------------------------------------------------------------------------
__global__ __launch_bounds__(256) void qbk_dot(
    const double* __restrict__ Q64, const float* __restrict__ bk_,
    double* __restrict__ qbk)
{
  const int b = blockIdx.x * 4 + (threadIdx.x >> 6);
  const int lane = threadIdx.x & 63;
  const double* qrow = Q64 + (size_t)b * D_DIM + lane * 16;
  const float* bkrow = bk_ + lane * 16;
  double acc = 0.0;
#pragma unroll
  for (int i = 0; i < 4; ++i) {
    const float4 bv = *(const float4*)(bkrow + i * 4);
    const double2 qa = *(const double2*)(qrow + i * 4);
    const double2 qb2 = *(const double2*)(qrow + i * 4 + 2);
    acc = fma(qa.x, (double)bv.x, acc);
    acc = fma(qa.y, (double)bv.y, acc);
    acc = fma(qb2.x, (double)bv.z, acc);
    acc = fma(qb2.y, (double)bv.w, acc);
  }
#pragma unroll
  for (int off = 32; off > 0; off >>= 1) acc += __shfl_down(acc, off);
  if (lane == 0) qbk[b] = acc;
}

// ---------------------------------------------------------------------------
// u = q64 @ Wk (NN, f64): u[b,d] = sum_n q64[b,n]*Wk[n,d]. (round-10-proven)
// ---------------------------------------------------------------------------
__global__ __launch_bounds__(256) void uproj_f64(
    const double* __restrict__ A, const float* __restrict__ Bw,
    double* __restrict__ U)
{
  __shared__ double sAd[BM][BK + 1];   // 33.0 KB
  __shared__ float sBf[BK][BN + 4];    // 8.7 KB
  const int tid = threadIdx.x;
  const int tx = tid & 15, ty = tid >> 4;
  const int row0 = blockIdx.x * BM;
  const int col0 = blockIdx.y * BN;

  double acc[2][4][4];
#pragma unroll
  for (int g = 0; g < 2; ++g)
#pragma unroll
    for (int i = 0; i < 4; ++i)
#pragma unroll
      for (int j = 0; j < 4; ++j) acc[g][i][j] = 0.0;

  for (int k0 = 0; k0 < D_DIM; k0 += BK) {
#pragma unroll
    for (int it = 0; it < 8; ++it) {
      const int L = it * 256 + tid;
      const int row = L >> 4, kp = (L & 15) * 2;
      const double2 d2 = *(const double2*)(A + (size_t)(row0 + row) * D_DIM + k0 + kp);
      sAd[row][kp] = d2.x;
      sAd[row][kp + 1] = d2.y;
    }
#pragma unroll
    for (int it = 0; it < 2; ++it) {
      const int L = it * 256 + tid;
      const int kk = L >> 4, j4 = (L & 15) * 4;
      const float4 v = *(const float4*)(Bw + (size_t)(k0 + kk) * D_DIM + col0 + j4);
      sBf[kk][j4 + 0] = v.x;
      sBf[kk][j4 + 1] = v.y;
      sBf[kk][j4 + 2] = v.z;
      sBf[kk][j4 + 3] = v.w;
    }
    __syncthreads();
#pragma unroll
    for (int kk = 0; kk < BK; ++kk) {
      const double a0[4] = {sAd[ty * 4 + 0][kk], sAd[ty * 4 + 1][kk],
                            sAd[ty * 4 + 2][kk], sAd[ty * 4 + 3][kk]};
      const double a1[4] = {sAd[64 + ty * 4 + 0][kk], sAd[64 + ty * 4 + 1][kk],
                            sAd[64 + ty * 4 + 2][kk], sAd[64 + ty * 4 + 3][kk]};
      const float4 Bv = *(const float4*)&sBf[kk][tx * 4];
      const double bb[4] = {Bv.x, Bv.y, Bv.z, Bv.w};
#pragma unroll
      for (int i = 0; i < 4; ++i)
#pragma unroll
        for (int j = 0; j < 4; ++j) {
          acc[0][i][j] = fma(a0[i], bb[j], acc[0][i][j]);
          acc[1][i][j] = fma(a1[i], bb[j], acc[1][i][j]);
        }
    }
    __syncthreads();
  }
#pragma unroll
  for (int g = 0; g < 2; ++g)
#pragma unroll
    for (int i = 0; i < 4; ++i) {
      const size_t base = (size_t)(row0 + g * 64 + ty * 4 + i) * D_DIM + col0 + tx * 4;
      *(double2*)(U + base)     = (double2){acc[g][i][0], acc[g][i][1]};
      *(double2*)(U + base + 2) = (double2){acc[g][i][2], acc[g][i][3]};
    }
}

// ---------------------------------------------------------------------------
// Fused sims + per-half top-4. Changes vs round 10 (latency-bound fix):
//  (a) XCD-chunked block swizzle: XCD x runs cbs [32x,32x+32) consecutively
//      -> each 256KB B-panel L2-resident on one XCD.
//  (b) LDS union: sC half-tile (128x68) reuses the sA/sB region after the
//      K-loop -> 17.4 KB total -> VGPR-limited ~5 blocks/CU (was 3).
//  (c) Epilogue: two half-passes; 128 threads scan 64 cols each with
//      insN<4> (top-4 per 64-col half; union still covers true top-8:
//      P(>=5 of top-8 in one 64-col window) ~ 3.5e-6 across all rows).
//      parts layout unchanged ([row][cb][8]); merge is comparator-over-all.
// K-loop byte-identical to rounds 5-10.
// ---------------------------------------------------------------------------
__global__ __launch_bounds__(256) void sims_topc_gemm(
    const unsigned short* __restrict__ A, const unsigned short* __restrict__ B,
    float* __restrict__ part_v, int* __restrict__ part_i)
{
  __shared__ unsigned short smem[128 * 68];   // 17.4 KB union
  unsigned short* sA = smem;                  // 128*32 during K-loop
  unsigned short* sB = smem + 128 * 32;       // 128*32 during K-loop

  const int tid = threadIdx.x;
  const int lane = tid & 63;
  const int wave = tid >> 6;
  const int wr = wave >> 1, wc = wave & 1;

  // XCD-chunked swizzle (8192 blocks, 8 XCDs, bijective).
  const int bid = blockIdx.x;
  const int orig = (bid & 7) * 1024 + (bid >> 3);
  const int row0 = (orig & 31) * 128;
  const int cb = orig >> 5;
  const int col0 = cb * 128;

  const int st_r = lane >> 2;          // row within 16-row segment
  const int st_cb = (lane & 3) * 16;   // byte offset within 64B row

  f32x4 acc[4][4];
#pragma unroll
  for (int m = 0; m < 4; ++m)
#pragma unroll
    for (int n = 0; n < 4; ++n) acc[m][n] = (f32x4){0.f, 0.f, 0.f, 0.f};

  for (int k0 = 0; k0 < D_DIM; k0 += 32) {
#pragma unroll
    for (int i = 0; i < 2; ++i) {
      const int seg = wave * 2 + i;
      const int rr = seg * 16 + st_r;
      async_copy16((char*)sA + seg * 1024,
                   (const char*)(A + (size_t)(row0 + rr) * D_DIM + k0) + st_cb);
      async_copy16((char*)sB + seg * 1024,
                   (const char*)(B + (size_t)(col0 + rr) * D_DIM + k0) + st_cb);
    }
    __syncthreads();
    bf16x8 af[4], bfr[4];
#pragma unroll
    for (int m = 0; m < 4; ++m)
      af[m] = *(const bf16x8*)(sA + (wr * 64 + m * 16 + (lane & 15)) * 32 + (lane >> 4) * 8);
#pragma unroll
    for (int n = 0; n < 4; ++n)
      bfr[n] = *(const bf16x8*)(sB + (wc * 64 + n * 16 + (lane & 15)) * 32 + (lane >> 4) * 8);
#pragma unroll
    for (int m = 0; m < 4; ++m)
#pragma unroll
      for (int n = 0; n < 4; ++n)
        acc[m][n] = __builtin_amdgcn_mfma_f32_16x16x32_bf16(af[m], bfr[n], acc[m][n], 0, 0, 0);
    __syncthreads();
  }
  // K-loop done (last barrier passed): smem is free for the C half-tiles.

#pragma unroll
  for (int h = 0; h < 2; ++h) {
    if (wc == h) {
      // C/D layout (m89): col=lane&15 (within 16), row=(lane>>4)*4+reg.
#pragma unroll
      for (int m = 0; m < 4; ++m)
#pragma unroll
        for (int n = 0; n < 4; ++n)
#pragma unroll
          for (int r = 0; r < 4; ++r) {
            const int row = wr * 64 + m * 16 + (lane >> 4) * 4 + r;
            const int colL = n * 16 + (lane & 15);
            smem[row * 68 + colL] = f32_to_bf16(acc[m][n][r]);
          }
    }
    __syncthreads();
    if (tid < 128) {
      float tv[4];
      int ti_[4];
#pragma unroll
      for (int p = 0; p < 4; ++p) { tv[p] = -INFINITY; ti_[p] = 0; }
      const unsigned short* crow = smem + tid * 68;
      const int gcol = col0 + h * 64;
      for (int j = 0; j < 64; j += 4) {
        const ushort4 c4 = *(const ushort4*)(crow + j);
        insN<4>(bf16_to_f32(c4.x), gcol + j + 0, tv, ti_);
        insN<4>(bf16_to_f32(c4.y), gcol + j + 1, tv, ti_);
        insN<4>(bf16_to_f32(c4.z), gcol + j + 2, tv, ti_);
        insN<4>(bf16_to_f32(c4.w), gcol + j + 3, tv, ti_);
      }
      const size_t base = ((size_t)(row0 + tid) * NCB + cb) * TOPB + h * 4;
      *(float4*)(part_v + base) = (float4){tv[0], tv[1], tv[2], tv[3]};
      *(int4*)(part_i + base)   = (int4){ti_[0], ti_[1], ti_[2], ti_[3]};
    }
    __syncthreads();
  }
}

// ---------------------------------------------------------------------------
// Merge all per-(row,cb) entries -> 16 candidates (round-8-proven; comparator
// over all 2048 entries, list structure irrelevant).
// ---------------------------------------------------------------------------
__global__ __launch_bounds__(256) void merge_cand256(
    const float* __restrict__ part_v, const int* __restrict__ part_i,
    int* __restrict__ cand)
{
  const int r = blockIdx.x;
  const int tid = threadIdx.x;

  __shared__ float lv[256][TOPB];
  __shared__ int li[256][TOPB];

  {
    const size_t base = ((size_t)r * NCB + tid) * TOPB;
    const float4 a0 = *(const float4*)(part_v + base);
    const float4 a1 = *(const float4*)(part_v + base + 4);
    const int4 b0 = *(const int4*)(part_i + base);
    const int4 b1 = *(const int4*)(part_i + base + 4);
    lv[tid][0] = a0.x; lv[tid][1] = a0.y; lv[tid][2] = a0.z; lv[tid][3] = a0.w;
    lv[tid][4] = a1.x; lv[tid][5] = a1.y; lv[tid][6] = a1.z; lv[tid][7] = a1.w;
    li[tid][0] = b0.x; li[tid][1] = b0.y; li[tid][2] = b0.z; li[tid][3] = b0.w;
    li[tid][4] = b1.x; li[tid][5] = b1.y; li[tid][6] = b1.z; li[tid][7] = b1.w;
  }
  __syncthreads();

  __shared__ float mv16[16][TOPC];
  __shared__ int mi16[16][TOPC];
  if (tid < 16) {
    float mv[TOPC];
    int mi[TOPC];
#pragma unroll
    for (int p = 0; p < TOPC; ++p) { mv[p] = -INFINITY; mi[p] = 0; }
    for (int s = tid * 16; s < tid * 16 + 16; ++s)
      for (int p0 = 0; p0 < TOPB; ++p0) insN<TOPC>(lv[s][p0], li[s][p0], mv, mi);
#pragma unroll
    for (int p = 0; p < TOPC; ++p) { mv16[tid][p] = mv[p]; mi16[tid][p] = mi[p]; }
  }
  __syncthreads();

  if (tid == 0) {
    float mv[TOPC];
    int mi[TOPC];
#pragma unroll
    for (int p = 0; p < TOPC; ++p) { mv[p] = -INFINITY; mi[p] = 0; }
    for (int s = 0; s < 16; ++s)
      for (int p0 = 0; p0 < TOPC; ++p0) insN<TOPC>(mv16[s][p0], mi16[s][p0], mv, mi);
#pragma unroll
    for (int p = 0; p < TOPC; ++p)
      cand[(size_t)r * TOPC + p] = mi[p];
  }
}

// ---------------------------------------------------------------------------
// fp64 rescore via u: sims_ci = dot_f64(u_b, mem_ci) + qbk_b (round-10-proven).
// ---------------------------------------------------------------------------
__global__ __launch_bounds__(256) void rescore_topk_u(
    const double* __restrict__ U, const double* __restrict__ qbk,
    const float* __restrict__ mem, const int* __restrict__ cand,
    int* __restrict__ topi)
{
  const int b = blockIdx.x;
  const int tid = threadIdx.x;
  const int wave = tid >> 6;
  const int lane = tid & 63;

  __shared__ double sval[TOPC];
  __shared__ int sidx[TOPC];

  const double* urow = U + (size_t)b * D_DIM + lane * 16;
  double uv[16];
#pragma unroll
  for (int i = 0; i < 8; ++i) {
    const double2 d2 = *(const double2*)(urow + i * 2);
    uv[i * 2] = d2.x;
    uv[i * 2 + 1] = d2.y;
  }
  const double qb = qbk[b];

  for (int c = wave; c < TOPC; c += 4) {
    const int ci = cand[(size_t)b * TOPC + c];
    const float* mrow = mem + (size_t)ci * D_DIM + lane * 16;
    double acc = 0.0;
#pragma unroll
    for (int i = 0; i < 4; ++i) {
      const float4 mv = *(const float4*)(mrow + i * 4);
      acc = fma(uv[i * 4 + 0], (double)mv.x, acc);
      acc = fma(uv[i * 4 + 1], (double)mv.y, acc);
      acc = fma(uv[i * 4 + 2], (double)mv.z, acc);
      acc = fma(uv[i * 4 + 3], (double)mv.w, acc);
    }
#pragma unroll
    for (int off = 32; off > 0; off >>= 1) acc += __shfl_down(acc, off);
    if (lane == 0) { sval[c] = acc + qb; sidx[c] = ci; }
  }
  __syncthreads();

  if (tid == 0) {
    bool used[TOPC];
#pragma unroll
    for (int p = 0; p < TOPC; ++p) used[p] = false;
#pragma unroll
    for (int p = 0; p < TOPK; ++p) {
      int best = -1;
      double bv = 0.0;
      int bi = 0;
      for (int c = 0; c < TOPC; ++c) {
        if (used[c]) continue;
        const double v = sval[c];
        const int ix = sidx[c];
        if (best < 0 || v > bv || (v == bv && ix < bi)) { best = c; bv = v; bi = ix; }
      }
      used[best] = true;
      topi[(size_t)b * TOPK + p] = bi;
    }
  }
}

// ---------------------------------------------------------------------------
// f32 -> bf16 cast (vectorized).
// ---------------------------------------------------------------------------
__global__ __launch_bounds__(256) void cast_f32_bf16(
    const float* __restrict__ src, unsigned short* __restrict__ dst, int n4)
{
  const int i = blockIdx.x * 256 + threadIdx.x;
  if (i >= n4) return;
  const float4 v = *(const float4*)(src + (size_t)i * 4);
  ushort4 o;
  o.x = f32_to_bf16(v.x);
  o.y = f32_to_bf16(v.y);
  o.z = f32_to_bf16(v.z);
  o.w = f32_to_bf16(v.w);
  *(ushort4*)(dst + (size_t)i * 4) = o;
}

// ---------------------------------------------------------------------------
// K projection via bf16 MFMA, bf16 output (round-10-proven).
// ---------------------------------------------------------------------------
__global__ __launch_bounds__(256) void kproj_bf16(
    const unsigned short* __restrict__ A,   // mem_bf [M_ROWS][D_DIM]
    const unsigned short* __restrict__ B,   // Wk_bf  [D_DIM][D_DIM]
    const float* __restrict__ bias,
    unsigned short* __restrict__ C)         // [M_ROWS][D_DIM] bf16
{
  __shared__ unsigned short sA[128 * 32];
  __shared__ unsigned short sB[128 * 32];

  const int tid = threadIdx.x;
  const int lane = tid & 63;
  const int wave = tid >> 6;
  const int wr = wave >> 1, wc = wave & 1;
  const int row0 = blockIdx.x * 128;
  const int col0 = blockIdx.y * 128;

  const int st_r = lane >> 2;
  const int st_cb = (lane & 3) * 16;

  f32x4 acc[4][4];
#pragma unroll
  for (int m = 0; m < 4; ++m)
#pragma unroll
    for (int n = 0; n < 4; ++n) acc[m][n] = (f32x4){0.f, 0.f, 0.f, 0.f};

  for (int k0 = 0; k0 < D_DIM; k0 += 32) {
#pragma unroll
    for (int i = 0; i < 2; ++i) {
      const int seg = wave * 2 + i;
      const int rr = seg * 16 + st_r;
      async_copy16((char*)sA + seg * 1024,
                   (const char*)(A + (size_t)(row0 + rr) * D_DIM + k0) + st_cb);
      async_copy16((char*)sB + seg * 1024,
                   (const char*)(B + (size_t)(col0 + rr) * D_DIM + k0) + st_cb);
    }
    __syncthreads();
    bf16x8 af[4], bfr[4];
#pragma unroll
    for (int m = 0; m < 4; ++m)
      af[m] = *(const bf16x8*)(sA + (wr * 64 + m * 16 + (lane & 15)) * 32 + (lane >> 4) * 8);
#pragma unroll
    for (int n = 0; n < 4; ++n)
      bfr[n] = *(const bf16x8*)(sB + (wc * 64 + n * 16 + (lane & 15)) * 32 + (lane >> 4) * 8);
#pragma unroll
    for (int m = 0; m < 4; ++m)
#pragma unroll
      for (int n = 0; n < 4; ++n)
        acc[m][n] = __builtin_amdgcn_mfma_f32_16x16x32_bf16(af[m], bfr[n], acc[m][n], 0, 0, 0);
    __syncthreads();
  }

#pragma unroll
  for (int n = 0; n < 4; ++n) {
    const int col = col0 + wc * 64 + n * 16 + (lane & 15);
    const float bcol = bias[col];
#pragma unroll
    for (int m = 0; m < 4; ++m)
#pragma unroll
      for (int r = 0; r < 4; ++r) {
        const int row = row0 + wr * 64 + m * 16 + (lane >> 4) * 4 + r;
        C[(size_t)row * D_DIM + col] = f32_to_bf16(acc[m][n][r] + bcol);
      }
  }
}

// ---------------------------------------------------------------------------
// V projection via bf16 MFMA (round-7..10-proven).
// ---------------------------------------------------------------------------
__global__ __launch_bounds__(256) void vproj_bf16(
    const unsigned short* __restrict__ A,
    const unsigned short* __restrict__ B,
    const float* __restrict__ bias,
    float* __restrict__ C)
{
  __shared__ unsigned short sA[128 * 32];
  __shared__ unsigned short sB[128 * 32];

  const int tid = threadIdx.x;
  const int lane = tid & 63;
  const int wave = tid >> 6;
  const int wr = wave >> 1, wc = wave & 1;
  const int row0 = blockIdx.x * 128;
  const int col0 = blockIdx.y * 128;

  const int st_r = lane >> 2;
  const int st_cb = (lane & 3) * 16;

  f32x4 acc[4][4];
#pragma unroll
  for (int m = 0; m < 4; ++m)
#pragma unroll
    for (int n = 0; n < 4; ++n) acc[m][n] = (f32x4){0.f, 0.f, 0.f, 0.f};

  for (int k0 = 0; k0 < D_DIM; k0 += 32) {
#pragma unroll
    for (int i = 0; i < 2; ++i) {
      const int seg = wave * 2 + i;
      const int rr = seg * 16 + st_r;
      async_copy16((char*)sA + seg * 1024,
                   (const char*)(A + (size_t)(row0 + rr) * D_DIM + k0) + st_cb);
      async_copy16((char*)sB + seg * 1024,
                   (const char*)(B + (size_t)(col0 + rr) * D_DIM + k0) + st_cb);
    }
    __syncthreads();
    bf16x8 af[4], bfr[4];
#pragma unroll
    for (int m = 0; m < 4; ++m)
      af[m] = *(const bf16x8*)(sA + (wr * 64 + m * 16 + (lane & 15)) * 32 + (lane >> 4) * 8);
#pragma unroll
    for (int n = 0; n < 4; ++n)
      bfr[n] = *(const bf16x8*)(sB + (wc * 64 + n * 16 + (lane & 15)) * 32 + (lane >> 4) * 8);
#pragma unroll
    for (int m = 0; m < 4; ++m)
#pragma unroll
      for (int n = 0; n < 4; ++n)
        acc[m][n] = __builtin_amdgcn_mfma_f32_16x16x32_bf16(af[m], bfr[n], acc[m][n], 0, 0, 0);
    __syncthreads();
  }

#pragma unroll
  for (int n = 0; n < 4; ++n) {
    const int col = col0 + wc * 64 + n * 16 + (lane & 15);
    const float bcol = bias[col];
#pragma unroll
    for (int m = 0; m < 4; ++m)
#pragma unroll
      for (int r = 0; r < 4; ++r) {
        const int row = row0 + wr * 64 + m * 16 + (lane >> 4) * 4 + r;
        C[(size_t)row * D_DIM + col] = acc[m][n][r] + bcol;
      }
  }
}

// ---------------------------------------------------------------------------
// Gather selected V rows + LayerNorm (unchanged).
// ---------------------------------------------------------------------------
__global__ __launch_bounds__(256) void gather_ln(
    const float* __restrict__ V, const int* __restrict__ topi,
    const float* __restrict__ gamma, const float* __restrict__ beta,
    float* __restrict__ out)
{
  const int row = blockIdx.x;
  const int tid = threadIdx.x;
  const int idx = topi[row];
  const float* src = V + (size_t)idx * D_DIM;
  const float4 v = *(const float4*)(src + tid * 4);
  float s = v.x + v.y + v.z + v.w;
  float s2 = v.x * v.x + v.y * v.y + v.z * v.z + v.w * v.w;
#pragma unroll
  for (int off = 32; off > 0; off >>= 1) {
    s += __shfl_down(s, off);
    s2 += __shfl_down(s2, off);
  }
  __shared__ float red[8];
  __shared__ float stats[2];
  const int wid = tid >> 6;
  if ((tid & 63) == 0) { red[wid] = s; red[4 + wid] = s2; }
  __syncthreads();
  if (tid == 0) {
    const float S = red[0] + red[1] + red[2] + red[3];
    const float S2 = red[4] + red[5] + red[6] + red[7];
    const float mu = S * (1.0f / D_DIM);
    const float var = S2 * (1.0f / D_DIM) - mu * mu;
    stats[0] = mu;
    stats[1] = rsqrtf(var + 1e-5f);
  }
  __syncthreads();
  const float mu = stats[0], rstd = stats[1];
  const float4 g4 = *(const float4*)(gamma + tid * 4);
  const float4 b4 = *(const float4*)(beta + tid * 4);
  float4 o;
  o.x = (v.x - mu) * rstd * g4.x + b4.x;
  o.y = (v.y - mu) * rstd * g4.y + b4.y;
  o.z = (v.z - mu) * rstd * g4.z + b4.z;
  o.w = (v.w - mu) * rstd * g4.w + b4.w;
  *(float4*)(out + (size_t)row * D_DIM + tid * 4) = o;
}

extern "C" void kernel_launch(void* const* d_in, const int* in_sizes, int n_in,
                              void* d_out, int out_size, void* d_ws, size_t ws_size,
                              hipStream_t stream)
{
  const float* query = (const float*)d_in[0];
  const float* mem   = (const float*)d_in[1];
  const float* Wq    = (const float*)d_in[2];
  const float* bq    = (const float*)d_in[3];
  const float* Wk    = (const float*)d_in[4];
  const float* bk    = (const float*)d_in[5];
  const float* Wv    = (const float*)d_in[6];
  const float* bv    = (const float*)d_in[7];
  const float* gamma = (const float*)d_in[8];
  const float* beta  = (const float*)d_in[9];
  float* out = (float*)d_out;

  char* ws = (char*)d_ws;
  double* q64 = (double*)ws;   ws += (size_t)B_ROWS * D_DIM * sizeof(double);   // 33.6 MB
  double* u64 = (double*)ws;   ws += (size_t)B_ROWS * D_DIM * sizeof(double);   // 33.6 MB
  unsigned short* qbf = (unsigned short*)ws;
  ws += (size_t)B_ROWS * D_DIM * sizeof(unsigned short);                        // 8.4 MB
  unsigned short* membf = (unsigned short*)ws;
  ws += (size_t)M_ROWS * D_DIM * sizeof(unsigned short);                        // 67.1 MB
  char* Aregion = ws;
  ws += (size_t)M_ROWS * D_DIM * sizeof(unsigned short)                         // Kbf 67.1
      + 2 * (size_t)B_ROWS * NCB * TOPB * sizeof(float);                        // parts 67.1
  double* qbk = (double*)ws;   ws += (size_t)B_ROWS * sizeof(double);
  int* cand = (int*)ws;        ws += (size_t)B_ROWS * TOPC * sizeof(int);
  int* topi = (int*)ws;

  // Lifetimes (in-order stream):
  //  q64: dead after qbk+uproj -> hosts wkbf/wvbf casts.
  //  Aregion: Kbf+parts until merge; then Vout (exactly 134.2 MB) overlays.
  unsigned short* Kbf = (unsigned short*)Aregion;
  float* part_v = (float*)(Aregion + (size_t)M_ROWS * D_DIM * sizeof(unsigned short));
  int* part_i = (int*)((char*)part_v + (size_t)B_ROWS * NCB * TOPB * sizeof(float));
  unsigned short* wkbf = (unsigned short*)q64;
  unsigned short* wvbf = wkbf + (size_t)D_DIM * D_DIM;
  float* Vout = (float*)Aregion;

  qproj_f64<<<dim3(B_ROWS / BM, D_DIM / BN), 256, 0, stream>>>(query, Wq, bq, q64, qbf);
  qbk_dot<<<dim3(B_ROWS / 4), 256, 0, stream>>>(q64, bk, qbk);
  uproj_f64<<<dim3(B_ROWS / BM, D_DIM / BN), 256, 0, stream>>>(q64, Wk, u64);

  // q64 now dead -> casts may overwrite it.
  cast_f32_bf16<<<dim3((M_ROWS * D_DIM / 4 + 255) / 256), 256, 0, stream>>>(mem, membf, M_ROWS * D_DIM / 4);
  cast_f32_bf16<<<dim3((D_DIM * D_DIM / 4 + 255) / 256), 256, 0, stream>>>(Wk, wkbf, D_DIM * D_DIM / 4);
  cast_f32_bf16<<<dim3((D_DIM * D_DIM / 4 + 255) / 256), 256, 0, stream>>>(Wv, wvbf, D_DIM * D_DIM / 4);

  kproj_bf16<<<dim3(M_ROWS / 128, D_DIM / 128), 256, 0, stream>>>(membf, wkbf, bk, Kbf);
  sims_topc_gemm<<<dim3((B_ROWS / 128) * NCB), 256, 0, stream>>>(qbf, Kbf, part_v, part_i);
  merge_cand256<<<dim3(B_ROWS), 256, 0, stream>>>(part_v, part_i, cand);
  rescore_topk_u<<<dim3(B_ROWS), 256, 0, stream>>>(u64, qbk, mem, cand, topi);

  vproj_bf16<<<dim3(M_ROWS / 128, D_DIM / 128), 256, 0, stream>>>(membf, wvbf, bv, Vout);
  gather_ln<<<dim3(B_ROWS * TOPK), 256, 0, stream>>>(Vout, topi, gamma, beta, out);
}

// Round 12
// 2417.274 us; speedup vs baseline: 3.3137x; 1.0160x over previous
//
#include <hip/hip_runtime.h>
#include <hip/hip_bf16.h>
#include <math.h>

#define D_DIM 1024
#define B_ROWS 4096
#define M_ROWS 32768
#define TOPK 8
#define TOPC 16                // candidates per row after merge
#define TOPB 8                 // entries stored per (row, col-block): 2 halves x top-4
#define NCB (M_ROWS / 128)     // 256 col-blocks

#define BM 128
#define BN 64
#define BK 32

typedef __attribute__((ext_vector_type(8))) short bf16x8;
typedef __attribute__((ext_vector_type(4))) float f32x4;

__device__ __forceinline__ unsigned short f32_to_bf16(float f) {
  unsigned int u = __float_as_uint(f);
  unsigned int r = (u + 0x7FFFu + ((u >> 16) & 1u)) >> 16;
  return (unsigned short)r;
}
__device__ __forceinline__ float bf16_to_f32(unsigned short h) {
  return __uint_as_float(((unsigned int)h) << 16);
}
__device__ __forceinline__ void async_copy16(void* lds, const void* g) {
  __builtin_amdgcn_global_load_lds(
      (const __attribute__((address_space(1))) unsigned int*)g,
      (__attribute__((address_space(3))) unsigned int*)lds, 16, 0, 0);
}

// Ordered insert into a register top-N list sorted by (value desc, index asc).
template <int N>
__device__ __forceinline__ void insN(float v, int idx,
                                     float* __restrict__ tv,
                                     int* __restrict__ ti) {
  if (v < tv[N - 1]) return;
  if (v == tv[N - 1] && idx > ti[N - 1]) return;
  float cv = v;
  int ci = idx;
#pragma unroll
  for (int p = 0; p < N; ++p) {
    if (cv > tv[p] || (cv == tv[p] && ci < ti[p])) {
      const float t0 = tv[p]; tv[p] = cv; cv = t0;
      const int t1 = ti[p]; ti[p] = ci; ci = t1;
    }
  }
}

// ---------------------------------------------------------------------------
// q projection: q64[b,n] = sum_e query[b,e]*Wq[n,e] + bq[n], f64 accumulation
// (selection chain). Emits f64 q (for uproj/qbk) + bf16 q (candidate GEMM).
// ---------------------------------------------------------------------------
__global__ __launch_bounds__(256) void qproj_f64(
    const float* __restrict__ X, const float* __restrict__ W,
    const float* __restrict__ bias, double* __restrict__ out64,
    unsigned short* __restrict__ outbf)
{
  __shared__ float sA[BK][BM + 4];
  __shared__ float sB[BK][BN + 4];
  const int tid = threadIdx.x;
  const int tx = tid & 15, ty = tid >> 4;
  const int row0 = blockIdx.x * BM;
  const int col0 = blockIdx.y * BN;
  const int lr = tid >> 3;         // 0..31
  const int lc = (tid & 7) << 2;   // 0,4,...,28

  double acc[2][4][4];
#pragma unroll
  for (int g = 0; g < 2; ++g)
#pragma unroll
    for (int i = 0; i < 4; ++i)
#pragma unroll
      for (int j = 0; j < 4; ++j) acc[g][i][j] = 0.0;

  for (int k0 = 0; k0 < D_DIM; k0 += BK) {
#pragma unroll
    for (int rr = 0; rr < 4; ++rr) {
      const float4 v = *(const float4*)(X + (size_t)(row0 + lr + 32 * rr) * D_DIM + k0 + lc);
      sA[lc + 0][lr + 32 * rr] = v.x;
      sA[lc + 1][lr + 32 * rr] = v.y;
      sA[lc + 2][lr + 32 * rr] = v.z;
      sA[lc + 3][lr + 32 * rr] = v.w;
    }
#pragma unroll
    for (int rr = 0; rr < 2; ++rr) {
      const float4 v = *(const float4*)(W + (size_t)(col0 + lr + 32 * rr) * D_DIM + k0 + lc);
      sB[lc + 0][lr + 32 * rr] = v.x;
      sB[lc + 1][lr + 32 * rr] = v.y;
      sB[lc + 2][lr + 32 * rr] = v.z;
      sB[lc + 3][lr + 32 * rr] = v.w;
    }
    __syncthreads();
#pragma unroll
    for (int kk = 0; kk < BK; ++kk) {
      const float4 A0 = *(const float4*)&sA[kk][ty * 4];
      const float4 A1 = *(const float4*)&sA[kk][64 + ty * 4];
      const float4 Bv = *(const float4*)&sB[kk][tx * 4];
      const double a0[4] = {A0.x, A0.y, A0.z, A0.w};
      const double a1[4] = {A1.x, A1.y, A1.z, A1.w};
      const double bb[4] = {Bv.x, Bv.y, Bv.z, Bv.w};
#pragma unroll
      for (int i = 0; i < 4; ++i)
#pragma unroll
        for (int j = 0; j < 4; ++j) {
          acc[0][i][j] = fma(a0[i], bb[j], acc[0][i][j]);
          acc[1][i][j] = fma(a1[i], bb[j], acc[1][i][j]);
        }
    }
    __syncthreads();
  }
  const float4 bv4 = *(const float4*)(bias + col0 + tx * 4);
  const double bb[4] = {bv4.x, bv4.y, bv4.z, bv4.w};
#pragma unroll
  for (int g = 0; g < 2; ++g)
#pragma unroll
    for (int i = 0; i < 4; ++i) {
      double o[4];
#pragma unroll
      for (int j = 0; j < 4; ++j) o[j] = acc[g][i][j] + bb[j];
      const size_t base = (size_t)(row0 + g * 64 + ty * 4 + i) * D_DIM + col0 + tx * 4;
      *(double2*)(out64 + base)     = (double2){o[0], o[1]};
      *(double2*)(out64 + base + 2) = (double2){o[2], o[3]};
      ushort4 ob;
      ob.x = f32_to_bf16((float)o[0]);
      ob.y = f32_to_bf16((float)o[1]);
      ob.z = f32_to_bf16((float)o[2]);
      ob.w = f32_to_bf16((float)o[3]);
      *(ushort4*)(outbf + base) = ob;
    }
}

// ---------------------------------------------------------------------------
// qbk[b] = dot_f64(q64[b,:], bk). One wave per row.
// ---------------------------------------------------------------------------
__global__ __launch_bounds__(256) void qbk_dot(
    const double* __restrict__ Q64, const float* __restrict__ bk_,
    double* __restrict__ qbk)
{
  const int b = blockIdx.x * 4 + (threadIdx.x >> 6);
  const int lane = threadIdx.x & 63;
  const double* qrow = Q64 + (size_t)b * D_DIM + lane * 16;
  const float* bkrow = bk_ + lane * 16;
  double acc = 0.0;
#pragma unroll
  for (int i = 0; i < 4; ++i) {
    const float4 bv = *(const float4*)(bkrow + i * 4);
    const double2 qa = *(const double2*)(qrow + i * 4);
    const double2 qb2 = *(const double2*)(qrow + i * 4 + 2);
    acc = fma(qa.x, (double)bv.x, acc);
    acc = fma(qa.y, (double)bv.y, acc);
    acc = fma(qb2.x, (double)bv.z, acc);
    acc = fma(qb2.y, (double)bv.w, acc);
  }
#pragma unroll
  for (int off = 32; off > 0; off >>= 1) acc += __shfl_down(acc, off);
  if (lane == 0) qbk[b] = acc;
}

// ---------------------------------------------------------------------------
// u = q64 @ Wk (NN, f64): u[b,d] = sum_n q64[b,n]*Wk[n,d]. (round-10-proven)
// ---------------------------------------------------------------------------
__global__ __launch_bounds__(256) void uproj_f64(
    const double* __restrict__ A, const float* __restrict__ Bw,
    double* __restrict__ U)
{
  __shared__ double sAd[BM][BK + 1];   // 33.0 KB
  __shared__ float sBf[BK][BN + 4];    // 8.7 KB
  const int tid = threadIdx.x;
  const int tx = tid & 15, ty = tid >> 4;
  const int row0 = blockIdx.x * BM;
  const int col0 = blockIdx.y * BN;

  double acc[2][4][4];
#pragma unroll
  for (int g = 0; g < 2; ++g)
#pragma unroll
    for (int i = 0; i < 4; ++i)
#pragma unroll
      for (int j = 0; j < 4; ++j) acc[g][i][j] = 0.0;

  for (int k0 = 0; k0 < D_DIM; k0 += BK) {
#pragma unroll
    for (int it = 0; it < 8; ++it) {
      const int L = it * 256 + tid;
      const int row = L >> 4, kp = (L & 15) * 2;
      const double2 d2 = *(const double2*)(A + (size_t)(row0 + row) * D_DIM + k0 + kp);
      sAd[row][kp] = d2.x;
      sAd[row][kp + 1] = d2.y;
    }
#pragma unroll
    for (int it = 0; it < 2; ++it) {
      const int L = it * 256 + tid;
      const int kk = L >> 4, j4 = (L & 15) * 4;
      const float4 v = *(const float4*)(Bw + (size_t)(k0 + kk) * D_DIM + col0 + j4);
      sBf[kk][j4 + 0] = v.x;
      sBf[kk][j4 + 1] = v.y;
      sBf[kk][j4 + 2] = v.z;
      sBf[kk][j4 + 3] = v.w;
    }
    __syncthreads();
#pragma unroll
    for (int kk = 0; kk < BK; ++kk) {
      const double a0[4] = {sAd[ty * 4 + 0][kk], sAd[ty * 4 + 1][kk],
                            sAd[ty * 4 + 2][kk], sAd[ty * 4 + 3][kk]};
      const double a1[4] = {sAd[64 + ty * 4 + 0][kk], sAd[64 + ty * 4 + 1][kk],
                            sAd[64 + ty * 4 + 2][kk], sAd[64 + ty * 4 + 3][kk]};
      const float4 Bv = *(const float4*)&sBf[kk][tx * 4];
      const double bb[4] = {Bv.x, Bv.y, Bv.z, Bv.w};
#pragma unroll
      for (int i = 0; i < 4; ++i)
#pragma unroll
        for (int j = 0; j < 4; ++j) {
          acc[0][i][j] = fma(a0[i], bb[j], acc[0][i][j]);
          acc[1][i][j] = fma(a1[i], bb[j], acc[1][i][j]);
        }
    }
    __syncthreads();
  }
#pragma unroll
  for (int g = 0; g < 2; ++g)
#pragma unroll
    for (int i = 0; i < 4; ++i) {
      const size_t base = (size_t)(row0 + g * 64 + ty * 4 + i) * D_DIM + col0 + tx * 4;
      *(double2*)(U + base)     = (double2){acc[g][i][0], acc[g][i][1]};
      *(double2*)(U + base + 2) = (double2){acc[g][i][2], acc[g][i][3]};
    }
}

// ---------------------------------------------------------------------------
// Fused sims + per-half top-4. Round-12 changes (vs round 11):
//  (a) cb-resident XCD mapping: XCD x owns cb-groups [x*4, x*4+4) of 8 cbs
//      each; within a group blocks iterate r-major (8 same-r blocks share an
//      A-panel; 2MB B-group stays L2-resident). Predicted L2-miss ~350MB.
//  (b) BK=64: 16 K-steps (half the vmcnt(0)+barrier drains), 32 MFMA/step.
//  (c) XOR-swizzled staging (both-sides, rule #21): global chunk
//      (lane&7)^(lane>>3) with linear LDS dest; reads XOR chunk with row&7
//      -> conflict-free ds_read_b128 (removes the legacy 8-way alias too).
// Epilogue (two half-passes, insN<4>) unchanged from round 11.
// ---------------------------------------------------------------------------
__global__ __launch_bounds__(256) void sims_topc_gemm(
    const unsigned short* __restrict__ A, const unsigned short* __restrict__ B,
    float* __restrict__ part_v, int* __restrict__ part_i)
{
  __shared__ unsigned short smem[2 * 128 * 64];   // 32 KB: sA | sB (K-loop)
  unsigned short* sA = smem;                      // [128][64] swizzled
  unsigned short* sB = smem + 128 * 64;

  const int tid = threadIdx.x;
  const int lane = tid & 63;
  const int wave = tid >> 6;
  const int wr = wave >> 1, wc = wave & 1;

  // cb-resident mapping (bijective over 8192 blocks):
  // x=bid&7 (XCD), t=bid>>3; cbg=t>>8 (0..3), r=(t>>3)&31, cbl=t&7.
  const int bid = blockIdx.x;
  const int x = bid & 7;
  const int t = bid >> 3;
  const int cbg = t >> 8;
  const int r = (t >> 3) & 31;
  const int cbl = t & 7;
  const int cb = (x * 4 + cbg) * 8 + cbl;
  const int row0 = r * 128;
  const int col0 = cb * 128;

  const int st_r = lane >> 3;                         // row within 8-row segment
  const int st_swz = ((lane & 7) ^ st_r) * 16;        // pre-swizzled global chunk

  f32x4 acc[4][4];
#pragma unroll
  for (int m = 0; m < 4; ++m)
#pragma unroll
    for (int n = 0; n < 4; ++n) acc[m][n] = (f32x4){0.f, 0.f, 0.f, 0.f};

  for (int k0 = 0; k0 < D_DIM; k0 += 64) {
    // stage 16 KB per tile: 16 segments of 8 rows x 128 B; wave does 4 A + 4 B.
#pragma unroll
    for (int i = 0; i < 4; ++i) {
      const int seg = wave * 4 + i;
      const int rr = seg * 8 + st_r;
      async_copy16((char*)sA + seg * 1024,
                   (const char*)(A + (size_t)(row0 + rr) * D_DIM + k0) + st_swz);
      async_copy16((char*)sB + seg * 1024,
                   (const char*)(B + (size_t)(col0 + rr) * D_DIM + k0) + st_swz);
    }
    __syncthreads();
#pragma unroll
    for (int ks = 0; ks < 2; ++ks) {
      bf16x8 af[4], bfr[4];
      const int ch = ks * 4 + (lane >> 4);            // 16B chunk 0..7
#pragma unroll
      for (int m = 0; m < 4; ++m) {
        const int Ra = wr * 64 + m * 16 + (lane & 15);
        af[m] = *(const bf16x8*)((const char*)sA + Ra * 128 + ((ch ^ (Ra & 7)) * 16));
      }
#pragma unroll
      for (int n = 0; n < 4; ++n) {
        const int Rb = wc * 64 + n * 16 + (lane & 15);
        bfr[n] = *(const bf16x8*)((const char*)sB + Rb * 128 + ((ch ^ (Rb & 7)) * 16));
      }
#pragma unroll
      for (int m = 0; m < 4; ++m)
#pragma unroll
        for (int n = 0; n < 4; ++n)
          acc[m][n] = __builtin_amdgcn_mfma_f32_16x16x32_bf16(af[m], bfr[n], acc[m][n], 0, 0, 0);
    }
    __syncthreads();
  }
  // K-loop done: smem free for C half-tiles (128 x 68 bf16 = 17.4 KB <= 32 KB).

#pragma unroll
  for (int h = 0; h < 2; ++h) {
    if (wc == h) {
      // C/D layout (m89): col=lane&15 (within 16), row=(lane>>4)*4+reg.
#pragma unroll
      for (int m = 0; m < 4; ++m)
#pragma unroll
        for (int n = 0; n < 4; ++n)
#pragma unroll
          for (int rg = 0; rg < 4; ++rg) {
            const int row = wr * 64 + m * 16 + (lane >> 4) * 4 + rg;
            const int colL = n * 16 + (lane & 15);
            smem[row * 68 + colL] = f32_to_bf16(acc[m][n][rg]);
          }
    }
    __syncthreads();
    if (tid < 128) {
      float tv[4];
      int ti_[4];
#pragma unroll
      for (int p = 0; p < 4; ++p) { tv[p] = -INFINITY; ti_[p] = 0; }
      const unsigned short* crow = smem + tid * 68;
      const int gcol = col0 + h * 64;
      for (int j = 0; j < 64; j += 4) {
        const ushort4 c4 = *(const ushort4*)(crow + j);
        insN<4>(bf16_to_f32(c4.x), gcol + j + 0, tv, ti_);
        insN<4>(bf16_to_f32(c4.y), gcol + j + 1, tv, ti_);
        insN<4>(bf16_to_f32(c4.z), gcol + j + 2, tv, ti_);
        insN<4>(bf16_to_f32(c4.w), gcol + j + 3, tv, ti_);
      }
      const size_t base = ((size_t)(row0 + tid) * NCB + cb) * TOPB + h * 4;
      *(float4*)(part_v + base) = (float4){tv[0], tv[1], tv[2], tv[3]};
      *(int4*)(part_i + base)   = (int4){ti_[0], ti_[1], ti_[2], ti_[3]};
    }
    __syncthreads();
  }
}

// ---------------------------------------------------------------------------
// Merge all per-(row,cb) entries -> 16 candidates (round-8-proven).
// ---------------------------------------------------------------------------
__global__ __launch_bounds__(256) void merge_cand256(
    const float* __restrict__ part_v, const int* __restrict__ part_i,
    int* __restrict__ cand)
{
  const int r = blockIdx.x;
  const int tid = threadIdx.x;

  __shared__ float lv[256][TOPB];
  __shared__ int li[256][TOPB];

  {
    const size_t base = ((size_t)r * NCB + tid) * TOPB;
    const float4 a0 = *(const float4*)(part_v + base);
    const float4 a1 = *(const float4*)(part_v + base + 4);
    const int4 b0 = *(const int4*)(part_i + base);
    const int4 b1 = *(const int4*)(part_i + base + 4);
    lv[tid][0] = a0.x; lv[tid][1] = a0.y; lv[tid][2] = a0.z; lv[tid][3] = a0.w;
    lv[tid][4] = a1.x; lv[tid][5] = a1.y; lv[tid][6] = a1.z; lv[tid][7] = a1.w;
    li[tid][0] = b0.x; li[tid][1] = b0.y; li[tid][2] = b0.z; li[tid][3] = b0.w;
    li[tid][4] = b1.x; li[tid][5] = b1.y; li[tid][6] = b1.z; li[tid][7] = b1.w;
  }
  __syncthreads();

  __shared__ float mv16[16][TOPC];
  __shared__ int mi16[16][TOPC];
  if (tid < 16) {
    float mv[TOPC];
    int mi[TOPC];
#pragma unroll
    for (int p = 0; p < TOPC; ++p) { mv[p] = -INFINITY; mi[p] = 0; }
    for (int s = tid * 16; s < tid * 16 + 16; ++s)
      for (int p0 = 0; p0 < TOPB; ++p0) insN<TOPC>(lv[s][p0], li[s][p0], mv, mi);
#pragma unroll
    for (int p = 0; p < TOPC; ++p) { mv16[tid][p] = mv[p]; mi16[tid][p] = mi[p]; }
  }
  __syncthreads();

  if (tid == 0) {
    float mv[TOPC];
    int mi[TOPC];
#pragma unroll
    for (int p = 0; p < TOPC; ++p) { mv[p] = -INFINITY; mi[p] = 0; }
    for (int s = 0; s < 16; ++s)
      for (int p0 = 0; p0 < TOPC; ++p0) insN<TOPC>(mv16[s][p0], mi16[s][p0], mv, mi);
#pragma unroll
    for (int p = 0; p < TOPC; ++p)
      cand[(size_t)r * TOPC + p] = mi[p];
  }
}

// ---------------------------------------------------------------------------
// fp64 rescore via u: sims_ci = dot_f64(u_b, mem_ci) + qbk_b (round-10-proven).
// ---------------------------------------------------------------------------
__global__ __launch_bounds__(256) void rescore_topk_u(
    const double* __restrict__ U, const double* __restrict__ qbk,
    const float* __restrict__ mem, const int* __restrict__ cand,
    int* __restrict__ topi)
{
  const int b = blockIdx.x;
  const int tid = threadIdx.x;
  const int wave = tid >> 6;
  const int lane = tid & 63;

  __shared__ double sval[TOPC];
  __shared__ int sidx[TOPC];

  const double* urow = U + (size_t)b * D_DIM + lane * 16;
  double uv[16];
#pragma unroll
  for (int i = 0; i < 8; ++i) {
    const double2 d2 = *(const double2*)(urow + i * 2);
    uv[i * 2] = d2.x;
    uv[i * 2 + 1] = d2.y;
  }
  const double qb = qbk[b];

  for (int c = wave; c < TOPC; c += 4) {
    const int ci = cand[(size_t)b * TOPC + c];
    const float* mrow = mem + (size_t)ci * D_DIM + lane * 16;
    double acc = 0.0;
#pragma unroll
    for (int i = 0; i < 4; ++i) {
      const float4 mv = *(const float4*)(mrow + i * 4);
      acc = fma(uv[i * 4 + 0], (double)mv.x, acc);
      acc = fma(uv[i * 4 + 1], (double)mv.y, acc);
      acc = fma(uv[i * 4 + 2], (double)mv.z, acc);
      acc = fma(uv[i * 4 + 3], (double)mv.w, acc);
    }
#pragma unroll
    for (int off = 32; off > 0; off >>= 1) acc += __shfl_down(acc, off);
    if (lane == 0) { sval[c] = acc + qb; sidx[c] = ci; }
  }
  __syncthreads();

  if (tid == 0) {
    bool used[TOPC];
#pragma unroll
    for (int p = 0; p < TOPC; ++p) used[p] = false;
#pragma unroll
    for (int p = 0; p < TOPK; ++p) {
      int best = -1;
      double bv = 0.0;
      int bi = 0;
      for (int c = 0; c < TOPC; ++c) {
        if (used[c]) continue;
        const double v = sval[c];
        const int ix = sidx[c];
        if (best < 0 || v > bv || (v == bv && ix < bi)) { best = c; bv = v; bi = ix; }
      }
      used[best] = true;
      topi[(size_t)b * TOPK + p] = bi;
    }
  }
}

// ---------------------------------------------------------------------------
// f32 -> bf16 cast (vectorized).
// ---------------------------------------------------------------------------
__global__ __launch_bounds__(256) void cast_f32_bf16(
    const float* __restrict__ src, unsigned short* __restrict__ dst, int n4)
{
  const int i = blockIdx.x * 256 + threadIdx.x;
  if (i >= n4) return;
  const float4 v = *(const float4*)(src + (size_t)i * 4);
  ushort4 o;
  o.x = f32_to_bf16(v.x);
  o.y = f32_to_bf16(v.y);
  o.z = f32_to_bf16(v.z);
  o.w = f32_to_bf16(v.w);
  *(ushort4*)(dst + (size_t)i * 4) = o;
}

// ---------------------------------------------------------------------------
// K projection via bf16 MFMA, bf16 output (round-10-proven, untouched).
// ---------------------------------------------------------------------------
__global__ __launch_bounds__(256) void kproj_bf16(
    const unsigned short* __restrict__ A,   // mem_bf [M_ROWS][D_DIM]
    const unsigned short* __restrict__ B,   // Wk_bf  [D_DIM][D_DIM]
    const float* __restrict__ bias,
    unsigned short* __restrict__ C)         // [M_ROWS][D_DIM] bf16
{
  __shared__ unsigned short sA[128 * 32];
  __shared__ unsigned short sB[128 * 32];

  const int tid = threadIdx.x;
  const int lane = tid & 63;
  const int wave = tid >> 6;
  const int wr = wave >> 1, wc = wave & 1;
  const int row0 = blockIdx.x * 128;
  const int col0 = blockIdx.y * 128;

  const int st_r = lane >> 2;
  const int st_cb = (lane & 3) * 16;

  f32x4 acc[4][4];
#pragma unroll
  for (int m = 0; m < 4; ++m)
#pragma unroll
    for (int n = 0; n < 4; ++n) acc[m][n] = (f32x4){0.f, 0.f, 0.f, 0.f};

  for (int k0 = 0; k0 < D_DIM; k0 += 32) {
#pragma unroll
    for (int i = 0; i < 2; ++i) {
      const int seg = wave * 2 + i;
      const int rr = seg * 16 + st_r;
      async_copy16((char*)sA + seg * 1024,
                   (const char*)(A + (size_t)(row0 + rr) * D_DIM + k0) + st_cb);
      async_copy16((char*)sB + seg * 1024,
                   (const char*)(B + (size_t)(col0 + rr) * D_DIM + k0) + st_cb);
    }
    __syncthreads();
    bf16x8 af[4], bfr[4];
#pragma unroll
    for (int m = 0; m < 4; ++m)
      af[m] = *(const bf16x8*)(sA + (wr * 64 + m * 16 + (lane & 15)) * 32 + (lane >> 4) * 8);
#pragma unroll
    for (int n = 0; n < 4; ++n)
      bfr[n] = *(const bf16x8*)(sB + (wc * 64 + n * 16 + (lane & 15)) * 32 + (lane >> 4) * 8);
#pragma unroll
    for (int m = 0; m < 4; ++m)
#pragma unroll
      for (int n = 0; n < 4; ++n)
        acc[m][n] = __builtin_amdgcn_mfma_f32_16x16x32_bf16(af[m], bfr[n], acc[m][n], 0, 0, 0);
    __syncthreads();
  }

#pragma unroll
  for (int n = 0; n < 4; ++n) {
    const int col = col0 + wc * 64 + n * 16 + (lane & 15);
    const float bcol = bias[col];
#pragma unroll
    for (int m = 0; m < 4; ++m)
#pragma unroll
      for (int r = 0; r < 4; ++r) {
        const int row = row0 + wr * 64 + m * 16 + (lane >> 4) * 4 + r;
        C[(size_t)row * D_DIM + col] = f32_to_bf16(acc[m][n][r] + bcol);
      }
  }
}

// ---------------------------------------------------------------------------
// V projection via bf16 MFMA (round-7..10-proven, untouched).
// ---------------------------------------------------------------------------
__global__ __launch_bounds__(256) void vproj_bf16(
    const unsigned short* __restrict__ A,
    const unsigned short* __restrict__ B,
    const float* __restrict__ bias,
    float* __restrict__ C)
{
  __shared__ unsigned short sA[128 * 32];
  __shared__ unsigned short sB[128 * 32];

  const int tid = threadIdx.x;
  const int lane = tid & 63;
  const int wave = tid >> 6;
  const int wr = wave >> 1, wc = wave & 1;
  const int row0 = blockIdx.x * 128;
  const int col0 = blockIdx.y * 128;

  const int st_r = lane >> 2;
  const int st_cb = (lane & 3) * 16;

  f32x4 acc[4][4];
#pragma unroll
  for (int m = 0; m < 4; ++m)
#pragma unroll
    for (int n = 0; n < 4; ++n) acc[m][n] = (f32x4){0.f, 0.f, 0.f, 0.f};

  for (int k0 = 0; k0 < D_DIM; k0 += 32) {
#pragma unroll
    for (int i = 0; i < 2; ++i) {
      const int seg = wave * 2 + i;
      const int rr = seg * 16 + st_r;
      async_copy16((char*)sA + seg * 1024,
                   (const char*)(A + (size_t)(row0 + rr) * D_DIM + k0) + st_cb);
      async_copy16((char*)sB + seg * 1024,
                   (const char*)(B + (size_t)(col0 + rr) * D_DIM + k0) + st_cb);
    }
    __syncthreads();
    bf16x8 af[4], bfr[4];
#pragma unroll
    for (int m = 0; m < 4; ++m)
      af[m] = *(const bf16x8*)(sA + (wr * 64 + m * 16 + (lane & 15)) * 32 + (lane >> 4) * 8);
#pragma unroll
    for (int n = 0; n < 4; ++n)
      bfr[n] = *(const bf16x8*)(sB + (wc * 64 + n * 16 + (lane & 15)) * 32 + (lane >> 4) * 8);
#pragma unroll
    for (int m = 0; m < 4; ++m)
#pragma unroll
      for (int n = 0; n < 4; ++n)
        acc[m][n] = __builtin_amdgcn_mfma_f32_16x16x32_bf16(af[m], bfr[n], acc[m][n], 0, 0, 0);
    __syncthreads();
  }

#pragma unroll
  for (int n = 0; n < 4; ++n) {
    const int col = col0 + wc * 64 + n * 16 + (lane & 15);
    const float bcol = bias[col];
#pragma unroll
    for (int m = 0; m < 4; ++m)
#pragma unroll
      for (int r = 0; r < 4; ++r) {
        const int row = row0 + wr * 64 + m * 16 + (lane >> 4) * 4 + r;
        C[(size_t)row * D_DIM + col] = acc[m][n][r] + bcol;
      }
  }
}

// ---------------------------------------------------------------------------
// Gather selected V rows + LayerNorm (unchanged).
// ---------------------------------------------------------------------------
__global__ __launch_bounds__(256) void gather_ln(
    const float* __restrict__ V, const int* __restrict__ topi,
    const float* __restrict__ gamma, const float* __restrict__ beta,
    float* __restrict__ out)
{
  const int row = blockIdx.x;
  const int tid = threadIdx.x;
  const int idx = topi[row];
  const float* src = V + (size_t)idx * D_DIM;
  const float4 v = *(const float4*)(src + tid * 4);
  float s = v.x + v.y + v.z + v.w;
  float s2 = v.x * v.x + v.y * v.y + v.z * v.z + v.w * v.w;
#pragma unroll
  for (int off = 32; off > 0; off >>= 1) {
    s += __shfl_down(s, off);
    s2 += __shfl_down(s2, off);
  }
  __shared__ float red[8];
  __shared__ float stats[2];
  const int wid = tid >> 6;
  if ((tid & 63) == 0) { red[wid] = s; red[4 + wid] = s2; }
  __syncthreads();
  if (tid == 0) {
    const float S = red[0] + red[1] + red[2] + red[3];
    const float S2 = red[4] + red[5] + red[6] + red[7];
    const float mu = S * (1.0f / D_DIM);
    const float var = S2 * (1.0f / D_DIM) - mu * mu;
    stats[0] = mu;
    stats[1] = rsqrtf(var + 1e-5f);
  }
  __syncthreads();
  const float mu = stats[0], rstd = stats[1];
  const float4 g4 = *(const float4*)(gamma + tid * 4);
  const float4 b4 = *(const float4*)(beta + tid * 4);
  float4 o;
  o.x = (v.x - mu) * rstd * g4.x + b4.x;
  o.y = (v.y - mu) * rstd * g4.y + b4.y;
  o.z = (v.z - mu) * rstd * g4.z + b4.z;
  o.w = (v.w - mu) * rstd * g4.w + b4.w;
  *(float4*)(out + (size_t)row * D_DIM + tid * 4) = o;
}

extern "C" void kernel_launch(void* const* d_in, const int* in_sizes, int n_in,
                              void* d_out, int out_size, void* d_ws, size_t ws_size,
                              hipStream_t stream)
{
  const float* query = (const float*)d_in[0];
  const float* mem   = (const float*)d_in[1];
  const float* Wq    = (const float*)d_in[2];
  const float* bq    = (const float*)d_in[3];
  const float* Wk    = (const float*)d_in[4];
  const float* bk    = (const float*)d_in[5];
  const float* Wv    = (const float*)d_in[6];
  const float* bv    = (const float*)d_in[7];
  const float* gamma = (const float*)d_in[8];
  const float* beta  = (const float*)d_in[9];
  float* out = (float*)d_out;

  char* ws = (char*)d_ws;
  double* q64 = (double*)ws;   ws += (size_t)B_ROWS * D_DIM * sizeof(double);   // 33.6 MB
  double* u64 = (double*)ws;   ws += (size_t)B_ROWS * D_DIM * sizeof(double);   // 33.6 MB
  unsigned short* qbf = (unsigned short*)ws;
  ws += (size_t)B_ROWS * D_DIM * sizeof(unsigned short);                        // 8.4 MB
  unsigned short* membf = (unsigned short*)ws;
  ws += (size_t)M_ROWS * D_DIM * sizeof(unsigned short);                        // 67.1 MB
  char* Aregion = ws;
  ws += (size_t)M_ROWS * D_DIM * sizeof(unsigned short)                         // Kbf 67.1
      + 2 * (size_t)B_ROWS * NCB * TOPB * sizeof(float);                        // parts 67.1
  double* qbk = (double*)ws;   ws += (size_t)B_ROWS * sizeof(double);
  int* cand = (int*)ws;        ws += (size_t)B_ROWS * TOPC * sizeof(int);
  int* topi = (int*)ws;

  // Lifetimes (in-order stream):
  //  q64: dead after qbk+uproj -> hosts wkbf/wvbf casts.
  //  Aregion: Kbf+parts until merge; then Vout (exactly 134.2 MB) overlays.
  unsigned short* Kbf = (unsigned short*)Aregion;
  float* part_v = (float*)(Aregion + (size_t)M_ROWS * D_DIM * sizeof(unsigned short));
  int* part_i = (int*)((char*)part_v + (size_t)B_ROWS * NCB * TOPB * sizeof(float));
  unsigned short* wkbf = (unsigned short*)q64;
  unsigned short* wvbf = wkbf + (size_t)D_DIM * D_DIM;
  float* Vout = (float*)Aregion;

  qproj_f64<<<dim3(B_ROWS / BM, D_DIM / BN), 256, 0, stream>>>(query, Wq, bq, q64, qbf);
  qbk_dot<<<dim3(B_ROWS / 4), 256, 0, stream>>>(q64, bk, qbk);
  uproj_f64<<<dim3(B_ROWS / BM, D_DIM / BN), 256, 0, stream>>>(q64, Wk, u64);

  // q64 now dead -> casts may overwrite it.
  cast_f32_bf16<<<dim3((M_ROWS * D_DIM / 4 + 255) / 256), 256, 0, stream>>>(mem, membf, M_ROWS * D_DIM / 4);
  cast_f32_bf16<<<dim3((D_DIM * D_DIM / 4 + 255) / 256), 256, 0, stream>>>(Wk, wkbf, D_DIM * D_DIM / 4);
  cast_f32_bf16<<<dim3((D_DIM * D_DIM / 4 + 255) / 256), 256, 0, stream>>>(Wv, wvbf, D_DIM * D_DIM / 4);

  kproj_bf16<<<dim3(M_ROWS / 128, D_DIM / 128), 256, 0, stream>>>(membf, wkbf, bk, Kbf);
  sims_topc_gemm<<<dim3((B_ROWS / 128) * NCB), 256, 0, stream>>>(qbf, Kbf, part_v, part_i);
  merge_cand256<<<dim3(B_ROWS), 256, 0, stream>>>(part_v, part_i, cand);
  rescore_topk_u<<<dim3(B_ROWS), 256, 0, stream>>>(u64, qbk, mem, cand, topi);

  vproj_bf16<<<dim3(M_ROWS / 128, D_DIM / 128), 256, 0, stream>>>(membf, wvbf, bv, Vout);
  gather_ln<<<dim3(B_ROWS * TOPK), 256, 0, stream>>>(Vout, topi, gamma, beta, out);
}

// Round 13
// 2343.185 us; speedup vs baseline: 3.4185x; 1.0316x over previous
//
#include <hip/hip_runtime.h>
#include <hip/hip_bf16.h>
#include <math.h>

#define D_DIM 1024
#define B_ROWS 4096
#define M_ROWS 32768
#define TOPK 8
#define TOPC 16                // candidates per row after merge
#define TOPB 8                 // entries stored per (row, col-block): 2 halves x top-4
#define NCB (M_ROWS / 128)     // 256 col-blocks

#define BM 128
#define BN 64
#define BK 32

typedef __attribute__((ext_vector_type(8))) short bf16x8;
typedef __attribute__((ext_vector_type(4))) float f32x4;

__device__ __forceinline__ unsigned short f32_to_bf16(float f) {
  unsigned int u = __float_as_uint(f);
  unsigned int r = (u + 0x7FFFu + ((u >> 16) & 1u)) >> 16;
  return (unsigned short)r;
}
__device__ __forceinline__ float bf16_to_f32(unsigned short h) {
  return __uint_as_float(((unsigned int)h) << 16);
}
__device__ __forceinline__ void async_copy16(void* lds, const void* g) {
  __builtin_amdgcn_global_load_lds(
      (const __attribute__((address_space(1))) unsigned int*)g,
      (__attribute__((address_space(3))) unsigned int*)lds, 16, 0, 0);
}

// Ordered insert into a register top-N list sorted by (value desc, index asc).
template <int N>
__device__ __forceinline__ void insN(float v, int idx,
                                     float* __restrict__ tv,
                                     int* __restrict__ ti) {
  if (v < tv[N - 1]) return;
  if (v == tv[N - 1] && idx > ti[N - 1]) return;
  float cv = v;
  int ci = idx;
#pragma unroll
  for (int p = 0; p < N; ++p) {
    if (cv > tv[p] || (cv == tv[p] && ci < ti[p])) {
      const float t0 = tv[p]; tv[p] = cv; cv = t0;
      const int t1 = ti[p]; ti[p] = ci; ci = t1;
    }
  }
}

// ---------------------------------------------------------------------------
// q projection: f64 accumulation (selection chain). Unchanged (compute-bound).
// ---------------------------------------------------------------------------
__global__ __launch_bounds__(256) void qproj_f64(
    const float* __restrict__ X, const float* __restrict__ W,
    const float* __restrict__ bias, double* __restrict__ out64,
    unsigned short* __restrict__ outbf)
{
  __shared__ float sA[BK][BM + 4];
  __shared__ float sB[BK][BN + 4];
  const int tid = threadIdx.x;
  const int tx = tid & 15, ty = tid >> 4;
  const int row0 = blockIdx.x * BM;
  const int col0 = blockIdx.y * BN;
  const int lr = tid >> 3;         // 0..31
  const int lc = (tid & 7) << 2;   // 0,4,...,28

  double acc[2][4][4];
#pragma unroll
  for (int g = 0; g < 2; ++g)
#pragma unroll
    for (int i = 0; i < 4; ++i)
#pragma unroll
      for (int j = 0; j < 4; ++j) acc[g][i][j] = 0.0;

  for (int k0 = 0; k0 < D_DIM; k0 += BK) {
#pragma unroll
    for (int rr = 0; rr < 4; ++rr) {
      const float4 v = *(const float4*)(X + (size_t)(row0 + lr + 32 * rr) * D_DIM + k0 + lc);
      sA[lc + 0][lr + 32 * rr] = v.x;
      sA[lc + 1][lr + 32 * rr] = v.y;
      sA[lc + 2][lr + 32 * rr] = v.z;
      sA[lc + 3][lr + 32 * rr] = v.w;
    }
#pragma unroll
    for (int rr = 0; rr < 2; ++rr) {
      const float4 v = *(const float4*)(W + (size_t)(col0 + lr + 32 * rr) * D_DIM + k0 + lc);
      sB[lc + 0][lr + 32 * rr] = v.x;
      sB[lc + 1][lr + 32 * rr] = v.y;
      sB[lc + 2][lr + 32 * rr] = v.z;
      sB[lc + 3][lr + 32 * rr] = v.w;
    }
    __syncthreads();
#pragma unroll
    for (int kk = 0; kk < BK; ++kk) {
      const float4 A0 = *(const float4*)&sA[kk][ty * 4];
      const float4 A1 = *(const float4*)&sA[kk][64 + ty * 4];
      const float4 Bv = *(const float4*)&sB[kk][tx * 4];
      const double a0[4] = {A0.x, A0.y, A0.z, A0.w};
      const double a1[4] = {A1.x, A1.y, A1.z, A1.w};
      const double bb[4] = {Bv.x, Bv.y, Bv.z, Bv.w};
#pragma unroll
      for (int i = 0; i < 4; ++i)
#pragma unroll
        for (int j = 0; j < 4; ++j) {
          acc[0][i][j] = fma(a0[i], bb[j], acc[0][i][j]);
          acc[1][i][j] = fma(a1[i], bb[j], acc[1][i][j]);
        }
    }
    __syncthreads();
  }
  const float4 bv4 = *(const float4*)(bias + col0 + tx * 4);
  const double bb[4] = {bv4.x, bv4.y, bv4.z, bv4.w};
#pragma unroll
  for (int g = 0; g < 2; ++g)
#pragma unroll
    for (int i = 0; i < 4; ++i) {
      double o[4];
#pragma unroll
      for (int j = 0; j < 4; ++j) o[j] = acc[g][i][j] + bb[j];
      const size_t base = (size_t)(row0 + g * 64 + ty * 4 + i) * D_DIM + col0 + tx * 4;
      *(double2*)(out64 + base)     = (double2){o[0], o[1]};
      *(double2*)(out64 + base + 2) = (double2){o[2], o[3]};
      ushort4 ob;
      ob.x = f32_to_bf16((float)o[0]);
      ob.y = f32_to_bf16((float)o[1]);
      ob.z = f32_to_bf16((float)o[2]);
      ob.w = f32_to_bf16((float)o[3]);
      *(ushort4*)(outbf + base) = ob;
    }
}

// ---------------------------------------------------------------------------
// qbk[b] = dot_f64(q64[b,:], bk). One wave per row.
// ---------------------------------------------------------------------------
__global__ __launch_bounds__(256) void qbk_dot(
    const double* __restrict__ Q64, const float* __restrict__ bk_,
    double* __restrict__ qbk)
{
  const int b = blockIdx.x * 4 + (threadIdx.x >> 6);
  const int lane = threadIdx.x & 63;
  const double* qrow = Q64 + (size_t)b * D_DIM + lane * 16;
  const float* bkrow = bk_ + lane * 16;
  double acc = 0.0;
#pragma unroll
  for (int i = 0; i < 4; ++i) {
    const float4 bv = *(const float4*)(bkrow + i * 4);
    const double2 qa = *(const double2*)(qrow + i * 4);
    const double2 qb2 = *(const double2*)(qrow + i * 4 + 2);
    acc = fma(qa.x, (double)bv.x, acc);
    acc = fma(qa.y, (double)bv.y, acc);
    acc = fma(qb2.x, (double)bv.z, acc);
    acc = fma(qb2.y, (double)bv.w, acc);
  }
#pragma unroll
  for (int off = 32; off > 0; off >>= 1) acc += __shfl_down(acc, off);
  if (lane == 0) qbk[b] = acc;
}

// ---------------------------------------------------------------------------
// u = q64 @ Wk (NN, f64). Unchanged (compute-bound).
// ---------------------------------------------------------------------------
__global__ __launch_bounds__(256) void uproj_f64(
    const double* __restrict__ A, const float* __restrict__ Bw,
    double* __restrict__ U)
{
  __shared__ double sAd[BM][BK + 1];   // 33.0 KB
  __shared__ float sBf[BK][BN + 4];    // 8.7 KB
  const int tid = threadIdx.x;
  const int tx = tid & 15, ty = tid >> 4;
  const int row0 = blockIdx.x * BM;
  const int col0 = blockIdx.y * BN;

  double acc[2][4][4];
#pragma unroll
  for (int g = 0; g < 2; ++g)
#pragma unroll
    for (int i = 0; i < 4; ++i)
#pragma unroll
      for (int j = 0; j < 4; ++j) acc[g][i][j] = 0.0;

  for (int k0 = 0; k0 < D_DIM; k0 += BK) {
#pragma unroll
    for (int it = 0; it < 8; ++it) {
      const int L = it * 256 + tid;
      const int row = L >> 4, kp = (L & 15) * 2;
      const double2 d2 = *(const double2*)(A + (size_t)(row0 + row) * D_DIM + k0 + kp);
      sAd[row][kp] = d2.x;
      sAd[row][kp + 1] = d2.y;
    }
#pragma unroll
    for (int it = 0; it < 2; ++it) {
      const int L = it * 256 + tid;
      const int kk = L >> 4, j4 = (L & 15) * 4;
      const float4 v = *(const float4*)(Bw + (size_t)(k0 + kk) * D_DIM + col0 + j4);
      sBf[kk][j4 + 0] = v.x;
      sBf[kk][j4 + 1] = v.y;
      sBf[kk][j4 + 2] = v.z;
      sBf[kk][j4 + 3] = v.w;
    }
    __syncthreads();
#pragma unroll
    for (int kk = 0; kk < BK; ++kk) {
      const double a0[4] = {sAd[ty * 4 + 0][kk], sAd[ty * 4 + 1][kk],
                            sAd[ty * 4 + 2][kk], sAd[ty * 4 + 3][kk]};
      const double a1[4] = {sAd[64 + ty * 4 + 0][kk], sAd[64 + ty * 4 + 1][kk],
                            sAd[64 + ty * 4 + 2][kk], sAd[64 + ty * 4 + 3][kk]};
      const float4 Bv = *(const float4*)&sBf[kk][tx * 4];
      const double bb[4] = {Bv.x, Bv.y, Bv.z, Bv.w};
#pragma unroll
      for (int i = 0; i < 4; ++i)
#pragma unroll
        for (int j = 0; j < 4; ++j) {
          acc[0][i][j] = fma(a0[i], bb[j], acc[0][i][j]);
          acc[1][i][j] = fma(a1[i], bb[j], acc[1][i][j]);
        }
    }
    __syncthreads();
  }
#pragma unroll
  for (int g = 0; g < 2; ++g)
#pragma unroll
    for (int i = 0; i < 4; ++i) {
      const size_t base = (size_t)(row0 + g * 64 + ty * 4 + i) * D_DIM + col0 + tx * 4;
      *(double2*)(U + base)     = (double2){acc[g][i][0], acc[g][i][1]};
      *(double2*)(U + base + 2) = (double2){acc[g][i][2], acc[g][i][3]};
    }
}

// ---------------------------------------------------------------------------
// Fused sims + per-half top-4. Round-13 change (T3 minimal 2-phase):
// double-buffered LDS; STAGE(t+1) issued BEFORE compute(t); the compiler's
// pre-barrier vmcnt(0) now drains loads that had the whole compute phase to
// land (round-12 structure exposed full load latency at every K-step).
// cb-resident XCD mapping, BK=64, XOR swizzle, epilogue: unchanged (proven).
// ---------------------------------------------------------------------------
__global__ __launch_bounds__(256) void sims_topc_gemm(
    const unsigned short* __restrict__ A, const unsigned short* __restrict__ B,
    float* __restrict__ part_v, int* __restrict__ part_i)
{
  __shared__ unsigned short smem[4 * 128 * 64];   // 64 KB: 2 x (sA | sB)

  const int tid = threadIdx.x;
  const int lane = tid & 63;
  const int wave = tid >> 6;
  const int wr = wave >> 1, wc = wave & 1;

  // cb-resident mapping (bijective over 8192 blocks) — round-12-proven.
  const int bid = blockIdx.x;
  const int x = bid & 7;
  const int t0_ = bid >> 3;
  const int cbg = t0_ >> 8;
  const int r = (t0_ >> 3) & 31;
  const int cbl = t0_ & 7;
  const int cb = (x * 4 + cbg) * 8 + cbl;
  const int row0 = r * 128;
  const int col0 = cb * 128;

  const int st_r = lane >> 3;                         // row within 8-row segment
  const int st_swz = ((lane & 7) ^ st_r) * 16;        // pre-swizzled global chunk

  // STAGE: issue the 16 KB tile (t-th K-step) into buffer d. LDS dest is
  // wave-uniform base + lane*16 (linear), global src pre-swizzled (rule #21).
  auto STAGE = [&](int d, int k0) {
    unsigned short* dA = smem + d * (2 * 128 * 64);
    unsigned short* dB = dA + 128 * 64;
#pragma unroll
    for (int i = 0; i < 4; ++i) {
      const int seg = wave * 4 + i;
      const int rr = seg * 8 + st_r;
      async_copy16((char*)dA + seg * 1024,
                   (const char*)(A + (size_t)(row0 + rr) * D_DIM + k0) + st_swz);
      async_copy16((char*)dB + seg * 1024,
                   (const char*)(B + (size_t)(col0 + rr) * D_DIM + k0) + st_swz);
    }
  };

  f32x4 acc[4][4];
#pragma unroll
  for (int m = 0; m < 4; ++m)
#pragma unroll
    for (int n = 0; n < 4; ++n) acc[m][n] = (f32x4){0.f, 0.f, 0.f, 0.f};

  STAGE(0, 0);
  __syncthreads();           // tile 0 resident
  int cur = 0;

  for (int t = 0; t < 16; ++t) {
    if (t < 15) STAGE(cur ^ 1, (t + 1) * 64);   // prefetch BEFORE compute
    const unsigned short* sA = smem + cur * (2 * 128 * 64);
    const unsigned short* sB = sA + 128 * 64;
#pragma unroll
    for (int ks = 0; ks < 2; ++ks) {
      bf16x8 af[4], bfr[4];
      const int ch = ks * 4 + (lane >> 4);            // 16B chunk 0..7
#pragma unroll
      for (int m = 0; m < 4; ++m) {
        const int Ra = wr * 64 + m * 16 + (lane & 15);
        af[m] = *(const bf16x8*)((const char*)sA + Ra * 128 + ((ch ^ (Ra & 7)) * 16));
      }
#pragma unroll
      for (int n = 0; n < 4; ++n) {
        const int Rb = wc * 64 + n * 16 + (lane & 15);
        bfr[n] = *(const bf16x8*)((const char*)sB + Rb * 128 + ((ch ^ (Rb & 7)) * 16));
      }
#pragma unroll
      for (int m = 0; m < 4; ++m)
#pragma unroll
        for (int n = 0; n < 4; ++n)
          acc[m][n] = __builtin_amdgcn_mfma_f32_16x16x32_bf16(af[m], bfr[n], acc[m][n], 0, 0, 0);
    }
    __syncthreads();         // drains t+1 loads (in flight during compute) + frees cur
    cur ^= 1;
  }
  // K-loop done: smem free for C half-tiles (128 x 68 bf16 = 17.4 KB).

#pragma unroll
  for (int h = 0; h < 2; ++h) {
    if (wc == h) {
      // C/D layout (m89): col=lane&15 (within 16), row=(lane>>4)*4+reg.
#pragma unroll
      for (int m = 0; m < 4; ++m)
#pragma unroll
        for (int n = 0; n < 4; ++n)
#pragma unroll
          for (int rg = 0; rg < 4; ++rg) {
            const int row = wr * 64 + m * 16 + (lane >> 4) * 4 + rg;
            const int colL = n * 16 + (lane & 15);
            smem[row * 68 + colL] = f32_to_bf16(acc[m][n][rg]);
          }
    }
    __syncthreads();
    if (tid < 128) {
      float tv[4];
      int ti_[4];
#pragma unroll
      for (int p = 0; p < 4; ++p) { tv[p] = -INFINITY; ti_[p] = 0; }
      const unsigned short* crow = smem + tid * 68;
      const int gcol = col0 + h * 64;
      for (int j = 0; j < 64; j += 4) {
        const ushort4 c4 = *(const ushort4*)(crow + j);
        insN<4>(bf16_to_f32(c4.x), gcol + j + 0, tv, ti_);
        insN<4>(bf16_to_f32(c4.y), gcol + j + 1, tv, ti_);
        insN<4>(bf16_to_f32(c4.z), gcol + j + 2, tv, ti_);
        insN<4>(bf16_to_f32(c4.w), gcol + j + 3, tv, ti_);
      }
      const size_t base = ((size_t)(row0 + tid) * NCB + cb) * TOPB + h * 4;
      *(float4*)(part_v + base) = (float4){tv[0], tv[1], tv[2], tv[3]};
      *(int4*)(part_i + base)   = (int4){ti_[0], ti_[1], ti_[2], ti_[3]};
    }
    __syncthreads();
  }
}

// ---------------------------------------------------------------------------
// Merge all per-(row,cb) entries -> 16 candidates (round-8-proven).
// ---------------------------------------------------------------------------
__global__ __launch_bounds__(256) void merge_cand256(
    const float* __restrict__ part_v, const int* __restrict__ part_i,
    int* __restrict__ cand)
{
  const int r = blockIdx.x;
  const int tid = threadIdx.x;

  __shared__ float lv[256][TOPB];
  __shared__ int li[256][TOPB];

  {
    const size_t base = ((size_t)r * NCB + tid) * TOPB;
    const float4 a0 = *(const float4*)(part_v + base);
    const float4 a1 = *(const float4*)(part_v + base + 4);
    const int4 b0 = *(const int4*)(part_i + base);
    const int4 b1 = *(const int4*)(part_i + base + 4);
    lv[tid][0] = a0.x; lv[tid][1] = a0.y; lv[tid][2] = a0.z; lv[tid][3] = a0.w;
    lv[tid][4] = a1.x; lv[tid][5] = a1.y; lv[tid][6] = a1.z; lv[tid][7] = a1.w;
    li[tid][0] = b0.x; li[tid][1] = b0.y; li[tid][2] = b0.z; li[tid][3] = b0.w;
    li[tid][4] = b1.x; li[tid][5] = b1.y; li[tid][6] = b1.z; li[tid][7] = b1.w;
  }
  __syncthreads();

  __shared__ float mv16[16][TOPC];
  __shared__ int mi16[16][TOPC];
  if (tid < 16) {
    float mv[TOPC];
    int mi[TOPC];
#pragma unroll
    for (int p = 0; p < TOPC; ++p) { mv[p] = -INFINITY; mi[p] = 0; }
    for (int s = tid * 16; s < tid * 16 + 16; ++s)
      for (int p0 = 0; p0 < TOPB; ++p0) insN<TOPC>(lv[s][p0], li[s][p0], mv, mi);
#pragma unroll
    for (int p = 0; p < TOPC; ++p) { mv16[tid][p] = mv[p]; mi16[tid][p] = mi[p]; }
  }
  __syncthreads();

  if (tid == 0) {
    float mv[TOPC];
    int mi[TOPC];
#pragma unroll
    for (int p = 0; p < TOPC; ++p) { mv[p] = -INFINITY; mi[p] = 0; }
    for (int s = 0; s < 16; ++s)
      for (int p0 = 0; p0 < TOPC; ++p0) insN<TOPC>(mv16[s][p0], mi16[s][p0], mv, mi);
#pragma unroll
    for (int p = 0; p < TOPC; ++p)
      cand[(size_t)r * TOPC + p] = mi[p];
  }
}

// ---------------------------------------------------------------------------
// fp64 rescore via u: sims_ci = dot_f64(u_b, mem_ci) + qbk_b (round-10-proven).
// ---------------------------------------------------------------------------
__global__ __launch_bounds__(256) void rescore_topk_u(
    const double* __restrict__ U, const double* __restrict__ qbk,
    const float* __restrict__ mem, const int* __restrict__ cand,
    int* __restrict__ topi)
{
  const int b = blockIdx.x;
  const int tid = threadIdx.x;
  const int wave = tid >> 6;
  const int lane = tid & 63;

  __shared__ double sval[TOPC];
  __shared__ int sidx[TOPC];

  const double* urow = U + (size_t)b * D_DIM + lane * 16;
  double uv[16];
#pragma unroll
  for (int i = 0; i < 8; ++i) {
    const double2 d2 = *(const double2*)(urow + i * 2);
    uv[i * 2] = d2.x;
    uv[i * 2 + 1] = d2.y;
  }
  const double qb = qbk[b];

  for (int c = wave; c < TOPC; c += 4) {
    const int ci = cand[(size_t)b * TOPC + c];
    const float* mrow = mem + (size_t)ci * D_DIM + lane * 16;
    double acc = 0.0;
#pragma unroll
    for (int i = 0; i < 4; ++i) {
      const float4 mv = *(const float4*)(mrow + i * 4);
      acc = fma(uv[i * 4 + 0], (double)mv.x, acc);
      acc = fma(uv[i * 4 + 1], (double)mv.y, acc);
      acc = fma(uv[i * 4 + 2], (double)mv.z, acc);
      acc = fma(uv[i * 4 + 3], (double)mv.w, acc);
    }
#pragma unroll
    for (int off = 32; off > 0; off >>= 1) acc += __shfl_down(acc, off);
    if (lane == 0) { sval[c] = acc + qb; sidx[c] = ci; }
  }
  __syncthreads();

  if (tid == 0) {
    bool used[TOPC];
#pragma unroll
    for (int p = 0; p < TOPC; ++p) used[p] = false;
#pragma unroll
    for (int p = 0; p < TOPK; ++p) {
      int best = -1;
      double bv = 0.0;
      int bi = 0;
      for (int c = 0; c < TOPC; ++c) {
        if (used[c]) continue;
        const double v = sval[c];
        const int ix = sidx[c];
        if (best < 0 || v > bv || (v == bv && ix < bi)) { best = c; bv = v; bi = ix; }
      }
      used[best] = true;
      topi[(size_t)b * TOPK + p] = bi;
    }
  }
}

// ---------------------------------------------------------------------------
// f32 -> bf16 cast (vectorized).
// ---------------------------------------------------------------------------
__global__ __launch_bounds__(256) void cast_f32_bf16(
    const float* __restrict__ src, unsigned short* __restrict__ dst, int n4)
{
  const int i = blockIdx.x * 256 + threadIdx.x;
  if (i >= n4) return;
  const float4 v = *(const float4*)(src + (size_t)i * 4);
  ushort4 o;
  o.x = f32_to_bf16(v.x);
  o.y = f32_to_bf16(v.y);
  o.z = f32_to_bf16(v.z);
  o.w = f32_to_bf16(v.w);
  *(ushort4*)(dst + (size_t)i * 4) = o;
}

// ---------------------------------------------------------------------------
// K projection via bf16 MFMA, bf16 output — with the same 2-phase prefetch.
// ---------------------------------------------------------------------------
__global__ __launch_bounds__(256) void kproj_bf16(
    const unsigned short* __restrict__ A,   // mem_bf [M_ROWS][D_DIM]
    const unsigned short* __restrict__ B,   // Wk_bf  [D_DIM][D_DIM]
    const float* __restrict__ bias,
    unsigned short* __restrict__ C)         // [M_ROWS][D_DIM] bf16
{
  __shared__ unsigned short smem[2 * 2 * 128 * 32];   // 32 KB: 2 x (sA | sB)

  const int tid = threadIdx.x;
  const int lane = tid & 63;
  const int wave = tid >> 6;
  const int wr = wave >> 1, wc = wave & 1;
  const int row0 = blockIdx.x * 128;
  const int col0 = blockIdx.y * 128;

  const int st_r = lane >> 2;
  const int st_cb = (lane & 3) * 16;

  auto STAGE = [&](int d, int k0) {
    unsigned short* dA = smem + d * (2 * 128 * 32);
    unsigned short* dB = dA + 128 * 32;
#pragma unroll
    for (int i = 0; i < 2; ++i) {
      const int seg = wave * 2 + i;
      const int rr = seg * 16 + st_r;
      async_copy16((char*)dA + seg * 1024,
                   (const char*)(A + (size_t)(row0 + rr) * D_DIM + k0) + st_cb);
      async_copy16((char*)dB + seg * 1024,
                   (const char*)(B + (size_t)(col0 + rr) * D_DIM + k0) + st_cb);
    }
  };

  f32x4 acc[4][4];
#pragma unroll
  for (int m = 0; m < 4; ++m)
#pragma unroll
    for (int n = 0; n < 4; ++n) acc[m][n] = (f32x4){0.f, 0.f, 0.f, 0.f};

  STAGE(0, 0);
  __syncthreads();
  int cur = 0;
  for (int t = 0; t < 32; ++t) {
    if (t < 31) STAGE(cur ^ 1, (t + 1) * 32);
    const unsigned short* sA = smem + cur * (2 * 128 * 32);
    const unsigned short* sB = sA + 128 * 32;
    bf16x8 af[4], bfr[4];
#pragma unroll
    for (int m = 0; m < 4; ++m)
      af[m] = *(const bf16x8*)(sA + (wr * 64 + m * 16 + (lane & 15)) * 32 + (lane >> 4) * 8);
#pragma unroll
    for (int n = 0; n < 4; ++n)
      bfr[n] = *(const bf16x8*)(sB + (wc * 64 + n * 16 + (lane & 15)) * 32 + (lane >> 4) * 8);
#pragma unroll
    for (int m = 0; m < 4; ++m)
#pragma unroll
      for (int n = 0; n < 4; ++n)
        acc[m][n] = __builtin_amdgcn_mfma_f32_16x16x32_bf16(af[m], bfr[n], acc[m][n], 0, 0, 0);
    __syncthreads();
    cur ^= 1;
  }

#pragma unroll
  for (int n = 0; n < 4; ++n) {
    const int col = col0 + wc * 64 + n * 16 + (lane & 15);
    const float bcol = bias[col];
#pragma unroll
    for (int m = 0; m < 4; ++m)
#pragma unroll
      for (int r = 0; r < 4; ++r) {
        const int row = row0 + wr * 64 + m * 16 + (lane >> 4) * 4 + r;
        C[(size_t)row * D_DIM + col] = f32_to_bf16(acc[m][n][r] + bcol);
      }
  }
}

// ---------------------------------------------------------------------------
// V projection via bf16 MFMA — with the same 2-phase prefetch.
// ---------------------------------------------------------------------------
__global__ __launch_bounds__(256) void vproj_bf16(
    const unsigned short* __restrict__ A,
    const unsigned short* __restrict__ B,
    const float* __restrict__ bias,
    float* __restrict__ C)
{
  __shared__ unsigned short smem[2 * 2 * 128 * 32];   // 32 KB

  const int tid = threadIdx.x;
  const int lane = tid & 63;
  const int wave = tid >> 6;
  const int wr = wave >> 1, wc = wave & 1;
  const int row0 = blockIdx.x * 128;
  const int col0 = blockIdx.y * 128;

  const int st_r = lane >> 2;
  const int st_cb = (lane & 3) * 16;

  auto STAGE = [&](int d, int k0) {
    unsigned short* dA = smem + d * (2 * 128 * 32);
    unsigned short* dB = dA + 128 * 32;
#pragma unroll
    for (int i = 0; i < 2; ++i) {
      const int seg = wave * 2 + i;
      const int rr = seg * 16 + st_r;
      async_copy16((char*)dA + seg * 1024,
                   (const char*)(A + (size_t)(row0 + rr) * D_DIM + k0) + st_cb);
      async_copy16((char*)dB + seg * 1024,
                   (const char*)(B + (size_t)(col0 + rr) * D_DIM + k0) + st_cb);
    }
  };

  f32x4 acc[4][4];
#pragma unroll
  for (int m = 0; m < 4; ++m)
#pragma unroll
    for (int n = 0; n < 4; ++n) acc[m][n] = (f32x4){0.f, 0.f, 0.f, 0.f};

  STAGE(0, 0);
  __syncthreads();
  int cur = 0;
  for (int t = 0; t < 32; ++t) {
    if (t < 31) STAGE(cur ^ 1, (t + 1) * 32);
    const unsigned short* sA = smem + cur * (2 * 128 * 32);
    const unsigned short* sB = sA + 128 * 32;
    bf16x8 af[4], bfr[4];
#pragma unroll
    for (int m = 0; m < 4; ++m)
      af[m] = *(const bf16x8*)(sA + (wr * 64 + m * 16 + (lane & 15)) * 32 + (lane >> 4) * 8);
#pragma unroll
    for (int n = 0; n < 4; ++n)
      bfr[n] = *(const bf16x8*)(sB + (wc * 64 + n * 16 + (lane & 15)) * 32 + (lane >> 4) * 8);
#pragma unroll
    for (int m = 0; m < 4; ++m)
#pragma unroll
      for (int n = 0; n < 4; ++n)
        acc[m][n] = __builtin_amdgcn_mfma_f32_16x16x32_bf16(af[m], bfr[n], acc[m][n], 0, 0, 0);
    __syncthreads();
    cur ^= 1;
  }

#pragma unroll
  for (int n = 0; n < 4; ++n) {
    const int col = col0 + wc * 64 + n * 16 + (lane & 15);
    const float bcol = bias[col];
#pragma unroll
    for (int m = 0; m < 4; ++m)
#pragma unroll
      for (int r = 0; r < 4; ++r) {
        const int row = row0 + wr * 64 + m * 16 + (lane >> 4) * 4 + r;
        C[(size_t)row * D_DIM + col] = acc[m][n][r] + bcol;
      }
  }
}

// ---------------------------------------------------------------------------
// Gather selected V rows + LayerNorm (unchanged).
// ---------------------------------------------------------------------------
__global__ __launch_bounds__(256) void gather_ln(
    const float* __restrict__ V, const int* __restrict__ topi,
    const float* __restrict__ gamma, const float* __restrict__ beta,
    float* __restrict__ out)
{
  const int row = blockIdx.x;
  const int tid = threadIdx.x;
  const int idx = topi[row];
  const float* src = V + (size_t)idx * D_DIM;
  const float4 v = *(const float4*)(src + tid * 4);
  float s = v.x + v.y + v.z + v.w;
  float s2 = v.x * v.x + v.y * v.y + v.z * v.z + v.w * v.w;
#pragma unroll
  for (int off = 32; off > 0; off >>= 1) {
    s += __shfl_down(s, off);
    s2 += __shfl_down(s2, off);
  }
  __shared__ float red[8];
  __shared__ float stats[2];
  const int wid = tid >> 6;
  if ((tid & 63) == 0) { red[wid] = s; red[4 + wid] = s2; }
  __syncthreads();
  if (tid == 0) {
    const float S = red[0] + red[1] + red[2] + red[3];
    const float S2 = red[4] + red[5] + red[6] + red[7];
    const float mu = S * (1.0f / D_DIM);
    const float var = S2 * (1.0f / D_DIM) - mu * mu;
    stats[0] = mu;
    stats[1] = rsqrtf(var + 1e-5f);
  }
  __syncthreads();
  const float mu = stats[0], rstd = stats[1];
  const float4 g4 = *(const float4*)(gamma + tid * 4);
  const float4 b4 = *(const float4*)(beta + tid * 4);
  float4 o;
  o.x = (v.x - mu) * rstd * g4.x + b4.x;
  o.y = (v.y - mu) * rstd * g4.y + b4.y;
  o.z = (v.z - mu) * rstd * g4.z + b4.z;
  o.w = (v.w - mu) * rstd * g4.w + b4.w;
  *(float4*)(out + (size_t)row * D_DIM + tid * 4) = o;
}

extern "C" void kernel_launch(void* const* d_in, const int* in_sizes, int n_in,
                              void* d_out, int out_size, void* d_ws, size_t ws_size,
                              hipStream_t stream)
{
  const float* query = (const float*)d_in[0];
  const float* mem   = (const float*)d_in[1];
  const float* Wq    = (const float*)d_in[2];
  const float* bq    = (const float*)d_in[3];
  const float* Wk    = (const float*)d_in[4];
  const float* bk    = (const float*)d_in[5];
  const float* Wv    = (const float*)d_in[6];
  const float* bv    = (const float*)d_in[7];
  const float* gamma = (const float*)d_in[8];
  const float* beta  = (const float*)d_in[9];
  float* out = (float*)d_out;

  char* ws = (char*)d_ws;
  double* q64 = (double*)ws;   ws += (size_t)B_ROWS * D_DIM * sizeof(double);   // 33.6 MB
  double* u64 = (double*)ws;   ws += (size_t)B_ROWS * D_DIM * sizeof(double);   // 33.6 MB
  unsigned short* qbf = (unsigned short*)ws;
  ws += (size_t)B_ROWS * D_DIM * sizeof(unsigned short);                        // 8.4 MB
  unsigned short* membf = (unsigned short*)ws;
  ws += (size_t)M_ROWS * D_DIM * sizeof(unsigned short);                        // 67.1 MB
  char* Aregion = ws;
  ws += (size_t)M_ROWS * D_DIM * sizeof(unsigned short)                         // Kbf 67.1
      + 2 * (size_t)B_ROWS * NCB * TOPB * sizeof(float);                        // parts 67.1
  double* qbk = (double*)ws;   ws += (size_t)B_ROWS * sizeof(double);
  int* cand = (int*)ws;        ws += (size_t)B_ROWS * TOPC * sizeof(int);
  int* topi = (int*)ws;

  // Lifetimes (in-order stream):
  //  q64: dead after qbk+uproj -> hosts wkbf/wvbf casts.
  //  Aregion: Kbf+parts until merge; then Vout (exactly 134.2 MB) overlays.
  unsigned short* Kbf = (unsigned short*)Aregion;
  float* part_v = (float*)(Aregion + (size_t)M_ROWS * D_DIM * sizeof(unsigned short));
  int* part_i = (int*)((char*)part_v + (size_t)B_ROWS * NCB * TOPB * sizeof(float));
  unsigned short* wkbf = (unsigned short*)q64;
  unsigned short* wvbf = wkbf + (size_t)D_DIM * D_DIM;
  float* Vout = (float*)Aregion;

  qproj_f64<<<dim3(B_ROWS / BM, D_DIM / BN), 256, 0, stream>>>(query, Wq, bq, q64, qbf);
  qbk_dot<<<dim3(B_ROWS / 4), 256, 0, stream>>>(q64, bk, qbk);
  uproj_f64<<<dim3(B_ROWS / BM, D_DIM / BN), 256, 0, stream>>>(q64, Wk, u64);

  // q64 now dead -> casts may overwrite it.
  cast_f32_bf16<<<dim3((M_ROWS * D_DIM / 4 + 255) / 256), 256, 0, stream>>>(mem, membf, M_ROWS * D_DIM / 4);
  cast_f32_bf16<<<dim3((D_DIM * D_DIM / 4 + 255) / 256), 256, 0, stream>>>(Wk, wkbf, D_DIM * D_DIM / 4);
  cast_f32_bf16<<<dim3((D_DIM * D_DIM / 4 + 255) / 256), 256, 0, stream>>>(Wv, wvbf, D_DIM * D_DIM / 4);

  kproj_bf16<<<dim3(M_ROWS / 128, D_DIM / 128), 256, 0, stream>>>(membf, wkbf, bk, Kbf);
  sims_topc_gemm<<<dim3((B_ROWS / 128) * NCB), 256, 0, stream>>>(qbf, Kbf, part_v, part_i);
  merge_cand256<<<dim3(B_ROWS), 256, 0, stream>>>(part_v, part_i, cand);
  rescore_topk_u<<<dim3(B_ROWS), 256, 0, stream>>>(u64, qbk, mem, cand, topi);

  vproj_bf16<<<dim3(M_ROWS / 128, D_DIM / 128), 256, 0, stream>>>(membf, wvbf, bv, Vout);
  gather_ln<<<dim3(B_ROWS * TOPK), 256, 0, stream>>>(Vout, topi, gamma, beta, out);
}

// Round 14
// 2132.740 us; speedup vs baseline: 3.7558x; 1.0987x over previous
//
#include <hip/hip_runtime.h>
#include <hip/hip_bf16.h>
#include <math.h>

#define D_DIM 1024
#define B_ROWS 4096
#define M_ROWS 32768
#define TOPK 8
#define TOPC 16                // candidates per row after merge
#define TOPB 8                 // entries stored per (row, col-block): 2 halves x top-4
#define NCB (M_ROWS / 128)     // 256 col-blocks

#define BM 128
#define BN 64
#define BK 32

typedef __attribute__((ext_vector_type(8))) short bf16x8;
typedef __attribute__((ext_vector_type(4))) float f32x4;

__device__ __forceinline__ unsigned short f32_to_bf16(float f) {
  unsigned int u = __float_as_uint(f);
  unsigned int r = (u + 0x7FFFu + ((u >> 16) & 1u)) >> 16;
  return (unsigned short)r;
}
__device__ __forceinline__ float bf16_to_f32(unsigned short h) {
  return __uint_as_float(((unsigned int)h) << 16);
}
__device__ __forceinline__ void async_copy16(void* lds, const void* g) {
  __builtin_amdgcn_global_load_lds(
      (const __attribute__((address_space(1))) unsigned int*)g,
      (__attribute__((address_space(3))) unsigned int*)lds, 16, 0, 0);
}

// Ordered insert into a register top-N list sorted by (value desc, index asc).
template <int N>
__device__ __forceinline__ void insN(float v, int idx,
                                     float* __restrict__ tv,
                                     int* __restrict__ ti) {
  if (v < tv[N - 1]) return;
  if (v == tv[N - 1] && idx > ti[N - 1]) return;
  float cv = v;
  int ci = idx;
#pragma unroll
  for (int p = 0; p < N; ++p) {
    if (cv > tv[p] || (cv == tv[p] && ci < ti[p])) {
      const float t0 = tv[p]; tv[p] = cv; cv = t0;
      const int t1 = ti[p]; ti[p] = ci; ci = t1;
    }
  }
}

// ---------------------------------------------------------------------------
// q projection: f64 accumulation (selection chain). Unchanged.
// ---------------------------------------------------------------------------
__global__ __launch_bounds__(256) void qproj_f64(
    const float* __restrict__ X, const float* __restrict__ W,
    const float* __restrict__ bias, double* __restrict__ out64,
    unsigned short* __restrict__ outbf)
{
  __shared__ float sA[BK][BM + 4];
  __shared__ float sB[BK][BN + 4];
  const int tid = threadIdx.x;
  const int tx = tid & 15, ty = tid >> 4;
  const int row0 = blockIdx.x * BM;
  const int col0 = blockIdx.y * BN;
  const int lr = tid >> 3;         // 0..31
  const int lc = (tid & 7) << 2;   // 0,4,...,28

  double acc[2][4][4];
#pragma unroll
  for (int g = 0; g < 2; ++g)
#pragma unroll
    for (int i = 0; i < 4; ++i)
#pragma unroll
      for (int j = 0; j < 4; ++j) acc[g][i][j] = 0.0;

  for (int k0 = 0; k0 < D_DIM; k0 += BK) {
#pragma unroll
    for (int rr = 0; rr < 4; ++rr) {
      const float4 v = *(const float4*)(X + (size_t)(row0 + lr + 32 * rr) * D_DIM + k0 + lc);
      sA[lc + 0][lr + 32 * rr] = v.x;
      sA[lc + 1][lr + 32 * rr] = v.y;
      sA[lc + 2][lr + 32 * rr] = v.z;
      sA[lc + 3][lr + 32 * rr] = v.w;
    }
#pragma unroll
    for (int rr = 0; rr < 2; ++rr) {
      const float4 v = *(const float4*)(W + (size_t)(col0 + lr + 32 * rr) * D_DIM + k0 + lc);
      sB[lc + 0][lr + 32 * rr] = v.x;
      sB[lc + 1][lr + 32 * rr] = v.y;
      sB[lc + 2][lr + 32 * rr] = v.z;
      sB[lc + 3][lr + 32 * rr] = v.w;
    }
    __syncthreads();
#pragma unroll
    for (int kk = 0; kk < BK; ++kk) {
      const float4 A0 = *(const float4*)&sA[kk][ty * 4];
      const float4 A1 = *(const float4*)&sA[kk][64 + ty * 4];
      const float4 Bv = *(const float4*)&sB[kk][tx * 4];
      const double a0[4] = {A0.x, A0.y, A0.z, A0.w};
      const double a1[4] = {A1.x, A1.y, A1.z, A1.w};
      const double bb[4] = {Bv.x, Bv.y, Bv.z, Bv.w};
#pragma unroll
      for (int i = 0; i < 4; ++i)
#pragma unroll
        for (int j = 0; j < 4; ++j) {
          acc[0][i][j] = fma(a0[i], bb[j], acc[0][i][j]);
          acc[1][i][j] = fma(a1[i], bb[j], acc[1][i][j]);
        }
    }
    __syncthreads();
  }
  const float4 bv4 = *(const float4*)(bias + col0 + tx * 4);
  const double bb[4] = {bv4.x, bv4.y, bv4.z, bv4.w};
#pragma unroll
  for (int g = 0; g < 2; ++g)
#pragma unroll
    for (int i = 0; i < 4; ++i) {
      double o[4];
#pragma unroll
      for (int j = 0; j < 4; ++j) o[j] = acc[g][i][j] + bb[j];
      const size_t base = (size_t)(row0 + g * 64 + ty * 4 + i) * D_DIM + col0 + tx * 4;
      *(double2*)(out64 + base)     = (double2){o[0], o[1]};
      *(double2*)(out64 + base + 2) = (double2){o[2], o[3]};
      ushort4 ob;
      ob.x = f32_to_bf16((float)o[0]);
      ob.y = f32_to_bf16((float)o[1]);
      ob.z = f32_to_bf16((float)o[2]);
      ob.w = f32_to_bf16((float)o[3]);
      *(ushort4*)(outbf + base) = ob;
    }
}

// ---------------------------------------------------------------------------
// qbk[b] = dot_f64(q64[b,:], bk). One wave per row.
// ---------------------------------------------------------------------------
__global__ __launch_bounds__(256) void qbk_dot(
    const double* __restrict__ Q64, const float* __restrict__ bk_,
    double* __restrict__ qbk)
{
  const int b = blockIdx.x * 4 + (threadIdx.x >> 6);
  const int lane = threadIdx.x & 63;
  const double* qrow = Q64 + (size_t)b * D_DIM + lane * 16;
  const float* bkrow = bk_ + lane * 16;
  double acc = 0.0;
#pragma unroll
  for (int i = 0; i < 4; ++i) {
    const float4 bv = *(const float4*)(bkrow + i * 4);
    const double2 qa = *(const double2*)(qrow + i * 4);
    const double2 qb2 = *(const double2*)(qrow + i * 4 + 2);
    acc = fma(qa.x, (double)bv.x, acc);
    acc = fma(qa.y, (double)bv.y, acc);
    acc = fma(qb2.x, (double)bv.z, acc);
    acc = fma(qb2.y, (double)bv.w, acc);
  }
#pragma unroll
  for (int off = 32; off > 0; off >>= 1) acc += __shfl_down(acc, off);
  if (lane == 0) qbk[b] = acc;
}

// ---------------------------------------------------------------------------
// u = q64 @ Wk (NN, f64). Unchanged.
// ---------------------------------------------------------------------------
__global__ __launch_bounds__(256) void uproj_f64(
    const double* __restrict__ A, const float* __restrict__ Bw,
    double* __restrict__ U)
{
  __shared__ double sAd[BM][BK + 1];   // 33.0 KB
  __shared__ float sBf[BK][BN + 4];    // 8.7 KB
  const int tid = threadIdx.x;
  const int tx = tid & 15, ty = tid >> 4;
  const int row0 = blockIdx.x * BM;
  const int col0 = blockIdx.y * BN;

  double acc[2][4][4];
#pragma unroll
  for (int g = 0; g < 2; ++g)
#pragma unroll
    for (int i = 0; i < 4; ++i)
#pragma unroll
      for (int j = 0; j < 4; ++j) acc[g][i][j] = 0.0;

  for (int k0 = 0; k0 < D_DIM; k0 += BK) {
#pragma unroll
    for (int it = 0; it < 8; ++it) {
      const int L = it * 256 + tid;
      const int row = L >> 4, kp = (L & 15) * 2;
      const double2 d2 = *(const double2*)(A + (size_t)(row0 + row) * D_DIM + k0 + kp);
      sAd[row][kp] = d2.x;
      sAd[row][kp + 1] = d2.y;
    }
#pragma unroll
    for (int it = 0; it < 2; ++it) {
      const int L = it * 256 + tid;
      const int kk = L >> 4, j4 = (L & 15) * 4;
      const float4 v = *(const float4*)(Bw + (size_t)(k0 + kk) * D_DIM + col0 + j4);
      sBf[kk][j4 + 0] = v.x;
      sBf[kk][j4 + 1] = v.y;
      sBf[kk][j4 + 2] = v.z;
      sBf[kk][j4 + 3] = v.w;
    }
    __syncthreads();
#pragma unroll
    for (int kk = 0; kk < BK; ++kk) {
      const double a0[4] = {sAd[ty * 4 + 0][kk], sAd[ty * 4 + 1][kk],
                            sAd[ty * 4 + 2][kk], sAd[ty * 4 + 3][kk]};
      const double a1[4] = {sAd[64 + ty * 4 + 0][kk], sAd[64 + ty * 4 + 1][kk],
                            sAd[64 + ty * 4 + 2][kk], sAd[64 + ty * 4 + 3][kk]};
      const float4 Bv = *(const float4*)&sBf[kk][tx * 4];
      const double bb[4] = {Bv.x, Bv.y, Bv.z, Bv.w};
#pragma unroll
      for (int i = 0; i < 4; ++i)
#pragma unroll
        for (int j = 0; j < 4; ++j) {
          acc[0][i][j] = fma(a0[i], bb[j], acc[0][i][j]);
          acc[1][i][j] = fma(a1[i], bb[j], acc[1][i][j]);
        }
    }
    __syncthreads();
  }
#pragma unroll
  for (int g = 0; g < 2; ++g)
#pragma unroll
    for (int i = 0; i < 4; ++i) {
      const size_t base = (size_t)(row0 + g * 64 + ty * 4 + i) * D_DIM + col0 + tx * 4;
      *(double2*)(U + base)     = (double2){acc[g][i][0], acc[g][i][1]};
      *(double2*)(U + base + 2) = (double2){acc[g][i][2], acc[g][i][3]};
    }
}

// ---------------------------------------------------------------------------
// Fused sims + per-half top-4. Round-14: depth-2-ahead COUNTED-vmcnt pipeline
// (T3+T4 coarse form): 512 threads (8 waves, 2/SIMD even at 1 block/CU),
// 256x128 tile (256 MFMA per barrier), BK=64, 3 LDS buffers (144 KB).
// Loop: STAGE(t+2) -> compute(t) -> vmcnt(6) [tile t+1 landed, t+2 still in
// flight ACROSS the barrier] -> sched_barrier -> raw s_barrier. vmcnt never
// drains to 0 in steady state (AITER pattern). Hazards: buf(t+2)%3 differs
// from bufs t,(t+1); per-wave issue-order vmcnt proves stage(t) landed;
// ds_reads are register-complete before barriers (MFMA forces lgkmcnt).
// XOR swizzle (0 conflicts), cb-resident XCD mapping, insN<4> epilogue kept.
// ---------------------------------------------------------------------------
#define SBUF 24576   // 48 KB per buffer, in ushorts (A 32KB + B 16KB)
__global__ __launch_bounds__(512, 2) void sims_topc_gemm(
    const unsigned short* __restrict__ A, const unsigned short* __restrict__ B,
    float* __restrict__ part_v, int* __restrict__ part_i)
{
  __shared__ unsigned short smem[3 * SBUF];   // 144 KB

  const int tid = threadIdx.x;
  const int lane = tid & 63;
  const int wave = tid >> 6;          // 0..7
  const int wr = wave >> 1;           // 0..3 -> A rows wr*64
  const int wc = wave & 1;            // 0..1 -> B rows wc*64

  // cb-resident mapping (bijective over 4096 blocks): XCD x owns 4 groups of
  // 8 cbs; within a group 16 row-blocks iterate r-major (2MB B-group L2-hot).
  const int bid = blockIdx.x;
  const int x = bid & 7;
  const int t9 = bid >> 3;            // 0..511
  const int cbg = t9 >> 7;            // 0..3
  const int r = (t9 >> 3) & 15;       // 0..15
  const int cbl = t9 & 7;             // 0..7
  const int cb = (x * 4 + cbg) * 8 + cbl;
  const int row0 = r * 256;
  const int col0 = cb * 128;

  const int st_r = lane >> 3;                    // row within 8-row segment
  const int st_swz = ((lane & 7) ^ st_r) * 16;   // pre-swizzled global chunk

  // STAGE tile t into buffer d: A 256x64 (32 segs of 1KB) + B 128x64 (16 segs).
  // Wave w issues segs 6w..6w+5; LDS dest wave-uniform base + lane*16.
  auto STAGE = [&](int d, int k0) {
    unsigned short* buf = smem + d * SBUF;
#pragma unroll
    for (int i = 0; i < 6; ++i) {
      const int seg = wave * 6 + i;
      if (seg < 32) {
        const int grow = row0 + seg * 8 + st_r;
        async_copy16((char*)(buf + seg * 512),
                     (const char*)(A + (size_t)grow * D_DIM + k0) + st_swz);
      } else {
        const int s2 = seg - 32;
        const int grow = col0 + s2 * 8 + st_r;
        async_copy16((char*)(buf + 16384 + s2 * 512),
                     (const char*)(B + (size_t)grow * D_DIM + k0) + st_swz);
      }
    }
  };

  f32x4 acc[4][4];
#pragma unroll
  for (int m = 0; m < 4; ++m)
#pragma unroll
    for (int n = 0; n < 4; ++n) acc[m][n] = (f32x4){0.f, 0.f, 0.f, 0.f};

  auto COMPUTE = [&](int d) {
    const unsigned short* sA = smem + d * SBUF;
    const unsigned short* sB = sA + 16384;
#pragma unroll
    for (int ks = 0; ks < 2; ++ks) {
      bf16x8 af[4], bfr[4];
      const int ch = ks * 4 + (lane >> 4);       // 16B chunk 0..7 of 128B row
#pragma unroll
      for (int m = 0; m < 4; ++m) {
        const int Ra = wr * 64 + m * 16 + (lane & 15);
        af[m] = *(const bf16x8*)((const char*)sA + Ra * 128 + ((ch ^ (Ra & 7)) * 16));
      }
#pragma unroll
      for (int n = 0; n < 4; ++n) {
        const int Rb = wc * 64 + n * 16 + (lane & 15);
        bfr[n] = *(const bf16x8*)((const char*)sB + Rb * 128 + ((ch ^ (Rb & 7)) * 16));
      }
#pragma unroll
      for (int m = 0; m < 4; ++m)
#pragma unroll
        for (int n = 0; n < 4; ++n)
          acc[m][n] = __builtin_amdgcn_mfma_f32_16x16x32_bf16(af[m], bfr[n], acc[m][n], 0, 0, 0);
    }
  };

  // Prologue: tiles 0,1 in flight; wait tile 0 (oldest 6 of 12 per wave).
  STAGE(0, 0);
  STAGE(1, 64);
  asm volatile("s_waitcnt vmcnt(6)" ::: "memory");
  __builtin_amdgcn_sched_barrier(0);
  __builtin_amdgcn_s_barrier();

  for (int t = 0; t < 16; ++t) {
    if (t < 14) STAGE((t + 2) % 3, (t + 2) * 64);
    COMPUTE(t % 3);
    if (t < 14) {
      asm volatile("s_waitcnt vmcnt(6)" ::: "memory");   // tile t+1 landed
    } else if (t == 14) {
      asm volatile("s_waitcnt vmcnt(0)" ::: "memory");   // tile 15 landed
    }
    __builtin_amdgcn_sched_barrier(0);
    __builtin_amdgcn_s_barrier();
  }
  // K-loop done (final barrier passed): smem free for the C tile.

  // C/D layout (m89): col=lane&15 (within 16), row=(lane>>4)*4+reg.
#pragma unroll
  for (int m = 0; m < 4; ++m)
#pragma unroll
    for (int n = 0; n < 4; ++n)
#pragma unroll
      for (int rg = 0; rg < 4; ++rg) {
        const int row = wr * 64 + m * 16 + (lane >> 4) * 4 + rg;
        const int colL = wc * 64 + n * 16 + (lane & 15);
        smem[row * 132 + colL] = f32_to_bf16(acc[m][n][rg]);
      }
  __syncthreads();

  {
    const int row = tid & 255;          // 0..255
    const int h = tid >> 8;             // 0..1 (64-col half)
    float tv[4];
    int ti_[4];
#pragma unroll
    for (int p = 0; p < 4; ++p) { tv[p] = -INFINITY; ti_[p] = 0; }
    const unsigned short* crow = smem + row * 132 + h * 64;
    const int gcol = col0 + h * 64;
    for (int j = 0; j < 64; j += 4) {
      const ushort4 c4 = *(const ushort4*)(crow + j);
      insN<4>(bf16_to_f32(c4.x), gcol + j + 0, tv, ti_);
      insN<4>(bf16_to_f32(c4.y), gcol + j + 1, tv, ti_);
      insN<4>(bf16_to_f32(c4.z), gcol + j + 2, tv, ti_);
      insN<4>(bf16_to_f32(c4.w), gcol + j + 3, tv, ti_);
    }
    const size_t base = ((size_t)(row0 + row) * NCB + cb) * TOPB + h * 4;
    *(float4*)(part_v + base) = (float4){tv[0], tv[1], tv[2], tv[3]};
    *(int4*)(part_i + base)   = (int4){ti_[0], ti_[1], ti_[2], ti_[3]};
  }
}

// ---------------------------------------------------------------------------
// Merge all per-(row,cb) entries -> 16 candidates (round-8-proven).
// ---------------------------------------------------------------------------
__global__ __launch_bounds__(256) void merge_cand256(
    const float* __restrict__ part_v, const int* __restrict__ part_i,
    int* __restrict__ cand)
{
  const int r = blockIdx.x;
  const int tid = threadIdx.x;

  __shared__ float lv[256][TOPB];
  __shared__ int li[256][TOPB];

  {
    const size_t base = ((size_t)r * NCB + tid) * TOPB;
    const float4 a0 = *(const float4*)(part_v + base);
    const float4 a1 = *(const float4*)(part_v + base + 4);
    const int4 b0 = *(const int4*)(part_i + base);
    const int4 b1 = *(const int4*)(part_i + base + 4);
    lv[tid][0] = a0.x; lv[tid][1] = a0.y; lv[tid][2] = a0.z; lv[tid][3] = a0.w;
    lv[tid][4] = a1.x; lv[tid][5] = a1.y; lv[tid][6] = a1.z; lv[tid][7] = a1.w;
    li[tid][0] = b0.x; li[tid][1] = b0.y; li[tid][2] = b0.z; li[tid][3] = b0.w;
    li[tid][4] = b1.x; li[tid][5] = b1.y; li[tid][6] = b1.z; li[tid][7] = b1.w;
  }
  __syncthreads();

  __shared__ float mv16[16][TOPC];
  __shared__ int mi16[16][TOPC];
  if (tid < 16) {
    float mv[TOPC];
    int mi[TOPC];
#pragma unroll
    for (int p = 0; p < TOPC; ++p) { mv[p] = -INFINITY; mi[p] = 0; }
    for (int s = tid * 16; s < tid * 16 + 16; ++s)
      for (int p0 = 0; p0 < TOPB; ++p0) insN<TOPC>(lv[s][p0], li[s][p0], mv, mi);
#pragma unroll
    for (int p = 0; p < TOPC; ++p) { mv16[tid][p] = mv[p]; mi16[tid][p] = mi[p]; }
  }
  __syncthreads();

  if (tid == 0) {
    float mv[TOPC];
    int mi[TOPC];
#pragma unroll
    for (int p = 0; p < TOPC; ++p) { mv[p] = -INFINITY; mi[p] = 0; }
    for (int s = 0; s < 16; ++s)
      for (int p0 = 0; p0 < TOPC; ++p0) insN<TOPC>(mv16[s][p0], mi16[s][p0], mv, mi);
#pragma unroll
    for (int p = 0; p < TOPC; ++p)
      cand[(size_t)r * TOPC + p] = mi[p];
  }
}

// ---------------------------------------------------------------------------
// fp64 rescore via u: sims_ci = dot_f64(u_b, mem_ci) + qbk_b (round-10-proven).
// ---------------------------------------------------------------------------
__global__ __launch_bounds__(256) void rescore_topk_u(
    const double* __restrict__ U, const double* __restrict__ qbk,
    const float* __restrict__ mem, const int* __restrict__ cand,
    int* __restrict__ topi)
{
  const int b = blockIdx.x;
  const int tid = threadIdx.x;
  const int wave = tid >> 6;
  const int lane = tid & 63;

  __shared__ double sval[TOPC];
  __shared__ int sidx[TOPC];

  const double* urow = U + (size_t)b * D_DIM + lane * 16;
  double uv[16];
#pragma unroll
  for (int i = 0; i < 8; ++i) {
    const double2 d2 = *(const double2*)(urow + i * 2);
    uv[i * 2] = d2.x;
    uv[i * 2 + 1] = d2.y;
  }
  const double qb = qbk[b];

  for (int c = wave; c < TOPC; c += 4) {
    const int ci = cand[(size_t)b * TOPC + c];
    const float* mrow = mem + (size_t)ci * D_DIM + lane * 16;
    double acc = 0.0;
#pragma unroll
    for (int i = 0; i < 4; ++i) {
      const float4 mv = *(const float4*)(mrow + i * 4);
      acc = fma(uv[i * 4 + 0], (double)mv.x, acc);
      acc = fma(uv[i * 4 + 1], (double)mv.y, acc);
      acc = fma(uv[i * 4 + 2], (double)mv.z, acc);
      acc = fma(uv[i * 4 + 3], (double)mv.w, acc);
    }
#pragma unroll
    for (int off = 32; off > 0; off >>= 1) acc += __shfl_down(acc, off);
    if (lane == 0) { sval[c] = acc + qb; sidx[c] = ci; }
  }
  __syncthreads();

  if (tid == 0) {
    bool used[TOPC];
#pragma unroll
    for (int p = 0; p < TOPC; ++p) used[p] = false;
#pragma unroll
    for (int p = 0; p < TOPK; ++p) {
      int best = -1;
      double bv = 0.0;
      int bi = 0;
      for (int c = 0; c < TOPC; ++c) {
        if (used[c]) continue;
        const double v = sval[c];
        const int ix = sidx[c];
        if (best < 0 || v > bv || (v == bv && ix < bi)) { best = c; bv = v; bi = ix; }
      }
      used[best] = true;
      topi[(size_t)b * TOPK + p] = bi;
    }
  }
}

// ---------------------------------------------------------------------------
// f32 -> bf16 cast (vectorized).
// ---------------------------------------------------------------------------
__global__ __launch_bounds__(256) void cast_f32_bf16(
    const float* __restrict__ src, unsigned short* __restrict__ dst, int n4)
{
  const int i = blockIdx.x * 256 + threadIdx.x;
  if (i >= n4) return;
  const float4 v = *(const float4*)(src + (size_t)i * 4);
  ushort4 o;
  o.x = f32_to_bf16(v.x);
  o.y = f32_to_bf16(v.y);
  o.z = f32_to_bf16(v.z);
  o.w = f32_to_bf16(v.w);
  *(ushort4*)(dst + (size_t)i * 4) = o;
}

// ---------------------------------------------------------------------------
// K projection via bf16 MFMA, bf16 output — round-13 2-phase dbuf (proven).
// ---------------------------------------------------------------------------
__global__ __launch_bounds__(256) void kproj_bf16(
    const unsigned short* __restrict__ A,   // mem_bf [M_ROWS][D_DIM]
    const unsigned short* __restrict__ B,   // Wk_bf  [D_DIM][D_DIM]
    const float* __restrict__ bias,
    unsigned short* __restrict__ C)         // [M_ROWS][D_DIM] bf16
{
  __shared__ unsigned short smem[2 * 2 * 128 * 32];   // 32 KB: 2 x (sA | sB)

  const int tid = threadIdx.x;
  const int lane = tid & 63;
  const int wave = tid >> 6;
  const int wr = wave >> 1, wc = wave & 1;
  const int row0 = blockIdx.x * 128;
  const int col0 = blockIdx.y * 128;

  const int st_r = lane >> 2;
  const int st_cb = (lane & 3) * 16;

  auto STAGE = [&](int d, int k0) {
    unsigned short* dA = smem + d * (2 * 128 * 32);
    unsigned short* dB = dA + 128 * 32;
#pragma unroll
    for (int i = 0; i < 2; ++i) {
      const int seg = wave * 2 + i;
      const int rr = seg * 16 + st_r;
      async_copy16((char*)dA + seg * 1024,
                   (const char*)(A + (size_t)(row0 + rr) * D_DIM + k0) + st_cb);
      async_copy16((char*)dB + seg * 1024,
                   (const char*)(B + (size_t)(col0 + rr) * D_DIM + k0) + st_cb);
    }
  };

  f32x4 acc[4][4];
#pragma unroll
  for (int m = 0; m < 4; ++m)
#pragma unroll
    for (int n = 0; n < 4; ++n) acc[m][n] = (f32x4){0.f, 0.f, 0.f, 0.f};

  STAGE(0, 0);
  __syncthreads();
  int cur = 0;
  for (int t = 0; t < 32; ++t) {
    if (t < 31) STAGE(cur ^ 1, (t + 1) * 32);
    const unsigned short* sA = smem + cur * (2 * 128 * 32);
    const unsigned short* sB = sA + 128 * 32;
    bf16x8 af[4], bfr[4];
#pragma unroll
    for (int m = 0; m < 4; ++m)
      af[m] = *(const bf16x8*)(sA + (wr * 64 + m * 16 + (lane & 15)) * 32 + (lane >> 4) * 8);
#pragma unroll
    for (int n = 0; n < 4; ++n)
      bfr[n] = *(const bf16x8*)(sB + (wc * 64 + n * 16 + (lane & 15)) * 32 + (lane >> 4) * 8);
#pragma unroll
    for (int m = 0; m < 4; ++m)
#pragma unroll
      for (int n = 0; n < 4; ++n)
        acc[m][n] = __builtin_amdgcn_mfma_f32_16x16x32_bf16(af[m], bfr[n], acc[m][n], 0, 0, 0);
    __syncthreads();
    cur ^= 1;
  }

#pragma unroll
  for (int n = 0; n < 4; ++n) {
    const int col = col0 + wc * 64 + n * 16 + (lane & 15);
    const float bcol = bias[col];
#pragma unroll
    for (int m = 0; m < 4; ++m)
#pragma unroll
      for (int r = 0; r < 4; ++r) {
        const int row = row0 + wr * 64 + m * 16 + (lane >> 4) * 4 + r;
        C[(size_t)row * D_DIM + col] = f32_to_bf16(acc[m][n][r] + bcol);
      }
  }
}

// ---------------------------------------------------------------------------
// V projection via bf16 MFMA — round-13 2-phase dbuf (proven).
// ---------------------------------------------------------------------------
__global__ __launch_bounds__(256) void vproj_bf16(
    const unsigned short* __restrict__ A,
    const unsigned short* __restrict__ B,
    const float* __restrict__ bias,
    float* __restrict__ C)
{
  __shared__ unsigned short smem[2 * 2 * 128 * 32];   // 32 KB

  const int tid = threadIdx.x;
  const int lane = tid & 63;
  const int wave = tid >> 6;
  const int wr = wave >> 1, wc = wave & 1;
  const int row0 = blockIdx.x * 128;
  const int col0 = blockIdx.y * 128;

  const int st_r = lane >> 2;
  const int st_cb = (lane & 3) * 16;

  auto STAGE = [&](int d, int k0) {
    unsigned short* dA = smem + d * (2 * 128 * 32);
    unsigned short* dB = dA + 128 * 32;
#pragma unroll
    for (int i = 0; i < 2; ++i) {
      const int seg = wave * 2 + i;
      const int rr = seg * 16 + st_r;
      async_copy16((char*)dA + seg * 1024,
                   (const char*)(A + (size_t)(row0 + rr) * D_DIM + k0) + st_cb);
      async_copy16((char*)dB + seg * 1024,
                   (const char*)(B + (size_t)(col0 + rr) * D_DIM + k0) + st_cb);
    }
  };

  f32x4 acc[4][4];
#pragma unroll
  for (int m = 0; m < 4; ++m)
#pragma unroll
    for (int n = 0; n < 4; ++n) acc[m][n] = (f32x4){0.f, 0.f, 0.f, 0.f};

  STAGE(0, 0);
  __syncthreads();
  int cur = 0;
  for (int t = 0; t < 32; ++t) {
    if (t < 31) STAGE(cur ^ 1, (t + 1) * 32);
    const unsigned short* sA = smem + cur * (2 * 128 * 32);
    const unsigned short* sB = sA + 128 * 32;
    bf16x8 af[4], bfr[4];
#pragma unroll
    for (int m = 0; m < 4; ++m)
      af[m] = *(const bf16x8*)(sA + (wr * 64 + m * 16 + (lane & 15)) * 32 + (lane >> 4) * 8);
#pragma unroll
    for (int n = 0; n < 4; ++n)
      bfr[n] = *(const bf16x8*)(sB + (wc * 64 + n * 16 + (lane & 15)) * 32 + (lane >> 4) * 8);
#pragma unroll
    for (int m = 0; m < 4; ++m)
#pragma unroll
      for (int n = 0; n < 4; ++n)
        acc[m][n] = __builtin_amdgcn_mfma_f32_16x16x32_bf16(af[m], bfr[n], acc[m][n], 0, 0, 0);
    __syncthreads();
    cur ^= 1;
  }

#pragma unroll
  for (int n = 0; n < 4; ++n) {
    const int col = col0 + wc * 64 + n * 16 + (lane & 15);
    const float bcol = bias[col];
#pragma unroll
    for (int m = 0; m < 4; ++m)
#pragma unroll
      for (int r = 0; r < 4; ++r) {
        const int row = row0 + wr * 64 + m * 16 + (lane >> 4) * 4 + r;
        C[(size_t)row * D_DIM + col] = acc[m][n][r] + bcol;
      }
  }
}

// ---------------------------------------------------------------------------
// Gather selected V rows + LayerNorm (unchanged).
// ---------------------------------------------------------------------------
__global__ __launch_bounds__(256) void gather_ln(
    const float* __restrict__ V, const int* __restrict__ topi,
    const float* __restrict__ gamma, const float* __restrict__ beta,
    float* __restrict__ out)
{
  const int row = blockIdx.x;
  const int tid = threadIdx.x;
  const int idx = topi[row];
  const float* src = V + (size_t)idx * D_DIM;
  const float4 v = *(const float4*)(src + tid * 4);
  float s = v.x + v.y + v.z + v.w;
  float s2 = v.x * v.x + v.y * v.y + v.z * v.z + v.w * v.w;
#pragma unroll
  for (int off = 32; off > 0; off >>= 1) {
    s += __shfl_down(s, off);
    s2 += __shfl_down(s2, off);
  }
  __shared__ float red[8];
  __shared__ float stats[2];
  const int wid = tid >> 6;
  if ((tid & 63) == 0) { red[wid] = s; red[4 + wid] = s2; }
  __syncthreads();
  if (tid == 0) {
    const float S = red[0] + red[1] + red[2] + red[3];
    const float S2 = red[4] + red[5] + red[6] + red[7];
    const float mu = S * (1.0f / D_DIM);
    const float var = S2 * (1.0f / D_DIM) - mu * mu;
    stats[0] = mu;
    stats[1] = rsqrtf(var + 1e-5f);
  }
  __syncthreads();
  const float mu = stats[0], rstd = stats[1];
  const float4 g4 = *(const float4*)(gamma + tid * 4);
  const float4 b4 = *(const float4*)(beta + tid * 4);
  float4 o;
  o.x = (v.x - mu) * rstd * g4.x + b4.x;
  o.y = (v.y - mu) * rstd * g4.y + b4.y;
  o.z = (v.z - mu) * rstd * g4.z + b4.z;
  o.w = (v.w - mu) * rstd * g4.w + b4.w;
  *(float4*)(out + (size_t)row * D_DIM + tid * 4) = o;
}

extern "C" void kernel_launch(void* const* d_in, const int* in_sizes, int n_in,
                              void* d_out, int out_size, void* d_ws, size_t ws_size,
                              hipStream_t stream)
{
  const float* query = (const float*)d_in[0];
  const float* mem   = (const float*)d_in[1];
  const float* Wq    = (const float*)d_in[2];
  const float* bq    = (const float*)d_in[3];
  const float* Wk    = (const float*)d_in[4];
  const float* bk    = (const float*)d_in[5];
  const float* Wv    = (const float*)d_in[6];
  const float* bv    = (const float*)d_in[7];
  const float* gamma = (const float*)d_in[8];
  const float* beta  = (const float*)d_in[9];
  float* out = (float*)d_out;

  char* ws = (char*)d_ws;
  double* q64 = (double*)ws;   ws += (size_t)B_ROWS * D_DIM * sizeof(double);   // 33.6 MB
  double* u64 = (double*)ws;   ws += (size_t)B_ROWS * D_DIM * sizeof(double);   // 33.6 MB
  unsigned short* qbf = (unsigned short*)ws;
  ws += (size_t)B_ROWS * D_DIM * sizeof(unsigned short);                        // 8.4 MB
  unsigned short* membf = (unsigned short*)ws;
  ws += (size_t)M_ROWS * D_DIM * sizeof(unsigned short);                        // 67.1 MB
  char* Aregion = ws;
  ws += (size_t)M_ROWS * D_DIM * sizeof(unsigned short)                         // Kbf 67.1
      + 2 * (size_t)B_ROWS * NCB * TOPB * sizeof(float);                        // parts 67.1
  double* qbk = (double*)ws;   ws += (size_t)B_ROWS * sizeof(double);
  int* cand = (int*)ws;        ws += (size_t)B_ROWS * TOPC * sizeof(int);
  int* topi = (int*)ws;

  // Lifetimes (in-order stream):
  //  q64: dead after qbk+uproj -> hosts wkbf/wvbf casts.
  //  Aregion: Kbf+parts until merge; then Vout (exactly 134.2 MB) overlays.
  unsigned short* Kbf = (unsigned short*)Aregion;
  float* part_v = (float*)(Aregion + (size_t)M_ROWS * D_DIM * sizeof(unsigned short));
  int* part_i = (int*)((char*)part_v + (size_t)B_ROWS * NCB * TOPB * sizeof(float));
  unsigned short* wkbf = (unsigned short*)q64;
  unsigned short* wvbf = wkbf + (size_t)D_DIM * D_DIM;
  float* Vout = (float*)Aregion;

  qproj_f64<<<dim3(B_ROWS / BM, D_DIM / BN), 256, 0, stream>>>(query, Wq, bq, q64, qbf);
  qbk_dot<<<dim3(B_ROWS / 4), 256, 0, stream>>>(q64, bk, qbk);
  uproj_f64<<<dim3(B_ROWS / BM, D_DIM / BN), 256, 0, stream>>>(q64, Wk, u64);

  // q64 now dead -> casts may overwrite it.
  cast_f32_bf16<<<dim3((M_ROWS * D_DIM / 4 + 255) / 256), 256, 0, stream>>>(mem, membf, M_ROWS * D_DIM / 4);
  cast_f32_bf16<<<dim3((D_DIM * D_DIM / 4 + 255) / 256), 256, 0, stream>>>(Wk, wkbf, D_DIM * D_DIM / 4);
  cast_f32_bf16<<<dim3((D_DIM * D_DIM / 4 + 255) / 256), 256, 0, stream>>>(Wv, wvbf, D_DIM * D_DIM / 4);

  kproj_bf16<<<dim3(M_ROWS / 128, D_DIM / 128), 256, 0, stream>>>(membf, wkbf, bk, Kbf);
  sims_topc_gemm<<<dim3((B_ROWS / 256) * NCB), 512, 0, stream>>>(qbf, Kbf, part_v, part_i);
  merge_cand256<<<dim3(B_ROWS), 256, 0, stream>>>(part_v, part_i, cand);
  rescore_topk_u<<<dim3(B_ROWS), 256, 0, stream>>>(u64, qbk, mem, cand, topi);

  vproj_bf16<<<dim3(M_ROWS / 128, D_DIM / 128), 256, 0, stream>>>(membf, wvbf, bv, Vout);
  gather_ln<<<dim3(B_ROWS * TOPK), 256, 0, stream>>>(Vout, topi, gamma, beta, out);
}

// Round 15
// 1474.758 us; speedup vs baseline: 5.4315x; 1.4462x over previous
//
#include <hip/hip_runtime.h>
#include <hip/hip_bf16.h>
#include <math.h>

#define D_DIM 1024
#define B_ROWS 4096
#define M_ROWS 32768
#define TOPK 8
#define TOPC 16                // candidates per row after merge
#define TOPB 8                 // entries stored per (row, col-block): 2 halves x top-4
#define NCB (M_ROWS / 128)     // 256 col-blocks

#define BM 128
#define BN 64
#define BK 32

typedef __attribute__((ext_vector_type(8))) short bf16x8;
typedef __attribute__((ext_vector_type(4))) float f32x4;

__device__ __forceinline__ unsigned short f32_to_bf16(float f) {
  unsigned int u = __float_as_uint(f);
  unsigned int r = (u + 0x7FFFu + ((u >> 16) & 1u)) >> 16;
  return (unsigned short)r;
}
__device__ __forceinline__ float bf16_to_f32(unsigned short h) {
  return __uint_as_float(((unsigned int)h) << 16);
}
__device__ __forceinline__ void async_copy16(void* lds, const void* g) {
  __builtin_amdgcn_global_load_lds(
      (const __attribute__((address_space(1))) unsigned int*)g,
      (__attribute__((address_space(3))) unsigned int*)lds, 16, 0, 0);
}

// Ordered insert into a register top-N list sorted by (value desc, index asc).
template <int N>
__device__ __forceinline__ void insN(float v, int idx,
                                     float* __restrict__ tv,
                                     int* __restrict__ ti) {
  if (v < tv[N - 1]) return;
  if (v == tv[N - 1] && idx > ti[N - 1]) return;
  float cv = v;
  int ci = idx;
#pragma unroll
  for (int p = 0; p < N; ++p) {
    if (cv > tv[p] || (cv == tv[p] && ci < ti[p])) {
      const float t0 = tv[p]; tv[p] = cv; cv = t0;
      const int t1 = ti[p]; ti[p] = ci; ci = t1;
    }
  }
}

// ---------------------------------------------------------------------------
// q projection: f64 accumulation (selection chain). Unchanged.
// ---------------------------------------------------------------------------
__global__ __launch_bounds__(256) void qproj_f64(
    const float* __restrict__ X, const float* __restrict__ W,
    const float* __restrict__ bias, double* __restrict__ out64,
    unsigned short* __restrict__ outbf)
{
  __shared__ float sA[BK][BM + 4];
  __shared__ float sB[BK][BN + 4];
  const int tid = threadIdx.x;
  const int tx = tid & 15, ty = tid >> 4;
  const int row0 = blockIdx.x * BM;
  const int col0 = blockIdx.y * BN;
  const int lr = tid >> 3;         // 0..31
  const int lc = (tid & 7) << 2;   // 0,4,...,28

  double acc[2][4][4];
#pragma unroll
  for (int g = 0; g < 2; ++g)
#pragma unroll
    for (int i = 0; i < 4; ++i)
#pragma unroll
      for (int j = 0; j < 4; ++j) acc[g][i][j] = 0.0;

  for (int k0 = 0; k0 < D_DIM; k0 += BK) {
#pragma unroll
    for (int rr = 0; rr < 4; ++rr) {
      const float4 v = *(const float4*)(X + (size_t)(row0 + lr + 32 * rr) * D_DIM + k0 + lc);
      sA[lc + 0][lr + 32 * rr] = v.x;
      sA[lc + 1][lr + 32 * rr] = v.y;
      sA[lc + 2][lr + 32 * rr] = v.z;
      sA[lc + 3][lr + 32 * rr] = v.w;
    }
#pragma unroll
    for (int rr = 0; rr < 2; ++rr) {
      const float4 v = *(const float4*)(W + (size_t)(col0 + lr + 32 * rr) * D_DIM + k0 + lc);
      sB[lc + 0][lr + 32 * rr] = v.x;
      sB[lc + 1][lr + 32 * rr] = v.y;
      sB[lc + 2][lr + 32 * rr] = v.z;
      sB[lc + 3][lr + 32 * rr] = v.w;
    }
    __syncthreads();
#pragma unroll
    for (int kk = 0; kk < BK; ++kk) {
      const float4 A0 = *(const float4*)&sA[kk][ty * 4];
      const float4 A1 = *(const float4*)&sA[kk][64 + ty * 4];
      const float4 Bv = *(const float4*)&sB[kk][tx * 4];
      const double a0[4] = {A0.x, A0.y, A0.z, A0.w};
      const double a1[4] = {A1.x, A1.y, A1.z, A1.w};
      const double bb[4] = {Bv.x, Bv.y, Bv.z, Bv.w};
#pragma unroll
      for (int i = 0; i < 4; ++i)
#pragma unroll
        for (int j = 0; j < 4; ++j) {
          acc[0][i][j] = fma(a0[i], bb[j], acc[0][i][j]);
          acc[1][i][j] = fma(a1[i], bb[j], acc[1][i][j]);
        }
    }
    __syncthreads();
  }
  const float4 bv4 = *(const float4*)(bias + col0 + tx * 4);
  const double bb[4] = {bv4.x, bv4.y, bv4.z, bv4.w};
#pragma unroll
  for (int g = 0; g < 2; ++g)
#pragma unroll
    for (int i = 0; i < 4; ++i) {
      double o[4];
#pragma unroll
      for (int j = 0; j < 4; ++j) o[j] = acc[g][i][j] + bb[j];
      const size_t base = (size_t)(row0 + g * 64 + ty * 4 + i) * D_DIM + col0 + tx * 4;
      *(double2*)(out64 + base)     = (double2){o[0], o[1]};
      *(double2*)(out64 + base + 2) = (double2){o[2], o[3]};
      ushort4 ob;
      ob.x = f32_to_bf16((float)o[0]);
      ob.y = f32_to_bf16((float)o[1]);
      ob.z = f32_to_bf16((float)o[2]);
      ob.w = f32_to_bf16((float)o[3]);
      *(ushort4*)(outbf + base) = ob;
    }
}

// ---------------------------------------------------------------------------
// qbk[b] = dot_f64(q64[b,:], bk). One wave per row.
// ---------------------------------------------------------------------------
__global__ __launch_bounds__(256) void qbk_dot(
    const double* __restrict__ Q64, const float* __restrict__ bk_,
    double* __restrict__ qbk)
{
  const int b = blockIdx.x * 4 + (threadIdx.x >> 6);
  const int lane = threadIdx.x & 63;
  const double* qrow = Q64 + (size_t)b * D_DIM + lane * 16;
  const float* bkrow = bk_ + lane * 16;
  double acc = 0.0;
#pragma unroll
  for (int i = 0; i < 4; ++i) {
    const float4 bv = *(const float4*)(bkrow + i * 4);
    const double2 qa = *(const double2*)(qrow + i * 4);
    const double2 qb2 = *(const double2*)(qrow + i * 4 + 2);
    acc = fma(qa.x, (double)bv.x, acc);
    acc = fma(qa.y, (double)bv.y, acc);
    acc = fma(qb2.x, (double)bv.z, acc);
    acc = fma(qb2.y, (double)bv.w, acc);
  }
#pragma unroll
  for (int off = 32; off > 0; off >>= 1) acc += __shfl_down(acc, off);
  if (lane == 0) qbk[b] = acc;
}

// ---------------------------------------------------------------------------
// u = q64 @ Wk (NN, f64). Unchanged.
// ---------------------------------------------------------------------------
__global__ __launch_bounds__(256) void uproj_f64(
    const double* __restrict__ A, const float* __restrict__ Bw,
    double* __restrict__ U)
{
  __shared__ double sAd[BM][BK + 1];   // 33.0 KB
  __shared__ float sBf[BK][BN + 4];    // 8.7 KB
  const int tid = threadIdx.x;
  const int tx = tid & 15, ty = tid >> 4;
  const int row0 = blockIdx.x * BM;
  const int col0 = blockIdx.y * BN;

  double acc[2][4][4];
#pragma unroll
  for (int g = 0; g < 2; ++g)
#pragma unroll
    for (int i = 0; i < 4; ++i)
#pragma unroll
      for (int j = 0; j < 4; ++j) acc[g][i][j] = 0.0;

  for (int k0 = 0; k0 < D_DIM; k0 += BK) {
#pragma unroll
    for (int it = 0; it < 8; ++it) {
      const int L = it * 256 + tid;
      const int row = L >> 4, kp = (L & 15) * 2;
      const double2 d2 = *(const double2*)(A + (size_t)(row0 + row) * D_DIM + k0 + kp);
      sAd[row][kp] = d2.x;
      sAd[row][kp + 1] = d2.y;
    }
#pragma unroll
    for (int it = 0; it < 2; ++it) {
      const int L = it * 256 + tid;
      const int kk = L >> 4, j4 = (L & 15) * 4;
      const float4 v = *(const float4*)(Bw + (size_t)(k0 + kk) * D_DIM + col0 + j4);
      sBf[kk][j4 + 0] = v.x;
      sBf[kk][j4 + 1] = v.y;
      sBf[kk][j4 + 2] = v.z;
      sBf[kk][j4 + 3] = v.w;
    }
    __syncthreads();
#pragma unroll
    for (int kk = 0; kk < BK; ++kk) {
      const double a0[4] = {sAd[ty * 4 + 0][kk], sAd[ty * 4 + 1][kk],
                            sAd[ty * 4 + 2][kk], sAd[ty * 4 + 3][kk]};
      const double a1[4] = {sAd[64 + ty * 4 + 0][kk], sAd[64 + ty * 4 + 1][kk],
                            sAd[64 + ty * 4 + 2][kk], sAd[64 + ty * 4 + 3][kk]};
      const float4 Bv = *(const float4*)&sBf[kk][tx * 4];
      const double bb[4] = {Bv.x, Bv.y, Bv.z, Bv.w};
#pragma unroll
      for (int i = 0; i < 4; ++i)
#pragma unroll
        for (int j = 0; j < 4; ++j) {
          acc[0][i][j] = fma(a0[i], bb[j], acc[0][i][j]);
          acc[1][i][j] = fma(a1[i], bb[j], acc[1][i][j]);
        }
    }
    __syncthreads();
  }
#pragma unroll
  for (int g = 0; g < 2; ++g)
#pragma unroll
    for (int i = 0; i < 4; ++i) {
      const size_t base = (size_t)(row0 + g * 64 + ty * 4 + i) * D_DIM + col0 + tx * 4;
      *(double2*)(U + base)     = (double2){acc[g][i][0], acc[g][i][1]};
      *(double2*)(U + base + 2) = (double2){acc[g][i][2], acc[g][i][3]};
    }
}

// ---------------------------------------------------------------------------
// Fused sims + per-half top-4 (round-14-proven counted-vmcnt pipeline).
// ---------------------------------------------------------------------------
#define SBUF 24576   // 48 KB per buffer, in ushorts (A 32KB + B 16KB)
__global__ __launch_bounds__(512, 2) void sims_topc_gemm(
    const unsigned short* __restrict__ A, const unsigned short* __restrict__ B,
    float* __restrict__ part_v, int* __restrict__ part_i)
{
  __shared__ unsigned short smem[3 * SBUF];   // 144 KB

  const int tid = threadIdx.x;
  const int lane = tid & 63;
  const int wave = tid >> 6;          // 0..7
  const int wr = wave >> 1;           // 0..3 -> A rows wr*64
  const int wc = wave & 1;            // 0..1 -> B rows wc*64

  // cb-resident mapping (bijective over 4096 blocks).
  const int bid = blockIdx.x;
  const int x = bid & 7;
  const int t9 = bid >> 3;            // 0..511
  const int cbg = t9 >> 7;            // 0..3
  const int r = (t9 >> 3) & 15;       // 0..15
  const int cbl = t9 & 7;             // 0..7
  const int cb = (x * 4 + cbg) * 8 + cbl;
  const int row0 = r * 256;
  const int col0 = cb * 128;

  const int st_r = lane >> 3;                    // row within 8-row segment
  const int st_swz = ((lane & 7) ^ st_r) * 16;   // pre-swizzled global chunk

  auto STAGE = [&](int d, int k0) {
    unsigned short* buf = smem + d * SBUF;
#pragma unroll
    for (int i = 0; i < 6; ++i) {
      const int seg = wave * 6 + i;
      if (seg < 32) {
        const int grow = row0 + seg * 8 + st_r;
        async_copy16((char*)(buf + seg * 512),
                     (const char*)(A + (size_t)grow * D_DIM + k0) + st_swz);
      } else {
        const int s2 = seg - 32;
        const int grow = col0 + s2 * 8 + st_r;
        async_copy16((char*)(buf + 16384 + s2 * 512),
                     (const char*)(B + (size_t)grow * D_DIM + k0) + st_swz);
      }
    }
  };

  f32x4 acc[4][4];
#pragma unroll
  for (int m = 0; m < 4; ++m)
#pragma unroll
    for (int n = 0; n < 4; ++n) acc[m][n] = (f32x4){0.f, 0.f, 0.f, 0.f};

  auto COMPUTE = [&](int d) {
    const unsigned short* sA = smem + d * SBUF;
    const unsigned short* sB = sA + 16384;
#pragma unroll
    for (int ks = 0; ks < 2; ++ks) {
      bf16x8 af[4], bfr[4];
      const int ch = ks * 4 + (lane >> 4);       // 16B chunk 0..7 of 128B row
#pragma unroll
      for (int m = 0; m < 4; ++m) {
        const int Ra = wr * 64 + m * 16 + (lane & 15);
        af[m] = *(const bf16x8*)((const char*)sA + Ra * 128 + ((ch ^ (Ra & 7)) * 16));
      }
#pragma unroll
      for (int n = 0; n < 4; ++n) {
        const int Rb = wc * 64 + n * 16 + (lane & 15);
        bfr[n] = *(const bf16x8*)((const char*)sB + Rb * 128 + ((ch ^ (Rb & 7)) * 16));
      }
#pragma unroll
      for (int m = 0; m < 4; ++m)
#pragma unroll
        for (int n = 0; n < 4; ++n)
          acc[m][n] = __builtin_amdgcn_mfma_f32_16x16x32_bf16(af[m], bfr[n], acc[m][n], 0, 0, 0);
    }
  };

  STAGE(0, 0);
  STAGE(1, 64);
  asm volatile("s_waitcnt vmcnt(6)" ::: "memory");
  __builtin_amdgcn_sched_barrier(0);
  __builtin_amdgcn_s_barrier();

  for (int t = 0; t < 16; ++t) {
    if (t < 14) STAGE((t + 2) % 3, (t + 2) * 64);
    COMPUTE(t % 3);
    if (t < 14) {
      asm volatile("s_waitcnt vmcnt(6)" ::: "memory");   // tile t+1 landed
    } else if (t == 14) {
      asm volatile("s_waitcnt vmcnt(0)" ::: "memory");   // tile 15 landed
    }
    __builtin_amdgcn_sched_barrier(0);
    __builtin_amdgcn_s_barrier();
  }

  // C/D layout (m89): col=lane&15 (within 16), row=(lane>>4)*4+reg.
#pragma unroll
  for (int m = 0; m < 4; ++m)
#pragma unroll
    for (int n = 0; n < 4; ++n)
#pragma unroll
      for (int rg = 0; rg < 4; ++rg) {
        const int row = wr * 64 + m * 16 + (lane >> 4) * 4 + rg;
        const int colL = wc * 64 + n * 16 + (lane & 15);
        smem[row * 132 + colL] = f32_to_bf16(acc[m][n][rg]);
      }
  __syncthreads();

  {
    const int row = tid & 255;          // 0..255
    const int h = tid >> 8;             // 0..1 (64-col half)
    float tv[4];
    int ti_[4];
#pragma unroll
    for (int p = 0; p < 4; ++p) { tv[p] = -INFINITY; ti_[p] = 0; }
    const unsigned short* crow = smem + row * 132 + h * 64;
    const int gcol = col0 + h * 64;
    for (int j = 0; j < 64; j += 4) {
      const ushort4 c4 = *(const ushort4*)(crow + j);
      insN<4>(bf16_to_f32(c4.x), gcol + j + 0, tv, ti_);
      insN<4>(bf16_to_f32(c4.y), gcol + j + 1, tv, ti_);
      insN<4>(bf16_to_f32(c4.z), gcol + j + 2, tv, ti_);
      insN<4>(bf16_to_f32(c4.w), gcol + j + 3, tv, ti_);
    }
    const size_t base = ((size_t)(row0 + row) * NCB + cb) * TOPB + h * 4;
    *(float4*)(part_v + base) = (float4){tv[0], tv[1], tv[2], tv[3]};
    *(int4*)(part_i + base)   = (int4){ti_[0], ti_[1], ti_[2], ti_[3]};
  }
}

// ---------------------------------------------------------------------------
// Merge: parallel iterative max-extraction (round-15 rewrite). 256 threads
// hold the row's 2048 entries in registers (8 each, static indexing); 16
// rounds of block-argmax on (value desc, index asc): masked 8-scan ->
// 64-lane shfl pair-reduce -> 4-way LDS combine -> broadcast -> owner clears
// bit (indices unique per row => index-equality removal exact). Same selected
// SET as the old comparator hierarchy, ~100x less serial dependent work.
// ---------------------------------------------------------------------------
__global__ __launch_bounds__(256) void merge_cand256(
    const float* __restrict__ part_v, const int* __restrict__ part_i,
    int* __restrict__ cand)
{
  const int r = blockIdx.x;
  const int tid = threadIdx.x;
  const int lane = tid & 63;
  const int wave = tid >> 6;

  float tv[8];
  int ti[8];
  {
    const size_t base = ((size_t)r * NCB + tid) * TOPB;
    const float4 a0 = *(const float4*)(part_v + base);
    const float4 a1 = *(const float4*)(part_v + base + 4);
    const int4 b0 = *(const int4*)(part_i + base);
    const int4 b1 = *(const int4*)(part_i + base + 4);
    tv[0] = a0.x; tv[1] = a0.y; tv[2] = a0.z; tv[3] = a0.w;
    tv[4] = a1.x; tv[5] = a1.y; tv[6] = a1.z; tv[7] = a1.w;
    ti[0] = b0.x; ti[1] = b0.y; ti[2] = b0.z; ti[3] = b0.w;
    ti[4] = b1.x; ti[5] = b1.y; ti[6] = b1.z; ti[7] = b1.w;
  }
  unsigned rem = 0xFFu;

  __shared__ float wv4[4];
  __shared__ int wi4[4];
  __shared__ int winner;

  for (int p = 0; p < TOPC; ++p) {
    float bv = -INFINITY;
    int bi = 0x7FFFFFFF;
#pragma unroll
    for (int e = 0; e < 8; ++e) {
      const bool alive = (rem >> e) & 1u;
      const float v = tv[e];
      const int ix = ti[e];
      if (alive && (v > bv || (v == bv && ix < bi))) { bv = v; bi = ix; }
    }
#pragma unroll
    for (int off = 32; off > 0; off >>= 1) {
      const float ov = __shfl_down(bv, off);
      const int oi = __shfl_down(bi, off);
      if (ov > bv || (ov == bv && oi < bi)) { bv = ov; bi = oi; }
    }
    if (lane == 0) { wv4[wave] = bv; wi4[wave] = bi; }
    __syncthreads();
    if (tid == 0) {
      float gv = wv4[0];
      int gi = wi4[0];
#pragma unroll
      for (int w = 1; w < 4; ++w)
        if (wv4[w] > gv || (wv4[w] == gv && wi4[w] < gi)) { gv = wv4[w]; gi = wi4[w]; }
      winner = gi;
      cand[(size_t)r * TOPC + p] = gi;
    }
    __syncthreads();
    const int wgi = winner;
#pragma unroll
    for (int e = 0; e < 8; ++e)
      if (ti[e] == wgi) rem &= ~(1u << e);
  }
}

// ---------------------------------------------------------------------------
// fp64 rescore via u: sims_ci = dot_f64(u_b, mem_ci) + qbk_b (round-10-proven).
// ---------------------------------------------------------------------------
__global__ __launch_bounds__(256) void rescore_topk_u(
    const double* __restrict__ U, const double* __restrict__ qbk,
    const float* __restrict__ mem, const int* __restrict__ cand,
    int* __restrict__ topi)
{
  const int b = blockIdx.x;
  const int tid = threadIdx.x;
  const int wave = tid >> 6;
  const int lane = tid & 63;

  __shared__ double sval[TOPC];
  __shared__ int sidx[TOPC];

  const double* urow = U + (size_t)b * D_DIM + lane * 16;
  double uv[16];
#pragma unroll
  for (int i = 0; i < 8; ++i) {
    const double2 d2 = *(const double2*)(urow + i * 2);
    uv[i * 2] = d2.x;
    uv[i * 2 + 1] = d2.y;
  }
  const double qb = qbk[b];

  for (int c = wave; c < TOPC; c += 4) {
    const int ci = cand[(size_t)b * TOPC + c];
    const float* mrow = mem + (size_t)ci * D_DIM + lane * 16;
    double acc = 0.0;
#pragma unroll
    for (int i = 0; i < 4; ++i) {
      const float4 mv = *(const float4*)(mrow + i * 4);
      acc = fma(uv[i * 4 + 0], (double)mv.x, acc);
      acc = fma(uv[i * 4 + 1], (double)mv.y, acc);
      acc = fma(uv[i * 4 + 2], (double)mv.z, acc);
      acc = fma(uv[i * 4 + 3], (double)mv.w, acc);
    }
#pragma unroll
    for (int off = 32; off > 0; off >>= 1) acc += __shfl_down(acc, off);
    if (lane == 0) { sval[c] = acc + qb; sidx[c] = ci; }
  }
  __syncthreads();

  if (tid == 0) {
    bool used[TOPC];
#pragma unroll
    for (int p = 0; p < TOPC; ++p) used[p] = false;
#pragma unroll
    for (int p = 0; p < TOPK; ++p) {
      int best = -1;
      double bv = 0.0;
      int bi = 0;
      for (int c = 0; c < TOPC; ++c) {
        if (used[c]) continue;
        const double v = sval[c];
        const int ix = sidx[c];
        if (best < 0 || v > bv || (v == bv && ix < bi)) { best = c; bv = v; bi = ix; }
      }
      used[best] = true;
      topi[(size_t)b * TOPK + p] = bi;
    }
  }
}

// ---------------------------------------------------------------------------
// f32 -> bf16 cast (vectorized).
// ---------------------------------------------------------------------------
__global__ __launch_bounds__(256) void cast_f32_bf16(
    const float* __restrict__ src, unsigned short* __restrict__ dst, int n4)
{
  const int i = blockIdx.x * 256 + threadIdx.x;
  if (i >= n4) return;
  const float4 v = *(const float4*)(src + (size_t)i * 4);
  ushort4 o;
  o.x = f32_to_bf16(v.x);
  o.y = f32_to_bf16(v.y);
  o.z = f32_to_bf16(v.z);
  o.w = f32_to_bf16(v.w);
  *(ushort4*)(dst + (size_t)i * 4) = o;
}

// ---------------------------------------------------------------------------
// K projection via bf16 MFMA, bf16 output — round-13 2-phase dbuf (proven).
// ---------------------------------------------------------------------------
__global__ __launch_bounds__(256) void kproj_bf16(
    const unsigned short* __restrict__ A,   // mem_bf [M_ROWS][D_DIM]
    const unsigned short* __restrict__ B,   // Wk_bf  [D_DIM][D_DIM]
    const float* __restrict__ bias,
    unsigned short* __restrict__ C)         // [M_ROWS][D_DIM] bf16
{
  __shared__ unsigned short smem[2 * 2 * 128 * 32];   // 32 KB: 2 x (sA | sB)

  const int tid = threadIdx.x;
  const int lane = tid & 63;
  const int wave = tid >> 6;
  const int wr = wave >> 1, wc = wave & 1;
  const int row0 = blockIdx.x * 128;
  const int col0 = blockIdx.y * 128;

  const int st_r = lane >> 2;
  const int st_cb = (lane & 3) * 16;

  auto STAGE = [&](int d, int k0) {
    unsigned short* dA = smem + d * (2 * 128 * 32);
    unsigned short* dB = dA + 128 * 32;
#pragma unroll
    for (int i = 0; i < 2; ++i) {
      const int seg = wave * 2 + i;
      const int rr = seg * 16 + st_r;
      async_copy16((char*)dA + seg * 1024,
                   (const char*)(A + (size_t)(row0 + rr) * D_DIM + k0) + st_cb);
      async_copy16((char*)dB + seg * 1024,
                   (const char*)(B + (size_t)(col0 + rr) * D_DIM + k0) + st_cb);
    }
  };

  f32x4 acc[4][4];
#pragma unroll
  for (int m = 0; m < 4; ++m)
#pragma unroll
    for (int n = 0; n < 4; ++n) acc[m][n] = (f32x4){0.f, 0.f, 0.f, 0.f};

  STAGE(0, 0);
  __syncthreads();
  int cur = 0;
  for (int t = 0; t < 32; ++t) {
    if (t < 31) STAGE(cur ^ 1, (t + 1) * 32);
    const unsigned short* sA = smem + cur * (2 * 128 * 32);
    const unsigned short* sB = sA + 128 * 32;
    bf16x8 af[4], bfr[4];
#pragma unroll
    for (int m = 0; m < 4; ++m)
      af[m] = *(const bf16x8*)(sA + (wr * 64 + m * 16 + (lane & 15)) * 32 + (lane >> 4) * 8);
#pragma unroll
    for (int n = 0; n < 4; ++n)
      bfr[n] = *(const bf16x8*)(sB + (wc * 64 + n * 16 + (lane & 15)) * 32 + (lane >> 4) * 8);
#pragma unroll
    for (int m = 0; m < 4; ++m)
#pragma unroll
      for (int n = 0; n < 4; ++n)
        acc[m][n] = __builtin_amdgcn_mfma_f32_16x16x32_bf16(af[m], bfr[n], acc[m][n], 0, 0, 0);
    __syncthreads();
    cur ^= 1;
  }

#pragma unroll
  for (int n = 0; n < 4; ++n) {
    const int col = col0 + wc * 64 + n * 16 + (lane & 15);
    const float bcol = bias[col];
#pragma unroll
    for (int m = 0; m < 4; ++m)
#pragma unroll
      for (int r = 0; r < 4; ++r) {
        const int row = row0 + wr * 64 + m * 16 + (lane >> 4) * 4 + r;
        C[(size_t)row * D_DIM + col] = f32_to_bf16(acc[m][n][r] + bcol);
      }
  }
}

// ---------------------------------------------------------------------------
// V projection via bf16 MFMA — round-13 2-phase dbuf (proven).
// ---------------------------------------------------------------------------
__global__ __launch_bounds__(256) void vproj_bf16(
    const unsigned short* __restrict__ A,
    const unsigned short* __restrict__ B,
    const float* __restrict__ bias,
    float* __restrict__ C)
{
  __shared__ unsigned short smem[2 * 2 * 128 * 32];   // 32 KB

  const int tid = threadIdx.x;
  const int lane = tid & 63;
  const int wave = tid >> 6;
  const int wr = wave >> 1, wc = wave & 1;
  const int row0 = blockIdx.x * 128;
  const int col0 = blockIdx.y * 128;

  const int st_r = lane >> 2;
  const int st_cb = (lane & 3) * 16;

  auto STAGE = [&](int d, int k0) {
    unsigned short* dA = smem + d * (2 * 128 * 32);
    unsigned short* dB = dA + 128 * 32;
#pragma unroll
    for (int i = 0; i < 2; ++i) {
      const int seg = wave * 2 + i;
      const int rr = seg * 16 + st_r;
      async_copy16((char*)dA + seg * 1024,
                   (const char*)(A + (size_t)(row0 + rr) * D_DIM + k0) + st_cb);
      async_copy16((char*)dB + seg * 1024,
                   (const char*)(B + (size_t)(col0 + rr) * D_DIM + k0) + st_cb);
    }
  };

  f32x4 acc[4][4];
#pragma unroll
  for (int m = 0; m < 4; ++m)
#pragma unroll
    for (int n = 0; n < 4; ++n) acc[m][n] = (f32x4){0.f, 0.f, 0.f, 0.f};

  STAGE(0, 0);
  __syncthreads();
  int cur = 0;
  for (int t = 0; t < 32; ++t) {
    if (t < 31) STAGE(cur ^ 1, (t + 1) * 32);
    const unsigned short* sA = smem + cur * (2 * 128 * 32);
    const unsigned short* sB = sA + 128 * 32;
    bf16x8 af[4], bfr[4];
#pragma unroll
    for (int m = 0; m < 4; ++m)
      af[m] = *(const bf16x8*)(sA + (wr * 64 + m * 16 + (lane & 15)) * 32 + (lane >> 4) * 8);
#pragma unroll
    for (int n = 0; n < 4; ++n)
      bfr[n] = *(const bf16x8*)(sB + (wc * 64 + n * 16 + (lane & 15)) * 32 + (lane >> 4) * 8);
#pragma unroll
    for (int m = 0; m < 4; ++m)
#pragma unroll
      for (int n = 0; n < 4; ++n)
        acc[m][n] = __builtin_amdgcn_mfma_f32_16x16x32_bf16(af[m], bfr[n], acc[m][n], 0, 0, 0);
    __syncthreads();
    cur ^= 1;
  }

#pragma unroll
  for (int n = 0; n < 4; ++n) {
    const int col = col0 + wc * 64 + n * 16 + (lane & 15);
    const float bcol = bias[col];
#pragma unroll
    for (int m = 0; m < 4; ++m)
#pragma unroll
      for (int r = 0; r < 4; ++r) {
        const int row = row0 + wr * 64 + m * 16 + (lane >> 4) * 4 + r;
        C[(size_t)row * D_DIM + col] = acc[m][n][r] + bcol;
      }
  }
}

// ---------------------------------------------------------------------------
// Gather selected V rows + LayerNorm (unchanged).
// ---------------------------------------------------------------------------
__global__ __launch_bounds__(256) void gather_ln(
    const float* __restrict__ V, const int* __restrict__ topi,
    const float* __restrict__ gamma, const float* __restrict__ beta,
    float* __restrict__ out)
{
  const int row = blockIdx.x;
  const int tid = threadIdx.x;
  const int idx = topi[row];
  const float* src = V + (size_t)idx * D_DIM;
  const float4 v = *(const float4*)(src + tid * 4);
  float s = v.x + v.y + v.z + v.w;
  float s2 = v.x * v.x + v.y * v.y + v.z * v.z + v.w * v.w;
#pragma unroll
  for (int off = 32; off > 0; off >>= 1) {
    s += __shfl_down(s, off);
    s2 += __shfl_down(s2, off);
  }
  __shared__ float red[8];
  __shared__ float stats[2];
  const int wid = tid >> 6;
  if ((tid & 63) == 0) { red[wid] = s; red[4 + wid] = s2; }
  __syncthreads();
  if (tid == 0) {
    const float S = red[0] + red[1] + red[2] + red[3];
    const float S2 = red[4] + red[5] + red[6] + red[7];
    const float mu = S * (1.0f / D_DIM);
    const float var = S2 * (1.0f / D_DIM) - mu * mu;
    stats[0] = mu;
    stats[1] = rsqrtf(var + 1e-5f);
  }
  __syncthreads();
  const float mu = stats[0], rstd = stats[1];
  const float4 g4 = *(const float4*)(gamma + tid * 4);
  const float4 b4 = *(const float4*)(beta + tid * 4);
  float4 o;
  o.x = (v.x - mu) * rstd * g4.x + b4.x;
  o.y = (v.y - mu) * rstd * g4.y + b4.y;
  o.z = (v.z - mu) * rstd * g4.z + b4.z;
  o.w = (v.w - mu) * rstd * g4.w + b4.w;
  *(float4*)(out + (size_t)row * D_DIM + tid * 4) = o;
}

extern "C" void kernel_launch(void* const* d_in, const int* in_sizes, int n_in,
                              void* d_out, int out_size, void* d_ws, size_t ws_size,
                              hipStream_t stream)
{
  const float* query = (const float*)d_in[0];
  const float* mem   = (const float*)d_in[1];
  const float* Wq    = (const float*)d_in[2];
  const float* bq    = (const float*)d_in[3];
  const float* Wk    = (const float*)d_in[4];
  const float* bk    = (const float*)d_in[5];
  const float* Wv    = (const float*)d_in[6];
  const float* bv    = (const float*)d_in[7];
  const float* gamma = (const float*)d_in[8];
  const float* beta  = (const float*)d_in[9];
  float* out = (float*)d_out;

  char* ws = (char*)d_ws;
  double* q64 = (double*)ws;   ws += (size_t)B_ROWS * D_DIM * sizeof(double);   // 33.6 MB
  double* u64 = (double*)ws;   ws += (size_t)B_ROWS * D_DIM * sizeof(double);   // 33.6 MB
  unsigned short* qbf = (unsigned short*)ws;
  ws += (size_t)B_ROWS * D_DIM * sizeof(unsigned short);                        // 8.4 MB
  unsigned short* membf = (unsigned short*)ws;
  ws += (size_t)M_ROWS * D_DIM * sizeof(unsigned short);                        // 67.1 MB
  char* Aregion = ws;
  ws += (size_t)M_ROWS * D_DIM * sizeof(unsigned short)                         // Kbf 67.1
      + 2 * (size_t)B_ROWS * NCB * TOPB * sizeof(float);                        // parts 67.1
  double* qbk = (double*)ws;   ws += (size_t)B_ROWS * sizeof(double);
  int* cand = (int*)ws;        ws += (size_t)B_ROWS * TOPC * sizeof(int);
  int* topi = (int*)ws;

  // Lifetimes (in-order stream):
  //  q64: dead after qbk+uproj -> hosts wkbf/wvbf casts.
  //  Aregion: Kbf+parts until merge; then Vout (exactly 134.2 MB) overlays.
  unsigned short* Kbf = (unsigned short*)Aregion;
  float* part_v = (float*)(Aregion + (size_t)M_ROWS * D_DIM * sizeof(unsigned short));
  int* part_i = (int*)((char*)part_v + (size_t)B_ROWS * NCB * TOPB * sizeof(float));
  unsigned short* wkbf = (unsigned short*)q64;
  unsigned short* wvbf = wkbf + (size_t)D_DIM * D_DIM;
  float* Vout = (float*)Aregion;

  qproj_f64<<<dim3(B_ROWS / BM, D_DIM / BN), 256, 0, stream>>>(query, Wq, bq, q64, qbf);
  qbk_dot<<<dim3(B_ROWS / 4), 256, 0, stream>>>(q64, bk, qbk);
  uproj_f64<<<dim3(B_ROWS / BM, D_DIM / BN), 256, 0, stream>>>(q64, Wk, u64);

  // q64 now dead -> casts may overwrite it.
  cast_f32_bf16<<<dim3((M_ROWS * D_DIM / 4 + 255) / 256), 256, 0, stream>>>(mem, membf, M_ROWS * D_DIM / 4);
  cast_f32_bf16<<<dim3((D_DIM * D_DIM / 4 + 255) / 256), 256, 0, stream>>>(Wk, wkbf, D_DIM * D_DIM / 4);
  cast_f32_bf16<<<dim3((D_DIM * D_DIM / 4 + 255) / 256), 256, 0, stream>>>(Wv, wvbf, D_DIM * D_DIM / 4);

  kproj_bf16<<<dim3(M_ROWS / 128, D_DIM / 128), 256, 0, stream>>>(membf, wkbf, bk, Kbf);
  sims_topc_gemm<<<dim3((B_ROWS / 256) * NCB), 512, 0, stream>>>(qbf, Kbf, part_v, part_i);
  merge_cand256<<<dim3(B_ROWS), 256, 0, stream>>>(part_v, part_i, cand);
  rescore_topk_u<<<dim3(B_ROWS), 256, 0, stream>>>(u64, qbk, mem, cand, topi);

  vproj_bf16<<<dim3(M_ROWS / 128, D_DIM / 128), 256, 0, stream>>>(membf, wvbf, bv, Vout);
  gather_ln<<<dim3(B_ROWS * TOPK), 256, 0, stream>>>(Vout, topi, gamma, beta, out);
}

// Round 16
// 1316.969 us; speedup vs baseline: 6.0822x; 1.1198x over previous
//
#include <hip/hip_runtime.h>
#include <hip/hip_bf16.h>
#include <math.h>

#define D_DIM 1024
#define B_ROWS 4096
#define M_ROWS 32768
#define TOPK 8
#define TOPC 16                // candidates per row after merge
#define TOPB 8                 // entries stored per (row, col-block): 2 halves x top-4
#define NCB (M_ROWS / 128)     // 256 col-blocks

#define BM 128
#define BN 64
#define BK 32

typedef __attribute__((ext_vector_type(8))) short bf16x8;
typedef __attribute__((ext_vector_type(4))) float f32x4;

__device__ __forceinline__ unsigned short f32_to_bf16(float f) {
  unsigned int u = __float_as_uint(f);
  unsigned int r = (u + 0x7FFFu + ((u >> 16) & 1u)) >> 16;
  return (unsigned short)r;
}
__device__ __forceinline__ float bf16_to_f32(unsigned short h) {
  return __uint_as_float(((unsigned int)h) << 16);
}
__device__ __forceinline__ void async_copy16(void* lds, const void* g) {
  __builtin_amdgcn_global_load_lds(
      (const __attribute__((address_space(1))) unsigned int*)g,
      (__attribute__((address_space(3))) unsigned int*)lds, 16, 0, 0);
}

// Ordered insert into a register top-N list sorted by (value desc, index asc).
template <int N>
__device__ __forceinline__ void insN(float v, int idx,
                                     float* __restrict__ tv,
                                     int* __restrict__ ti) {
  if (v < tv[N - 1]) return;
  if (v == tv[N - 1] && idx > ti[N - 1]) return;
  float cv = v;
  int ci = idx;
#pragma unroll
  for (int p = 0; p < N; ++p) {
    if (cv > tv[p] || (cv == tv[p] && ci < ti[p])) {
      const float t0 = tv[p]; tv[p] = cv; cv = t0;
      const int t1 = ti[p]; ti[p] = ci; ci = t1;
    }
  }
}

// ---------------------------------------------------------------------------
// G[f][e] = sum_n Wq[n][f] * Wk[n][e], f64 accumulation (selection chain).
// 64x64 tiles, both operands staged coalesced (rows of Wq/Wk are contiguous).
// ---------------------------------------------------------------------------
__global__ __launch_bounds__(256) void gram_f64(
    const float* __restrict__ Wq, const float* __restrict__ Wk,
    double* __restrict__ G)
{
  __shared__ float sA[32][68];
  __shared__ float sB[32][68];
  const int tid = threadIdx.x;
  const int tx = tid & 15, ty = tid >> 4;
  const int f0 = blockIdx.x * 64;
  const int e0 = blockIdx.y * 64;

  double acc[4][4];
#pragma unroll
  for (int i = 0; i < 4; ++i)
#pragma unroll
    for (int j = 0; j < 4; ++j) acc[i][j] = 0.0;

  for (int k0 = 0; k0 < D_DIM; k0 += 32) {
#pragma unroll
    for (int it = 0; it < 2; ++it) {
      const int L = it * 256 + tid;
      const int kk = L >> 4, c4 = (L & 15) * 4;
      *(float4*)&sA[kk][c4] = *(const float4*)(Wq + (size_t)(k0 + kk) * D_DIM + f0 + c4);
      *(float4*)&sB[kk][c4] = *(const float4*)(Wk + (size_t)(k0 + kk) * D_DIM + e0 + c4);
    }
    __syncthreads();
#pragma unroll
    for (int kk = 0; kk < 32; ++kk) {
      const double a[4] = {sA[kk][ty * 4 + 0], sA[kk][ty * 4 + 1],
                           sA[kk][ty * 4 + 2], sA[kk][ty * 4 + 3]};
      const double b[4] = {sB[kk][tx * 4 + 0], sB[kk][tx * 4 + 1],
                           sB[kk][tx * 4 + 2], sB[kk][tx * 4 + 3]};
#pragma unroll
      for (int i = 0; i < 4; ++i)
#pragma unroll
        for (int j = 0; j < 4; ++j)
          acc[i][j] = fma(a[i], b[j], acc[i][j]);
    }
    __syncthreads();
  }
#pragma unroll
  for (int i = 0; i < 4; ++i)
#pragma unroll
    for (int j = 0; j < 4; ++j)
      G[(size_t)(f0 + ty * 4 + i) * D_DIM + e0 + tx * 4 + j] = acc[i][j];
}

// ---------------------------------------------------------------------------
// outv[c] = sum_n W[n][c] * v[n], f64 (coalesced across threads per row).
// ---------------------------------------------------------------------------
__global__ __launch_bounds__(256) void colred_f64(
    const float* __restrict__ W, const float* __restrict__ v,
    double* __restrict__ outv)
{
  const int c = blockIdx.x * 256 + threadIdx.x;
  double acc = 0.0;
  for (int n = 0; n < D_DIM; ++n)
    acc = fma((double)W[(size_t)n * D_DIM + c], (double)v[n], acc);
  outv[c] = acc;
}

// ---------------------------------------------------------------------------
// out[0] = dot_f64(a, b) over 1024 elements (one block).
// ---------------------------------------------------------------------------
__global__ __launch_bounds__(256) void dot1024_f64(
    const float* __restrict__ a, const float* __restrict__ b,
    double* __restrict__ out)
{
  const int tid = threadIdx.x;
  double acc = 0.0;
#pragma unroll
  for (int i = 0; i < 4; ++i) {
    const int idx = tid * 4 + i;
    acc = fma((double)a[idx], (double)b[idx], acc);
  }
#pragma unroll
  for (int off = 32; off > 0; off >>= 1) acc += __shfl_down(acc, off);
  __shared__ double red[4];
  if ((tid & 63) == 0) red[tid >> 6] = acc;
  __syncthreads();
  if (tid == 0) out[0] = red[0] + red[1] + red[2] + red[3];
}

// ---------------------------------------------------------------------------
// qbk[b] = dot_f64(query[b,:], w) + s0.  (w = Wq^T bk, s0 = bq.bk)
// ---------------------------------------------------------------------------
__global__ __launch_bounds__(256) void qbk_w(
    const float* __restrict__ query, const double* __restrict__ w,
    const double* __restrict__ s0, double* __restrict__ qbk)
{
  const int b = blockIdx.x * 4 + (threadIdx.x >> 6);
  const int lane = threadIdx.x & 63;
  const float* qrow = query + (size_t)b * D_DIM + lane * 16;
  const double* wrow = w + lane * 16;
  double acc = 0.0;
#pragma unroll
  for (int i = 0; i < 16; ++i)
    acc = fma((double)qrow[i], wrow[i], acc);
#pragma unroll
  for (int off = 32; off > 0; off >>= 1) acc += __shfl_down(acc, off);
  if (lane == 0) qbk[b] = acc + s0[0];
}

// ---------------------------------------------------------------------------
// u[b,d] = sum_e query[b,e] * G[e,d] + ubias[d], f64 accumulation.
// Replaces qproj_f64 + uproj_f64 (u = query@G is the only big f64 GEMM left).
// ---------------------------------------------------------------------------
__global__ __launch_bounds__(256) void uproj_G(
    const float* __restrict__ query, const double* __restrict__ G,
    const double* __restrict__ ubias, double* __restrict__ U)
{
  __shared__ float sAf[128][36];    // 18.4 KB (36: float4-aligned rows)
  __shared__ double sBd[32][68];    // 17.4 KB
  const int tid = threadIdx.x;
  const int tx = tid & 15, ty = tid >> 4;
  const int row0 = blockIdx.x * 128;
  const int col0 = blockIdx.y * 64;

  double acc[2][4][4];
#pragma unroll
  for (int g = 0; g < 2; ++g)
#pragma unroll
    for (int i = 0; i < 4; ++i)
#pragma unroll
      for (int j = 0; j < 4; ++j) acc[g][i][j] = 0.0;

  for (int k0 = 0; k0 < D_DIM; k0 += 32) {
#pragma unroll
    for (int it = 0; it < 4; ++it) {
      const int L = it * 256 + tid;
      const int rowa = L >> 3, c4 = (L & 7) * 4;
      *(float4*)&sAf[rowa][c4] =
          *(const float4*)(query + (size_t)(row0 + rowa) * D_DIM + k0 + c4);
    }
#pragma unroll
    for (int it = 0; it < 4; ++it) {
      const int L = it * 256 + tid;
      const int kk = L >> 5, c2 = (L & 31) * 2;
      *(double2*)&sBd[kk][c2] =
          *(const double2*)(G + (size_t)(k0 + kk) * D_DIM + col0 + c2);
    }
    __syncthreads();
#pragma unroll
    for (int kk = 0; kk < 32; ++kk) {
      const double a0[4] = {sAf[ty * 4 + 0][kk], sAf[ty * 4 + 1][kk],
                            sAf[ty * 4 + 2][kk], sAf[ty * 4 + 3][kk]};
      const double a1[4] = {sAf[64 + ty * 4 + 0][kk], sAf[64 + ty * 4 + 1][kk],
                            sAf[64 + ty * 4 + 2][kk], sAf[64 + ty * 4 + 3][kk]};
      const double bb[4] = {sBd[kk][tx * 4 + 0], sBd[kk][tx * 4 + 1],
                            sBd[kk][tx * 4 + 2], sBd[kk][tx * 4 + 3]};
#pragma unroll
      for (int i = 0; i < 4; ++i)
#pragma unroll
        for (int j = 0; j < 4; ++j) {
          acc[0][i][j] = fma(a0[i], bb[j], acc[0][i][j]);
          acc[1][i][j] = fma(a1[i], bb[j], acc[1][i][j]);
        }
    }
    __syncthreads();
  }
  const double ub[4] = {ubias[col0 + tx * 4 + 0], ubias[col0 + tx * 4 + 1],
                        ubias[col0 + tx * 4 + 2], ubias[col0 + tx * 4 + 3]};
#pragma unroll
  for (int g = 0; g < 2; ++g)
#pragma unroll
    for (int i = 0; i < 4; ++i) {
      const size_t base = (size_t)(row0 + g * 64 + ty * 4 + i) * D_DIM + col0 + tx * 4;
      *(double2*)(U + base)     = (double2){acc[g][i][0] + ub[0], acc[g][i][1] + ub[1]};
      *(double2*)(U + base + 2) = (double2){acc[g][i][2] + ub[2], acc[g][i][3] + ub[3]};
    }
}

// ---------------------------------------------------------------------------
// Fused sims + per-half top-4. Round-16: BK=32, 3 buffers x 24KB = 72KB ->
// TWO 512-thread blocks/CU (16 waves). Depth-2-ahead counted-vmcnt pipeline
// (3 loads/wave/stage -> vmcnt(3)); swizzle re-derived for 64B rows
// (slot = ch ^ (row&3); wave b128 read = uniform 8 dwords/bank, conflict-
// free); T5 setprio around MFMA cluster (cross-block diversity now exists).
// cb-resident XCD mapping + epilogue unchanged (proven).
// ---------------------------------------------------------------------------
#define SBUF3 12288   // ushorts per buffer: A 8192 (16KB) + B 4096 (8KB)
__global__ __launch_bounds__(512, 4) void sims_topc_gemm(
    const unsigned short* __restrict__ A, const unsigned short* __restrict__ B,
    float* __restrict__ part_v, int* __restrict__ part_i)
{
  __shared__ unsigned short smem[3 * SBUF3];   // 72 KB

  const int tid = threadIdx.x;
  const int lane = tid & 63;
  const int wave = tid >> 6;          // 0..7
  const int wr = wave >> 1;           // 0..3 -> A rows wr*64
  const int wc = wave & 1;            // 0..1 -> B rows wc*64

  // cb-resident mapping (bijective over 4096 blocks) — rounds 12-15 proven.
  const int bid = blockIdx.x;
  const int x = bid & 7;
  const int t9 = bid >> 3;
  const int cbg = t9 >> 7;
  const int r = (t9 >> 3) & 15;
  const int cbl = t9 & 7;
  const int cb = (x * 4 + cbg) * 8 + cbl;
  const int row0 = r * 256;
  const int col0 = cb * 128;

  const int st_r = lane >> 2;                          // 0..15 row in 16-row seg
  const int st_swz = ((lane & 3) ^ (st_r & 3)) * 16;   // pre-swizzled 16B chunk

  auto STAGE = [&](int d, int k0) {
    unsigned short* buf = smem + d * SBUF3;
#pragma unroll
    for (int i = 0; i < 3; ++i) {
      const int seg = wave * 3 + i;                    // 0..23
      if (seg < 16) {
        const int grow = row0 + seg * 16 + st_r;
        async_copy16((char*)(buf + seg * 512),
                     (const char*)(A + (size_t)grow * D_DIM + k0) + st_swz);
      } else {
        const int s2 = seg - 16;
        const int grow = col0 + s2 * 16 + st_r;
        async_copy16((char*)(buf + 8192 + s2 * 512),
                     (const char*)(B + (size_t)grow * D_DIM + k0) + st_swz);
      }
    }
  };

  f32x4 acc[4][4];
#pragma unroll
  for (int m = 0; m < 4; ++m)
#pragma unroll
    for (int n = 0; n < 4; ++n) acc[m][n] = (f32x4){0.f, 0.f, 0.f, 0.f};

  auto COMPUTE = [&](int d) {
    const unsigned short* sA = smem + d * SBUF3;
    const unsigned short* sB = sA + 8192;
    bf16x8 af[4], bfr[4];
    const int ch = lane >> 4;                          // 16B chunk 0..3
#pragma unroll
    for (int m = 0; m < 4; ++m) {
      const int Ra = wr * 64 + m * 16 + (lane & 15);
      af[m] = *(const bf16x8*)((const char*)sA + Ra * 64 + ((ch ^ (Ra & 3)) * 16));
    }
#pragma unroll
    for (int n = 0; n < 4; ++n) {
      const int Rb = wc * 64 + n * 16 + (lane & 15);
      bfr[n] = *(const bf16x8*)((const char*)sB + Rb * 64 + ((ch ^ (Rb & 3)) * 16));
    }
    __builtin_amdgcn_s_setprio(1);
#pragma unroll
    for (int m = 0; m < 4; ++m)
#pragma unroll
      for (int n = 0; n < 4; ++n)
        acc[m][n] = __builtin_amdgcn_mfma_f32_16x16x32_bf16(af[m], bfr[n], acc[m][n], 0, 0, 0);
    __builtin_amdgcn_s_setprio(0);
  };

  STAGE(0, 0);
  STAGE(1, 32);
  asm volatile("s_waitcnt vmcnt(3)" ::: "memory");
  __builtin_amdgcn_sched_barrier(0);
  __builtin_amdgcn_s_barrier();

  for (int t = 0; t < 32; ++t) {
    if (t < 30) STAGE((t + 2) % 3, (t + 2) * 32);
    COMPUTE(t % 3);
    if (t < 30) {
      asm volatile("s_waitcnt vmcnt(3)" ::: "memory");   // tile t+1 landed
    } else if (t == 30) {
      asm volatile("s_waitcnt vmcnt(0)" ::: "memory");   // tile 31 landed
    }
    __builtin_amdgcn_sched_barrier(0);
    __builtin_amdgcn_s_barrier();
  }
  // K-loop done: smem free for the C tile (256x132 bf16 = 67.6 KB <= 72 KB).

  // C/D layout (m89): col=lane&15 (within 16), row=(lane>>4)*4+reg.
#pragma unroll
  for (int m = 0; m < 4; ++m)
#pragma unroll
    for (int n = 0; n < 4; ++n)
#pragma unroll
      for (int rg = 0; rg < 4; ++rg) {
        const int row = wr * 64 + m * 16 + (lane >> 4) * 4 + rg;
        const int colL = wc * 64 + n * 16 + (lane & 15);
        smem[row * 132 + colL] = f32_to_bf16(acc[m][n][rg]);
      }
  __syncthreads();

  {
    const int row = tid & 255;
    const int h = tid >> 8;             // 64-col half
    float tv[4];
    int ti_[4];
#pragma unroll
    for (int p = 0; p < 4; ++p) { tv[p] = -INFINITY; ti_[p] = 0; }
    const unsigned short* crow = smem + row * 132 + h * 64;
    const int gcol = col0 + h * 64;
    for (int j = 0; j < 64; j += 4) {
      const ushort4 c4 = *(const ushort4*)(crow + j);
      insN<4>(bf16_to_f32(c4.x), gcol + j + 0, tv, ti_);
      insN<4>(bf16_to_f32(c4.y), gcol + j + 1, tv, ti_);
      insN<4>(bf16_to_f32(c4.z), gcol + j + 2, tv, ti_);
      insN<4>(bf16_to_f32(c4.w), gcol + j + 3, tv, ti_);
    }
    const size_t base = ((size_t)(row0 + row) * NCB + cb) * TOPB + h * 4;
    *(float4*)(part_v + base) = (float4){tv[0], tv[1], tv[2], tv[3]};
    *(int4*)(part_i + base)   = (int4){ti_[0], ti_[1], ti_[2], ti_[3]};
  }
}

// ---------------------------------------------------------------------------
// Merge: parallel iterative max-extraction (round-15-proven).
// ---------------------------------------------------------------------------
__global__ __launch_bounds__(256) void merge_cand256(
    const float* __restrict__ part_v, const int* __restrict__ part_i,
    int* __restrict__ cand)
{
  const int r = blockIdx.x;
  const int tid = threadIdx.x;
  const int lane = tid & 63;
  const int wave = tid >> 6;

  float tv[8];
  int ti[8];
  {
    const size_t base = ((size_t)r * NCB + tid) * TOPB;
    const float4 a0 = *(const float4*)(part_v + base);
    const float4 a1 = *(const float4*)(part_v + base + 4);
    const int4 b0 = *(const int4*)(part_i + base);
    const int4 b1 = *(const int4*)(part_i + base + 4);
    tv[0] = a0.x; tv[1] = a0.y; tv[2] = a0.z; tv[3] = a0.w;
    tv[4] = a1.x; tv[5] = a1.y; tv[6] = a1.z; tv[7] = a1.w;
    ti[0] = b0.x; ti[1] = b0.y; ti[2] = b0.z; ti[3] = b0.w;
    ti[4] = b1.x; ti[5] = b1.y; ti[6] = b1.z; ti[7] = b1.w;
  }
  unsigned rem = 0xFFu;

  __shared__ float wv4[4];
  __shared__ int wi4[4];
  __shared__ int winner;

  for (int p = 0; p < TOPC; ++p) {
    float bv = -INFINITY;
    int bi = 0x7FFFFFFF;
#pragma unroll
    for (int e = 0; e < 8; ++e) {
      const bool alive = (rem >> e) & 1u;
      const float v = tv[e];
      const int ix = ti[e];
      if (alive && (v > bv || (v == bv && ix < bi))) { bv = v; bi = ix; }
    }
#pragma unroll
    for (int off = 32; off > 0; off >>= 1) {
      const float ov = __shfl_down(bv, off);
      const int oi = __shfl_down(bi, off);
      if (ov > bv || (ov == bv && oi < bi)) { bv = ov; bi = oi; }
    }
    if (lane == 0) { wv4[wave] = bv; wi4[wave] = bi; }
    __syncthreads();
    if (tid == 0) {
      float gv = wv4[0];
      int gi = wi4[0];
#pragma unroll
      for (int w = 1; w < 4; ++w)
        if (wv4[w] > gv || (wv4[w] == gv && wi4[w] < gi)) { gv = wv4[w]; gi = wi4[w]; }
      winner = gi;
      cand[(size_t)r * TOPC + p] = gi;
    }
    __syncthreads();
    const int wgi = winner;
#pragma unroll
    for (int e = 0; e < 8; ++e)
      if (ti[e] == wgi) rem &= ~(1u << e);
  }
}

// ---------------------------------------------------------------------------
// fp64 rescore via u: sims_ci = dot_f64(u_b, mem_ci) + qbk_b (proven).
// ---------------------------------------------------------------------------
__global__ __launch_bounds__(256) void rescore_topk_u(
    const double* __restrict__ U, const double* __restrict__ qbk,
    const float* __restrict__ mem, const int* __restrict__ cand,
    int* __restrict__ topi)
{
  const int b = blockIdx.x;
  const int tid = threadIdx.x;
  const int wave = tid >> 6;
  const int lane = tid & 63;

  __shared__ double sval[TOPC];
  __shared__ int sidx[TOPC];

  const double* urow = U + (size_t)b * D_DIM + lane * 16;
  double uv[16];
#pragma unroll
  for (int i = 0; i < 8; ++i) {
    const double2 d2 = *(const double2*)(urow + i * 2);
    uv[i * 2] = d2.x;
    uv[i * 2 + 1] = d2.y;
  }
  const double qb = qbk[b];

  for (int c = wave; c < TOPC; c += 4) {
    const int ci = cand[(size_t)b * TOPC + c];
    const float* mrow = mem + (size_t)ci * D_DIM + lane * 16;
    double acc = 0.0;
#pragma unroll
    for (int i = 0; i < 4; ++i) {
      const float4 mv = *(const float4*)(mrow + i * 4);
      acc = fma(uv[i * 4 + 0], (double)mv.x, acc);
      acc = fma(uv[i * 4 + 1], (double)mv.y, acc);
      acc = fma(uv[i * 4 + 2], (double)mv.z, acc);
      acc = fma(uv[i * 4 + 3], (double)mv.w, acc);
    }
#pragma unroll
    for (int off = 32; off > 0; off >>= 1) acc += __shfl_down(acc, off);
    if (lane == 0) { sval[c] = acc + qb; sidx[c] = ci; }
  }
  __syncthreads();

  if (tid == 0) {
    bool used[TOPC];
#pragma unroll
    for (int p = 0; p < TOPC; ++p) used[p] = false;
#pragma unroll
    for (int p = 0; p < TOPK; ++p) {
      int best = -1;
      double bv = 0.0;
      int bi = 0;
      for (int c = 0; c < TOPC; ++c) {
        if (used[c]) continue;
        const double v = sval[c];
        const int ix = sidx[c];
        if (best < 0 || v > bv || (v == bv && ix < bi)) { best = c; bv = v; bi = ix; }
      }
      used[best] = true;
      topi[(size_t)b * TOPK + p] = bi;
    }
  }
}

// ---------------------------------------------------------------------------
// f32 -> bf16 cast (vectorized).
// ---------------------------------------------------------------------------
__global__ __launch_bounds__(256) void cast_f32_bf16(
    const float* __restrict__ src, unsigned short* __restrict__ dst, int n4)
{
  const int i = blockIdx.x * 256 + threadIdx.x;
  if (i >= n4) return;
  const float4 v = *(const float4*)(src + (size_t)i * 4);
  ushort4 o;
  o.x = f32_to_bf16(v.x);
  o.y = f32_to_bf16(v.y);
  o.z = f32_to_bf16(v.z);
  o.w = f32_to_bf16(v.w);
  *(ushort4*)(dst + (size_t)i * 4) = o;
}

// ---------------------------------------------------------------------------
// Projection via bf16 MFMA, bf16 output (rounds 10-15 proven). Used for K
// (mem_bf x Wk_bf) AND for q (query_bf x Wq_bf) — same kernel, different grid.
// ---------------------------------------------------------------------------
__global__ __launch_bounds__(256) void kproj_bf16(
    const unsigned short* __restrict__ A,
    const unsigned short* __restrict__ B,
    const float* __restrict__ bias,
    unsigned short* __restrict__ C)
{
  __shared__ unsigned short smem[2 * 2 * 128 * 32];   // 32 KB: 2 x (sA | sB)

  const int tid = threadIdx.x;
  const int lane = tid & 63;
  const int wave = tid >> 6;
  const int wr = wave >> 1, wc = wave & 1;
  const int row0 = blockIdx.x * 128;
  const int col0 = blockIdx.y * 128;

  const int st_r = lane >> 2;
  const int st_cb = (lane & 3) * 16;

  auto STAGE = [&](int d, int k0) {
    unsigned short* dA = smem + d * (2 * 128 * 32);
    unsigned short* dB = dA + 128 * 32;
#pragma unroll
    for (int i = 0; i < 2; ++i) {
      const int seg = wave * 2 + i;
      const int rr = seg * 16 + st_r;
      async_copy16((char*)dA + seg * 1024,
                   (const char*)(A + (size_t)(row0 + rr) * D_DIM + k0) + st_cb);
      async_copy16((char*)dB + seg * 1024,
                   (const char*)(B + (size_t)(col0 + rr) * D_DIM + k0) + st_cb);
    }
  };

  f32x4 acc[4][4];
#pragma unroll
  for (int m = 0; m < 4; ++m)
#pragma unroll
    for (int n = 0; n < 4; ++n) acc[m][n] = (f32x4){0.f, 0.f, 0.f, 0.f};

  STAGE(0, 0);
  __syncthreads();
  int cur = 0;
  for (int t = 0; t < 32; ++t) {
    if (t < 31) STAGE(cur ^ 1, (t + 1) * 32);
    const unsigned short* sA = smem + cur * (2 * 128 * 32);
    const unsigned short* sB = sA + 128 * 32;
    bf16x8 af[4], bfr[4];
#pragma unroll
    for (int m = 0; m < 4; ++m)
      af[m] = *(const bf16x8*)(sA + (wr * 64 + m * 16 + (lane & 15)) * 32 + (lane >> 4) * 8);
#pragma unroll
    for (int n = 0; n < 4; ++n)
      bfr[n] = *(const bf16x8*)(sB + (wc * 64 + n * 16 + (lane & 15)) * 32 + (lane >> 4) * 8);
#pragma unroll
    for (int m = 0; m < 4; ++m)
#pragma unroll
      for (int n = 0; n < 4; ++n)
        acc[m][n] = __builtin_amdgcn_mfma_f32_16x16x32_bf16(af[m], bfr[n], acc[m][n], 0, 0, 0);
    __syncthreads();
    cur ^= 1;
  }

#pragma unroll
  for (int n = 0; n < 4; ++n) {
    const int col = col0 + wc * 64 + n * 16 + (lane & 15);
    const float bcol = bias[col];
#pragma unroll
    for (int m = 0; m < 4; ++m)
#pragma unroll
      for (int r = 0; r < 4; ++r) {
        const int row = row0 + wr * 64 + m * 16 + (lane >> 4) * 4 + r;
        C[(size_t)row * D_DIM + col] = f32_to_bf16(acc[m][n][r] + bcol);
      }
  }
}

// ---------------------------------------------------------------------------
// V projection via bf16 MFMA, f32 output (rounds 7-15 proven).
// ---------------------------------------------------------------------------
__global__ __launch_bounds__(256) void vproj_bf16(
    const unsigned short* __restrict__ A,
    const unsigned short* __restrict__ B,
    const float* __restrict__ bias,
    float* __restrict__ C)
{
  __shared__ unsigned short smem[2 * 2 * 128 * 32];   // 32 KB

  const int tid = threadIdx.x;
  const int lane = tid & 63;
  const int wave = tid >> 6;
  const int wr = wave >> 1, wc = wave & 1;
  const int row0 = blockIdx.x * 128;
  const int col0 = blockIdx.y * 128;

  const int st_r = lane >> 2;
  const int st_cb = (lane & 3) * 16;

  auto STAGE = [&](int d, int k0) {
    unsigned short* dA = smem + d * (2 * 128 * 32);
    unsigned short* dB = dA + 128 * 32;
#pragma unroll
    for (int i = 0; i < 2; ++i) {
      const int seg = wave * 2 + i;
      const int rr = seg * 16 + st_r;
      async_copy16((char*)dA + seg * 1024,
                   (const char*)(A + (size_t)(row0 + rr) * D_DIM + k0) + st_cb);
      async_copy16((char*)dB + seg * 1024,
                   (const char*)(B + (size_t)(col0 + rr) * D_DIM + k0) + st_cb);
    }
  };

  f32x4 acc[4][4];
#pragma unroll
  for (int m = 0; m < 4; ++m)
#pragma unroll
    for (int n = 0; n < 4; ++n) acc[m][n] = (f32x4){0.f, 0.f, 0.f, 0.f};

  STAGE(0, 0);
  __syncthreads();
  int cur = 0;
  for (int t = 0; t < 32; ++t) {
    if (t < 31) STAGE(cur ^ 1, (t + 1) * 32);
    const unsigned short* sA = smem + cur * (2 * 128 * 32);
    const unsigned short* sB = sA + 128 * 32;
    bf16x8 af[4], bfr[4];
#pragma unroll
    for (int m = 0; m < 4; ++m)
      af[m] = *(const bf16x8*)(sA + (wr * 64 + m * 16 + (lane & 15)) * 32 + (lane >> 4) * 8);
#pragma unroll
    for (int n = 0; n < 4; ++n)
      bfr[n] = *(const bf16x8*)(sB + (wc * 64 + n * 16 + (lane & 15)) * 32 + (lane >> 4) * 8);
#pragma unroll
    for (int m = 0; m < 4; ++m)
#pragma unroll
      for (int n = 0; n < 4; ++n)
        acc[m][n] = __builtin_amdgcn_mfma_f32_16x16x32_bf16(af[m], bfr[n], acc[m][n], 0, 0, 0);
    __syncthreads();
    cur ^= 1;
  }

#pragma unroll
  for (int n = 0; n < 4; ++n) {
    const int col = col0 + wc * 64 + n * 16 + (lane & 15);
    const float bcol = bias[col];
#pragma unroll
    for (int m = 0; m < 4; ++m)
#pragma unroll
      for (int r = 0; r < 4; ++r) {
        const int row = row0 + wr * 64 + m * 16 + (lane >> 4) * 4 + r;
        C[(size_t)row * D_DIM + col] = acc[m][n][r] + bcol;
      }
  }
}

// ---------------------------------------------------------------------------
// Gather selected V rows + LayerNorm (unchanged).
// ---------------------------------------------------------------------------
__global__ __launch_bounds__(256) void gather_ln(
    const float* __restrict__ V, const int* __restrict__ topi,
    const float* __restrict__ gamma, const float* __restrict__ beta,
    float* __restrict__ out)
{
  const int row = blockIdx.x;
  const int tid = threadIdx.x;
  const int idx = topi[row];
  const float* src = V + (size_t)idx * D_DIM;
  const float4 v = *(const float4*)(src + tid * 4);
  float s = v.x + v.y + v.z + v.w;
  float s2 = v.x * v.x + v.y * v.y + v.z * v.z + v.w * v.w;
#pragma unroll
  for (int off = 32; off > 0; off >>= 1) {
    s += __shfl_down(s, off);
    s2 += __shfl_down(s2, off);
  }
  __shared__ float red[8];
  __shared__ float stats[2];
  const int wid = tid >> 6;
  if ((tid & 63) == 0) { red[wid] = s; red[4 + wid] = s2; }
  __syncthreads();
  if (tid == 0) {
    const float S = red[0] + red[1] + red[2] + red[3];
    const float S2 = red[4] + red[5] + red[6] + red[7];
    const float mu = S * (1.0f / D_DIM);
    const float var = S2 * (1.0f / D_DIM) - mu * mu;
    stats[0] = mu;
    stats[1] = rsqrtf(var + 1e-5f);
  }
  __syncthreads();
  const float mu = stats[0], rstd = stats[1];
  const float4 g4 = *(const float4*)(gamma + tid * 4);
  const float4 b4 = *(const float4*)(beta + tid * 4);
  float4 o;
  o.x = (v.x - mu) * rstd * g4.x + b4.x;
  o.y = (v.y - mu) * rstd * g4.y + b4.y;
  o.z = (v.z - mu) * rstd * g4.z + b4.z;
  o.w = (v.w - mu) * rstd * g4.w + b4.w;
  *(float4*)(out + (size_t)row * D_DIM + tid * 4) = o;
}

extern "C" void kernel_launch(void* const* d_in, const int* in_sizes, int n_in,
                              void* d_out, int out_size, void* d_ws, size_t ws_size,
                              hipStream_t stream)
{
  const float* query = (const float*)d_in[0];
  const float* mem   = (const float*)d_in[1];
  const float* Wq    = (const float*)d_in[2];
  const float* bq    = (const float*)d_in[3];
  const float* Wk    = (const float*)d_in[4];
  const float* bk    = (const float*)d_in[5];
  const float* Wv    = (const float*)d_in[6];
  const float* bv    = (const float*)d_in[7];
  const float* gamma = (const float*)d_in[8];
  const float* beta  = (const float*)d_in[9];
  float* out = (float*)d_out;

  char* ws = (char*)d_ws;
  double* u64 = (double*)ws;   ws += (size_t)B_ROWS * D_DIM * sizeof(double);   // 33.6 MB
  double* G = (double*)ws;     ws += (size_t)D_DIM * D_DIM * sizeof(double);    // 8.4 MB
  unsigned short* qbf = (unsigned short*)ws;
  ws += (size_t)B_ROWS * D_DIM * sizeof(unsigned short);                        // 8.4 MB
  unsigned short* querybf = (unsigned short*)ws;
  ws += (size_t)B_ROWS * D_DIM * sizeof(unsigned short);                        // 8.4 MB
  unsigned short* membf = (unsigned short*)ws;
  ws += (size_t)M_ROWS * D_DIM * sizeof(unsigned short);                        // 67.1 MB
  char* Aregion = ws;
  ws += (size_t)M_ROWS * D_DIM * sizeof(unsigned short)                         // Kbf 67.1
      + 2 * (size_t)B_ROWS * NCB * TOPB * sizeof(float);                        // parts 67.1
  double* wvec = (double*)ws;  ws += (size_t)D_DIM * sizeof(double);
  double* ubias = (double*)ws; ws += (size_t)D_DIM * sizeof(double);
  double* s0 = (double*)ws;    ws += 2 * sizeof(double);
  double* qbk = (double*)ws;   ws += (size_t)B_ROWS * sizeof(double);
  int* cand = (int*)ws;        ws += (size_t)B_ROWS * TOPC * sizeof(int);
  int* topi = (int*)ws;

  // Lifetimes (in-order stream):
  //  G: dead after uproj_G -> hosts wkbf/wvbf/wqbf casts (6.3 <= 8.4 MB).
  //  Aregion: Kbf+parts until merge; then Vout (134.2 MB) overlays.
  unsigned short* Kbf = (unsigned short*)Aregion;
  float* part_v = (float*)(Aregion + (size_t)M_ROWS * D_DIM * sizeof(unsigned short));
  int* part_i = (int*)((char*)part_v + (size_t)B_ROWS * NCB * TOPB * sizeof(float));
  unsigned short* wkbf = (unsigned short*)G;
  unsigned short* wvbf = wkbf + (size_t)D_DIM * D_DIM;
  unsigned short* wqbf = wvbf + (size_t)D_DIM * D_DIM;
  float* Vout = (float*)Aregion;

  // Selection chain (f64): G = Wq^T@Wk; u = query@G + bq@Wk; qbk = query.(Wq^T bk) + bq.bk
  gram_f64<<<dim3(16, 16), 256, 0, stream>>>(Wq, Wk, G);
  colred_f64<<<dim3(4), 256, 0, stream>>>(Wq, bk, wvec);
  colred_f64<<<dim3(4), 256, 0, stream>>>(Wk, bq, ubias);
  dot1024_f64<<<dim3(1), 256, 0, stream>>>(bq, bk, s0);
  qbk_w<<<dim3(B_ROWS / 4), 256, 0, stream>>>(query, wvec, s0, qbk);
  uproj_G<<<dim3(B_ROWS / 128, D_DIM / 64), 256, 0, stream>>>(query, G, ubias, u64);

  // Candidate chain (bf16): casts; G dead -> W casts overlay it.
  cast_f32_bf16<<<dim3((M_ROWS * D_DIM / 4 + 255) / 256), 256, 0, stream>>>(mem, membf, M_ROWS * D_DIM / 4);
  cast_f32_bf16<<<dim3((B_ROWS * D_DIM / 4 + 255) / 256), 256, 0, stream>>>(query, querybf, B_ROWS * D_DIM / 4);
  cast_f32_bf16<<<dim3((D_DIM * D_DIM / 4 + 255) / 256), 256, 0, stream>>>(Wk, wkbf, D_DIM * D_DIM / 4);
  cast_f32_bf16<<<dim3((D_DIM * D_DIM / 4 + 255) / 256), 256, 0, stream>>>(Wv, wvbf, D_DIM * D_DIM / 4);
  cast_f32_bf16<<<dim3((D_DIM * D_DIM / 4 + 255) / 256), 256, 0, stream>>>(Wq, wqbf, D_DIM * D_DIM / 4);

  kproj_bf16<<<dim3(M_ROWS / 128, D_DIM / 128), 256, 0, stream>>>(membf, wkbf, bk, Kbf);
  kproj_bf16<<<dim3(B_ROWS / 128, D_DIM / 128), 256, 0, stream>>>(querybf, wqbf, bq, qbf);

  sims_topc_gemm<<<dim3((B_ROWS / 256) * NCB), 512, 0, stream>>>(qbf, Kbf, part_v, part_i);
  merge_cand256<<<dim3(B_ROWS), 256, 0, stream>>>(part_v, part_i, cand);
  rescore_topk_u<<<dim3(B_ROWS), 256, 0, stream>>>(u64, qbk, mem, cand, topi);

  vproj_bf16<<<dim3(M_ROWS / 128, D_DIM / 128), 256, 0, stream>>>(membf, wvbf, bv, Vout);
  gather_ln<<<dim3(B_ROWS * TOPK), 256, 0, stream>>>(Vout, topi, gamma, beta, out);
}

// Round 17
// 1315.853 us; speedup vs baseline: 6.0874x; 1.0008x over previous
//
#include <hip/hip_runtime.h>
#include <hip/hip_bf16.h>
#include <math.h>

#define D_DIM 1024
#define B_ROWS 4096
#define M_ROWS 32768
#define TOPK 8
#define TOPC 16                // candidates per row after merge
#define TOPB 8                 // entries stored per (row, col-block): 2 halves x top-4
#define NCB (M_ROWS / 128)     // 256 col-blocks

#define BM 128
#define BN 64
#define BK 32

typedef __attribute__((ext_vector_type(8))) short bf16x8;
typedef __attribute__((ext_vector_type(4))) float f32x4;

__device__ __forceinline__ unsigned short f32_to_bf16(float f) {
  unsigned int u = __float_as_uint(f);
  unsigned int r = (u + 0x7FFFu + ((u >> 16) & 1u)) >> 16;
  return (unsigned short)r;
}
__device__ __forceinline__ float bf16_to_f32(unsigned short h) {
  return __uint_as_float(((unsigned int)h) << 16);
}
__device__ __forceinline__ void async_copy16(void* lds, const void* g) {
  __builtin_amdgcn_global_load_lds(
      (const __attribute__((address_space(1))) unsigned int*)g,
      (__attribute__((address_space(3))) unsigned int*)lds, 16, 0, 0);
}

// Ordered insert into a register top-N list sorted by (value desc, index asc).
template <int N>
__device__ __forceinline__ void insN(float v, int idx,
                                     float* __restrict__ tv,
                                     int* __restrict__ ti) {
  if (v < tv[N - 1]) return;
  if (v == tv[N - 1] && idx > ti[N - 1]) return;
  float cv = v;
  int ci = idx;
#pragma unroll
  for (int p = 0; p < N; ++p) {
    if (cv > tv[p] || (cv == tv[p] && ci < ti[p])) {
      const float t0 = tv[p]; tv[p] = cv; cv = t0;
      const int t1 = ti[p]; ti[p] = ci; ci = t1;
    }
  }
}

// ---------------------------------------------------------------------------
// G[f][e] = sum_n Wq[n][f] * Wk[n][e], f64 accumulation (round-16-proven).
// ---------------------------------------------------------------------------
__global__ __launch_bounds__(256) void gram_f64(
    const float* __restrict__ Wq, const float* __restrict__ Wk,
    double* __restrict__ G)
{
  __shared__ float sA[32][68];
  __shared__ float sB[32][68];
  const int tid = threadIdx.x;
  const int tx = tid & 15, ty = tid >> 4;
  const int f0 = blockIdx.x * 64;
  const int e0 = blockIdx.y * 64;

  double acc[4][4];
#pragma unroll
  for (int i = 0; i < 4; ++i)
#pragma unroll
    for (int j = 0; j < 4; ++j) acc[i][j] = 0.0;

  for (int k0 = 0; k0 < D_DIM; k0 += 32) {
#pragma unroll
    for (int it = 0; it < 2; ++it) {
      const int L = it * 256 + tid;
      const int kk = L >> 4, c4 = (L & 15) * 4;
      *(float4*)&sA[kk][c4] = *(const float4*)(Wq + (size_t)(k0 + kk) * D_DIM + f0 + c4);
      *(float4*)&sB[kk][c4] = *(const float4*)(Wk + (size_t)(k0 + kk) * D_DIM + e0 + c4);
    }
    __syncthreads();
#pragma unroll
    for (int kk = 0; kk < 32; ++kk) {
      const double a[4] = {sA[kk][ty * 4 + 0], sA[kk][ty * 4 + 1],
                           sA[kk][ty * 4 + 2], sA[kk][ty * 4 + 3]};
      const double b[4] = {sB[kk][tx * 4 + 0], sB[kk][tx * 4 + 1],
                           sB[kk][tx * 4 + 2], sB[kk][tx * 4 + 3]};
#pragma unroll
      for (int i = 0; i < 4; ++i)
#pragma unroll
        for (int j = 0; j < 4; ++j)
          acc[i][j] = fma(a[i], b[j], acc[i][j]);
    }
    __syncthreads();
  }
#pragma unroll
  for (int i = 0; i < 4; ++i)
#pragma unroll
    for (int j = 0; j < 4; ++j)
      G[(size_t)(f0 + ty * 4 + i) * D_DIM + e0 + tx * 4 + j] = acc[i][j];
}

// ---------------------------------------------------------------------------
// outv[c] = sum_n W[n][c] * v[n], f64 (round-16-proven).
// ---------------------------------------------------------------------------
__global__ __launch_bounds__(256) void colred_f64(
    const float* __restrict__ W, const float* __restrict__ v,
    double* __restrict__ outv)
{
  const int c = blockIdx.x * 256 + threadIdx.x;
  double acc = 0.0;
  for (int n = 0; n < D_DIM; ++n)
    acc = fma((double)W[(size_t)n * D_DIM + c], (double)v[n], acc);
  outv[c] = acc;
}

// ---------------------------------------------------------------------------
// out[0] = dot_f64(a, b) over 1024 elements (round-16-proven).
// ---------------------------------------------------------------------------
__global__ __launch_bounds__(256) void dot1024_f64(
    const float* __restrict__ a, const float* __restrict__ b,
    double* __restrict__ out)
{
  const int tid = threadIdx.x;
  double acc = 0.0;
#pragma unroll
  for (int i = 0; i < 4; ++i) {
    const int idx = tid * 4 + i;
    acc = fma((double)a[idx], (double)b[idx], acc);
  }
#pragma unroll
  for (int off = 32; off > 0; off >>= 1) acc += __shfl_down(acc, off);
  __shared__ double red[4];
  if ((tid & 63) == 0) red[tid >> 6] = acc;
  __syncthreads();
  if (tid == 0) out[0] = red[0] + red[1] + red[2] + red[3];
}

// ---------------------------------------------------------------------------
// qbk[b] = dot_f64(query[b,:], w) + s0 (round-16-proven).
// ---------------------------------------------------------------------------
__global__ __launch_bounds__(256) void qbk_w(
    const float* __restrict__ query, const double* __restrict__ w,
    const double* __restrict__ s0, double* __restrict__ qbk)
{
  const int b = blockIdx.x * 4 + (threadIdx.x >> 6);
  const int lane = threadIdx.x & 63;
  const float* qrow = query + (size_t)b * D_DIM + lane * 16;
  const double* wrow = w + lane * 16;
  double acc = 0.0;
#pragma unroll
  for (int i = 0; i < 16; ++i)
    acc = fma((double)qrow[i], wrow[i], acc);
#pragma unroll
  for (int off = 32; off > 0; off >>= 1) acc += __shfl_down(acc, off);
  if (lane == 0) qbk[b] = acc + s0[0];
}

// ---------------------------------------------------------------------------
// u[b,d] = sum_e query[b,e] * G[e,d] + ubias[d], f64 (round-16-proven).
// ---------------------------------------------------------------------------
__global__ __launch_bounds__(256) void uproj_G(
    const float* __restrict__ query, const double* __restrict__ G,
    const double* __restrict__ ubias, double* __restrict__ U)
{
  __shared__ float sAf[128][36];
  __shared__ double sBd[32][68];
  const int tid = threadIdx.x;
  const int tx = tid & 15, ty = tid >> 4;
  const int row0 = blockIdx.x * 128;
  const int col0 = blockIdx.y * 64;

  double acc[2][4][4];
#pragma unroll
  for (int g = 0; g < 2; ++g)
#pragma unroll
    for (int i = 0; i < 4; ++i)
#pragma unroll
      for (int j = 0; j < 4; ++j) acc[g][i][j] = 0.0;

  for (int k0 = 0; k0 < D_DIM; k0 += 32) {
#pragma unroll
    for (int it = 0; it < 4; ++it) {
      const int L = it * 256 + tid;
      const int rowa = L >> 3, c4 = (L & 7) * 4;
      *(float4*)&sAf[rowa][c4] =
          *(const float4*)(query + (size_t)(row0 + rowa) * D_DIM + k0 + c4);
    }
#pragma unroll
    for (int it = 0; it < 4; ++it) {
      const int L = it * 256 + tid;
      const int kk = L >> 5, c2 = (L & 31) * 2;
      *(double2*)&sBd[kk][c2] =
          *(const double2*)(G + (size_t)(k0 + kk) * D_DIM + col0 + c2);
    }
    __syncthreads();
#pragma unroll
    for (int kk = 0; kk < 32; ++kk) {
      const double a0[4] = {sAf[ty * 4 + 0][kk], sAf[ty * 4 + 1][kk],
                            sAf[ty * 4 + 2][kk], sAf[ty * 4 + 3][kk]};
      const double a1[4] = {sAf[64 + ty * 4 + 0][kk], sAf[64 + ty * 4 + 1][kk],
                            sAf[64 + ty * 4 + 2][kk], sAf[64 + ty * 4 + 3][kk]};
      const double bb[4] = {sBd[kk][tx * 4 + 0], sBd[kk][tx * 4 + 1],
                            sBd[kk][tx * 4 + 2], sBd[kk][tx * 4 + 3]};
#pragma unroll
      for (int i = 0; i < 4; ++i)
#pragma unroll
        for (int j = 0; j < 4; ++j) {
          acc[0][i][j] = fma(a0[i], bb[j], acc[0][i][j]);
          acc[1][i][j] = fma(a1[i], bb[j], acc[1][i][j]);
        }
    }
    __syncthreads();
  }
  const double ub[4] = {ubias[col0 + tx * 4 + 0], ubias[col0 + tx * 4 + 1],
                        ubias[col0 + tx * 4 + 2], ubias[col0 + tx * 4 + 3]};
#pragma unroll
  for (int g = 0; g < 2; ++g)
#pragma unroll
    for (int i = 0; i < 4; ++i) {
      const size_t base = (size_t)(row0 + g * 64 + ty * 4 + i) * D_DIM + col0 + tx * 4;
      *(double2*)(U + base)     = (double2){acc[g][i][0] + ub[0], acc[g][i][1] + ub[1]};
      *(double2*)(U + base + 2) = (double2){acc[g][i][2] + ub[2], acc[g][i][3] + ub[3]};
    }
}

// ---------------------------------------------------------------------------
// Fused sims + per-half top-4 (round-16 structure). Round-17 change: swizzle
// key (R>>1)&3 instead of R&3. Bank audit: per 8-lane issue group rows 0..7
// alternate parity halves; key (R>>1)&3 cycles all 4 slots within each half
// -> 32 banks x 1 dword = conflict-free (key R&3 left half the banks idle,
// 2-way hot => the measured 2^25 conflicts = 4 extra cyc per ds_read_b128).
// ---------------------------------------------------------------------------
#define SBUF3 12288   // ushorts per buffer: A 8192 (16KB) + B 4096 (8KB)
__global__ __launch_bounds__(512, 4) void sims_topc_gemm(
    const unsigned short* __restrict__ A, const unsigned short* __restrict__ B,
    float* __restrict__ part_v, int* __restrict__ part_i)
{
  __shared__ unsigned short smem[3 * SBUF3];   // 72 KB

  const int tid = threadIdx.x;
  const int lane = tid & 63;
  const int wave = tid >> 6;          // 0..7
  const int wr = wave >> 1;           // 0..3 -> A rows wr*64
  const int wc = wave & 1;            // 0..1 -> B rows wc*64

  // cb-resident mapping (bijective over 4096 blocks) — rounds 12-16 proven.
  const int bid = blockIdx.x;
  const int x = bid & 7;
  const int t9 = bid >> 3;
  const int cbg = t9 >> 7;
  const int r = (t9 >> 3) & 15;
  const int cbl = t9 & 7;
  const int cb = (x * 4 + cbg) * 8 + cbl;
  const int row0 = r * 256;
  const int col0 = cb * 128;

  const int st_r = lane >> 2;                               // 0..15 row in seg
  const int st_swz = ((lane & 3) ^ ((st_r >> 1) & 3)) * 16; // NEW key

  auto STAGE = [&](int d, int k0) {
    unsigned short* buf = smem + d * SBUF3;
#pragma unroll
    for (int i = 0; i < 3; ++i) {
      const int seg = wave * 3 + i;                    // 0..23
      if (seg < 16) {
        const int grow = row0 + seg * 16 + st_r;
        async_copy16((char*)(buf + seg * 512),
                     (const char*)(A + (size_t)grow * D_DIM + k0) + st_swz);
      } else {
        const int s2 = seg - 16;
        const int grow = col0 + s2 * 16 + st_r;
        async_copy16((char*)(buf + 8192 + s2 * 512),
                     (const char*)(B + (size_t)grow * D_DIM + k0) + st_swz);
      }
    }
  };

  f32x4 acc[4][4];
#pragma unroll
  for (int m = 0; m < 4; ++m)
#pragma unroll
    for (int n = 0; n < 4; ++n) acc[m][n] = (f32x4){0.f, 0.f, 0.f, 0.f};

  auto COMPUTE = [&](int d) {
    const unsigned short* sA = smem + d * SBUF3;
    const unsigned short* sB = sA + 8192;
    bf16x8 af[4], bfr[4];
    const int ch = lane >> 4;                          // 16B chunk 0..3
#pragma unroll
    for (int m = 0; m < 4; ++m) {
      const int Ra = wr * 64 + m * 16 + (lane & 15);
      af[m] = *(const bf16x8*)((const char*)sA + Ra * 64 + ((ch ^ ((Ra >> 1) & 3)) * 16));
    }
#pragma unroll
    for (int n = 0; n < 4; ++n) {
      const int Rb = wc * 64 + n * 16 + (lane & 15);
      bfr[n] = *(const bf16x8*)((const char*)sB + Rb * 64 + ((ch ^ ((Rb >> 1) & 3)) * 16));
    }
    __builtin_amdgcn_s_setprio(1);
#pragma unroll
    for (int m = 0; m < 4; ++m)
#pragma unroll
      for (int n = 0; n < 4; ++n)
        acc[m][n] = __builtin_amdgcn_mfma_f32_16x16x32_bf16(af[m], bfr[n], acc[m][n], 0, 0, 0);
    __builtin_amdgcn_s_setprio(0);
  };

  STAGE(0, 0);
  STAGE(1, 32);
  asm volatile("s_waitcnt vmcnt(3)" ::: "memory");
  __builtin_amdgcn_sched_barrier(0);
  __builtin_amdgcn_s_barrier();

  for (int t = 0; t < 32; ++t) {
    if (t < 30) STAGE((t + 2) % 3, (t + 2) * 32);
    COMPUTE(t % 3);
    if (t < 30) {
      asm volatile("s_waitcnt vmcnt(3)" ::: "memory");   // tile t+1 landed
    } else if (t == 30) {
      asm volatile("s_waitcnt vmcnt(0)" ::: "memory");   // tile 31 landed
    }
    __builtin_amdgcn_sched_barrier(0);
    __builtin_amdgcn_s_barrier();
  }
  // K-loop done: smem free for the C tile (256x132 bf16 = 67.6 KB <= 72 KB).

  // C/D layout (m89): col=lane&15 (within 16), row=(lane>>4)*4+reg.
#pragma unroll
  for (int m = 0; m < 4; ++m)
#pragma unroll
    for (int n = 0; n < 4; ++n)
#pragma unroll
      for (int rg = 0; rg < 4; ++rg) {
        const int row = wr * 64 + m * 16 + (lane >> 4) * 4 + rg;
        const int colL = wc * 64 + n * 16 + (lane & 15);
        smem[row * 132 + colL] = f32_to_bf16(acc[m][n][rg]);
      }
  __syncthreads();

  {
    const int row = tid & 255;
    const int h = tid >> 8;             // 64-col half
    float tv[4];
    int ti_[4];
#pragma unroll
    for (int p = 0; p < 4; ++p) { tv[p] = -INFINITY; ti_[p] = 0; }
    const unsigned short* crow = smem + row * 132 + h * 64;
    const int gcol = col0 + h * 64;
    for (int j = 0; j < 64; j += 4) {
      const ushort4 c4 = *(const ushort4*)(crow + j);
      insN<4>(bf16_to_f32(c4.x), gcol + j + 0, tv, ti_);
      insN<4>(bf16_to_f32(c4.y), gcol + j + 1, tv, ti_);
      insN<4>(bf16_to_f32(c4.z), gcol + j + 2, tv, ti_);
      insN<4>(bf16_to_f32(c4.w), gcol + j + 3, tv, ti_);
    }
    const size_t base = ((size_t)(row0 + row) * NCB + cb) * TOPB + h * 4;
    *(float4*)(part_v + base) = (float4){tv[0], tv[1], tv[2], tv[3]};
    *(int4*)(part_i + base)   = (int4){ti_[0], ti_[1], ti_[2], ti_[3]};
  }
}

// ---------------------------------------------------------------------------
// Merge: parallel iterative max-extraction (round-15-proven).
// ---------------------------------------------------------------------------
__global__ __launch_bounds__(256) void merge_cand256(
    const float* __restrict__ part_v, const int* __restrict__ part_i,
    int* __restrict__ cand)
{
  const int r = blockIdx.x;
  const int tid = threadIdx.x;
  const int lane = tid & 63;
  const int wave = tid >> 6;

  float tv[8];
  int ti[8];
  {
    const size_t base = ((size_t)r * NCB + tid) * TOPB;
    const float4 a0 = *(const float4*)(part_v + base);
    const float4 a1 = *(const float4*)(part_v + base + 4);
    const int4 b0 = *(const int4*)(part_i + base);
    const int4 b1 = *(const int4*)(part_i + base + 4);
    tv[0] = a0.x; tv[1] = a0.y; tv[2] = a0.z; tv[3] = a0.w;
    tv[4] = a1.x; tv[5] = a1.y; tv[6] = a1.z; tv[7] = a1.w;
    ti[0] = b0.x; ti[1] = b0.y; ti[2] = b0.z; ti[3] = b0.w;
    ti[4] = b1.x; ti[5] = b1.y; ti[6] = b1.z; ti[7] = b1.w;
  }
  unsigned rem = 0xFFu;

  __shared__ float wv4[4];
  __shared__ int wi4[4];
  __shared__ int winner;

  for (int p = 0; p < TOPC; ++p) {
    float bv = -INFINITY;
    int bi = 0x7FFFFFFF;
#pragma unroll
    for (int e = 0; e < 8; ++e) {
      const bool alive = (rem >> e) & 1u;
      const float v = tv[e];
      const int ix = ti[e];
      if (alive && (v > bv || (v == bv && ix < bi))) { bv = v; bi = ix; }
    }
#pragma unroll
    for (int off = 32; off > 0; off >>= 1) {
      const float ov = __shfl_down(bv, off);
      const int oi = __shfl_down(bi, off);
      if (ov > bv || (ov == bv && oi < bi)) { bv = ov; bi = oi; }
    }
    if (lane == 0) { wv4[wave] = bv; wi4[wave] = bi; }
    __syncthreads();
    if (tid == 0) {
      float gv = wv4[0];
      int gi = wi4[0];
#pragma unroll
      for (int w = 1; w < 4; ++w)
        if (wv4[w] > gv || (wv4[w] == gv && wi4[w] < gi)) { gv = wv4[w]; gi = wi4[w]; }
      winner = gi;
      cand[(size_t)r * TOPC + p] = gi;
    }
    __syncthreads();
    const int wgi = winner;
#pragma unroll
    for (int e = 0; e < 8; ++e)
      if (ti[e] == wgi) rem &= ~(1u << e);
  }
}

// ---------------------------------------------------------------------------
// fp64 rescore via u: sims_ci = dot_f64(u_b, mem_ci) + qbk_b (proven).
// ---------------------------------------------------------------------------
__global__ __launch_bounds__(256) void rescore_topk_u(
    const double* __restrict__ U, const double* __restrict__ qbk,
    const float* __restrict__ mem, const int* __restrict__ cand,
    int* __restrict__ topi)
{
  const int b = blockIdx.x;
  const int tid = threadIdx.x;
  const int wave = tid >> 6;
  const int lane = tid & 63;

  __shared__ double sval[TOPC];
  __shared__ int sidx[TOPC];

  const double* urow = U + (size_t)b * D_DIM + lane * 16;
  double uv[16];
#pragma unroll
  for (int i = 0; i < 8; ++i) {
    const double2 d2 = *(const double2*)(urow + i * 2);
    uv[i * 2] = d2.x;
    uv[i * 2 + 1] = d2.y;
  }
  const double qb = qbk[b];

  for (int c = wave; c < TOPC; c += 4) {
    const int ci = cand[(size_t)b * TOPC + c];
    const float* mrow = mem + (size_t)ci * D_DIM + lane * 16;
    double acc = 0.0;
#pragma unroll
    for (int i = 0; i < 4; ++i) {
      const float4 mv = *(const float4*)(mrow + i * 4);
      acc = fma(uv[i * 4 + 0], (double)mv.x, acc);
      acc = fma(uv[i * 4 + 1], (double)mv.y, acc);
      acc = fma(uv[i * 4 + 2], (double)mv.z, acc);
      acc = fma(uv[i * 4 + 3], (double)mv.w, acc);
    }
#pragma unroll
    for (int off = 32; off > 0; off >>= 1) acc += __shfl_down(acc, off);
    if (lane == 0) { sval[c] = acc + qb; sidx[c] = ci; }
  }
  __syncthreads();

  if (tid == 0) {
    bool used[TOPC];
#pragma unroll
    for (int p = 0; p < TOPC; ++p) used[p] = false;
#pragma unroll
    for (int p = 0; p < TOPK; ++p) {
      int best = -1;
      double bv = 0.0;
      int bi = 0;
      for (int c = 0; c < TOPC; ++c) {
        if (used[c]) continue;
        const double v = sval[c];
        const int ix = sidx[c];
        if (best < 0 || v > bv || (v == bv && ix < bi)) { best = c; bv = v; bi = ix; }
      }
      used[best] = true;
      topi[(size_t)b * TOPK + p] = bi;
    }
  }
}

// ---------------------------------------------------------------------------
// Fused f32 -> bf16 cast: mem, query, Wk, Wv, Wq in ONE launch (flat index,
// wave-uniform range branches). Replaces 5 launches (~20 us of dispatch gap).
// ---------------------------------------------------------------------------
#define N4_MEM   (M_ROWS * D_DIM / 4)          // 8388608
#define N4_QUERY (B_ROWS * D_DIM / 4)          // 1048576
#define N4_W     (D_DIM * D_DIM / 4)           // 262144
#define N4_TOTAL (N4_MEM + N4_QUERY + 3 * N4_W)

__global__ __launch_bounds__(256) void cast_all_bf16(
    const float* __restrict__ mem, const float* __restrict__ query,
    const float* __restrict__ Wk, const float* __restrict__ Wv,
    const float* __restrict__ Wq,
    unsigned short* __restrict__ membf, unsigned short* __restrict__ querybf,
    unsigned short* __restrict__ wkbf, unsigned short* __restrict__ wvbf,
    unsigned short* __restrict__ wqbf)
{
  int i = blockIdx.x * 256 + threadIdx.x;
  if (i >= N4_TOTAL) return;
  const float* src;
  unsigned short* dst;
  if (i < N4_MEM) { src = mem; dst = membf; }
  else if ((i -= N4_MEM) < N4_QUERY) { src = query; dst = querybf; }
  else if ((i -= N4_QUERY) < N4_W) { src = Wk; dst = wkbf; }
  else if ((i -= N4_W) < N4_W) { src = Wv; dst = wvbf; }
  else { i -= N4_W; src = Wq; dst = wqbf; }
  const float4 v = *(const float4*)(src + (size_t)i * 4);
  ushort4 o;
  o.x = f32_to_bf16(v.x);
  o.y = f32_to_bf16(v.y);
  o.z = f32_to_bf16(v.z);
  o.w = f32_to_bf16(v.w);
  *(ushort4*)(dst + (size_t)i * 4) = o;
}

// ---------------------------------------------------------------------------
// Projection via bf16 MFMA, bf16 output. Round-17: XOR swizzle (key
// (R>>1)&3, both sides) added — the un-swizzled 64B-row reads were 4-way
// bank-conflicted since round 7. Structure otherwise rounds 10-16 proven.
// ---------------------------------------------------------------------------
__global__ __launch_bounds__(256) void kproj_bf16(
    const unsigned short* __restrict__ A,
    const unsigned short* __restrict__ B,
    const float* __restrict__ bias,
    unsigned short* __restrict__ C)
{
  __shared__ unsigned short smem[2 * 2 * 128 * 32];   // 32 KB: 2 x (sA | sB)

  const int tid = threadIdx.x;
  const int lane = tid & 63;
  const int wave = tid >> 6;
  const int wr = wave >> 1, wc = wave & 1;
  const int row0 = blockIdx.x * 128;
  const int col0 = blockIdx.y * 128;

  const int st_r = lane >> 2;
  const int st_swz = ((lane & 3) ^ ((st_r >> 1) & 3)) * 16;

  auto STAGE = [&](int d, int k0) {
    unsigned short* dA = smem + d * (2 * 128 * 32);
    unsigned short* dB = dA + 128 * 32;
#pragma unroll
    for (int i = 0; i < 2; ++i) {
      const int seg = wave * 2 + i;
      const int rr = seg * 16 + st_r;
      async_copy16((char*)dA + seg * 1024,
                   (const char*)(A + (size_t)(row0 + rr) * D_DIM + k0) + st_swz);
      async_copy16((char*)dB + seg * 1024,
                   (const char*)(B + (size_t)(col0 + rr) * D_DIM + k0) + st_swz);
    }
  };

  f32x4 acc[4][4];
#pragma unroll
  for (int m = 0; m < 4; ++m)
#pragma unroll
    for (int n = 0; n < 4; ++n) acc[m][n] = (f32x4){0.f, 0.f, 0.f, 0.f};

  STAGE(0, 0);
  __syncthreads();
  int cur = 0;
  const int ch = lane >> 4;
  for (int t = 0; t < 32; ++t) {
    if (t < 31) STAGE(cur ^ 1, (t + 1) * 32);
    const unsigned short* sA = smem + cur * (2 * 128 * 32);
    const unsigned short* sB = sA + 128 * 32;
    bf16x8 af[4], bfr[4];
#pragma unroll
    for (int m = 0; m < 4; ++m) {
      const int Ra = wr * 64 + m * 16 + (lane & 15);
      af[m] = *(const bf16x8*)((const char*)sA + Ra * 64 + ((ch ^ ((Ra >> 1) & 3)) * 16));
    }
#pragma unroll
    for (int n = 0; n < 4; ++n) {
      const int Rb = wc * 64 + n * 16 + (lane & 15);
      bfr[n] = *(const bf16x8*)((const char*)sB + Rb * 64 + ((ch ^ ((Rb >> 1) & 3)) * 16));
    }
#pragma unroll
    for (int m = 0; m < 4; ++m)
#pragma unroll
      for (int n = 0; n < 4; ++n)
        acc[m][n] = __builtin_amdgcn_mfma_f32_16x16x32_bf16(af[m], bfr[n], acc[m][n], 0, 0, 0);
    __syncthreads();
    cur ^= 1;
  }

#pragma unroll
  for (int n = 0; n < 4; ++n) {
    const int col = col0 + wc * 64 + n * 16 + (lane & 15);
    const float bcol = bias[col];
#pragma unroll
    for (int m = 0; m < 4; ++m)
#pragma unroll
      for (int r = 0; r < 4; ++r) {
        const int row = row0 + wr * 64 + m * 16 + (lane >> 4) * 4 + r;
        C[(size_t)row * D_DIM + col] = f32_to_bf16(acc[m][n][r] + bcol);
      }
  }
}

// ---------------------------------------------------------------------------
// V projection via bf16 MFMA, f32 output. Same round-17 swizzle.
// ---------------------------------------------------------------------------
__global__ __launch_bounds__(256) void vproj_bf16(
    const unsigned short* __restrict__ A,
    const unsigned short* __restrict__ B,
    const float* __restrict__ bias,
    float* __restrict__ C)
{
  __shared__ unsigned short smem[2 * 2 * 128 * 32];   // 32 KB

  const int tid = threadIdx.x;
  const int lane = tid & 63;
  const int wave = tid >> 6;
  const int wr = wave >> 1, wc = wave & 1;
  const int row0 = blockIdx.x * 128;
  const int col0 = blockIdx.y * 128;

  const int st_r = lane >> 2;
  const int st_swz = ((lane & 3) ^ ((st_r >> 1) & 3)) * 16;

  auto STAGE = [&](int d, int k0) {
    unsigned short* dA = smem + d * (2 * 128 * 32);
    unsigned short* dB = dA + 128 * 32;
#pragma unroll
    for (int i = 0; i < 2; ++i) {
      const int seg = wave * 2 + i;
      const int rr = seg * 16 + st_r;
      async_copy16((char*)dA + seg * 1024,
                   (const char*)(A + (size_t)(row0 + rr) * D_DIM + k0) + st_swz);
      async_copy16((char*)dB + seg * 1024,
                   (const char*)(B + (size_t)(col0 + rr) * D_DIM + k0) + st_swz);
    }
  };

  f32x4 acc[4][4];
#pragma unroll
  for (int m = 0; m < 4; ++m)
#pragma unroll
    for (int n = 0; n < 4; ++n) acc[m][n] = (f32x4){0.f, 0.f, 0.f, 0.f};

  STAGE(0, 0);
  __syncthreads();
  int cur = 0;
  const int ch = lane >> 4;
  for (int t = 0; t < 32; ++t) {
    if (t < 31) STAGE(cur ^ 1, (t + 1) * 32);
    const unsigned short* sA = smem + cur * (2 * 128 * 32);
    const unsigned short* sB = sA + 128 * 32;
    bf16x8 af[4], bfr[4];
#pragma unroll
    for (int m = 0; m < 4; ++m) {
      const int Ra = wr * 64 + m * 16 + (lane & 15);
      af[m] = *(const bf16x8*)((const char*)sA + Ra * 64 + ((ch ^ ((Ra >> 1) & 3)) * 16));
    }
#pragma unroll
    for (int n = 0; n < 4; ++n) {
      const int Rb = wc * 64 + n * 16 + (lane & 15);
      bfr[n] = *(const bf16x8*)((const char*)sB + Rb * 64 + ((ch ^ ((Rb >> 1) & 3)) * 16));
    }
#pragma unroll
    for (int m = 0; m < 4; ++m)
#pragma unroll
      for (int n = 0; n < 4; ++n)
        acc[m][n] = __builtin_amdgcn_mfma_f32_16x16x32_bf16(af[m], bfr[n], acc[m][n], 0, 0, 0);
    __syncthreads();
    cur ^= 1;
  }

#pragma unroll
  for (int n = 0; n < 4; ++n) {
    const int col = col0 + wc * 64 + n * 16 + (lane & 15);
    const float bcol = bias[col];
#pragma unroll
    for (int m = 0; m < 4; ++m)
#pragma unroll
      for (int r = 0; r < 4; ++r) {
        const int row = row0 + wr * 64 + m * 16 + (lane >> 4) * 4 + r;
        C[(size_t)row * D_DIM + col] = acc[m][n][r] + bcol;
      }
  }
}

// ---------------------------------------------------------------------------
// Gather selected V rows + LayerNorm (unchanged).
// ---------------------------------------------------------------------------
__global__ __launch_bounds__(256) void gather_ln(
    const float* __restrict__ V, const int* __restrict__ topi,
    const float* __restrict__ gamma, const float* __restrict__ beta,
    float* __restrict__ out)
{
  const int row = blockIdx.x;
  const int tid = threadIdx.x;
  const int idx = topi[row];
  const float* src = V + (size_t)idx * D_DIM;
  const float4 v = *(const float4*)(src + tid * 4);
  float s = v.x + v.y + v.z + v.w;
  float s2 = v.x * v.x + v.y * v.y + v.z * v.z + v.w * v.w;
#pragma unroll
  for (int off = 32; off > 0; off >>= 1) {
    s += __shfl_down(s, off);
    s2 += __shfl_down(s2, off);
  }
  __shared__ float red[8];
  __shared__ float stats[2];
  const int wid = tid >> 6;
  if ((tid & 63) == 0) { red[wid] = s; red[4 + wid] = s2; }
  __syncthreads();
  if (tid == 0) {
    const float S = red[0] + red[1] + red[2] + red[3];
    const float S2 = red[4] + red[5] + red[6] + red[7];
    const float mu = S * (1.0f / D_DIM);
    const float var = S2 * (1.0f / D_DIM) - mu * mu;
    stats[0] = mu;
    stats[1] = rsqrtf(var + 1e-5f);
  }
  __syncthreads();
  const float mu = stats[0], rstd = stats[1];
  const float4 g4 = *(const float4*)(gamma + tid * 4);
  const float4 b4 = *(const float4*)(beta + tid * 4);
  float4 o;
  o.x = (v.x - mu) * rstd * g4.x + b4.x;
  o.y = (v.y - mu) * rstd * g4.y + b4.y;
  o.z = (v.z - mu) * rstd * g4.z + b4.z;
  o.w = (v.w - mu) * rstd * g4.w + b4.w;
  *(float4*)(out + (size_t)row * D_DIM + tid * 4) = o;
}

extern "C" void kernel_launch(void* const* d_in, const int* in_sizes, int n_in,
                              void* d_out, int out_size, void* d_ws, size_t ws_size,
                              hipStream_t stream)
{
  const float* query = (const float*)d_in[0];
  const float* mem   = (const float*)d_in[1];
  const float* Wq    = (const float*)d_in[2];
  const float* bq    = (const float*)d_in[3];
  const float* Wk    = (const float*)d_in[4];
  const float* bk    = (const float*)d_in[5];
  const float* Wv    = (const float*)d_in[6];
  const float* bv    = (const float*)d_in[7];
  const float* gamma = (const float*)d_in[8];
  const float* beta  = (const float*)d_in[9];
  float* out = (float*)d_out;

  char* ws = (char*)d_ws;
  double* u64 = (double*)ws;   ws += (size_t)B_ROWS * D_DIM * sizeof(double);   // 33.6 MB
  double* G = (double*)ws;     ws += (size_t)D_DIM * D_DIM * sizeof(double);    // 8.4 MB
  unsigned short* qbf = (unsigned short*)ws;
  ws += (size_t)B_ROWS * D_DIM * sizeof(unsigned short);                        // 8.4 MB
  unsigned short* querybf = (unsigned short*)ws;
  ws += (size_t)B_ROWS * D_DIM * sizeof(unsigned short);                        // 8.4 MB
  unsigned short* membf = (unsigned short*)ws;
  ws += (size_t)M_ROWS * D_DIM * sizeof(unsigned short);                        // 67.1 MB
  char* Aregion = ws;
  ws += (size_t)M_ROWS * D_DIM * sizeof(unsigned short)                         // Kbf 67.1
      + 2 * (size_t)B_ROWS * NCB * TOPB * sizeof(float);                        // parts 67.1
  double* wvec = (double*)ws;  ws += (size_t)D_DIM * sizeof(double);
  double* ubias = (double*)ws; ws += (size_t)D_DIM * sizeof(double);
  double* s0 = (double*)ws;    ws += 2 * sizeof(double);
  double* qbk = (double*)ws;   ws += (size_t)B_ROWS * sizeof(double);
  int* cand = (int*)ws;        ws += (size_t)B_ROWS * TOPC * sizeof(int);
  int* topi = (int*)ws;

  // Lifetimes (in-order stream):
  //  G: dead after uproj_G -> hosts wkbf/wvbf/wqbf casts (6.3 <= 8.4 MB).
  //  Aregion: Kbf+parts until merge; then Vout (134.2 MB) overlays.
  unsigned short* Kbf = (unsigned short*)Aregion;
  float* part_v = (float*)(Aregion + (size_t)M_ROWS * D_DIM * sizeof(unsigned short));
  int* part_i = (int*)((char*)part_v + (size_t)B_ROWS * NCB * TOPB * sizeof(float));
  unsigned short* wkbf = (unsigned short*)G;
  unsigned short* wvbf = wkbf + (size_t)D_DIM * D_DIM;
  unsigned short* wqbf = wvbf + (size_t)D_DIM * D_DIM;
  float* Vout = (float*)Aregion;

  // Selection chain (f64): G = Wq^T@Wk; u = query@G + bq@Wk; qbk = query.(Wq^T bk) + bq.bk
  gram_f64<<<dim3(16, 16), 256, 0, stream>>>(Wq, Wk, G);
  colred_f64<<<dim3(4), 256, 0, stream>>>(Wq, bk, wvec);
  colred_f64<<<dim3(4), 256, 0, stream>>>(Wk, bq, ubias);
  dot1024_f64<<<dim3(1), 256, 0, stream>>>(bq, bk, s0);
  qbk_w<<<dim3(B_ROWS / 4), 256, 0, stream>>>(query, wvec, s0, qbk);
  uproj_G<<<dim3(B_ROWS / 128, D_DIM / 64), 256, 0, stream>>>(query, G, ubias, u64);

  // Candidate chain (bf16): fused casts; G dead -> W casts overlay it.
  cast_all_bf16<<<dim3((N4_TOTAL + 255) / 256), 256, 0, stream>>>(
      mem, query, Wk, Wv, Wq, membf, querybf, wkbf, wvbf, wqbf);

  kproj_bf16<<<dim3(M_ROWS / 128, D_DIM / 128), 256, 0, stream>>>(membf, wkbf, bk, Kbf);
  kproj_bf16<<<dim3(B_ROWS / 128, D_DIM / 128), 256, 0, stream>>>(querybf, wqbf, bq, qbf);

  sims_topc_gemm<<<dim3((B_ROWS / 256) * NCB), 512, 0, stream>>>(qbf, Kbf, part_v, part_i);
  merge_cand256<<<dim3(B_ROWS), 256, 0, stream>>>(part_v, part_i, cand);
  rescore_topk_u<<<dim3(B_ROWS), 256, 0, stream>>>(u64, qbk, mem, cand, topi);

  vproj_bf16<<<dim3(M_ROWS / 128, D_DIM / 128), 256, 0, stream>>>(membf, wvbf, bv, Vout);
  gather_ln<<<dim3(B_ROWS * TOPK), 256, 0, stream>>>(Vout, topi, gamma, beta, out);
}

// Round 18
// 1256.839 us; speedup vs baseline: 6.3732x; 1.0470x over previous
//
#include <hip/hip_runtime.h>
#include <hip/hip_bf16.h>
#include <math.h>

#define D_DIM 1024
#define B_ROWS 4096
#define M_ROWS 32768
#define TOPK 8
#define TOPC 16
#define TOPB 8
#define NCB (M_ROWS / 128)

#define BM 128
#define BN 64
#define BK 32

typedef __attribute__((ext_vector_type(8))) short bf16x8;
typedef __attribute__((ext_vector_type(4))) float f32x4;

__device__ __forceinline__ unsigned short f32_to_bf16(float f) {
  unsigned int u = __float_as_uint(f);
  unsigned int r = (u + 0x7FFFu + ((u >> 16) & 1u)) >> 16;
  return (unsigned short)r;
}
__device__ __forceinline__ float bf16_to_f32(unsigned short h) {
  return __uint_as_float(((unsigned int)h) << 16);
}
__device__ __forceinline__ void async_copy16(void* lds, const void* g) {
  __builtin_amdgcn_global_load_lds(
      (const __attribute__((address_space(1))) unsigned int*)g,
      (__attribute__((address_space(3))) unsigned int*)lds, 16, 0, 0);
}

template <int N>
__device__ __forceinline__ void insN(float v, int idx,
                                     float* __restrict__ tv,
                                     int* __restrict__ ti) {
  if (v < tv[N - 1]) return;
  if (v == tv[N - 1] && idx > ti[N - 1]) return;
  float cv = v;
  int ci = idx;
#pragma unroll
  for (int p = 0; p < N; ++p) {
    if (cv > tv[p] || (cv == tv[p] && ci < ti[p])) {
      const float t0 = tv[p]; tv[p] = cv; cv = t0;
      const int t1 = ti[p]; ti[p] = ci; ci = t1;
    }
  }
}

// ---------------------------------------------------------------------------
// G[f][e] = sum_n Wq[n][f] * Wk[n][e], f64 accumulation (round-16/17-proven).
// ---------------------------------------------------------------------------
__global__ __launch_bounds__(256) void gram_f64(
    const float* __restrict__ Wq, const float* __restrict__ Wk,
    double* __restrict__ G)
{
  __shared__ float sA[32][68];
  __shared__ float sB[32][68];
  const int tid = threadIdx.x;
  const int tx = tid & 15, ty = tid >> 4;
  const int f0 = blockIdx.x * 64;
  const int e0 = blockIdx.y * 64;

  double acc[4][4];
#pragma unroll
  for (int i = 0; i < 4; ++i)
#pragma unroll
    for (int j = 0; j < 4; ++j) acc[i][j] = 0.0;

  for (int k0 = 0; k0 < D_DIM; k0 += 32) {
#pragma unroll
    for (int it = 0; it < 2; ++it) {
      const int L = it * 256 + tid;
      const int kk = L >> 4, c4 = (L & 15) * 4;
      *(float4*)&sA[kk][c4] = *(const float4*)(Wq + (size_t)(k0 + kk) * D_DIM + f0 + c4);
      *(float4*)&sB[kk][c4] = *(const float4*)(Wk + (size_t)(k0 + kk) * D_DIM + e0 + c4);
    }
    __syncthreads();
#pragma unroll
    for (int kk = 0; kk < 32; ++kk) {
      const double a[4] = {sA[kk][ty * 4 + 0], sA[kk][ty * 4 + 1],
                           sA[kk][ty * 4 + 2], sA[kk][ty * 4 + 3]};
      const double b[4] = {sB[kk][tx * 4 + 0], sB[kk][tx * 4 + 1],
                           sB[kk][tx * 4 + 2], sB[kk][tx * 4 + 3]};
#pragma unroll
      for (int i = 0; i < 4; ++i)
#pragma unroll
        for (int j = 0; j < 4; ++j)
          acc[i][j] = fma(a[i], b[j], acc[i][j]);
    }
    __syncthreads();
  }
#pragma unroll
  for (int i = 0; i < 4; ++i)
#pragma unroll
    for (int j = 0; j < 4; ++j)
      G[(size_t)(f0 + ty * 4 + i) * D_DIM + e0 + tx * 4 + j] = acc[i][j];
}

// ---------------------------------------------------------------------------
// outv[c] = sum_n W[n][c] * v[n], f64 (proven).
// ---------------------------------------------------------------------------
__global__ __launch_bounds__(256) void colred_f64(
    const float* __restrict__ W, const float* __restrict__ v,
    double* __restrict__ outv)
{
  const int c = blockIdx.x * 256 + threadIdx.x;
  double acc = 0.0;
  for (int n = 0; n < D_DIM; ++n)
    acc = fma((double)W[(size_t)n * D_DIM + c], (double)v[n], acc);
  outv[c] = acc;
}

// ---------------------------------------------------------------------------
// out[0] = dot_f64(a, b) over 1024 elements (proven).
// ---------------------------------------------------------------------------
__global__ __launch_bounds__(256) void dot1024_f64(
    const float* __restrict__ a, const float* __restrict__ b,
    double* __restrict__ out)
{
  const int tid = threadIdx.x;
  double acc = 0.0;
#pragma unroll
  for (int i = 0; i < 4; ++i) {
    const int idx = tid * 4 + i;
    acc = fma((double)a[idx], (double)b[idx], acc);
  }
#pragma unroll
  for (int off = 32; off > 0; off >>= 1) acc += __shfl_down(acc, off);
  __shared__ double red[4];
  if ((tid & 63) == 0) red[tid >> 6] = acc;
  __syncthreads();
  if (tid == 0) out[0] = red[0] + red[1] + red[2] + red[3];
}

// ---------------------------------------------------------------------------
// qbk[b] = dot_f64(query[b,:], w) + s0 (proven).
// ---------------------------------------------------------------------------
__global__ __launch_bounds__(256) void qbk_w(
    const float* __restrict__ query, const double* __restrict__ w,
    const double* __restrict__ s0, double* __restrict__ qbk)
{
  const int b = blockIdx.x * 4 + (threadIdx.x >> 6);
  const int lane = threadIdx.x & 63;
  const float* qrow = query + (size_t)b * D_DIM + lane * 16;
  const double* wrow = w + lane * 16;
  double acc = 0.0;
#pragma unroll
  for (int i = 0; i < 16; ++i)
    acc = fma((double)qrow[i], wrow[i], acc);
#pragma unroll
  for (int off = 32; off > 0; off >>= 1) acc += __shfl_down(acc, off);
  if (lane == 0) qbk[b] = acc + s0[0];
}

// ---------------------------------------------------------------------------
// u[b,d] = sum_e query[b,e] * G[e,d] + ubias[d], f64. Round-18: A tile stored
// TRANSPOSED sAdT[kk][row] (pad 130 -> 16B-aligned double2 reads, broadcast
// across tx; write conflicts 4-way but amortized 1:16 vs reads). Halves the
// LDS issue count of the f64 hot loop (8 scalar b64 -> 4 b128 per kk).
// ---------------------------------------------------------------------------
__global__ __launch_bounds__(256) void uproj_G(
    const float* __restrict__ query, const double* __restrict__ G,
    const double* __restrict__ ubias, double* __restrict__ U)
{
  __shared__ double sAdT[32][130];   // 33.3 KB (transposed: [k][row])
  __shared__ double sBd[32][68];     // 17.4 KB
  const int tid = threadIdx.x;
  const int tx = tid & 15, ty = tid >> 4;
  const int row0 = blockIdx.x * 128;
  const int col0 = blockIdx.y * 64;

  double acc[2][4][4];
#pragma unroll
  for (int g = 0; g < 2; ++g)
#pragma unroll
    for (int i = 0; i < 4; ++i)
#pragma unroll
      for (int j = 0; j < 4; ++j) acc[g][i][j] = 0.0;

  for (int k0 = 0; k0 < D_DIM; k0 += 32) {
#pragma unroll
    for (int it = 0; it < 4; ++it) {
      const int L = it * 256 + tid;
      const int rowa = L >> 3, c4 = (L & 7) * 4;
      const float4 v =
          *(const float4*)(query + (size_t)(row0 + rowa) * D_DIM + k0 + c4);
      sAdT[c4 + 0][rowa] = (double)v.x;
      sAdT[c4 + 1][rowa] = (double)v.y;
      sAdT[c4 + 2][rowa] = (double)v.z;
      sAdT[c4 + 3][rowa] = (double)v.w;
    }
#pragma unroll
    for (int it = 0; it < 4; ++it) {
      const int L = it * 256 + tid;
      const int kk = L >> 5, c2 = (L & 31) * 2;
      *(double2*)&sBd[kk][c2] =
          *(const double2*)(G + (size_t)(k0 + kk) * D_DIM + col0 + c2);
    }
    __syncthreads();
#pragma unroll
    for (int kk = 0; kk < 32; ++kk) {
      const double2 p0 = *(const double2*)&sAdT[kk][ty * 4];
      const double2 p1 = *(const double2*)&sAdT[kk][ty * 4 + 2];
      const double2 p2 = *(const double2*)&sAdT[kk][64 + ty * 4];
      const double2 p3 = *(const double2*)&sAdT[kk][64 + ty * 4 + 2];
      const double a0[4] = {p0.x, p0.y, p1.x, p1.y};
      const double a1[4] = {p2.x, p2.y, p3.x, p3.y};
      const double bb[4] = {sBd[kk][tx * 4 + 0], sBd[kk][tx * 4 + 1],
                            sBd[kk][tx * 4 + 2], sBd[kk][tx * 4 + 3]};
#pragma unroll
      for (int i = 0; i < 4; ++i)
#pragma unroll
        for (int j = 0; j < 4; ++j) {
          acc[0][i][j] = fma(a0[i], bb[j], acc[0][i][j]);
          acc[1][i][j] = fma(a1[i], bb[j], acc[1][i][j]);
        }
    }
    __syncthreads();
  }
  const double ub[4] = {ubias[col0 + tx * 4 + 0], ubias[col0 + tx * 4 + 1],
                        ubias[col0 + tx * 4 + 2], ubias[col0 + tx * 4 + 3]};
#pragma unroll
  for (int g = 0; g < 2; ++g)
#pragma unroll
    for (int i = 0; i < 4; ++i) {
      const size_t base = (size_t)(row0 + g * 64 + ty * 4 + i) * D_DIM + col0 + tx * 4;
      *(double2*)(U + base)     = (double2){acc[g][i][0] + ub[0], acc[g][i][1] + ub[1]};
      *(double2*)(U + base + 2) = (double2){acc[g][i][2] + ub[2], acc[g][i][3] + ub[3]};
    }
}

// ---------------------------------------------------------------------------
// Fused sims + per-half top-4 (round-17 structure). Round-18: main loop
// unrolled by 3 with STATIC buffer indices -> all 24 LDS read addresses and
// the swizzle XORs hoisted out of the loop; removes %3 and range branches.
// Barrier/vmcnt order byte-identical to the proven dynamic loop.
// ---------------------------------------------------------------------------
#define SBUF3 12288   // ushorts per buffer: A 8192 (16KB) + B 4096 (8KB)
__global__ __launch_bounds__(512, 4) void sims_topc_gemm(
    const unsigned short* __restrict__ A, const unsigned short* __restrict__ B,
    float* __restrict__ part_v, int* __restrict__ part_i)
{
  __shared__ unsigned short smem[3 * SBUF3];   // 72 KB

  const int tid = threadIdx.x;
  const int lane = tid & 63;
  const int wave = tid >> 6;
  const int wr = wave >> 1;
  const int wc = wave & 1;

  // cb-resident mapping (bijective over 4096 blocks) — rounds 12-17 proven.
  const int bid = blockIdx.x;
  const int x = bid & 7;
  const int t9 = bid >> 3;
  const int cbg = t9 >> 7;
  const int r = (t9 >> 3) & 15;
  const int cbl = t9 & 7;
  const int cb = (x * 4 + cbg) * 8 + cbl;
  const int row0 = r * 256;
  const int col0 = cb * 128;

  const int st_r = lane >> 2;
  const int st_swz = ((lane & 3) ^ ((st_r >> 1) & 3)) * 16;

  auto STAGE = [&](int d, int k0) {
    unsigned short* buf = smem + d * SBUF3;
#pragma unroll
    for (int i = 0; i < 3; ++i) {
      const int seg = wave * 3 + i;
      if (seg < 16) {
        const int grow = row0 + seg * 16 + st_r;
        async_copy16((char*)(buf + seg * 512),
                     (const char*)(A + (size_t)grow * D_DIM + k0) + st_swz);
      } else {
        const int s2 = seg - 16;
        const int grow = col0 + s2 * 16 + st_r;
        async_copy16((char*)(buf + 8192 + s2 * 512),
                     (const char*)(B + (size_t)grow * D_DIM + k0) + st_swz);
      }
    }
  };

  f32x4 acc[4][4];
#pragma unroll
  for (int m = 0; m < 4; ++m)
#pragma unroll
    for (int n = 0; n < 4; ++n) acc[m][n] = (f32x4){0.f, 0.f, 0.f, 0.f};

  auto COMPUTE = [&](int d) {
    const unsigned short* sA = smem + d * SBUF3;
    const unsigned short* sB = sA + 8192;
    bf16x8 af[4], bfr[4];
    const int ch = lane >> 4;
#pragma unroll
    for (int m = 0; m < 4; ++m) {
      const int Ra = wr * 64 + m * 16 + (lane & 15);
      af[m] = *(const bf16x8*)((const char*)sA + Ra * 64 + ((ch ^ ((Ra >> 1) & 3)) * 16));
    }
#pragma unroll
    for (int n = 0; n < 4; ++n) {
      const int Rb = wc * 64 + n * 16 + (lane & 15);
      bfr[n] = *(const bf16x8*)((const char*)sB + Rb * 64 + ((ch ^ ((Rb >> 1) & 3)) * 16));
    }
    __builtin_amdgcn_s_setprio(1);
#pragma unroll
    for (int m = 0; m < 4; ++m)
#pragma unroll
      for (int n = 0; n < 4; ++n)
        acc[m][n] = __builtin_amdgcn_mfma_f32_16x16x32_bf16(af[m], bfr[n], acc[m][n], 0, 0, 0);
    __builtin_amdgcn_s_setprio(0);
  };

  STAGE(0, 0);
  STAGE(1, 32);
  asm volatile("s_waitcnt vmcnt(3)" ::: "memory");
  __builtin_amdgcn_sched_barrier(0);
  __builtin_amdgcn_s_barrier();

  // Unrolled by 3: per iteration computes tiles tt,tt+1,tt+2 (bufs 0,1,2) and
  // stages tiles tt+2,tt+3,tt+4 (bufs 2,0,1) — identical order to the proven
  // dynamic loop, but all buffer indices static.
  for (int tt = 0; tt < 30; tt += 3) {
    STAGE(2, (tt + 2) * 32);
    COMPUTE(0);
    asm volatile("s_waitcnt vmcnt(3)" ::: "memory");
    __builtin_amdgcn_sched_barrier(0);
    __builtin_amdgcn_s_barrier();

    STAGE(0, (tt + 3) * 32);
    COMPUTE(1);
    asm volatile("s_waitcnt vmcnt(3)" ::: "memory");
    __builtin_amdgcn_sched_barrier(0);
    __builtin_amdgcn_s_barrier();

    STAGE(1, (tt + 4) * 32);
    COMPUTE(2);
    asm volatile("s_waitcnt vmcnt(3)" ::: "memory");
    __builtin_amdgcn_sched_barrier(0);
    __builtin_amdgcn_s_barrier();
  }
  COMPUTE(0);                                   // t = 30
  asm volatile("s_waitcnt vmcnt(0)" ::: "memory");
  __builtin_amdgcn_sched_barrier(0);
  __builtin_amdgcn_s_barrier();
  COMPUTE(1);                                   // t = 31
  __builtin_amdgcn_sched_barrier(0);
  __builtin_amdgcn_s_barrier();
  // K-loop done: smem free for the C tile (256x132 bf16 = 67.6 KB).

  // C/D layout (m89): col=lane&15 (within 16), row=(lane>>4)*4+reg.
#pragma unroll
  for (int m = 0; m < 4; ++m)
#pragma unroll
    for (int n = 0; n < 4; ++n)
#pragma unroll
      for (int rg = 0; rg < 4; ++rg) {
        const int row = wr * 64 + m * 16 + (lane >> 4) * 4 + rg;
        const int colL = wc * 64 + n * 16 + (lane & 15);
        smem[row * 132 + colL] = f32_to_bf16(acc[m][n][rg]);
      }
  __syncthreads();

  {
    const int row = tid & 255;
    const int h = tid >> 8;
    float tv[4];
    int ti_[4];
#pragma unroll
    for (int p = 0; p < 4; ++p) { tv[p] = -INFINITY; ti_[p] = 0; }
    const unsigned short* crow = smem + row * 132 + h * 64;
    const int gcol = col0 + h * 64;
    for (int j = 0; j < 64; j += 4) {
      const ushort4 c4 = *(const ushort4*)(crow + j);
      insN<4>(bf16_to_f32(c4.x), gcol + j + 0, tv, ti_);
      insN<4>(bf16_to_f32(c4.y), gcol + j + 1, tv, ti_);
      insN<4>(bf16_to_f32(c4.z), gcol + j + 2, tv, ti_);
      insN<4>(bf16_to_f32(c4.w), gcol + j + 3, tv, ti_);
    }
    const size_t base = ((size_t)(row0 + row) * NCB + cb) * TOPB + h * 4;
    *(float4*)(part_v + base) = (float4){tv[0], tv[1], tv[2], tv[3]};
    *(int4*)(part_i + base)   = (int4){ti_[0], ti_[1], ti_[2], ti_[3]};
  }
}

// ---------------------------------------------------------------------------
// Merge: parallel iterative max-extraction (round-15-proven).
// ---------------------------------------------------------------------------
__global__ __launch_bounds__(256) void merge_cand256(
    const float* __restrict__ part_v, const int* __restrict__ part_i,
    int* __restrict__ cand)
{
  const int r = blockIdx.x;
  const int tid = threadIdx.x;
  const int lane = tid & 63;
  const int wave = tid >> 6;

  float tv[8];
  int ti[8];
  {
    const size_t base = ((size_t)r * NCB + tid) * TOPB;
    const float4 a0 = *(const float4*)(part_v + base);
    const float4 a1 = *(const float4*)(part_v + base + 4);
    const int4 b0 = *(const int4*)(part_i + base);
    const int4 b1 = *(const int4*)(part_i + base + 4);
    tv[0] = a0.x; tv[1] = a0.y; tv[2] = a0.z; tv[3] = a0.w;
    tv[4] = a1.x; tv[5] = a1.y; tv[6] = a1.z; tv[7] = a1.w;
    ti[0] = b0.x; ti[1] = b0.y; ti[2] = b0.z; ti[3] = b0.w;
    ti[4] = b1.x; ti[5] = b1.y; ti[6] = b1.z; ti[7] = b1.w;
  }
  unsigned rem = 0xFFu;

  __shared__ float wv4[4];
  __shared__ int wi4[4];
  __shared__ int winner;

  for (int p = 0; p < TOPC; ++p) {
    float bv = -INFINITY;
    int bi = 0x7FFFFFFF;
#pragma unroll
    for (int e = 0; e < 8; ++e) {
      const bool alive = (rem >> e) & 1u;
      const float v = tv[e];
      const int ix = ti[e];
      if (alive && (v > bv || (v == bv && ix < bi))) { bv = v; bi = ix; }
    }
#pragma unroll
    for (int off = 32; off > 0; off >>= 1) {
      const float ov = __shfl_down(bv, off);
      const int oi = __shfl_down(bi, off);
      if (ov > bv || (ov == bv && oi < bi)) { bv = ov; bi = oi; }
    }
    if (lane == 0) { wv4[wave] = bv; wi4[wave] = bi; }
    __syncthreads();
    if (tid == 0) {
      float gv = wv4[0];
      int gi = wi4[0];
#pragma unroll
      for (int w = 1; w < 4; ++w)
        if (wv4[w] > gv || (wv4[w] == gv && wi4[w] < gi)) { gv = wv4[w]; gi = wi4[w]; }
      winner = gi;
      cand[(size_t)r * TOPC + p] = gi;
    }
    __syncthreads();
    const int wgi = winner;
#pragma unroll
    for (int e = 0; e < 8; ++e)
      if (ti[e] == wgi) rem &= ~(1u << e);
  }
}

// ---------------------------------------------------------------------------
// fp64 rescore via u: sims_ci = dot_f64(u_b, mem_ci) + qbk_b (proven).
// ---------------------------------------------------------------------------
__global__ __launch_bounds__(256) void rescore_topk_u(
    const double* __restrict__ U, const double* __restrict__ qbk,
    const float* __restrict__ mem, const int* __restrict__ cand,
    int* __restrict__ topi)
{
  const int b = blockIdx.x;
  const int tid = threadIdx.x;
  const int wave = tid >> 6;
  const int lane = tid & 63;

  __shared__ double sval[TOPC];
  __shared__ int sidx[TOPC];

  const double* urow = U + (size_t)b * D_DIM + lane * 16;
  double uv[16];
#pragma unroll
  for (int i = 0; i < 8; ++i) {
    const double2 d2 = *(const double2*)(urow + i * 2);
    uv[i * 2] = d2.x;
    uv[i * 2 + 1] = d2.y;
  }
  const double qb = qbk[b];

  for (int c = wave; c < TOPC; c += 4) {
    const int ci = cand[(size_t)b * TOPC + c];
    const float* mrow = mem + (size_t)ci * D_DIM + lane * 16;
    double acc = 0.0;
#pragma unroll
    for (int i = 0; i < 4; ++i) {
      const float4 mv = *(const float4*)(mrow + i * 4);
      acc = fma(uv[i * 4 + 0], (double)mv.x, acc);
      acc = fma(uv[i * 4 + 1], (double)mv.y, acc);
      acc = fma(uv[i * 4 + 2], (double)mv.z, acc);
      acc = fma(uv[i * 4 + 3], (double)mv.w, acc);
    }
#pragma unroll
    for (int off = 32; off > 0; off >>= 1) acc += __shfl_down(acc, off);
    if (lane == 0) { sval[c] = acc + qb; sidx[c] = ci; }
  }
  __syncthreads();

  if (tid == 0) {
    bool used[TOPC];
#pragma unroll
    for (int p = 0; p < TOPC; ++p) used[p] = false;
#pragma unroll
    for (int p = 0; p < TOPK; ++p) {
      int best = -1;
      double bv = 0.0;
      int bi = 0;
      for (int c = 0; c < TOPC; ++c) {
        if (used[c]) continue;
        const double v = sval[c];
        const int ix = sidx[c];
        if (best < 0 || v > bv || (v == bv && ix < bi)) { best = c; bv = v; bi = ix; }
      }
      used[best] = true;
      topi[(size_t)b * TOPK + p] = bi;
    }
  }
}

// ---------------------------------------------------------------------------
// Fused f32 -> bf16 cast (round-17-proven).
// ---------------------------------------------------------------------------
#define N4_MEM   (M_ROWS * D_DIM / 4)
#define N4_QUERY (B_ROWS * D_DIM / 4)
#define N4_W     (D_DIM * D_DIM / 4)
#define N4_TOTAL (N4_MEM + N4_QUERY + 3 * N4_W)

__global__ __launch_bounds__(256) void cast_all_bf16(
    const float* __restrict__ mem, const float* __restrict__ query,
    const float* __restrict__ Wk, const float* __restrict__ Wv,
    const float* __restrict__ Wq,
    unsigned short* __restrict__ membf, unsigned short* __restrict__ querybf,
    unsigned short* __restrict__ wkbf, unsigned short* __restrict__ wvbf,
    unsigned short* __restrict__ wqbf)
{
  int i = blockIdx.x * 256 + threadIdx.x;
  if (i >= N4_TOTAL) return;
  const float* src;
  unsigned short* dst;
  if (i < N4_MEM) { src = mem; dst = membf; }
  else if ((i -= N4_MEM) < N4_QUERY) { src = query; dst = querybf; }
  else if ((i -= N4_QUERY) < N4_W) { src = Wk; dst = wkbf; }
  else if ((i -= N4_W) < N4_W) { src = Wv; dst = wvbf; }
  else { i -= N4_W; src = Wq; dst = wqbf; }
  const float4 v = *(const float4*)(src + (size_t)i * 4);
  ushort4 o;
  o.x = f32_to_bf16(v.x);
  o.y = f32_to_bf16(v.y);
  o.z = f32_to_bf16(v.z);
  o.w = f32_to_bf16(v.w);
  *(ushort4*)(dst + (size_t)i * 4) = o;
}

// ---------------------------------------------------------------------------
// Projection via bf16 MFMA, bf16 output (round-17-proven, swizzled).
// Used for K (mem_bf x Wk_bf), q (query_bf x Wq_bf), AND now V
// (mem_bf x Wv_bf — V stored bf16; gather_ln converts).
// ---------------------------------------------------------------------------
__global__ __launch_bounds__(256) void kproj_bf16(
    const unsigned short* __restrict__ A,
    const unsigned short* __restrict__ B,
    const float* __restrict__ bias,
    unsigned short* __restrict__ C)
{
  __shared__ unsigned short smem[2 * 2 * 128 * 32];   // 32 KB

  const int tid = threadIdx.x;
  const int lane = tid & 63;
  const int wave = tid >> 6;
  const int wr = wave >> 1, wc = wave & 1;
  const int row0 = blockIdx.x * 128;
  const int col0 = blockIdx.y * 128;

  const int st_r = lane >> 2;
  const int st_swz = ((lane & 3) ^ ((st_r >> 1) & 3)) * 16;

  auto STAGE = [&](int d, int k0) {
    unsigned short* dA = smem + d * (2 * 128 * 32);
    unsigned short* dB = dA + 128 * 32;
#pragma unroll
    for (int i = 0; i < 2; ++i) {
      const int seg = wave * 2 + i;
      const int rr = seg * 16 + st_r;
      async_copy16((char*)dA + seg * 1024,
                   (const char*)(A + (size_t)(row0 + rr) * D_DIM + k0) + st_swz);
      async_copy16((char*)dB + seg * 1024,
                   (const char*)(B + (size_t)(col0 + rr) * D_DIM + k0) + st_swz);
    }
  };

  f32x4 acc[4][4];
#pragma unroll
  for (int m = 0; m < 4; ++m)
#pragma unroll
    for (int n = 0; n < 4; ++n) acc[m][n] = (f32x4){0.f, 0.f, 0.f, 0.f};

  STAGE(0, 0);
  __syncthreads();
  int cur = 0;
  const int ch = lane >> 4;
  for (int t = 0; t < 32; ++t) {
    if (t < 31) STAGE(cur ^ 1, (t + 1) * 32);
    const unsigned short* sA = smem + cur * (2 * 128 * 32);
    const unsigned short* sB = sA + 128 * 32;
    bf16x8 af[4], bfr[4];
#pragma unroll
    for (int m = 0; m < 4; ++m) {
      const int Ra = wr * 64 + m * 16 + (lane & 15);
      af[m] = *(const bf16x8*)((const char*)sA + Ra * 64 + ((ch ^ ((Ra >> 1) & 3)) * 16));
    }
#pragma unroll
    for (int n = 0; n < 4; ++n) {
      const int Rb = wc * 64 + n * 16 + (lane & 15);
      bfr[n] = *(const bf16x8*)((const char*)sB + Rb * 64 + ((ch ^ ((Rb >> 1) & 3)) * 16));
    }
#pragma unroll
    for (int m = 0; m < 4; ++m)
#pragma unroll
      for (int n = 0; n < 4; ++n)
        acc[m][n] = __builtin_amdgcn_mfma_f32_16x16x32_bf16(af[m], bfr[n], acc[m][n], 0, 0, 0);
    __syncthreads();
    cur ^= 1;
  }

#pragma unroll
  for (int n = 0; n < 4; ++n) {
    const int col = col0 + wc * 64 + n * 16 + (lane & 15);
    const float bcol = bias[col];
#pragma unroll
    for (int m = 0; m < 4; ++m)
#pragma unroll
      for (int r = 0; r < 4; ++r) {
        const int row = row0 + wr * 64 + m * 16 + (lane >> 4) * 4 + r;
        C[(size_t)row * D_DIM + col] = f32_to_bf16(acc[m][n][r] + bcol);
      }
  }
}

// ---------------------------------------------------------------------------
// Gather selected V rows (bf16) + LayerNorm in f32 (biased var, eps=1e-5).
// ---------------------------------------------------------------------------
__global__ __launch_bounds__(256) void gather_ln(
    const unsigned short* __restrict__ V, const int* __restrict__ topi,
    const float* __restrict__ gamma, const float* __restrict__ beta,
    float* __restrict__ out)
{
  const int row = blockIdx.x;
  const int tid = threadIdx.x;
  const int idx = topi[row];
  const unsigned short* src = V + (size_t)idx * D_DIM;
  const ushort4 raw = *(const ushort4*)(src + tid * 4);
  const float v0 = bf16_to_f32(raw.x);
  const float v1 = bf16_to_f32(raw.y);
  const float v2 = bf16_to_f32(raw.z);
  const float v3 = bf16_to_f32(raw.w);
  float s = v0 + v1 + v2 + v3;
  float s2 = v0 * v0 + v1 * v1 + v2 * v2 + v3 * v3;
#pragma unroll
  for (int off = 32; off > 0; off >>= 1) {
    s += __shfl_down(s, off);
    s2 += __shfl_down(s2, off);
  }
  __shared__ float red[8];
  __shared__ float stats[2];
  const int wid = tid >> 6;
  if ((tid & 63) == 0) { red[wid] = s; red[4 + wid] = s2; }
  __syncthreads();
  if (tid == 0) {
    const float S = red[0] + red[1] + red[2] + red[3];
    const float S2 = red[4] + red[5] + red[6] + red[7];
    const float mu = S * (1.0f / D_DIM);
    const float var = S2 * (1.0f / D_DIM) - mu * mu;
    stats[0] = mu;
    stats[1] = rsqrtf(var + 1e-5f);
  }
  __syncthreads();
  const float mu = stats[0], rstd = stats[1];
  const float4 g4 = *(const float4*)(gamma + tid * 4);
  const float4 b4 = *(const float4*)(beta + tid * 4);
  float4 o;
  o.x = (v0 - mu) * rstd * g4.x + b4.x;
  o.y = (v1 - mu) * rstd * g4.y + b4.y;
  o.z = (v2 - mu) * rstd * g4.z + b4.z;
  o.w = (v3 - mu) * rstd * g4.w + b4.w;
  *(float4*)(out + (size_t)row * D_DIM + tid * 4) = o;
}

extern "C" void kernel_launch(void* const* d_in, const int* in_sizes, int n_in,
                              void* d_out, int out_size, void* d_ws, size_t ws_size,
                              hipStream_t stream)
{
  const float* query = (const float*)d_in[0];
  const float* mem   = (const float*)d_in[1];
  const float* Wq    = (const float*)d_in[2];
  const float* bq    = (const float*)d_in[3];
  const float* Wk    = (const float*)d_in[4];
  const float* bk    = (const float*)d_in[5];
  const float* Wv    = (const float*)d_in[6];
  const float* bv    = (const float*)d_in[7];
  const float* gamma = (const float*)d_in[8];
  const float* beta  = (const float*)d_in[9];
  float* out = (float*)d_out;

  char* ws = (char*)d_ws;
  double* u64 = (double*)ws;   ws += (size_t)B_ROWS * D_DIM * sizeof(double);   // 33.6 MB
  double* G = (double*)ws;     ws += (size_t)D_DIM * D_DIM * sizeof(double);    // 8.4 MB
  unsigned short* qbf = (unsigned short*)ws;
  ws += (size_t)B_ROWS * D_DIM * sizeof(unsigned short);                        // 8.4 MB
  unsigned short* querybf = (unsigned short*)ws;
  ws += (size_t)B_ROWS * D_DIM * sizeof(unsigned short);                        // 8.4 MB
  unsigned short* membf = (unsigned short*)ws;
  ws += (size_t)M_ROWS * D_DIM * sizeof(unsigned short);                        // 67.1 MB
  char* Aregion = ws;
  ws += (size_t)M_ROWS * D_DIM * sizeof(unsigned short)                         // Kbf 67.1
      + 2 * (size_t)B_ROWS * NCB * TOPB * sizeof(float);                        // parts 67.1
  double* wvec = (double*)ws;  ws += (size_t)D_DIM * sizeof(double);
  double* ubias = (double*)ws; ws += (size_t)D_DIM * sizeof(double);
  double* s0 = (double*)ws;    ws += 2 * sizeof(double);
  double* qbk = (double*)ws;   ws += (size_t)B_ROWS * sizeof(double);
  int* cand = (int*)ws;        ws += (size_t)B_ROWS * TOPC * sizeof(int);
  int* topi = (int*)ws;

  // Lifetimes: G dead after uproj_G -> W casts overlay it; Aregion holds
  // Kbf+parts until merge, then Vbf (67.1 MB, bf16) overlays.
  unsigned short* Kbf = (unsigned short*)Aregion;
  float* part_v = (float*)(Aregion + (size_t)M_ROWS * D_DIM * sizeof(unsigned short));
  int* part_i = (int*)((char*)part_v + (size_t)B_ROWS * NCB * TOPB * sizeof(float));
  unsigned short* wkbf = (unsigned short*)G;
  unsigned short* wvbf = wkbf + (size_t)D_DIM * D_DIM;
  unsigned short* wqbf = wvbf + (size_t)D_DIM * D_DIM;
  unsigned short* Vbf = (unsigned short*)Aregion;

  // Selection chain (f64): G = Wq^T@Wk; u = query@G + bq@Wk; qbk = query.(Wq^T bk) + bq.bk
  gram_f64<<<dim3(16, 16), 256, 0, stream>>>(Wq, Wk, G);
  colred_f64<<<dim3(4), 256, 0, stream>>>(Wq, bk, wvec);
  colred_f64<<<dim3(4), 256, 0, stream>>>(Wk, bq, ubias);
  dot1024_f64<<<dim3(1), 256, 0, stream>>>(bq, bk, s0);
  qbk_w<<<dim3(B_ROWS / 4), 256, 0, stream>>>(query, wvec, s0, qbk);
  uproj_G<<<dim3(B_ROWS / 128, D_DIM / 64), 256, 0, stream>>>(query, G, ubias, u64);

  // Candidate chain (bf16): fused casts; G dead -> W casts overlay it.
  cast_all_bf16<<<dim3((N4_TOTAL + 255) / 256), 256, 0, stream>>>(
      mem, query, Wk, Wv, Wq, membf, querybf, wkbf, wvbf, wqbf);

  kproj_bf16<<<dim3(M_ROWS / 128, D_DIM / 128), 256, 0, stream>>>(membf, wkbf, bk, Kbf);
  kproj_bf16<<<dim3(B_ROWS / 128, D_DIM / 128), 256, 0, stream>>>(querybf, wqbf, bq, qbf);

  sims_topc_gemm<<<dim3((B_ROWS / 256) * NCB), 512, 0, stream>>>(qbf, Kbf, part_v, part_i);
  merge_cand256<<<dim3(B_ROWS), 256, 0, stream>>>(part_v, part_i, cand);
  rescore_topk_u<<<dim3(B_ROWS), 256, 0, stream>>>(u64, qbk, mem, cand, topi);

  // V path (bf16 out, overlays dead Kbf/parts region).
  kproj_bf16<<<dim3(M_ROWS / 128, D_DIM / 128), 256, 0, stream>>>(membf, wvbf, bv, Vbf);
  gather_ln<<<dim3(B_ROWS * TOPK), 256, 0, stream>>>(Vbf, topi, gamma, beta, out);
}

// Round 19
// 1248.188 us; speedup vs baseline: 6.4174x; 1.0069x over previous
//
#include <hip/hip_runtime.h>
#include <hip/hip_bf16.h>
#include <math.h>

#define D_DIM 1024
#define B_ROWS 4096
#define M_ROWS 32768
#define TOPK 8
#define TOPC 16
#define TOPB 8
#define NCB (M_ROWS / 128)

typedef __attribute__((ext_vector_type(8))) short bf16x8;
typedef __attribute__((ext_vector_type(4))) float f32x4;

__device__ __forceinline__ unsigned short f32_to_bf16(float f) {
  unsigned int u = __float_as_uint(f);
  unsigned int r = (u + 0x7FFFu + ((u >> 16) & 1u)) >> 16;
  return (unsigned short)r;
}
__device__ __forceinline__ float bf16_to_f32(unsigned short h) {
  return __uint_as_float(((unsigned int)h) << 16);
}
__device__ __forceinline__ void async_copy16(void* lds, const void* g) {
  __builtin_amdgcn_global_load_lds(
      (const __attribute__((address_space(1))) unsigned int*)g,
      (__attribute__((address_space(3))) unsigned int*)lds, 16, 0, 0);
}

template <int N>
__device__ __forceinline__ void insN(float v, int idx,
                                     float* __restrict__ tv,
                                     int* __restrict__ ti) {
  if (v < tv[N - 1]) return;
  if (v == tv[N - 1] && idx > ti[N - 1]) return;
  float cv = v;
  int ci = idx;
#pragma unroll
  for (int p = 0; p < N; ++p) {
    if (cv > tv[p] || (cv == tv[p] && ci < ti[p])) {
      const float t0 = tv[p]; tv[p] = cv; cv = t0;
      const int t1 = ti[p]; ti[p] = ci; ci = t1;
    }
  }
}

// ---------------------------------------------------------------------------
// G[f][e] = sum_n Wq[n][f] * Wk[n][e], f64 accumulation (proven).
// ---------------------------------------------------------------------------
__global__ __launch_bounds__(256) void gram_f64(
    const float* __restrict__ Wq, const float* __restrict__ Wk,
    double* __restrict__ G)
{
  __shared__ float sA[32][68];
  __shared__ float sB[32][68];
  const int tid = threadIdx.x;
  const int tx = tid & 15, ty = tid >> 4;
  const int f0 = blockIdx.x * 64;
  const int e0 = blockIdx.y * 64;

  double acc[4][4];
#pragma unroll
  for (int i = 0; i < 4; ++i)
#pragma unroll
    for (int j = 0; j < 4; ++j) acc[i][j] = 0.0;

  for (int k0 = 0; k0 < D_DIM; k0 += 32) {
#pragma unroll
    for (int it = 0; it < 2; ++it) {
      const int L = it * 256 + tid;
      const int kk = L >> 4, c4 = (L & 15) * 4;
      *(float4*)&sA[kk][c4] = *(const float4*)(Wq + (size_t)(k0 + kk) * D_DIM + f0 + c4);
      *(float4*)&sB[kk][c4] = *(const float4*)(Wk + (size_t)(k0 + kk) * D_DIM + e0 + c4);
    }
    __syncthreads();
#pragma unroll
    for (int kk = 0; kk < 32; ++kk) {
      const double a[4] = {sA[kk][ty * 4 + 0], sA[kk][ty * 4 + 1],
                           sA[kk][ty * 4 + 2], sA[kk][ty * 4 + 3]};
      const double b[4] = {sB[kk][tx * 4 + 0], sB[kk][tx * 4 + 1],
                           sB[kk][tx * 4 + 2], sB[kk][tx * 4 + 3]};
#pragma unroll
      for (int i = 0; i < 4; ++i)
#pragma unroll
        for (int j = 0; j < 4; ++j)
          acc[i][j] = fma(a[i], b[j], acc[i][j]);
    }
    __syncthreads();
  }
#pragma unroll
  for (int i = 0; i < 4; ++i)
#pragma unroll
    for (int j = 0; j < 4; ++j)
      G[(size_t)(f0 + ty * 4 + i) * D_DIM + e0 + tx * 4 + j] = acc[i][j];
}

// ---------------------------------------------------------------------------
// outv[c] = sum_n W[n][c] * v[n], f64 (proven).
// ---------------------------------------------------------------------------
__global__ __launch_bounds__(256) void colred_f64(
    const float* __restrict__ W, const float* __restrict__ v,
    double* __restrict__ outv)
{
  const int c = blockIdx.x * 256 + threadIdx.x;
  double acc = 0.0;
  for (int n = 0; n < D_DIM; ++n)
    acc = fma((double)W[(size_t)n * D_DIM + c], (double)v[n], acc);
  outv[c] = acc;
}

// ---------------------------------------------------------------------------
// out[0] = dot_f64(a, b) over 1024 elements (proven).
// ---------------------------------------------------------------------------
__global__ __launch_bounds__(256) void dot1024_f64(
    const float* __restrict__ a, const float* __restrict__ b,
    double* __restrict__ out)
{
  const int tid = threadIdx.x;
  double acc = 0.0;
#pragma unroll
  for (int i = 0; i < 4; ++i) {
    const int idx = tid * 4 + i;
    acc = fma((double)a[idx], (double)b[idx], acc);
  }
#pragma unroll
  for (int off = 32; off > 0; off >>= 1) acc += __shfl_down(acc, off);
  __shared__ double red[4];
  if ((tid & 63) == 0) red[tid >> 6] = acc;
  __syncthreads();
  if (tid == 0) out[0] = red[0] + red[1] + red[2] + red[3];
}

// ---------------------------------------------------------------------------
// qbk[b] = dot_f64(query[b,:], w) + s0 (proven).
// ---------------------------------------------------------------------------
__global__ __launch_bounds__(256) void qbk_w(
    const float* __restrict__ query, const double* __restrict__ w,
    const double* __restrict__ s0, double* __restrict__ qbk)
{
  const int b = blockIdx.x * 4 + (threadIdx.x >> 6);
  const int lane = threadIdx.x & 63;
  const float* qrow = query + (size_t)b * D_DIM + lane * 16;
  const double* wrow = w + lane * 16;
  double acc = 0.0;
#pragma unroll
  for (int i = 0; i < 16; ++i)
    acc = fma((double)qrow[i], wrow[i], acc);
#pragma unroll
  for (int off = 32; off > 0; off >>= 1) acc += __shfl_down(acc, off);
  if (lane == 0) qbk[b] = acc + s0[0];
}

// ---------------------------------------------------------------------------
// u[b,d] = sum_e query[b,e] * G[e,d] + ubias[d], f64 (round-18-proven
// transposed-A variant).
// ---------------------------------------------------------------------------
__global__ __launch_bounds__(256) void uproj_G(
    const float* __restrict__ query, const double* __restrict__ G,
    const double* __restrict__ ubias, double* __restrict__ U)
{
  __shared__ double sAdT[32][130];
  __shared__ double sBd[32][68];
  const int tid = threadIdx.x;
  const int tx = tid & 15, ty = tid >> 4;
  const int row0 = blockIdx.x * 128;
  const int col0 = blockIdx.y * 64;

  double acc[2][4][4];
#pragma unroll
  for (int g = 0; g < 2; ++g)
#pragma unroll
    for (int i = 0; i < 4; ++i)
#pragma unroll
      for (int j = 0; j < 4; ++j) acc[g][i][j] = 0.0;

  for (int k0 = 0; k0 < D_DIM; k0 += 32) {
#pragma unroll
    for (int it = 0; it < 4; ++it) {
      const int L = it * 256 + tid;
      const int rowa = L >> 3, c4 = (L & 7) * 4;
      const float4 v =
          *(const float4*)(query + (size_t)(row0 + rowa) * D_DIM + k0 + c4);
      sAdT[c4 + 0][rowa] = (double)v.x;
      sAdT[c4 + 1][rowa] = (double)v.y;
      sAdT[c4 + 2][rowa] = (double)v.z;
      sAdT[c4 + 3][rowa] = (double)v.w;
    }
#pragma unroll
    for (int it = 0; it < 4; ++it) {
      const int L = it * 256 + tid;
      const int kk = L >> 5, c2 = (L & 31) * 2;
      *(double2*)&sBd[kk][c2] =
          *(const double2*)(G + (size_t)(k0 + kk) * D_DIM + col0 + c2);
    }
    __syncthreads();
#pragma unroll
    for (int kk = 0; kk < 32; ++kk) {
      const double2 p0 = *(const double2*)&sAdT[kk][ty * 4];
      const double2 p1 = *(const double2*)&sAdT[kk][ty * 4 + 2];
      const double2 p2 = *(const double2*)&sAdT[kk][64 + ty * 4];
      const double2 p3 = *(const double2*)&sAdT[kk][64 + ty * 4 + 2];
      const double a0[4] = {p0.x, p0.y, p1.x, p1.y};
      const double a1[4] = {p2.x, p2.y, p3.x, p3.y};
      const double bb[4] = {sBd[kk][tx * 4 + 0], sBd[kk][tx * 4 + 1],
                            sBd[kk][tx * 4 + 2], sBd[kk][tx * 4 + 3]};
#pragma unroll
      for (int i = 0; i < 4; ++i)
#pragma unroll
        for (int j = 0; j < 4; ++j) {
          acc[0][i][j] = fma(a0[i], bb[j], acc[0][i][j]);
          acc[1][i][j] = fma(a1[i], bb[j], acc[1][i][j]);
        }
    }
    __syncthreads();
  }
  const double ub[4] = {ubias[col0 + tx * 4 + 0], ubias[col0 + tx * 4 + 1],
                        ubias[col0 + tx * 4 + 2], ubias[col0 + tx * 4 + 3]};
#pragma unroll
  for (int g = 0; g < 2; ++g)
#pragma unroll
    for (int i = 0; i < 4; ++i) {
      const size_t base = (size_t)(row0 + g * 64 + ty * 4 + i) * D_DIM + col0 + tx * 4;
      *(double2*)(U + base)     = (double2){acc[g][i][0] + ub[0], acc[g][i][1] + ub[1]};
      *(double2*)(U + base + 2) = (double2){acc[g][i][2] + ub[2], acc[g][i][3] + ub[3]};
    }
}

// ---------------------------------------------------------------------------
// Fused sims + per-half top-4 (round-18-proven: 3-buffer counted-vmcnt,
// unroll-by-3 static buffers, swizzle key (R>>1)&3, cb-resident mapping).
// ---------------------------------------------------------------------------
#define SBUF3 12288   // ushorts per buffer: A 8192 (16KB) + B 4096 (8KB)
__global__ __launch_bounds__(512, 4) void sims_topc_gemm(
    const unsigned short* __restrict__ A, const unsigned short* __restrict__ B,
    float* __restrict__ part_v, int* __restrict__ part_i)
{
  __shared__ unsigned short smem[3 * SBUF3];   // 72 KB

  const int tid = threadIdx.x;
  const int lane = tid & 63;
  const int wave = tid >> 6;
  const int wr = wave >> 1;
  const int wc = wave & 1;

  const int bid = blockIdx.x;
  const int x = bid & 7;
  const int t9 = bid >> 3;
  const int cbg = t9 >> 7;
  const int r = (t9 >> 3) & 15;
  const int cbl = t9 & 7;
  const int cb = (x * 4 + cbg) * 8 + cbl;
  const int row0 = r * 256;
  const int col0 = cb * 128;

  const int st_r = lane >> 2;
  const int st_swz = ((lane & 3) ^ ((st_r >> 1) & 3)) * 16;

  auto STAGE = [&](int d, int k0) {
    unsigned short* buf = smem + d * SBUF3;
#pragma unroll
    for (int i = 0; i < 3; ++i) {
      const int seg = wave * 3 + i;
      if (seg < 16) {
        const int grow = row0 + seg * 16 + st_r;
        async_copy16((char*)(buf + seg * 512),
                     (const char*)(A + (size_t)grow * D_DIM + k0) + st_swz);
      } else {
        const int s2 = seg - 16;
        const int grow = col0 + s2 * 16 + st_r;
        async_copy16((char*)(buf + 8192 + s2 * 512),
                     (const char*)(B + (size_t)grow * D_DIM + k0) + st_swz);
      }
    }
  };

  f32x4 acc[4][4];
#pragma unroll
  for (int m = 0; m < 4; ++m)
#pragma unroll
    for (int n = 0; n < 4; ++n) acc[m][n] = (f32x4){0.f, 0.f, 0.f, 0.f};

  auto COMPUTE = [&](int d) {
    const unsigned short* sA = smem + d * SBUF3;
    const unsigned short* sB = sA + 8192;
    bf16x8 af[4], bfr[4];
    const int ch = lane >> 4;
#pragma unroll
    for (int m = 0; m < 4; ++m) {
      const int Ra = wr * 64 + m * 16 + (lane & 15);
      af[m] = *(const bf16x8*)((const char*)sA + Ra * 64 + ((ch ^ ((Ra >> 1) & 3)) * 16));
    }
#pragma unroll
    for (int n = 0; n < 4; ++n) {
      const int Rb = wc * 64 + n * 16 + (lane & 15);
      bfr[n] = *(const bf16x8*)((const char*)sB + Rb * 64 + ((ch ^ ((Rb >> 1) & 3)) * 16));
    }
    __builtin_amdgcn_s_setprio(1);
#pragma unroll
    for (int m = 0; m < 4; ++m)
#pragma unroll
      for (int n = 0; n < 4; ++n)
        acc[m][n] = __builtin_amdgcn_mfma_f32_16x16x32_bf16(af[m], bfr[n], acc[m][n], 0, 0, 0);
    __builtin_amdgcn_s_setprio(0);
  };

  STAGE(0, 0);
  STAGE(1, 32);
  asm volatile("s_waitcnt vmcnt(3)" ::: "memory");
  __builtin_amdgcn_sched_barrier(0);
  __builtin_amdgcn_s_barrier();

  for (int tt = 0; tt < 30; tt += 3) {
    STAGE(2, (tt + 2) * 32);
    COMPUTE(0);
    asm volatile("s_waitcnt vmcnt(3)" ::: "memory");
    __builtin_amdgcn_sched_barrier(0);
    __builtin_amdgcn_s_barrier();

    STAGE(0, (tt + 3) * 32);
    COMPUTE(1);
    asm volatile("s_waitcnt vmcnt(3)" ::: "memory");
    __builtin_amdgcn_sched_barrier(0);
    __builtin_amdgcn_s_barrier();

    STAGE(1, (tt + 4) * 32);
    COMPUTE(2);
    asm volatile("s_waitcnt vmcnt(3)" ::: "memory");
    __builtin_amdgcn_sched_barrier(0);
    __builtin_amdgcn_s_barrier();
  }
  COMPUTE(0);
  asm volatile("s_waitcnt vmcnt(0)" ::: "memory");
  __builtin_amdgcn_sched_barrier(0);
  __builtin_amdgcn_s_barrier();
  COMPUTE(1);
  __builtin_amdgcn_sched_barrier(0);
  __builtin_amdgcn_s_barrier();

#pragma unroll
  for (int m = 0; m < 4; ++m)
#pragma unroll
    for (int n = 0; n < 4; ++n)
#pragma unroll
      for (int rg = 0; rg < 4; ++rg) {
        const int row = wr * 64 + m * 16 + (lane >> 4) * 4 + rg;
        const int colL = wc * 64 + n * 16 + (lane & 15);
        smem[row * 132 + colL] = f32_to_bf16(acc[m][n][rg]);
      }
  __syncthreads();

  {
    const int row = tid & 255;
    const int h = tid >> 8;
    float tv[4];
    int ti_[4];
#pragma unroll
    for (int p = 0; p < 4; ++p) { tv[p] = -INFINITY; ti_[p] = 0; }
    const unsigned short* crow = smem + row * 132 + h * 64;
    const int gcol = col0 + h * 64;
    for (int j = 0; j < 64; j += 4) {
      const ushort4 c4 = *(const ushort4*)(crow + j);
      insN<4>(bf16_to_f32(c4.x), gcol + j + 0, tv, ti_);
      insN<4>(bf16_to_f32(c4.y), gcol + j + 1, tv, ti_);
      insN<4>(bf16_to_f32(c4.z), gcol + j + 2, tv, ti_);
      insN<4>(bf16_to_f32(c4.w), gcol + j + 3, tv, ti_);
    }
    const size_t base = ((size_t)(row0 + row) * NCB + cb) * TOPB + h * 4;
    *(float4*)(part_v + base) = (float4){tv[0], tv[1], tv[2], tv[3]};
    *(int4*)(part_i + base)   = (int4){ti_[0], ti_[1], ti_[2], ti_[3]};
  }
}

// ---------------------------------------------------------------------------
// Projection via bf16 MFMA, bf16 output. Round-19: ported to the sims-proven
// 3-buffer counted-vmcnt pipeline (512 threads, 256x128 tile, BK=32,
// unroll-by-3 static buffers, same swizzle). Only the epilogue (bias + bf16
// C-write, round-17-proven pattern) and the plain 2D grid mapping differ.
// Used for K (mem x Wk), q (query x Wq), V (mem x Wv).
// ---------------------------------------------------------------------------
__global__ __launch_bounds__(512, 4) void proj256_bf16(
    const unsigned short* __restrict__ A,
    const unsigned short* __restrict__ B,
    const float* __restrict__ bias,
    unsigned short* __restrict__ C)
{
  __shared__ unsigned short smem[3 * SBUF3];   // 72 KB

  const int tid = threadIdx.x;
  const int lane = tid & 63;
  const int wave = tid >> 6;
  const int wr = wave >> 1;
  const int wc = wave & 1;

  const int row0 = blockIdx.x * 256;
  const int col0 = blockIdx.y * 128;

  const int st_r = lane >> 2;
  const int st_swz = ((lane & 3) ^ ((st_r >> 1) & 3)) * 16;

  auto STAGE = [&](int d, int k0) {
    unsigned short* buf = smem + d * SBUF3;
#pragma unroll
    for (int i = 0; i < 3; ++i) {
      const int seg = wave * 3 + i;
      if (seg < 16) {
        const int grow = row0 + seg * 16 + st_r;
        async_copy16((char*)(buf + seg * 512),
                     (const char*)(A + (size_t)grow * D_DIM + k0) + st_swz);
      } else {
        const int s2 = seg - 16;
        const int grow = col0 + s2 * 16 + st_r;
        async_copy16((char*)(buf + 8192 + s2 * 512),
                     (const char*)(B + (size_t)grow * D_DIM + k0) + st_swz);
      }
    }
  };

  f32x4 acc[4][4];
#pragma unroll
  for (int m = 0; m < 4; ++m)
#pragma unroll
    for (int n = 0; n < 4; ++n) acc[m][n] = (f32x4){0.f, 0.f, 0.f, 0.f};

  auto COMPUTE = [&](int d) {
    const unsigned short* sA = smem + d * SBUF3;
    const unsigned short* sB = sA + 8192;
    bf16x8 af[4], bfr[4];
    const int ch = lane >> 4;
#pragma unroll
    for (int m = 0; m < 4; ++m) {
      const int Ra = wr * 64 + m * 16 + (lane & 15);
      af[m] = *(const bf16x8*)((const char*)sA + Ra * 64 + ((ch ^ ((Ra >> 1) & 3)) * 16));
    }
#pragma unroll
    for (int n = 0; n < 4; ++n) {
      const int Rb = wc * 64 + n * 16 + (lane & 15);
      bfr[n] = *(const bf16x8*)((const char*)sB + Rb * 64 + ((ch ^ ((Rb >> 1) & 3)) * 16));
    }
    __builtin_amdgcn_s_setprio(1);
#pragma unroll
    for (int m = 0; m < 4; ++m)
#pragma unroll
      for (int n = 0; n < 4; ++n)
        acc[m][n] = __builtin_amdgcn_mfma_f32_16x16x32_bf16(af[m], bfr[n], acc[m][n], 0, 0, 0);
    __builtin_amdgcn_s_setprio(0);
  };

  STAGE(0, 0);
  STAGE(1, 32);
  asm volatile("s_waitcnt vmcnt(3)" ::: "memory");
  __builtin_amdgcn_sched_barrier(0);
  __builtin_amdgcn_s_barrier();

  for (int tt = 0; tt < 30; tt += 3) {
    STAGE(2, (tt + 2) * 32);
    COMPUTE(0);
    asm volatile("s_waitcnt vmcnt(3)" ::: "memory");
    __builtin_amdgcn_sched_barrier(0);
    __builtin_amdgcn_s_barrier();

    STAGE(0, (tt + 3) * 32);
    COMPUTE(1);
    asm volatile("s_waitcnt vmcnt(3)" ::: "memory");
    __builtin_amdgcn_sched_barrier(0);
    __builtin_amdgcn_s_barrier();

    STAGE(1, (tt + 4) * 32);
    COMPUTE(2);
    asm volatile("s_waitcnt vmcnt(3)" ::: "memory");
    __builtin_amdgcn_sched_barrier(0);
    __builtin_amdgcn_s_barrier();
  }
  COMPUTE(0);
  asm volatile("s_waitcnt vmcnt(0)" ::: "memory");
  __builtin_amdgcn_sched_barrier(0);
  __builtin_amdgcn_s_barrier();
  COMPUTE(1);

  // Epilogue: bias + bf16 store (C/D layout m89).
#pragma unroll
  for (int n = 0; n < 4; ++n) {
    const int col = col0 + wc * 64 + n * 16 + (lane & 15);
    const float bcol = bias[col];
#pragma unroll
    for (int m = 0; m < 4; ++m)
#pragma unroll
      for (int rg = 0; rg < 4; ++rg) {
        const int row = row0 + wr * 64 + m * 16 + (lane >> 4) * 4 + rg;
        C[(size_t)row * D_DIM + col] = f32_to_bf16(acc[m][n][rg] + bcol);
      }
  }
}

// ---------------------------------------------------------------------------
// Merge: parallel iterative max-extraction (round-15-proven).
// ---------------------------------------------------------------------------
__global__ __launch_bounds__(256) void merge_cand256(
    const float* __restrict__ part_v, const int* __restrict__ part_i,
    int* __restrict__ cand)
{
  const int r = blockIdx.x;
  const int tid = threadIdx.x;
  const int lane = tid & 63;
  const int wave = tid >> 6;

  float tv[8];
  int ti[8];
  {
    const size_t base = ((size_t)r * NCB + tid) * TOPB;
    const float4 a0 = *(const float4*)(part_v + base);
    const float4 a1 = *(const float4*)(part_v + base + 4);
    const int4 b0 = *(const int4*)(part_i + base);
    const int4 b1 = *(const int4*)(part_i + base + 4);
    tv[0] = a0.x; tv[1] = a0.y; tv[2] = a0.z; tv[3] = a0.w;
    tv[4] = a1.x; tv[5] = a1.y; tv[6] = a1.z; tv[7] = a1.w;
    ti[0] = b0.x; ti[1] = b0.y; ti[2] = b0.z; ti[3] = b0.w;
    ti[4] = b1.x; ti[5] = b1.y; ti[6] = b1.z; ti[7] = b1.w;
  }
  unsigned rem = 0xFFu;

  __shared__ float wv4[4];
  __shared__ int wi4[4];
  __shared__ int winner;

  for (int p = 0; p < TOPC; ++p) {
    float bv = -INFINITY;
    int bi = 0x7FFFFFFF;
#pragma unroll
    for (int e = 0; e < 8; ++e) {
      const bool alive = (rem >> e) & 1u;
      const float v = tv[e];
      const int ix = ti[e];
      if (alive && (v > bv || (v == bv && ix < bi))) { bv = v; bi = ix; }
    }
#pragma unroll
    for (int off = 32; off > 0; off >>= 1) {
      const float ov = __shfl_down(bv, off);
      const int oi = __shfl_down(bi, off);
      if (ov > bv || (ov == bv && oi < bi)) { bv = ov; bi = oi; }
    }
    if (lane == 0) { wv4[wave] = bv; wi4[wave] = bi; }
    __syncthreads();
    if (tid == 0) {
      float gv = wv4[0];
      int gi = wi4[0];
#pragma unroll
      for (int w = 1; w < 4; ++w)
        if (wv4[w] > gv || (wv4[w] == gv && wi4[w] < gi)) { gv = wv4[w]; gi = wi4[w]; }
      winner = gi;
      cand[(size_t)r * TOPC + p] = gi;
    }
    __syncthreads();
    const int wgi = winner;
#pragma unroll
    for (int e = 0; e < 8; ++e)
      if (ti[e] == wgi) rem &= ~(1u << e);
  }
}

// ---------------------------------------------------------------------------
// fp64 rescore via u: sims_ci = dot_f64(u_b, mem_ci) + qbk_b (proven).
// ---------------------------------------------------------------------------
__global__ __launch_bounds__(256) void rescore_topk_u(
    const double* __restrict__ U, const double* __restrict__ qbk,
    const float* __restrict__ mem, const int* __restrict__ cand,
    int* __restrict__ topi)
{
  const int b = blockIdx.x;
  const int tid = threadIdx.x;
  const int wave = tid >> 6;
  const int lane = tid & 63;

  __shared__ double sval[TOPC];
  __shared__ int sidx[TOPC];

  const double* urow = U + (size_t)b * D_DIM + lane * 16;
  double uv[16];
#pragma unroll
  for (int i = 0; i < 8; ++i) {
    const double2 d2 = *(const double2*)(urow + i * 2);
    uv[i * 2] = d2.x;
    uv[i * 2 + 1] = d2.y;
  }
  const double qb = qbk[b];

  for (int c = wave; c < TOPC; c += 4) {
    const int ci = cand[(size_t)b * TOPC + c];
    const float* mrow = mem + (size_t)ci * D_DIM + lane * 16;
    double acc = 0.0;
#pragma unroll
    for (int i = 0; i < 4; ++i) {
      const float4 mv = *(const float4*)(mrow + i * 4);
      acc = fma(uv[i * 4 + 0], (double)mv.x, acc);
      acc = fma(uv[i * 4 + 1], (double)mv.y, acc);
      acc = fma(uv[i * 4 + 2], (double)mv.z, acc);
      acc = fma(uv[i * 4 + 3], (double)mv.w, acc);
    }
#pragma unroll
    for (int off = 32; off > 0; off >>= 1) acc += __shfl_down(acc, off);
    if (lane == 0) { sval[c] = acc + qb; sidx[c] = ci; }
  }
  __syncthreads();

  if (tid == 0) {
    bool used[TOPC];
#pragma unroll
    for (int p = 0; p < TOPC; ++p) used[p] = false;
#pragma unroll
    for (int p = 0; p < TOPK; ++p) {
      int best = -1;
      double bv = 0.0;
      int bi = 0;
      for (int c = 0; c < TOPC; ++c) {
        if (used[c]) continue;
        const double v = sval[c];
        const int ix = sidx[c];
        if (best < 0 || v > bv || (v == bv && ix < bi)) { best = c; bv = v; bi = ix; }
      }
      used[best] = true;
      topi[(size_t)b * TOPK + p] = bi;
    }
  }
}

// ---------------------------------------------------------------------------
// Fused f32 -> bf16 cast (round-17-proven).
// ---------------------------------------------------------------------------
#define N4_MEM   (M_ROWS * D_DIM / 4)
#define N4_QUERY (B_ROWS * D_DIM / 4)
#define N4_W     (D_DIM * D_DIM / 4)
#define N4_TOTAL (N4_MEM + N4_QUERY + 3 * N4_W)

__global__ __launch_bounds__(256) void cast_all_bf16(
    const float* __restrict__ mem, const float* __restrict__ query,
    const float* __restrict__ Wk, const float* __restrict__ Wv,
    const float* __restrict__ Wq,
    unsigned short* __restrict__ membf, unsigned short* __restrict__ querybf,
    unsigned short* __restrict__ wkbf, unsigned short* __restrict__ wvbf,
    unsigned short* __restrict__ wqbf)
{
  int i = blockIdx.x * 256 + threadIdx.x;
  if (i >= N4_TOTAL) return;
  const float* src;
  unsigned short* dst;
  if (i < N4_MEM) { src = mem; dst = membf; }
  else if ((i -= N4_MEM) < N4_QUERY) { src = query; dst = querybf; }
  else if ((i -= N4_QUERY) < N4_W) { src = Wk; dst = wkbf; }
  else if ((i -= N4_W) < N4_W) { src = Wv; dst = wvbf; }
  else { i -= N4_W; src = Wq; dst = wqbf; }
  const float4 v = *(const float4*)(src + (size_t)i * 4);
  ushort4 o;
  o.x = f32_to_bf16(v.x);
  o.y = f32_to_bf16(v.y);
  o.z = f32_to_bf16(v.z);
  o.w = f32_to_bf16(v.w);
  *(ushort4*)(dst + (size_t)i * 4) = o;
}

// ---------------------------------------------------------------------------
// Gather selected V rows (bf16) + LayerNorm in f32 (round-18-proven).
// ---------------------------------------------------------------------------
__global__ __launch_bounds__(256) void gather_ln(
    const unsigned short* __restrict__ V, const int* __restrict__ topi,
    const float* __restrict__ gamma, const float* __restrict__ beta,
    float* __restrict__ out)
{
  const int row = blockIdx.x;
  const int tid = threadIdx.x;
  const int idx = topi[row];
  const unsigned short* src = V + (size_t)idx * D_DIM;
  const ushort4 raw = *(const ushort4*)(src + tid * 4);
  const float v0 = bf16_to_f32(raw.x);
  const float v1 = bf16_to_f32(raw.y);
  const float v2 = bf16_to_f32(raw.z);
  const float v3 = bf16_to_f32(raw.w);
  float s = v0 + v1 + v2 + v3;
  float s2 = v0 * v0 + v1 * v1 + v2 * v2 + v3 * v3;
#pragma unroll
  for (int off = 32; off > 0; off >>= 1) {
    s += __shfl_down(s, off);
    s2 += __shfl_down(s2, off);
  }
  __shared__ float red[8];
  __shared__ float stats[2];
  const int wid = tid >> 6;
  if ((tid & 63) == 0) { red[wid] = s; red[4 + wid] = s2; }
  __syncthreads();
  if (tid == 0) {
    const float S = red[0] + red[1] + red[2] + red[3];
    const float S2 = red[4] + red[5] + red[6] + red[7];
    const float mu = S * (1.0f / D_DIM);
    const float var = S2 * (1.0f / D_DIM) - mu * mu;
    stats[0] = mu;
    stats[1] = rsqrtf(var + 1e-5f);
  }
  __syncthreads();
  const float mu = stats[0], rstd = stats[1];
  const float4 g4 = *(const float4*)(gamma + tid * 4);
  const float4 b4 = *(const float4*)(beta + tid * 4);
  float4 o;
  o.x = (v0 - mu) * rstd * g4.x + b4.x;
  o.y = (v1 - mu) * rstd * g4.y + b4.y;
  o.z = (v2 - mu) * rstd * g4.z + b4.z;
  o.w = (v3 - mu) * rstd * g4.w + b4.w;
  *(float4*)(out + (size_t)row * D_DIM + tid * 4) = o;
}

extern "C" void kernel_launch(void* const* d_in, const int* in_sizes, int n_in,
                              void* d_out, int out_size, void* d_ws, size_t ws_size,
                              hipStream_t stream)
{
  const float* query = (const float*)d_in[0];
  const float* mem   = (const float*)d_in[1];
  const float* Wq    = (const float*)d_in[2];
  const float* bq    = (const float*)d_in[3];
  const float* Wk    = (const float*)d_in[4];
  const float* bk    = (const float*)d_in[5];
  const float* Wv    = (const float*)d_in[6];
  const float* bv    = (const float*)d_in[7];
  const float* gamma = (const float*)d_in[8];
  const float* beta  = (const float*)d_in[9];
  float* out = (float*)d_out;

  char* ws = (char*)d_ws;
  double* u64 = (double*)ws;   ws += (size_t)B_ROWS * D_DIM * sizeof(double);
  double* G = (double*)ws;     ws += (size_t)D_DIM * D_DIM * sizeof(double);
  unsigned short* qbf = (unsigned short*)ws;
  ws += (size_t)B_ROWS * D_DIM * sizeof(unsigned short);
  unsigned short* querybf = (unsigned short*)ws;
  ws += (size_t)B_ROWS * D_DIM * sizeof(unsigned short);
  unsigned short* membf = (unsigned short*)ws;
  ws += (size_t)M_ROWS * D_DIM * sizeof(unsigned short);
  char* Aregion = ws;
  ws += (size_t)M_ROWS * D_DIM * sizeof(unsigned short)
      + 2 * (size_t)B_ROWS * NCB * TOPB * sizeof(float);
  double* wvec = (double*)ws;  ws += (size_t)D_DIM * sizeof(double);
  double* ubias = (double*)ws; ws += (size_t)D_DIM * sizeof(double);
  double* s0 = (double*)ws;    ws += 2 * sizeof(double);
  double* qbk = (double*)ws;   ws += (size_t)B_ROWS * sizeof(double);
  int* cand = (int*)ws;        ws += (size_t)B_ROWS * TOPC * sizeof(int);
  int* topi = (int*)ws;

  unsigned short* Kbf = (unsigned short*)Aregion;
  float* part_v = (float*)(Aregion + (size_t)M_ROWS * D_DIM * sizeof(unsigned short));
  int* part_i = (int*)((char*)part_v + (size_t)B_ROWS * NCB * TOPB * sizeof(float));
  unsigned short* wkbf = (unsigned short*)G;
  unsigned short* wvbf = wkbf + (size_t)D_DIM * D_DIM;
  unsigned short* wqbf = wvbf + (size_t)D_DIM * D_DIM;
  unsigned short* Vbf = (unsigned short*)Aregion;

  // Selection chain (f64): G = Wq^T@Wk; u = query@G + bq@Wk; qbk = query.(Wq^T bk) + bq.bk
  gram_f64<<<dim3(16, 16), 256, 0, stream>>>(Wq, Wk, G);
  colred_f64<<<dim3(4), 256, 0, stream>>>(Wq, bk, wvec);
  colred_f64<<<dim3(4), 256, 0, stream>>>(Wk, bq, ubias);
  dot1024_f64<<<dim3(1), 256, 0, stream>>>(bq, bk, s0);
  qbk_w<<<dim3(B_ROWS / 4), 256, 0, stream>>>(query, wvec, s0, qbk);
  uproj_G<<<dim3(B_ROWS / 128, D_DIM / 64), 256, 0, stream>>>(query, G, ubias, u64);

  // Candidate chain (bf16): fused casts; G dead -> W casts overlay it.
  cast_all_bf16<<<dim3((N4_TOTAL + 255) / 256), 256, 0, stream>>>(
      mem, query, Wk, Wv, Wq, membf, querybf, wkbf, wvbf, wqbf);

  proj256_bf16<<<dim3(M_ROWS / 256, D_DIM / 128), 512, 0, stream>>>(membf, wkbf, bk, Kbf);
  proj256_bf16<<<dim3(B_ROWS / 256, D_DIM / 128), 512, 0, stream>>>(querybf, wqbf, bq, qbf);

  sims_topc_gemm<<<dim3((B_ROWS / 256) * NCB), 512, 0, stream>>>(qbf, Kbf, part_v, part_i);
  merge_cand256<<<dim3(B_ROWS), 256, 0, stream>>>(part_v, part_i, cand);
  rescore_topk_u<<<dim3(B_ROWS), 256, 0, stream>>>(u64, qbk, mem, cand, topi);

  // V path (bf16 out, overlays dead Kbf/parts region).
  proj256_bf16<<<dim3(M_ROWS / 256, D_DIM / 128), 512, 0, stream>>>(membf, wvbf, bv, Vbf);
  gather_ln<<<dim3(B_ROWS * TOPK), 256, 0, stream>>>(Vbf, topi, gamma, beta, out);
}

// Round 20
// 1220.898 us; speedup vs baseline: 6.5608x; 1.0224x over previous
//
#include <hip/hip_runtime.h>
#include <hip/hip_bf16.h>
#include <math.h>

#define D_DIM 1024
#define B_ROWS 4096
#define M_ROWS 32768
#define TOPK 8
#define TOPC 16
#define TOPB 8
#define NCB (M_ROWS / 128)

typedef __attribute__((ext_vector_type(8))) short bf16x8;
typedef __attribute__((ext_vector_type(4))) float f32x4;

__device__ __forceinline__ unsigned short f32_to_bf16(float f) {
  unsigned int u = __float_as_uint(f);
  unsigned int r = (u + 0x7FFFu + ((u >> 16) & 1u)) >> 16;
  return (unsigned short)r;
}
__device__ __forceinline__ float bf16_to_f32(unsigned short h) {
  return __uint_as_float(((unsigned int)h) << 16);
}
__device__ __forceinline__ void async_copy16(void* lds, const void* g) {
  __builtin_amdgcn_global_load_lds(
      (const __attribute__((address_space(1))) unsigned int*)g,
      (__attribute__((address_space(3))) unsigned int*)lds, 16, 0, 0);
}

template <int N>
__device__ __forceinline__ void insN(float v, int idx,
                                     float* __restrict__ tv,
                                     int* __restrict__ ti) {
  if (v < tv[N - 1]) return;
  if (v == tv[N - 1] && idx > ti[N - 1]) return;
  float cv = v;
  int ci = idx;
#pragma unroll
  for (int p = 0; p < N; ++p) {
    if (cv > tv[p] || (cv == tv[p] && ci < ti[p])) {
      const float t0 = tv[p]; tv[p] = cv; cv = t0;
      const int t1 = ti[p]; ti[p] = ci; ci = t1;
    }
  }
}

// ---------------------------------------------------------------------------
// G[f][e] = sum_n Wq[n][f] * Wk[n][e], f64 accumulation (proven).
// ---------------------------------------------------------------------------
__global__ __launch_bounds__(256) void gram_f64(
    const float* __restrict__ Wq, const float* __restrict__ Wk,
    double* __restrict__ G)
{
  __shared__ float sA[32][68];
  __shared__ float sB[32][68];
  const int tid = threadIdx.x;
  const int tx = tid & 15, ty = tid >> 4;
  const int f0 = blockIdx.x * 64;
  const int e0 = blockIdx.y * 64;

  double acc[4][4];
#pragma unroll
  for (int i = 0; i < 4; ++i)
#pragma unroll
    for (int j = 0; j < 4; ++j) acc[i][j] = 0.0;

  for (int k0 = 0; k0 < D_DIM; k0 += 32) {
#pragma unroll
    for (int it = 0; it < 2; ++it) {
      const int L = it * 256 + tid;
      const int kk = L >> 4, c4 = (L & 15) * 4;
      *(float4*)&sA[kk][c4] = *(const float4*)(Wq + (size_t)(k0 + kk) * D_DIM + f0 + c4);
      *(float4*)&sB[kk][c4] = *(const float4*)(Wk + (size_t)(k0 + kk) * D_DIM + e0 + c4);
    }
    __syncthreads();
#pragma unroll
    for (int kk = 0; kk < 32; ++kk) {
      const double a[4] = {sA[kk][ty * 4 + 0], sA[kk][ty * 4 + 1],
                           sA[kk][ty * 4 + 2], sA[kk][ty * 4 + 3]};
      const double b[4] = {sB[kk][tx * 4 + 0], sB[kk][tx * 4 + 1],
                           sB[kk][tx * 4 + 2], sB[kk][tx * 4 + 3]};
#pragma unroll
      for (int i = 0; i < 4; ++i)
#pragma unroll
        for (int j = 0; j < 4; ++j)
          acc[i][j] = fma(a[i], b[j], acc[i][j]);
    }
    __syncthreads();
  }
#pragma unroll
  for (int i = 0; i < 4; ++i)
#pragma unroll
    for (int j = 0; j < 4; ++j)
      G[(size_t)(f0 + ty * 4 + i) * D_DIM + e0 + tx * 4 + j] = acc[i][j];
}

// ---------------------------------------------------------------------------
// Fused bias terms (round-20): blocks 0-3 -> wvec[c] = sum_n Wq[n][c]*bk[n];
// blocks 4-7 -> ubias[c] = sum_n Wk[n][c]*bq[n]; block 8 -> s0 = bq.bk.
// Replaces colred_f64 x2 + dot1024_f64 (3 launches -> 1).
// ---------------------------------------------------------------------------
__global__ __launch_bounds__(256) void bias_terms(
    const float* __restrict__ Wq, const float* __restrict__ Wk,
    const float* __restrict__ bq, const float* __restrict__ bk,
    double* __restrict__ wvec, double* __restrict__ ubias,
    double* __restrict__ s0)
{
  const int blk = blockIdx.x;
  const int tid = threadIdx.x;
  if (blk < 4) {
    const int c = blk * 256 + tid;
    double acc = 0.0;
    for (int n = 0; n < D_DIM; ++n)
      acc = fma((double)Wq[(size_t)n * D_DIM + c], (double)bk[n], acc);
    wvec[c] = acc;
  } else if (blk < 8) {
    const int c = (blk - 4) * 256 + tid;
    double acc = 0.0;
    for (int n = 0; n < D_DIM; ++n)
      acc = fma((double)Wk[(size_t)n * D_DIM + c], (double)bq[n], acc);
    ubias[c] = acc;
  } else {
    double acc = 0.0;
#pragma unroll
    for (int i = 0; i < 4; ++i) {
      const int idx = tid * 4 + i;
      acc = fma((double)bq[idx], (double)bk[idx], acc);
    }
#pragma unroll
    for (int off = 32; off > 0; off >>= 1) acc += __shfl_down(acc, off);
    __shared__ double red[4];
    if ((tid & 63) == 0) red[tid >> 6] = acc;
    __syncthreads();
    if (tid == 0) s0[0] = red[0] + red[1] + red[2] + red[3];
  }
}

// ---------------------------------------------------------------------------
// qbk[b] = dot_f64(query[b,:], w) + s0 (proven).
// ---------------------------------------------------------------------------
__global__ __launch_bounds__(256) void qbk_w(
    const float* __restrict__ query, const double* __restrict__ w,
    const double* __restrict__ s0, double* __restrict__ qbk)
{
  const int b = blockIdx.x * 4 + (threadIdx.x >> 6);
  const int lane = threadIdx.x & 63;
  const float* qrow = query + (size_t)b * D_DIM + lane * 16;
  const double* wrow = w + lane * 16;
  double acc = 0.0;
#pragma unroll
  for (int i = 0; i < 16; ++i)
    acc = fma((double)qrow[i], wrow[i], acc);
#pragma unroll
  for (int off = 32; off > 0; off >>= 1) acc += __shfl_down(acc, off);
  if (lane == 0) qbk[b] = acc + s0[0];
}

// ---------------------------------------------------------------------------
// u[b,d] = sum_e query[b,e]*G[e,d] + ubias[d], f64. Round-20: 64x64 tiles +
// 2-phase double-buffer (STAGE(t+1) before compute(t), round-13-proven
// pattern): 68.6 KB LDS -> 2 blocks/CU; load latency hidden under the f64
// FMA phase. Inner body = round-18-proven transposed-A idiom; acc 32 VGPR.
// ---------------------------------------------------------------------------
__global__ __launch_bounds__(256) void uproj_G(
    const float* __restrict__ query, const double* __restrict__ G,
    const double* __restrict__ ubias, double* __restrict__ U)
{
  __shared__ double sAdT[2][32][66];   // [buf][k][row], 16.9 KB each
  __shared__ double sBd[2][32][68];    // 17.4 KB each
  const int tid = threadIdx.x;
  const int tx = tid & 15, ty = tid >> 4;
  const int row0 = blockIdx.x * 64;
  const int col0 = blockIdx.y * 64;

  double acc[4][4];
#pragma unroll
  for (int i = 0; i < 4; ++i)
#pragma unroll
    for (int j = 0; j < 4; ++j) acc[i][j] = 0.0;

  auto STAGE = [&](int d, int k0) {
#pragma unroll
    for (int it = 0; it < 2; ++it) {
      const int L = it * 256 + tid;
      const int rowa = L >> 3, c4 = (L & 7) * 4;
      const float4 v =
          *(const float4*)(query + (size_t)(row0 + rowa) * D_DIM + k0 + c4);
      sAdT[d][c4 + 0][rowa] = (double)v.x;
      sAdT[d][c4 + 1][rowa] = (double)v.y;
      sAdT[d][c4 + 2][rowa] = (double)v.z;
      sAdT[d][c4 + 3][rowa] = (double)v.w;
    }
#pragma unroll
    for (int it = 0; it < 4; ++it) {
      const int L = it * 256 + tid;
      const int kk = L >> 5, c2 = (L & 31) * 2;
      *(double2*)&sBd[d][kk][c2] =
          *(const double2*)(G + (size_t)(k0 + kk) * D_DIM + col0 + c2);
    }
  };

  STAGE(0, 0);
  __syncthreads();
  int cur = 0;
  for (int t = 0; t < 32; ++t) {
    if (t < 31) STAGE(cur ^ 1, (t + 1) * 32);
#pragma unroll
    for (int kk = 0; kk < 32; ++kk) {
      const double2 p0 = *(const double2*)&sAdT[cur][kk][ty * 4];
      const double2 p1 = *(const double2*)&sAdT[cur][kk][ty * 4 + 2];
      const double a[4] = {p0.x, p0.y, p1.x, p1.y};
      const double bb[4] = {sBd[cur][kk][tx * 4 + 0], sBd[cur][kk][tx * 4 + 1],
                            sBd[cur][kk][tx * 4 + 2], sBd[cur][kk][tx * 4 + 3]};
#pragma unroll
      for (int i = 0; i < 4; ++i)
#pragma unroll
        for (int j = 0; j < 4; ++j)
          acc[i][j] = fma(a[i], bb[j], acc[i][j]);
    }
    __syncthreads();
    cur ^= 1;
  }
  const double ub[4] = {ubias[col0 + tx * 4 + 0], ubias[col0 + tx * 4 + 1],
                        ubias[col0 + tx * 4 + 2], ubias[col0 + tx * 4 + 3]};
#pragma unroll
  for (int i = 0; i < 4; ++i) {
    const size_t base = (size_t)(row0 + ty * 4 + i) * D_DIM + col0 + tx * 4;
    *(double2*)(U + base)     = (double2){acc[i][0] + ub[0], acc[i][1] + ub[1]};
    *(double2*)(U + base + 2) = (double2){acc[i][2] + ub[2], acc[i][3] + ub[3]};
  }
}

// ---------------------------------------------------------------------------
// Fused sims + per-half top-4 (round-18/19-proven).
// ---------------------------------------------------------------------------
#define SBUF3 12288   // ushorts per buffer: A 8192 (16KB) + B 4096 (8KB)
__global__ __launch_bounds__(512, 4) void sims_topc_gemm(
    const unsigned short* __restrict__ A, const unsigned short* __restrict__ B,
    float* __restrict__ part_v, int* __restrict__ part_i)
{
  __shared__ unsigned short smem[3 * SBUF3];   // 72 KB

  const int tid = threadIdx.x;
  const int lane = tid & 63;
  const int wave = tid >> 6;
  const int wr = wave >> 1;
  const int wc = wave & 1;

  const int bid = blockIdx.x;
  const int x = bid & 7;
  const int t9 = bid >> 3;
  const int cbg = t9 >> 7;
  const int r = (t9 >> 3) & 15;
  const int cbl = t9 & 7;
  const int cb = (x * 4 + cbg) * 8 + cbl;
  const int row0 = r * 256;
  const int col0 = cb * 128;

  const int st_r = lane >> 2;
  const int st_swz = ((lane & 3) ^ ((st_r >> 1) & 3)) * 16;

  auto STAGE = [&](int d, int k0) {
    unsigned short* buf = smem + d * SBUF3;
#pragma unroll
    for (int i = 0; i < 3; ++i) {
      const int seg = wave * 3 + i;
      if (seg < 16) {
        const int grow = row0 + seg * 16 + st_r;
        async_copy16((char*)(buf + seg * 512),
                     (const char*)(A + (size_t)grow * D_DIM + k0) + st_swz);
      } else {
        const int s2 = seg - 16;
        const int grow = col0 + s2 * 16 + st_r;
        async_copy16((char*)(buf + 8192 + s2 * 512),
                     (const char*)(B + (size_t)grow * D_DIM + k0) + st_swz);
      }
    }
  };

  f32x4 acc[4][4];
#pragma unroll
  for (int m = 0; m < 4; ++m)
#pragma unroll
    for (int n = 0; n < 4; ++n) acc[m][n] = (f32x4){0.f, 0.f, 0.f, 0.f};

  auto COMPUTE = [&](int d) {
    const unsigned short* sA = smem + d * SBUF3;
    const unsigned short* sB = sA + 8192;
    bf16x8 af[4], bfr[4];
    const int ch = lane >> 4;
#pragma unroll
    for (int m = 0; m < 4; ++m) {
      const int Ra = wr * 64 + m * 16 + (lane & 15);
      af[m] = *(const bf16x8*)((const char*)sA + Ra * 64 + ((ch ^ ((Ra >> 1) & 3)) * 16));
    }
#pragma unroll
    for (int n = 0; n < 4; ++n) {
      const int Rb = wc * 64 + n * 16 + (lane & 15);
      bfr[n] = *(const bf16x8*)((const char*)sB + Rb * 64 + ((ch ^ ((Rb >> 1) & 3)) * 16));
    }
    __builtin_amdgcn_s_setprio(1);
#pragma unroll
    for (int m = 0; m < 4; ++m)
#pragma unroll
      for (int n = 0; n < 4; ++n)
        acc[m][n] = __builtin_amdgcn_mfma_f32_16x16x32_bf16(af[m], bfr[n], acc[m][n], 0, 0, 0);
    __builtin_amdgcn_s_setprio(0);
  };

  STAGE(0, 0);
  STAGE(1, 32);
  asm volatile("s_waitcnt vmcnt(3)" ::: "memory");
  __builtin_amdgcn_sched_barrier(0);
  __builtin_amdgcn_s_barrier();

  for (int tt = 0; tt < 30; tt += 3) {
    STAGE(2, (tt + 2) * 32);
    COMPUTE(0);
    asm volatile("s_waitcnt vmcnt(3)" ::: "memory");
    __builtin_amdgcn_sched_barrier(0);
    __builtin_amdgcn_s_barrier();

    STAGE(0, (tt + 3) * 32);
    COMPUTE(1);
    asm volatile("s_waitcnt vmcnt(3)" ::: "memory");
    __builtin_amdgcn_sched_barrier(0);
    __builtin_amdgcn_s_barrier();

    STAGE(1, (tt + 4) * 32);
    COMPUTE(2);
    asm volatile("s_waitcnt vmcnt(3)" ::: "memory");
    __builtin_amdgcn_sched_barrier(0);
    __builtin_amdgcn_s_barrier();
  }
  COMPUTE(0);
  asm volatile("s_waitcnt vmcnt(0)" ::: "memory");
  __builtin_amdgcn_sched_barrier(0);
  __builtin_amdgcn_s_barrier();
  COMPUTE(1);
  __builtin_amdgcn_sched_barrier(0);
  __builtin_amdgcn_s_barrier();

#pragma unroll
  for (int m = 0; m < 4; ++m)
#pragma unroll
    for (int n = 0; n < 4; ++n)
#pragma unroll
      for (int rg = 0; rg < 4; ++rg) {
        const int row = wr * 64 + m * 16 + (lane >> 4) * 4 + rg;
        const int colL = wc * 64 + n * 16 + (lane & 15);
        smem[row * 132 + colL] = f32_to_bf16(acc[m][n][rg]);
      }
  __syncthreads();

  {
    const int row = tid & 255;
    const int h = tid >> 8;
    float tv[4];
    int ti_[4];
#pragma unroll
    for (int p = 0; p < 4; ++p) { tv[p] = -INFINITY; ti_[p] = 0; }
    const unsigned short* crow = smem + row * 132 + h * 64;
    const int gcol = col0 + h * 64;
    for (int j = 0; j < 64; j += 4) {
      const ushort4 c4 = *(const ushort4*)(crow + j);
      insN<4>(bf16_to_f32(c4.x), gcol + j + 0, tv, ti_);
      insN<4>(bf16_to_f32(c4.y), gcol + j + 1, tv, ti_);
      insN<4>(bf16_to_f32(c4.z), gcol + j + 2, tv, ti_);
      insN<4>(bf16_to_f32(c4.w), gcol + j + 3, tv, ti_);
    }
    const size_t base = ((size_t)(row0 + row) * NCB + cb) * TOPB + h * 4;
    *(float4*)(part_v + base) = (float4){tv[0], tv[1], tv[2], tv[3]};
    *(int4*)(part_i + base)   = (int4){ti_[0], ti_[1], ti_[2], ti_[3]};
  }
}

// ---------------------------------------------------------------------------
// Projection via bf16 MFMA, bf16 output (round-19-proven counted-vmcnt port).
// ---------------------------------------------------------------------------
__global__ __launch_bounds__(512, 4) void proj256_bf16(
    const unsigned short* __restrict__ A,
    const unsigned short* __restrict__ B,
    const float* __restrict__ bias,
    unsigned short* __restrict__ C)
{
  __shared__ unsigned short smem[3 * SBUF3];   // 72 KB

  const int tid = threadIdx.x;
  const int lane = tid & 63;
  const int wave = tid >> 6;
  const int wr = wave >> 1;
  const int wc = wave & 1;

  const int row0 = blockIdx.x * 256;
  const int col0 = blockIdx.y * 128;

  const int st_r = lane >> 2;
  const int st_swz = ((lane & 3) ^ ((st_r >> 1) & 3)) * 16;

  auto STAGE = [&](int d, int k0) {
    unsigned short* buf = smem + d * SBUF3;
#pragma unroll
    for (int i = 0; i < 3; ++i) {
      const int seg = wave * 3 + i;
      if (seg < 16) {
        const int grow = row0 + seg * 16 + st_r;
        async_copy16((char*)(buf + seg * 512),
                     (const char*)(A + (size_t)grow * D_DIM + k0) + st_swz);
      } else {
        const int s2 = seg - 16;
        const int grow = col0 + s2 * 16 + st_r;
        async_copy16((char*)(buf + 8192 + s2 * 512),
                     (const char*)(B + (size_t)grow * D_DIM + k0) + st_swz);
      }
    }
  };

  f32x4 acc[4][4];
#pragma unroll
  for (int m = 0; m < 4; ++m)
#pragma unroll
    for (int n = 0; n < 4; ++n) acc[m][n] = (f32x4){0.f, 0.f, 0.f, 0.f};

  auto COMPUTE = [&](int d) {
    const unsigned short* sA = smem + d * SBUF3;
    const unsigned short* sB = sA + 8192;
    bf16x8 af[4], bfr[4];
    const int ch = lane >> 4;
#pragma unroll
    for (int m = 0; m < 4; ++m) {
      const int Ra = wr * 64 + m * 16 + (lane & 15);
      af[m] = *(const bf16x8*)((const char*)sA + Ra * 64 + ((ch ^ ((Ra >> 1) & 3)) * 16));
    }
#pragma unroll
    for (int n = 0; n < 4; ++n) {
      const int Rb = wc * 64 + n * 16 + (lane & 15);
      bfr[n] = *(const bf16x8*)((const char*)sB + Rb * 64 + ((ch ^ ((Rb >> 1) & 3)) * 16));
    }
    __builtin_amdgcn_s_setprio(1);
#pragma unroll
    for (int m = 0; m < 4; ++m)
#pragma unroll
      for (int n = 0; n < 4; ++n)
        acc[m][n] = __builtin_amdgcn_mfma_f32_16x16x32_bf16(af[m], bfr[n], acc[m][n], 0, 0, 0);
    __builtin_amdgcn_s_setprio(0);
  };

  STAGE(0, 0);
  STAGE(1, 32);
  asm volatile("s_waitcnt vmcnt(3)" ::: "memory");
  __builtin_amdgcn_sched_barrier(0);
  __builtin_amdgcn_s_barrier();

  for (int tt = 0; tt < 30; tt += 3) {
    STAGE(2, (tt + 2) * 32);
    COMPUTE(0);
    asm volatile("s_waitcnt vmcnt(3)" ::: "memory");
    __builtin_amdgcn_sched_barrier(0);
    __builtin_amdgcn_s_barrier();

    STAGE(0, (tt + 3) * 32);
    COMPUTE(1);
    asm volatile("s_waitcnt vmcnt(3)" ::: "memory");
    __builtin_amdgcn_sched_barrier(0);
    __builtin_amdgcn_s_barrier();

    STAGE(1, (tt + 4) * 32);
    COMPUTE(2);
    asm volatile("s_waitcnt vmcnt(3)" ::: "memory");
    __builtin_amdgcn_sched_barrier(0);
    __builtin_amdgcn_s_barrier();
  }
  COMPUTE(0);
  asm volatile("s_waitcnt vmcnt(0)" ::: "memory");
  __builtin_amdgcn_sched_barrier(0);
  __builtin_amdgcn_s_barrier();
  COMPUTE(1);

#pragma unroll
  for (int n = 0; n < 4; ++n) {
    const int col = col0 + wc * 64 + n * 16 + (lane & 15);
    const float bcol = bias[col];
#pragma unroll
    for (int m = 0; m < 4; ++m)
#pragma unroll
      for (int rg = 0; rg < 4; ++rg) {
        const int row = row0 + wr * 64 + m * 16 + (lane >> 4) * 4 + rg;
        C[(size_t)row * D_DIM + col] = f32_to_bf16(acc[m][n][rg] + bcol);
      }
  }
}

// ---------------------------------------------------------------------------
// Merge: parallel iterative max-extraction (round-15-proven).
// ---------------------------------------------------------------------------
__global__ __launch_bounds__(256) void merge_cand256(
    const float* __restrict__ part_v, const int* __restrict__ part_i,
    int* __restrict__ cand)
{
  const int r = blockIdx.x;
  const int tid = threadIdx.x;
  const int lane = tid & 63;
  const int wave = tid >> 6;

  float tv[8];
  int ti[8];
  {
    const size_t base = ((size_t)r * NCB + tid) * TOPB;
    const float4 a0 = *(const float4*)(part_v + base);
    const float4 a1 = *(const float4*)(part_v + base + 4);
    const int4 b0 = *(const int4*)(part_i + base);
    const int4 b1 = *(const int4*)(part_i + base + 4);
    tv[0] = a0.x; tv[1] = a0.y; tv[2] = a0.z; tv[3] = a0.w;
    tv[4] = a1.x; tv[5] = a1.y; tv[6] = a1.z; tv[7] = a1.w;
    ti[0] = b0.x; ti[1] = b0.y; ti[2] = b0.z; ti[3] = b0.w;
    ti[4] = b1.x; ti[5] = b1.y; ti[6] = b1.z; ti[7] = b1.w;
  }
  unsigned rem = 0xFFu;

  __shared__ float wv4[4];
  __shared__ int wi4[4];
  __shared__ int winner;

  for (int p = 0; p < TOPC; ++p) {
    float bv = -INFINITY;
    int bi = 0x7FFFFFFF;
#pragma unroll
    for (int e = 0; e < 8; ++e) {
      const bool alive = (rem >> e) & 1u;
      const float v = tv[e];
      const int ix = ti[e];
      if (alive && (v > bv || (v == bv && ix < bi))) { bv = v; bi = ix; }
    }
#pragma unroll
    for (int off = 32; off > 0; off >>= 1) {
      const float ov = __shfl_down(bv, off);
      const int oi = __shfl_down(bi, off);
      if (ov > bv || (ov == bv && oi < bi)) { bv = ov; bi = oi; }
    }
    if (lane == 0) { wv4[wave] = bv; wi4[wave] = bi; }
    __syncthreads();
    if (tid == 0) {
      float gv = wv4[0];
      int gi = wi4[0];
#pragma unroll
      for (int w = 1; w < 4; ++w)
        if (wv4[w] > gv || (wv4[w] == gv && wi4[w] < gi)) { gv = wv4[w]; gi = wi4[w]; }
      winner = gi;
      cand[(size_t)r * TOPC + p] = gi;
    }
    __syncthreads();
    const int wgi = winner;
#pragma unroll
    for (int e = 0; e < 8; ++e)
      if (ti[e] == wgi) rem &= ~(1u << e);
  }
}

// ---------------------------------------------------------------------------
// fp64 rescore via u: sims_ci = dot_f64(u_b, mem_ci) + qbk_b (proven).
// ---------------------------------------------------------------------------
__global__ __launch_bounds__(256) void rescore_topk_u(
    const double* __restrict__ U, const double* __restrict__ qbk,
    const float* __restrict__ mem, const int* __restrict__ cand,
    int* __restrict__ topi)
{
  const int b = blockIdx.x;
  const int tid = threadIdx.x;
  const int wave = tid >> 6;
  const int lane = tid & 63;

  __shared__ double sval[TOPC];
  __shared__ int sidx[TOPC];

  const double* urow = U + (size_t)b * D_DIM + lane * 16;
  double uv[16];
#pragma unroll
  for (int i = 0; i < 8; ++i) {
    const double2 d2 = *(const double2*)(urow + i * 2);
    uv[i * 2] = d2.x;
    uv[i * 2 + 1] = d2.y;
  }
  const double qb = qbk[b];

  for (int c = wave; c < TOPC; c += 4) {
    const int ci = cand[(size_t)b * TOPC + c];
    const float* mrow = mem + (size_t)ci * D_DIM + lane * 16;
    double acc = 0.0;
#pragma unroll
    for (int i = 0; i < 4; ++i) {
      const float4 mv = *(const float4*)(mrow + i * 4);
      acc = fma(uv[i * 4 + 0], (double)mv.x, acc);
      acc = fma(uv[i * 4 + 1], (double)mv.y, acc);
      acc = fma(uv[i * 4 + 2], (double)mv.z, acc);
      acc = fma(uv[i * 4 + 3], (double)mv.w, acc);
    }
#pragma unroll
    for (int off = 32; off > 0; off >>= 1) acc += __shfl_down(acc, off);
    if (lane == 0) { sval[c] = acc + qb; sidx[c] = ci; }
  }
  __syncthreads();

  if (tid == 0) {
    bool used[TOPC];
#pragma unroll
    for (int p = 0; p < TOPC; ++p) used[p] = false;
#pragma unroll
    for (int p = 0; p < TOPK; ++p) {
      int best = -1;
      double bv = 0.0;
      int bi = 0;
      for (int c = 0; c < TOPC; ++c) {
        if (used[c]) continue;
        const double v = sval[c];
        const int ix = sidx[c];
        if (best < 0 || v > bv || (v == bv && ix < bi)) { best = c; bv = v; bi = ix; }
      }
      used[best] = true;
      topi[(size_t)b * TOPK + p] = bi;
    }
  }
}

// ---------------------------------------------------------------------------
// Fused f32 -> bf16 cast (round-17-proven).
// ---------------------------------------------------------------------------
#define N4_MEM   (M_ROWS * D_DIM / 4)
#define N4_QUERY (B_ROWS * D_DIM / 4)
#define N4_W     (D_DIM * D_DIM / 4)
#define N4_TOTAL (N4_MEM + N4_QUERY + 3 * N4_W)

__global__ __launch_bounds__(256) void cast_all_bf16(
    const float* __restrict__ mem, const float* __restrict__ query,
    const float* __restrict__ Wk, const float* __restrict__ Wv,
    const float* __restrict__ Wq,
    unsigned short* __restrict__ membf, unsigned short* __restrict__ querybf,
    unsigned short* __restrict__ wkbf, unsigned short* __restrict__ wvbf,
    unsigned short* __restrict__ wqbf)
{
  int i = blockIdx.x * 256 + threadIdx.x;
  if (i >= N4_TOTAL) return;
  const float* src;
  unsigned short* dst;
  if (i < N4_MEM) { src = mem; dst = membf; }
  else if ((i -= N4_MEM) < N4_QUERY) { src = query; dst = querybf; }
  else if ((i -= N4_QUERY) < N4_W) { src = Wk; dst = wkbf; }
  else if ((i -= N4_W) < N4_W) { src = Wv; dst = wvbf; }
  else { i -= N4_W; src = Wq; dst = wqbf; }
  const float4 v = *(const float4*)(src + (size_t)i * 4);
  ushort4 o;
  o.x = f32_to_bf16(v.x);
  o.y = f32_to_bf16(v.y);
  o.z = f32_to_bf16(v.z);
  o.w = f32_to_bf16(v.w);
  *(ushort4*)(dst + (size_t)i * 4) = o;
}

// ---------------------------------------------------------------------------
// Gather selected V rows (bf16) + LayerNorm in f32 (round-18-proven).
// ---------------------------------------------------------------------------
__global__ __launch_bounds__(256) void gather_ln(
    const unsigned short* __restrict__ V, const int* __restrict__ topi,
    const float* __restrict__ gamma, const float* __restrict__ beta,
    float* __restrict__ out)
{
  const int row = blockIdx.x;
  const int tid = threadIdx.x;
  const int idx = topi[row];
  const unsigned short* src = V + (size_t)idx * D_DIM;
  const ushort4 raw = *(const ushort4*)(src + tid * 4);
  const float v0 = bf16_to_f32(raw.x);
  const float v1 = bf16_to_f32(raw.y);
  const float v2 = bf16_to_f32(raw.z);
  const float v3 = bf16_to_f32(raw.w);
  float s = v0 + v1 + v2 + v3;
  float s2 = v0 * v0 + v1 * v1 + v2 * v2 + v3 * v3;
#pragma unroll
  for (int off = 32; off > 0; off >>= 1) {
    s += __shfl_down(s, off);
    s2 += __shfl_down(s2, off);
  }
  __shared__ float red[8];
  __shared__ float stats[2];
  const int wid = tid >> 6;
  if ((tid & 63) == 0) { red[wid] = s; red[4 + wid] = s2; }
  __syncthreads();
  if (tid == 0) {
    const float S = red[0] + red[1] + red[2] + red[3];
    const float S2 = red[4] + red[5] + red[6] + red[7];
    const float mu = S * (1.0f / D_DIM);
    const float var = S2 * (1.0f / D_DIM) - mu * mu;
    stats[0] = mu;
    stats[1] = rsqrtf(var + 1e-5f);
  }
  __syncthreads();
  const float mu = stats[0], rstd = stats[1];
  const float4 g4 = *(const float4*)(gamma + tid * 4);
  const float4 b4 = *(const float4*)(beta + tid * 4);
  float4 o;
  o.x = (v0 - mu) * rstd * g4.x + b4.x;
  o.y = (v1 - mu) * rstd * g4.y + b4.y;
  o.z = (v2 - mu) * rstd * g4.z + b4.z;
  o.w = (v3 - mu) * rstd * g4.w + b4.w;
  *(float4*)(out + (size_t)row * D_DIM + tid * 4) = o;
}

extern "C" void kernel_launch(void* const* d_in, const int* in_sizes, int n_in,
                              void* d_out, int out_size, void* d_ws, size_t ws_size,
                              hipStream_t stream)
{
  const float* query = (const float*)d_in[0];
  const float* mem   = (const float*)d_in[1];
  const float* Wq    = (const float*)d_in[2];
  const float* bq    = (const float*)d_in[3];
  const float* Wk    = (const float*)d_in[4];
  const float* bk    = (const float*)d_in[5];
  const float* Wv    = (const float*)d_in[6];
  const float* bv    = (const float*)d_in[7];
  const float* gamma = (const float*)d_in[8];
  const float* beta  = (const float*)d_in[9];
  float* out = (float*)d_out;

  char* ws = (char*)d_ws;
  double* u64 = (double*)ws;   ws += (size_t)B_ROWS * D_DIM * sizeof(double);
  double* G = (double*)ws;     ws += (size_t)D_DIM * D_DIM * sizeof(double);
  unsigned short* qbf = (unsigned short*)ws;
  ws += (size_t)B_ROWS * D_DIM * sizeof(unsigned short);
  unsigned short* querybf = (unsigned short*)ws;
  ws += (size_t)B_ROWS * D_DIM * sizeof(unsigned short);
  unsigned short* membf = (unsigned short*)ws;
  ws += (size_t)M_ROWS * D_DIM * sizeof(unsigned short);
  char* Aregion = ws;
  ws += (size_t)M_ROWS * D_DIM * sizeof(unsigned short)
      + 2 * (size_t)B_ROWS * NCB * TOPB * sizeof(float);
  double* wvec = (double*)ws;  ws += (size_t)D_DIM * sizeof(double);
  double* ubias = (double*)ws; ws += (size_t)D_DIM * sizeof(double);
  double* s0 = (double*)ws;    ws += 2 * sizeof(double);
  double* qbk = (double*)ws;   ws += (size_t)B_ROWS * sizeof(double);
  int* cand = (int*)ws;        ws += (size_t)B_ROWS * TOPC * sizeof(int);
  int* topi = (int*)ws;

  unsigned short* Kbf = (unsigned short*)Aregion;
  float* part_v = (float*)(Aregion + (size_t)M_ROWS * D_DIM * sizeof(unsigned short));
  int* part_i = (int*)((char*)part_v + (size_t)B_ROWS * NCB * TOPB * sizeof(float));
  unsigned short* wkbf = (unsigned short*)G;
  unsigned short* wvbf = wkbf + (size_t)D_DIM * D_DIM;
  unsigned short* wqbf = wvbf + (size_t)D_DIM * D_DIM;
  unsigned short* Vbf = (unsigned short*)Aregion;

  // Selection chain (f64): G = Wq^T@Wk; u = query@G + bq@Wk; qbk = query.(Wq^T bk) + bq.bk
  gram_f64<<<dim3(16, 16), 256, 0, stream>>>(Wq, Wk, G);
  bias_terms<<<dim3(9), 256, 0, stream>>>(Wq, Wk, bq, bk, wvec, ubias, s0);
  qbk_w<<<dim3(B_ROWS / 4), 256, 0, stream>>>(query, wvec, s0, qbk);
  uproj_G<<<dim3(B_ROWS / 64, D_DIM / 64), 256, 0, stream>>>(query, G, ubias, u64);

  // Candidate chain (bf16): fused casts; G dead -> W casts overlay it.
  cast_all_bf16<<<dim3((N4_TOTAL + 255) / 256), 256, 0, stream>>>(
      mem, query, Wk, Wv, Wq, membf, querybf, wkbf, wvbf, wqbf);

  proj256_bf16<<<dim3(M_ROWS / 256, D_DIM / 128), 512, 0, stream>>>(membf, wkbf, bk, Kbf);
  proj256_bf16<<<dim3(B_ROWS / 256, D_DIM / 128), 512, 0, stream>>>(querybf, wqbf, bq, qbf);

  sims_topc_gemm<<<dim3((B_ROWS / 256) * NCB), 512, 0, stream>>>(qbf, Kbf, part_v, part_i);
  merge_cand256<<<dim3(B_ROWS), 256, 0, stream>>>(part_v, part_i, cand);
  rescore_topk_u<<<dim3(B_ROWS), 256, 0, stream>>>(u64, qbk, mem, cand, topi);

  // V path (bf16 out, overlays dead Kbf/parts region).
  proj256_bf16<<<dim3(M_ROWS / 256, D_DIM / 128), 512, 0, stream>>>(membf, wvbf, bv, Vbf);
  gather_ln<<<dim3(B_ROWS * TOPK), 256, 0, stream>>>(Vbf, topi, gamma, beta, out);
}

// Round 21
// 1153.601 us; speedup vs baseline: 6.9436x; 1.0583x over previous
//
#include <hip/hip_runtime.h>
#include <hip/hip_bf16.h>
#include <math.h>

#define D_DIM 1024
#define B_ROWS 4096
#define M_ROWS 32768
#define TOPK 8
#define TOPC 16
#define TOPB 8
#define NCB (M_ROWS / 128)

typedef __attribute__((ext_vector_type(8))) short bf16x8;
typedef __attribute__((ext_vector_type(4))) float f32x4;

__device__ __forceinline__ unsigned short f32_to_bf16(float f) {
  unsigned int u = __float_as_uint(f);
  unsigned int r = (u + 0x7FFFu + ((u >> 16) & 1u)) >> 16;
  return (unsigned short)r;
}
__device__ __forceinline__ float bf16_to_f32(unsigned short h) {
  return __uint_as_float(((unsigned int)h) << 16);
}
__device__ __forceinline__ void async_copy16(void* lds, const void* g) {
  __builtin_amdgcn_global_load_lds(
      (const __attribute__((address_space(1))) unsigned int*)g,
      (__attribute__((address_space(3))) unsigned int*)lds, 16, 0, 0);
}

template <int N>
__device__ __forceinline__ void insN(float v, int idx,
                                     float* __restrict__ tv,
                                     int* __restrict__ ti) {
  if (v < tv[N - 1]) return;
  if (v == tv[N - 1] && idx > ti[N - 1]) return;
  float cv = v;
  int ci = idx;
#pragma unroll
  for (int p = 0; p < N; ++p) {
    if (cv > tv[p] || (cv == tv[p] && ci < ti[p])) {
      const float t0 = tv[p]; tv[p] = cv; cv = t0;
      const int t1 = ti[p]; ti[p] = ci; ci = t1;
    }
  }
}

// ---------------------------------------------------------------------------
// G[f][e] = sum_n Wq[n][f] * Wk[n][e], f64. Round-21: 2-phase double-buffer
// (STAGE(t+1) before compute(t)) — at 1 block/CU (256 blocks) the per-K-step
// drain was the whole stall; issue-early hides the load under 16 f64 fma x32.
// ---------------------------------------------------------------------------
__global__ __launch_bounds__(256) void gram_f64(
    const float* __restrict__ Wq, const float* __restrict__ Wk,
    double* __restrict__ G)
{
  __shared__ float sA[2][32][68];
  __shared__ float sB[2][32][68];
  const int tid = threadIdx.x;
  const int tx = tid & 15, ty = tid >> 4;
  const int f0 = blockIdx.x * 64;
  const int e0 = blockIdx.y * 64;

  double acc[4][4];
#pragma unroll
  for (int i = 0; i < 4; ++i)
#pragma unroll
    for (int j = 0; j < 4; ++j) acc[i][j] = 0.0;

  auto STAGE = [&](int d, int k0) {
#pragma unroll
    for (int it = 0; it < 2; ++it) {
      const int L = it * 256 + tid;
      const int kk = L >> 4, c4 = (L & 15) * 4;
      *(float4*)&sA[d][kk][c4] = *(const float4*)(Wq + (size_t)(k0 + kk) * D_DIM + f0 + c4);
      *(float4*)&sB[d][kk][c4] = *(const float4*)(Wk + (size_t)(k0 + kk) * D_DIM + e0 + c4);
    }
  };

  STAGE(0, 0);
  __syncthreads();
  int cur = 0;
  for (int t = 0; t < 32; ++t) {
    if (t < 31) STAGE(cur ^ 1, (t + 1) * 32);
#pragma unroll
    for (int kk = 0; kk < 32; ++kk) {
      const double a[4] = {sA[cur][kk][ty * 4 + 0], sA[cur][kk][ty * 4 + 1],
                           sA[cur][kk][ty * 4 + 2], sA[cur][kk][ty * 4 + 3]};
      const double b[4] = {sB[cur][kk][tx * 4 + 0], sB[cur][kk][tx * 4 + 1],
                           sB[cur][kk][tx * 4 + 2], sB[cur][kk][tx * 4 + 3]};
#pragma unroll
      for (int i = 0; i < 4; ++i)
#pragma unroll
        for (int j = 0; j < 4; ++j)
          acc[i][j] = fma(a[i], b[j], acc[i][j]);
    }
    __syncthreads();
    cur ^= 1;
  }
#pragma unroll
  for (int i = 0; i < 4; ++i)
#pragma unroll
    for (int j = 0; j < 4; ++j)
      G[(size_t)(f0 + ty * 4 + i) * D_DIM + e0 + tx * 4 + j] = acc[i][j];
}

// ---------------------------------------------------------------------------
// Fused bias terms (round-20-proven).
// ---------------------------------------------------------------------------
__global__ __launch_bounds__(256) void bias_terms(
    const float* __restrict__ Wq, const float* __restrict__ Wk,
    const float* __restrict__ bq, const float* __restrict__ bk,
    double* __restrict__ wvec, double* __restrict__ ubias,
    double* __restrict__ s0)
{
  const int blk = blockIdx.x;
  const int tid = threadIdx.x;
  if (blk < 4) {
    const int c = blk * 256 + tid;
    double acc = 0.0;
    for (int n = 0; n < D_DIM; ++n)
      acc = fma((double)Wq[(size_t)n * D_DIM + c], (double)bk[n], acc);
    wvec[c] = acc;
  } else if (blk < 8) {
    const int c = (blk - 4) * 256 + tid;
    double acc = 0.0;
    for (int n = 0; n < D_DIM; ++n)
      acc = fma((double)Wk[(size_t)n * D_DIM + c], (double)bq[n], acc);
    ubias[c] = acc;
  } else {
    double acc = 0.0;
#pragma unroll
    for (int i = 0; i < 4; ++i) {
      const int idx = tid * 4 + i;
      acc = fma((double)bq[idx], (double)bk[idx], acc);
    }
#pragma unroll
    for (int off = 32; off > 0; off >>= 1) acc += __shfl_down(acc, off);
    __shared__ double red[4];
    if ((tid & 63) == 0) red[tid >> 6] = acc;
    __syncthreads();
    if (tid == 0) s0[0] = red[0] + red[1] + red[2] + red[3];
  }
}

// ---------------------------------------------------------------------------
// qbk[b] = dot_f64(query[b,:], w) + s0 (proven).
// ---------------------------------------------------------------------------
__global__ __launch_bounds__(256) void qbk_w(
    const float* __restrict__ query, const double* __restrict__ w,
    const double* __restrict__ s0, double* __restrict__ qbk)
{
  const int b = blockIdx.x * 4 + (threadIdx.x >> 6);
  const int lane = threadIdx.x & 63;
  const float* qrow = query + (size_t)b * D_DIM + lane * 16;
  const double* wrow = w + lane * 16;
  double acc = 0.0;
#pragma unroll
  for (int i = 0; i < 16; ++i)
    acc = fma((double)qrow[i], wrow[i], acc);
#pragma unroll
  for (int off = 32; off > 0; off >>= 1) acc += __shfl_down(acc, off);
  if (lane == 0) qbk[b] = acc + s0[0];
}

// ---------------------------------------------------------------------------
// u[b,d] = sum_e query[b,e]*G[e,d] + ubias[d], f64 (round-20-proven dbuf).
// ---------------------------------------------------------------------------
__global__ __launch_bounds__(256) void uproj_G(
    const float* __restrict__ query, const double* __restrict__ G,
    const double* __restrict__ ubias, double* __restrict__ U)
{
  __shared__ double sAdT[2][32][66];
  __shared__ double sBd[2][32][68];
  const int tid = threadIdx.x;
  const int tx = tid & 15, ty = tid >> 4;
  const int row0 = blockIdx.x * 64;
  const int col0 = blockIdx.y * 64;

  double acc[4][4];
#pragma unroll
  for (int i = 0; i < 4; ++i)
#pragma unroll
    for (int j = 0; j < 4; ++j) acc[i][j] = 0.0;

  auto STAGE = [&](int d, int k0) {
#pragma unroll
    for (int it = 0; it < 2; ++it) {
      const int L = it * 256 + tid;
      const int rowa = L >> 3, c4 = (L & 7) * 4;
      const float4 v =
          *(const float4*)(query + (size_t)(row0 + rowa) * D_DIM + k0 + c4);
      sAdT[d][c4 + 0][rowa] = (double)v.x;
      sAdT[d][c4 + 1][rowa] = (double)v.y;
      sAdT[d][c4 + 2][rowa] = (double)v.z;
      sAdT[d][c4 + 3][rowa] = (double)v.w;
    }
#pragma unroll
    for (int it = 0; it < 4; ++it) {
      const int L = it * 256 + tid;
      const int kk = L >> 5, c2 = (L & 31) * 2;
      *(double2*)&sBd[d][kk][c2] =
          *(const double2*)(G + (size_t)(k0 + kk) * D_DIM + col0 + c2);
    }
  };

  STAGE(0, 0);
  __syncthreads();
  int cur = 0;
  for (int t = 0; t < 32; ++t) {
    if (t < 31) STAGE(cur ^ 1, (t + 1) * 32);
#pragma unroll
    for (int kk = 0; kk < 32; ++kk) {
      const double2 p0 = *(const double2*)&sAdT[cur][kk][ty * 4];
      const double2 p1 = *(const double2*)&sAdT[cur][kk][ty * 4 + 2];
      const double a[4] = {p0.x, p0.y, p1.x, p1.y};
      const double bb[4] = {sBd[cur][kk][tx * 4 + 0], sBd[cur][kk][tx * 4 + 1],
                            sBd[cur][kk][tx * 4 + 2], sBd[cur][kk][tx * 4 + 3]};
#pragma unroll
      for (int i = 0; i < 4; ++i)
#pragma unroll
        for (int j = 0; j < 4; ++j)
          acc[i][j] = fma(a[i], bb[j], acc[i][j]);
    }
    __syncthreads();
    cur ^= 1;
  }
  const double ub[4] = {ubias[col0 + tx * 4 + 0], ubias[col0 + tx * 4 + 1],
                        ubias[col0 + tx * 4 + 2], ubias[col0 + tx * 4 + 3]};
#pragma unroll
  for (int i = 0; i < 4; ++i) {
    const size_t base = (size_t)(row0 + ty * 4 + i) * D_DIM + col0 + tx * 4;
    *(double2*)(U + base)     = (double2){acc[i][0] + ub[0], acc[i][1] + ub[1]};
    *(double2*)(U + base + 2) = (double2){acc[i][2] + ub[2], acc[i][3] + ub[3]};
  }
}

// ---------------------------------------------------------------------------
// Fused sims + per-half top-4 (rounds 18-20 proven).
// ---------------------------------------------------------------------------
#define SBUF3 12288
__global__ __launch_bounds__(512, 4) void sims_topc_gemm(
    const unsigned short* __restrict__ A, const unsigned short* __restrict__ B,
    float* __restrict__ part_v, int* __restrict__ part_i)
{
  __shared__ unsigned short smem[3 * SBUF3];

  const int tid = threadIdx.x;
  const int lane = tid & 63;
  const int wave = tid >> 6;
  const int wr = wave >> 1;
  const int wc = wave & 1;

  const int bid = blockIdx.x;
  const int x = bid & 7;
  const int t9 = bid >> 3;
  const int cbg = t9 >> 7;
  const int r = (t9 >> 3) & 15;
  const int cbl = t9 & 7;
  const int cb = (x * 4 + cbg) * 8 + cbl;
  const int row0 = r * 256;
  const int col0 = cb * 128;

  const int st_r = lane >> 2;
  const int st_swz = ((lane & 3) ^ ((st_r >> 1) & 3)) * 16;

  auto STAGE = [&](int d, int k0) {
    unsigned short* buf = smem + d * SBUF3;
#pragma unroll
    for (int i = 0; i < 3; ++i) {
      const int seg = wave * 3 + i;
      if (seg < 16) {
        const int grow = row0 + seg * 16 + st_r;
        async_copy16((char*)(buf + seg * 512),
                     (const char*)(A + (size_t)grow * D_DIM + k0) + st_swz);
      } else {
        const int s2 = seg - 16;
        const int grow = col0 + s2 * 16 + st_r;
        async_copy16((char*)(buf + 8192 + s2 * 512),
                     (const char*)(B + (size_t)grow * D_DIM + k0) + st_swz);
      }
    }
  };

  f32x4 acc[4][4];
#pragma unroll
  for (int m = 0; m < 4; ++m)
#pragma unroll
    for (int n = 0; n < 4; ++n) acc[m][n] = (f32x4){0.f, 0.f, 0.f, 0.f};

  auto COMPUTE = [&](int d) {
    const unsigned short* sA = smem + d * SBUF3;
    const unsigned short* sB = sA + 8192;
    bf16x8 af[4], bfr[4];
    const int ch = lane >> 4;
#pragma unroll
    for (int m = 0; m < 4; ++m) {
      const int Ra = wr * 64 + m * 16 + (lane & 15);
      af[m] = *(const bf16x8*)((const char*)sA + Ra * 64 + ((ch ^ ((Ra >> 1) & 3)) * 16));
    }
#pragma unroll
    for (int n = 0; n < 4; ++n) {
      const int Rb = wc * 64 + n * 16 + (lane & 15);
      bfr[n] = *(const bf16x8*)((const char*)sB + Rb * 64 + ((ch ^ ((Rb >> 1) & 3)) * 16));
    }
    __builtin_amdgcn_s_setprio(1);
#pragma unroll
    for (int m = 0; m < 4; ++m)
#pragma unroll
      for (int n = 0; n < 4; ++n)
        acc[m][n] = __builtin_amdgcn_mfma_f32_16x16x32_bf16(af[m], bfr[n], acc[m][n], 0, 0, 0);
    __builtin_amdgcn_s_setprio(0);
  };

  STAGE(0, 0);
  STAGE(1, 32);
  asm volatile("s_waitcnt vmcnt(3)" ::: "memory");
  __builtin_amdgcn_sched_barrier(0);
  __builtin_amdgcn_s_barrier();

  for (int tt = 0; tt < 30; tt += 3) {
    STAGE(2, (tt + 2) * 32);
    COMPUTE(0);
    asm volatile("s_waitcnt vmcnt(3)" ::: "memory");
    __builtin_amdgcn_sched_barrier(0);
    __builtin_amdgcn_s_barrier();

    STAGE(0, (tt + 3) * 32);
    COMPUTE(1);
    asm volatile("s_waitcnt vmcnt(3)" ::: "memory");
    __builtin_amdgcn_sched_barrier(0);
    __builtin_amdgcn_s_barrier();

    STAGE(1, (tt + 4) * 32);
    COMPUTE(2);
    asm volatile("s_waitcnt vmcnt(3)" ::: "memory");
    __builtin_amdgcn_sched_barrier(0);
    __builtin_amdgcn_s_barrier();
  }
  COMPUTE(0);
  asm volatile("s_waitcnt vmcnt(0)" ::: "memory");
  __builtin_amdgcn_sched_barrier(0);
  __builtin_amdgcn_s_barrier();
  COMPUTE(1);
  __builtin_amdgcn_sched_barrier(0);
  __builtin_amdgcn_s_barrier();

#pragma unroll
  for (int m = 0; m < 4; ++m)
#pragma unroll
    for (int n = 0; n < 4; ++n)
#pragma unroll
      for (int rg = 0; rg < 4; ++rg) {
        const int row = wr * 64 + m * 16 + (lane >> 4) * 4 + rg;
        const int colL = wc * 64 + n * 16 + (lane & 15);
        smem[row * 132 + colL] = f32_to_bf16(acc[m][n][rg]);
      }
  __syncthreads();

  {
    const int row = tid & 255;
    const int h = tid >> 8;
    float tv[4];
    int ti_[4];
#pragma unroll
    for (int p = 0; p < 4; ++p) { tv[p] = -INFINITY; ti_[p] = 0; }
    const unsigned short* crow = smem + row * 132 + h * 64;
    const int gcol = col0 + h * 64;
    for (int j = 0; j < 64; j += 4) {
      const ushort4 c4 = *(const ushort4*)(crow + j);
      insN<4>(bf16_to_f32(c4.x), gcol + j + 0, tv, ti_);
      insN<4>(bf16_to_f32(c4.y), gcol + j + 1, tv, ti_);
      insN<4>(bf16_to_f32(c4.z), gcol + j + 2, tv, ti_);
      insN<4>(bf16_to_f32(c4.w), gcol + j + 3, tv, ti_);
    }
    const size_t base = ((size_t)(row0 + row) * NCB + cb) * TOPB + h * 4;
    *(float4*)(part_v + base) = (float4){tv[0], tv[1], tv[2], tv[3]};
    *(int4*)(part_i + base)   = (int4){ti_[0], ti_[1], ti_[2], ti_[3]};
  }
}

// ---------------------------------------------------------------------------
// Projection via bf16 MFMA, bf16 output (round-19/20-proven).
// ---------------------------------------------------------------------------
__global__ __launch_bounds__(512, 4) void proj256_bf16(
    const unsigned short* __restrict__ A,
    const unsigned short* __restrict__ B,
    const float* __restrict__ bias,
    unsigned short* __restrict__ C)
{
  __shared__ unsigned short smem[3 * SBUF3];

  const int tid = threadIdx.x;
  const int lane = tid & 63;
  const int wave = tid >> 6;
  const int wr = wave >> 1;
  const int wc = wave & 1;

  const int row0 = blockIdx.x * 256;
  const int col0 = blockIdx.y * 128;

  const int st_r = lane >> 2;
  const int st_swz = ((lane & 3) ^ ((st_r >> 1) & 3)) * 16;

  auto STAGE = [&](int d, int k0) {
    unsigned short* buf = smem + d * SBUF3;
#pragma unroll
    for (int i = 0; i < 3; ++i) {
      const int seg = wave * 3 + i;
      if (seg < 16) {
        const int grow = row0 + seg * 16 + st_r;
        async_copy16((char*)(buf + seg * 512),
                     (const char*)(A + (size_t)grow * D_DIM + k0) + st_swz);
      } else {
        const int s2 = seg - 16;
        const int grow = col0 + s2 * 16 + st_r;
        async_copy16((char*)(buf + 8192 + s2 * 512),
                     (const char*)(B + (size_t)grow * D_DIM + k0) + st_swz);
      }
    }
  };

  f32x4 acc[4][4];
#pragma unroll
  for (int m = 0; m < 4; ++m)
#pragma unroll
    for (int n = 0; n < 4; ++n) acc[m][n] = (f32x4){0.f, 0.f, 0.f, 0.f};

  auto COMPUTE = [&](int d) {
    const unsigned short* sA = smem + d * SBUF3;
    const unsigned short* sB = sA + 8192;
    bf16x8 af[4], bfr[4];
    const int ch = lane >> 4;
#pragma unroll
    for (int m = 0; m < 4; ++m) {
      const int Ra = wr * 64 + m * 16 + (lane & 15);
      af[m] = *(const bf16x8*)((const char*)sA + Ra * 64 + ((ch ^ ((Ra >> 1) & 3)) * 16));
    }
#pragma unroll
    for (int n = 0; n < 4; ++n) {
      const int Rb = wc * 64 + n * 16 + (lane & 15);
      bfr[n] = *(const bf16x8*)((const char*)sB + Rb * 64 + ((ch ^ ((Rb >> 1) & 3)) * 16));
    }
    __builtin_amdgcn_s_setprio(1);
#pragma unroll
    for (int m = 0; m < 4; ++m)
#pragma unroll
      for (int n = 0; n < 4; ++n)
        acc[m][n] = __builtin_amdgcn_mfma_f32_16x16x32_bf16(af[m], bfr[n], acc[m][n], 0, 0, 0);
    __builtin_amdgcn_s_setprio(0);
  };

  STAGE(0, 0);
  STAGE(1, 32);
  asm volatile("s_waitcnt vmcnt(3)" ::: "memory");
  __builtin_amdgcn_sched_barrier(0);
  __builtin_amdgcn_s_barrier();

  for (int tt = 0; tt < 30; tt += 3) {
    STAGE(2, (tt + 2) * 32);
    COMPUTE(0);
    asm volatile("s_waitcnt vmcnt(3)" ::: "memory");
    __builtin_amdgcn_sched_barrier(0);
    __builtin_amdgcn_s_barrier();

    STAGE(0, (tt + 3) * 32);
    COMPUTE(1);
    asm volatile("s_waitcnt vmcnt(3)" ::: "memory");
    __builtin_amdgcn_sched_barrier(0);
    __builtin_amdgcn_s_barrier();

    STAGE(1, (tt + 4) * 32);
    COMPUTE(2);
    asm volatile("s_waitcnt vmcnt(3)" ::: "memory");
    __builtin_amdgcn_sched_barrier(0);
    __builtin_amdgcn_s_barrier();
  }
  COMPUTE(0);
  asm volatile("s_waitcnt vmcnt(0)" ::: "memory");
  __builtin_amdgcn_sched_barrier(0);
  __builtin_amdgcn_s_barrier();
  COMPUTE(1);

#pragma unroll
  for (int n = 0; n < 4; ++n) {
    const int col = col0 + wc * 64 + n * 16 + (lane & 15);
    const float bcol = bias[col];
#pragma unroll
    for (int m = 0; m < 4; ++m)
#pragma unroll
      for (int rg = 0; rg < 4; ++rg) {
        const int row = row0 + wr * 64 + m * 16 + (lane >> 4) * 4 + rg;
        C[(size_t)row * D_DIM + col] = f32_to_bf16(acc[m][n][rg] + bcol);
      }
  }
}

// ---------------------------------------------------------------------------
// FUSED merge + rescore (round-21): per row, phase 1 = round-15-proven
// max-extraction into LDS cand16; phase 2 = round-16-proven fp64 rescore
// reading cand16 from LDS. Kills one launch + the cand global round-trip.
// ---------------------------------------------------------------------------
__global__ __launch_bounds__(256) void merge_rescore(
    const float* __restrict__ part_v, const int* __restrict__ part_i,
    const double* __restrict__ U, const double* __restrict__ qbk,
    const float* __restrict__ mem, int* __restrict__ topi)
{
  const int r = blockIdx.x;
  const int tid = threadIdx.x;
  const int lane = tid & 63;
  const int wave = tid >> 6;

  // ---- Phase 1: top-16 extraction (proven body) ----
  float tv[8];
  int ti[8];
  {
    const size_t base = ((size_t)r * NCB + tid) * TOPB;
    const float4 a0 = *(const float4*)(part_v + base);
    const float4 a1 = *(const float4*)(part_v + base + 4);
    const int4 b0 = *(const int4*)(part_i + base);
    const int4 b1 = *(const int4*)(part_i + base + 4);
    tv[0] = a0.x; tv[1] = a0.y; tv[2] = a0.z; tv[3] = a0.w;
    tv[4] = a1.x; tv[5] = a1.y; tv[6] = a1.z; tv[7] = a1.w;
    ti[0] = b0.x; ti[1] = b0.y; ti[2] = b0.z; ti[3] = b0.w;
    ti[4] = b1.x; ti[5] = b1.y; ti[6] = b1.z; ti[7] = b1.w;
  }
  unsigned rem = 0xFFu;

  __shared__ float wv4[4];
  __shared__ int wi4[4];
  __shared__ int winner;
  __shared__ int cand16[TOPC];

  for (int p = 0; p < TOPC; ++p) {
    float bv = -INFINITY;
    int bi = 0x7FFFFFFF;
#pragma unroll
    for (int e = 0; e < 8; ++e) {
      const bool alive = (rem >> e) & 1u;
      const float v = tv[e];
      const int ix = ti[e];
      if (alive && (v > bv || (v == bv && ix < bi))) { bv = v; bi = ix; }
    }
#pragma unroll
    for (int off = 32; off > 0; off >>= 1) {
      const float ov = __shfl_down(bv, off);
      const int oi = __shfl_down(bi, off);
      if (ov > bv || (ov == bv && oi < bi)) { bv = ov; bi = oi; }
    }
    if (lane == 0) { wv4[wave] = bv; wi4[wave] = bi; }
    __syncthreads();
    if (tid == 0) {
      float gv = wv4[0];
      int gi = wi4[0];
#pragma unroll
      for (int w = 1; w < 4; ++w)
        if (wv4[w] > gv || (wv4[w] == gv && wi4[w] < gi)) { gv = wv4[w]; gi = wi4[w]; }
      winner = gi;
      cand16[p] = gi;
    }
    __syncthreads();
    const int wgi = winner;
#pragma unroll
    for (int e = 0; e < 8; ++e)
      if (ti[e] == wgi) rem &= ~(1u << e);
  }

  // ---- Phase 2: fp64 rescore (proven body, cand from LDS) ----
  __shared__ double sval[TOPC];
  __shared__ int sidx[TOPC];

  const double* urow = U + (size_t)r * D_DIM + lane * 16;
  double uv[16];
#pragma unroll
  for (int i = 0; i < 8; ++i) {
    const double2 d2 = *(const double2*)(urow + i * 2);
    uv[i * 2] = d2.x;
    uv[i * 2 + 1] = d2.y;
  }
  const double qb = qbk[r];

  for (int c = wave; c < TOPC; c += 4) {
    const int ci = cand16[c];
    const float* mrow = mem + (size_t)ci * D_DIM + lane * 16;
    double acc = 0.0;
#pragma unroll
    for (int i = 0; i < 4; ++i) {
      const float4 mv = *(const float4*)(mrow + i * 4);
      acc = fma(uv[i * 4 + 0], (double)mv.x, acc);
      acc = fma(uv[i * 4 + 1], (double)mv.y, acc);
      acc = fma(uv[i * 4 + 2], (double)mv.z, acc);
      acc = fma(uv[i * 4 + 3], (double)mv.w, acc);
    }
#pragma unroll
    for (int off = 32; off > 0; off >>= 1) acc += __shfl_down(acc, off);
    if (lane == 0) { sval[c] = acc + qb; sidx[c] = ci; }
  }
  __syncthreads();

  if (tid == 0) {
    bool used[TOPC];
#pragma unroll
    for (int p = 0; p < TOPC; ++p) used[p] = false;
#pragma unroll
    for (int p = 0; p < TOPK; ++p) {
      int best = -1;
      double bv = 0.0;
      int bi = 0;
      for (int c = 0; c < TOPC; ++c) {
        if (used[c]) continue;
        const double v = sval[c];
        const int ix = sidx[c];
        if (best < 0 || v > bv || (v == bv && ix < bi)) { best = c; bv = v; bi = ix; }
      }
      used[best] = true;
      topi[(size_t)r * TOPK + p] = bi;
    }
  }
}

// ---------------------------------------------------------------------------
// Fused f32 -> bf16 cast (round-17-proven).
// ---------------------------------------------------------------------------
#define N4_MEM   (M_ROWS * D_DIM / 4)
#define N4_QUERY (B_ROWS * D_DIM / 4)
#define N4_W     (D_DIM * D_DIM / 4)
#define N4_TOTAL (N4_MEM + N4_QUERY + 3 * N4_W)

__global__ __launch_bounds__(256) void cast_all_bf16(
    const float* __restrict__ mem, const float* __restrict__ query,
    const float* __restrict__ Wk, const float* __restrict__ Wv,
    const float* __restrict__ Wq,
    unsigned short* __restrict__ membf, unsigned short* __restrict__ querybf,
    unsigned short* __restrict__ wkbf, unsigned short* __restrict__ wvbf,
    unsigned short* __restrict__ wqbf)
{
  int i = blockIdx.x * 256 + threadIdx.x;
  if (i >= N4_TOTAL) return;
  const float* src;
  unsigned short* dst;
  if (i < N4_MEM) { src = mem; dst = membf; }
  else if ((i -= N4_MEM) < N4_QUERY) { src = query; dst = querybf; }
  else if ((i -= N4_QUERY) < N4_W) { src = Wk; dst = wkbf; }
  else if ((i -= N4_W) < N4_W) { src = Wv; dst = wvbf; }
  else { i -= N4_W; src = Wq; dst = wqbf; }
  const float4 v = *(const float4*)(src + (size_t)i * 4);
  ushort4 o;
  o.x = f32_to_bf16(v.x);
  o.y = f32_to_bf16(v.y);
  o.z = f32_to_bf16(v.z);
  o.w = f32_to_bf16(v.w);
  *(ushort4*)(dst + (size_t)i * 4) = o;
}

// ---------------------------------------------------------------------------
// Gather selected V rows (bf16) + LayerNorm in f32 (round-18-proven).
// ---------------------------------------------------------------------------
__global__ __launch_bounds__(256) void gather_ln(
    const unsigned short* __restrict__ V, const int* __restrict__ topi,
    const float* __restrict__ gamma, const float* __restrict__ beta,
    float* __restrict__ out)
{
  const int row = blockIdx.x;
  const int tid = threadIdx.x;
  const int idx = topi[row];
  const unsigned short* src = V + (size_t)idx * D_DIM;
  const ushort4 raw = *(const ushort4*)(src + tid * 4);
  const float v0 = bf16_to_f32(raw.x);
  const float v1 = bf16_to_f32(raw.y);
  const float v2 = bf16_to_f32(raw.z);
  const float v3 = bf16_to_f32(raw.w);
  float s = v0 + v1 + v2 + v3;
  float s2 = v0 * v0 + v1 * v1 + v2 * v2 + v3 * v3;
#pragma unroll
  for (int off = 32; off > 0; off >>= 1) {
    s += __shfl_down(s, off);
    s2 += __shfl_down(s2, off);
  }
  __shared__ float red[8];
  __shared__ float stats[2];
  const int wid = tid >> 6;
  if ((tid & 63) == 0) { red[wid] = s; red[4 + wid] = s2; }
  __syncthreads();
  if (tid == 0) {
    const float S = red[0] + red[1] + red[2] + red[3];
    const float S2 = red[4] + red[5] + red[6] + red[7];
    const float mu = S * (1.0f / D_DIM);
    const float var = S2 * (1.0f / D_DIM) - mu * mu;
    stats[0] = mu;
    stats[1] = rsqrtf(var + 1e-5f);
  }
  __syncthreads();
  const float mu = stats[0], rstd = stats[1];
  const float4 g4 = *(const float4*)(gamma + tid * 4);
  const float4 b4 = *(const float4*)(beta + tid * 4);
  float4 o;
  o.x = (v0 - mu) * rstd * g4.x + b4.x;
  o.y = (v1 - mu) * rstd * g4.y + b4.y;
  o.z = (v2 - mu) * rstd * g4.z + b4.z;
  o.w = (v3 - mu) * rstd * g4.w + b4.w;
  *(float4*)(out + (size_t)row * D_DIM + tid * 4) = o;
}

extern "C" void kernel_launch(void* const* d_in, const int* in_sizes, int n_in,
                              void* d_out, int out_size, void* d_ws, size_t ws_size,
                              hipStream_t stream)
{
  const float* query = (const float*)d_in[0];
  const float* mem   = (const float*)d_in[1];
  const float* Wq    = (const float*)d_in[2];
  const float* bq    = (const float*)d_in[3];
  const float* Wk    = (const float*)d_in[4];
  const float* bk    = (const float*)d_in[5];
  const float* Wv    = (const float*)d_in[6];
  const float* bv    = (const float*)d_in[7];
  const float* gamma = (const float*)d_in[8];
  const float* beta  = (const float*)d_in[9];
  float* out = (float*)d_out;

  char* ws = (char*)d_ws;
  double* u64 = (double*)ws;   ws += (size_t)B_ROWS * D_DIM * sizeof(double);
  double* G = (double*)ws;     ws += (size_t)D_DIM * D_DIM * sizeof(double);
  unsigned short* qbf = (unsigned short*)ws;
  ws += (size_t)B_ROWS * D_DIM * sizeof(unsigned short);
  unsigned short* querybf = (unsigned short*)ws;
  ws += (size_t)B_ROWS * D_DIM * sizeof(unsigned short);
  unsigned short* membf = (unsigned short*)ws;
  ws += (size_t)M_ROWS * D_DIM * sizeof(unsigned short);
  char* Aregion = ws;
  ws += (size_t)M_ROWS * D_DIM * sizeof(unsigned short)
      + 2 * (size_t)B_ROWS * NCB * TOPB * sizeof(float);
  double* wvec = (double*)ws;  ws += (size_t)D_DIM * sizeof(double);
  double* ubias = (double*)ws; ws += (size_t)D_DIM * sizeof(double);
  double* s0 = (double*)ws;    ws += 2 * sizeof(double);
  double* qbk = (double*)ws;   ws += (size_t)B_ROWS * sizeof(double);
  int* topi = (int*)ws;

  unsigned short* Kbf = (unsigned short*)Aregion;
  float* part_v = (float*)(Aregion + (size_t)M_ROWS * D_DIM * sizeof(unsigned short));
  int* part_i = (int*)((char*)part_v + (size_t)B_ROWS * NCB * TOPB * sizeof(float));
  unsigned short* wkbf = (unsigned short*)G;
  unsigned short* wvbf = wkbf + (size_t)D_DIM * D_DIM;
  unsigned short* wqbf = wvbf + (size_t)D_DIM * D_DIM;
  unsigned short* Vbf = (unsigned short*)Aregion;

  // Selection chain (f64): G = Wq^T@Wk; u = query@G + bq@Wk; qbk = query.(Wq^T bk) + bq.bk
  gram_f64<<<dim3(16, 16), 256, 0, stream>>>(Wq, Wk, G);
  bias_terms<<<dim3(9), 256, 0, stream>>>(Wq, Wk, bq, bk, wvec, ubias, s0);
  qbk_w<<<dim3(B_ROWS / 4), 256, 0, stream>>>(query, wvec, s0, qbk);
  uproj_G<<<dim3(B_ROWS / 64, D_DIM / 64), 256, 0, stream>>>(query, G, ubias, u64);

  // Candidate chain (bf16): fused casts; G dead -> W casts overlay it.
  cast_all_bf16<<<dim3((N4_TOTAL + 255) / 256), 256, 0, stream>>>(
      mem, query, Wk, Wv, Wq, membf, querybf, wkbf, wvbf, wqbf);

  proj256_bf16<<<dim3(M_ROWS / 256, D_DIM / 128), 512, 0, stream>>>(membf, wkbf, bk, Kbf);
  proj256_bf16<<<dim3(B_ROWS / 256, D_DIM / 128), 512, 0, stream>>>(querybf, wqbf, bq, qbf);

  sims_topc_gemm<<<dim3((B_ROWS / 256) * NCB), 512, 0, stream>>>(qbf, Kbf, part_v, part_i);
  merge_rescore<<<dim3(B_ROWS), 256, 0, stream>>>(part_v, part_i, u64, qbk, mem, topi);

  // V path (bf16 out, overlays dead Kbf/parts region).
  proj256_bf16<<<dim3(M_ROWS / 256, D_DIM / 128), 512, 0, stream>>>(membf, wvbf, bv, Vbf);
  gather_ln<<<dim3(B_ROWS * TOPK), 256, 0, stream>>>(Vbf, topi, gamma, beta, out);
}